// Round 1
// baseline (1622.793 us; speedup 1.0000x reference)
//
#include <hip/hip_runtime.h>
#include <stdint.h>

#define N_TRIP 200000
#define N_ENT  200000
#define N_REL  500
#define D      128
#define MARGINF 6.0f
#define BN_EPSF 1e-5f
#define PHASE_C 50.26548245743669f   // PI / REL_RANGE, REL_RANGE = 8/128
#define NC 32                        // rel-partial contention-spreading copies

typedef unsigned short u16;
typedef unsigned int   u32;

__device__ inline float bfl(u32 u){ return __uint_as_float(u<<16); }
__device__ inline float bfh(u32 u){ return __uint_as_float(u&0xffff0000u); }
__device__ inline u16 f2bf(float f){
  u32 u = __float_as_uint(f);
  u32 r = (u + 0x7fffu + ((u>>16)&1u))>>16;
  return (u16)r;
}

// ---------------- K1: histogram of head / tail / rel indices ----------------
__global__ __launch_bounds__(256) void k_hist(const int* __restrict__ trip,
    int* __restrict__ cnt0, int* __restrict__ cnt1, int* __restrict__ cntr){
  int i = blockIdx.x*256 + threadIdx.x;
  if(i < N_TRIP){
    atomicAdd(&cnt0[trip[3*i]],   1);
    atomicAdd(&cnt1[trip[3*i+1]], 1);
    atomicAdd(&cntr[trip[3*i+2]], 1);
  }
}

// ------- K2: per-entity norm scale + weighted column stats (S0,S1,Q0,Q1) ----
__global__ __launch_bounds__(256) void k_entstats(const float* __restrict__ ent,
    const int* __restrict__ cnt0, const int* __restrict__ cnt1,
    float* __restrict__ scale, float* __restrict__ stats){
  __shared__ float acc[512];
  int t = threadIdx.x;
  acc[t] = 0.f; acc[t+256] = 0.f;
  __syncthreads();
  int lane = t & 63;
  int gw = blockIdx.x*4 + (t>>6);
  int nw = gridDim.x*4;
  float p0=0,p1=0,p2=0,p3=0,p4=0,p5=0,p6=0,p7=0;
  for(int e=gw; e<N_ENT; e+=nw){
    float2 x = *(const float2*)(ent + (size_t)e*D + 2*lane);
    float ss = x.x*x.x + x.y*x.y;
    #pragma unroll
    for(int o=32;o>0;o>>=1) ss += __shfl_xor(ss,o,64);
    float nrm = sqrtf(ss);
    float sc = nrm > 1.0f ? 1.0f/nrm : 1.0f;
    if(lane==0) scale[e] = sc;
    float w0 = (float)cnt0[e];
    float w1 = (float)cnt1[e];
    float sx = x.x*sc, sy = x.y*sc;
    p0 += w0*sx;    p1 += w0*sy;
    p2 += w1*sx;    p3 += w1*sy;
    p4 += w0*sx*sx; p5 += w0*sy*sy;
    p6 += w1*sx*sx; p7 += w1*sy*sy;
  }
  atomicAdd(&acc[      2*lane  ], p0);
  atomicAdd(&acc[      2*lane+1], p1);
  atomicAdd(&acc[128 + 2*lane  ], p2);
  atomicAdd(&acc[128 + 2*lane+1], p3);
  atomicAdd(&acc[256 + 2*lane  ], p4);
  atomicAdd(&acc[256 + 2*lane+1], p5);
  atomicAdd(&acc[384 + 2*lane  ], p6);
  atomicAdd(&acc[384 + 2*lane+1], p7);
  __syncthreads();
  atomicAdd(&stats[t],     acc[t]);
  atomicAdd(&stats[t+256], acc[t+256]);
}

// ------- K3: per-rel scale + Qr stats + cos/sin phase tables ---------------
__global__ __launch_bounds__(256) void k_relstats(const float* __restrict__ rel,
    const int* __restrict__ cntr, float* __restrict__ scale_rel,
    float* __restrict__ stats, float* __restrict__ cosr, float* __restrict__ sinr){
  int t = threadIdx.x, lane = t & 63;
  int r = blockIdx.x*4 + (t>>6);
  if(r >= N_REL) return;
  float2 x = *(const float2*)(rel + (size_t)r*D + 2*lane);
  float ss = x.x*x.x + x.y*x.y;
  #pragma unroll
  for(int o=32;o>0;o>>=1) ss += __shfl_xor(ss,o,64);
  float nrm = sqrtf(ss);
  float sc = nrm > 1.0f ? 1.0f/nrm : 1.0f;
  if(lane==0) scale_rel[r] = sc;
  float w = (float)cntr[r];
  float sx = x.x*sc, sy = x.y*sc;
  atomicAdd(&stats[512 + 2*lane  ], w*sx*sx);
  atomicAdd(&stats[512 + 2*lane+1], w*sy*sy);
  if(lane < 32){   // raw (unnormalized) coords 0..63 feed the phases
    cosr[r*64 + 2*lane  ] = cosf(x.x*PHASE_C);
    sinr[r*64 + 2*lane  ] = sinf(x.x*PHASE_C);
    cosr[r*64 + 2*lane+1] = cosf(x.y*PHASE_C);
    sinr[r*64 + 2*lane+1] = sinf(x.y*PHASE_C);
  }
}

// ------- K4: finalize BN0, build folded weights WtT/W2 and b' ---------------
__global__ __launch_bounds__(384) void k_bn0fin(const float* __restrict__ stats,
    const float* __restrict__ W_a, const float* __restrict__ b_a,
    const float* __restrict__ gamma0, const float* __restrict__ beta0,
    float* __restrict__ WtT, float* __restrict__ W2, float* __restrict__ bprime){
  __shared__ float a0[384], c0[384];
  int t = threadIdx.x;
  {
    int j = t & 127;
    float mu, ex2;
    if(t < 256){
      mu  = (stats[j]     + stats[128+j]) * (1.0f/(2.0f*N_TRIP));
      ex2 = (stats[256+j] + stats[384+j]) * (1.0f/(2.0f*N_TRIP));
    } else {
      mu  = 0.0f;
      ex2 = stats[512+j] * (1.0f/N_TRIP);
    }
    float var = ex2 - mu*mu;
    float a = gamma0[t]*rsqrtf(var + BN_EPSF);
    a0[t] = a;
    c0[t] = beta0[t] - mu*a;
  }
  __syncthreads();
  // WtT[j][k]: j<128 -> A proj (W cols 0..127), j>=128 -> B proj (W cols 128..255)
  for(int idx=t; idx<256*128; idx+=384){
    int j = idx>>7, k = idx&127;
    int ko = ((j>>7)<<7) + k;
    WtT[idx] = W_a[(j&127)*384 + ko]*a0[ko];
  }
  // W2[k][j] = W_a[j][256+k]*a0[256+k]   (rel slot, coalesced for k_relproj)
  for(int idx=t; idx<128*128; idx+=384){
    int k = idx>>7, j = idx&127;
    W2[idx] = W_a[j*384 + 256 + k]*a0[256+k];
  }
  if(t < 128){
    float s = b_a[t];
    for(int k=0;k<384;k++) s += W_a[t*384+k]*c0[k];
    bprime[t] = s;
  }
}

// ------- K5: R[r] = rel_n[r] @ W2 ------------------------------------------
__global__ __launch_bounds__(128) void k_relproj(const float* __restrict__ rel,
    const float* __restrict__ scale_rel, const float* __restrict__ W2,
    float* __restrict__ R){
  int r = blockIdx.x, j = threadIdx.x;
  __shared__ float x[128];
  x[j] = rel[(size_t)r*D + j]*scale_rel[r];
  __syncthreads();
  float s = 0.f;
  for(int k=0;k<128;k++) s += x[k]*W2[k*128+j];
  R[r*128+j] = s;
}

// ------- K6: A/B projection GEMM (200000x128 @ 128x256 -> bf16) -------------
__global__ __launch_bounds__(256) void k_ab(const float* __restrict__ ent,
    const float* __restrict__ scale, const float* __restrict__ WtT,
    u16* __restrict__ Abuf, u16* __restrict__ Bbuf){
  __shared__ float xs[32][128];
  int e0 = blockIdx.x*32;
  int t = threadIdx.x;
  for(int idx=t; idx<32*128; idx+=256){
    int e = idx>>7, k = idx&127;
    xs[e][k] = ent[(size_t)(e0+e)*D + k]*scale[e0+e];
  }
  __syncthreads();
  int tx = t & 63;
  int ty = t >> 6;
  float acc0[8], acc1[8], acc2[8], acc3[8];
  #pragma unroll
  for(int e=0;e<8;e++){ acc0[e]=0.f; acc1[e]=0.f; acc2[e]=0.f; acc3[e]=0.f; }
  for(int k=0;k<128;k+=4){
    float4 w0 = *(const float4*)&WtT[(tx     )*128 + k];
    float4 w1 = *(const float4*)&WtT[(tx+ 64)*128 + k];
    float4 w2 = *(const float4*)&WtT[(tx+128)*128 + k];
    float4 w3 = *(const float4*)&WtT[(tx+192)*128 + k];
    #pragma unroll
    for(int e=0;e<8;e++){
      float4 x = *(const float4*)&xs[ty*8+e][k];
      acc0[e] += x.x*w0.x + x.y*w0.y + x.z*w0.z + x.w*w0.w;
      acc1[e] += x.x*w1.x + x.y*w1.y + x.z*w1.z + x.w*w1.w;
      acc2[e] += x.x*w2.x + x.y*w2.y + x.z*w2.z + x.w*w2.w;
      acc3[e] += x.x*w3.x + x.y*w3.y + x.z*w3.z + x.w*w3.w;
    }
  }
  #pragma unroll
  for(int e=0;e<8;e++){
    size_t row = (size_t)(e0 + ty*8 + e)*D;
    Abuf[row + tx]      = f2bf(acc0[e]);
    Abuf[row + tx + 64] = f2bf(acc1[e]);
    Bbuf[row + tx]      = f2bf(acc2[e]);
    Bbuf[row + tx + 64] = f2bf(acc3[e]);
  }
}

// ------- K7: BN1 statistics over the 2n virtual rows ------------------------
__global__ __launch_bounds__(256) void k_bn1stats(const int* __restrict__ trip,
    const u16* __restrict__ A, const u16* __restrict__ B,
    const float* __restrict__ R, const float* __restrict__ bprime,
    float* __restrict__ sums){
  __shared__ float acc[256];
  int t = threadIdx.x;
  acc[t] = 0.f;
  __syncthreads();
  int lane = t & 63;
  int gw = blockIdx.x*4 + (t>>6), nw = gridDim.x*4;
  float bp0 = bprime[2*lane], bp1 = bprime[2*lane+1];
  float s0=0,s1=0,q0=0,q1=0;
  for(int i=gw; i<N_TRIP; i+=nw){
    int t0 = trip[3*i], t1 = trip[3*i+1], t2 = trip[3*i+2];
    u32 ua0 = *(const u32*)(A + (size_t)t0*D + 2*lane);
    u32 ua1 = *(const u32*)(A + (size_t)t1*D + 2*lane);
    u32 ub0 = *(const u32*)(B + (size_t)t0*D + 2*lane);
    u32 ub1 = *(const u32*)(B + (size_t)t1*D + 2*lane);
    float2 r = *(const float2*)(R + (size_t)t2*D + 2*lane);
    float y1x = bfl(ua0)+bfl(ub1)+r.x+bp0;
    float y1y = bfh(ua0)+bfh(ub1)+r.y+bp1;
    float y2x = bfl(ua1)+bfl(ub0)-r.x+bp0;
    float y2y = bfh(ua1)+bfh(ub0)-r.y+bp1;
    s0 += y1x+y2x; s1 += y1y+y2y;
    q0 += y1x*y1x + y2x*y2x; q1 += y1y*y1y + y2y*y2y;
  }
  atomicAdd(&acc[      2*lane  ], s0);
  atomicAdd(&acc[      2*lane+1], s1);
  atomicAdd(&acc[128 + 2*lane  ], q0);
  atomicAdd(&acc[128 + 2*lane+1], q1);
  __syncthreads();
  atomicAdd(&sums[t], acc[t]);
}

// ------- K8: finalize BN1 ---------------------------------------------------
__global__ __launch_bounds__(128) void k_bn1fin(const float* __restrict__ sums,
    const float* __restrict__ gamma1, const float* __restrict__ beta1,
    float* __restrict__ a1c){
  int j = threadIdx.x;
  float mu  = sums[j]    *(1.0f/(2.0f*N_TRIP));
  float var = sums[128+j]*(1.0f/(2.0f*N_TRIP)) - mu*mu;
  float a = gamma1[j]*rsqrtf(var + BN_EPSF);
  a1c[j]     = a;
  a1c[128+j] = beta1[j] - mu*a;
}

// ------- K9: main per-triplet pass (c, s, e_b, scatter-adds) ----------------
__global__ __launch_bounds__(256) void k_main(const int* __restrict__ trip,
    const u16* __restrict__ A, const u16* __restrict__ B,
    const float* __restrict__ R, const float* __restrict__ bprime,
    const float* __restrict__ a1c, const float* __restrict__ W_a2,
    const float* __restrict__ b_a2,
    float* __restrict__ hs, float* __restrict__ ebs, float* __restrict__ relpart){
  int t = threadIdx.x, lane = t & 63;
  int gw = blockIdx.x*4 + (t>>6), nw = gridDim.x*4;
  float bp0 = bprime[2*lane], bp1 = bprime[2*lane+1];
  float a1x = a1c[2*lane],     a1y = a1c[2*lane+1];
  float ccx = a1c[128+2*lane], ccy = a1c[128+2*lane+1];
  float wvx = W_a2[2*lane],    wvy = W_a2[2*lane+1];
  float ba2 = b_a2[0];
  float* rp = relpart + (size_t)(blockIdx.x & (NC-1))*N_REL*D;
  for(int i=gw; i<N_TRIP; i+=nw){
    int t0 = trip[3*i], t1 = trip[3*i+1], t2 = trip[3*i+2];
    u32 ua0 = *(const u32*)(A + (size_t)t0*D + 2*lane);
    u32 ua1 = *(const u32*)(A + (size_t)t1*D + 2*lane);
    u32 ub0 = *(const u32*)(B + (size_t)t0*D + 2*lane);
    u32 ub1 = *(const u32*)(B + (size_t)t1*D + 2*lane);
    float2 r = *(const float2*)(R + (size_t)t2*D + 2*lane);
    float y1x = bfl(ua0)+bfl(ub1)+r.x+bp0;
    float y1y = bfh(ua0)+bfh(ub1)+r.y+bp1;
    float y2x = bfl(ua1)+bfl(ub0)-r.x+bp0;
    float y2y = bfh(ua1)+bfh(ub0)-r.y+bp1;
    float c1x = y1x*a1x+ccx, c1y = y1y*a1y+ccy;
    float c2x = y2x*a1x+ccx, c2y = y2y*a1y+ccy;
    float r1 = c1x*wvx + c1y*wvy;
    float r2 = c2x*wvx + c2y*wvy;
    #pragma unroll
    for(int o=32;o>0;o>>=1){ r1 += __shfl_xor(r1,o,64); r2 += __shfl_xor(r2,o,64); }
    float s1 = r1 + ba2, s2 = r2 + ba2;
    float e1 = expf(s1 >= 0.f ? -s1 : -0.01f*s1);
    float e2 = expf(s2 >= 0.f ? -s2 : -0.01f*s2);
    float h1x = e1*c1x, h1y = e1*c1y;
    float h2x = e2*c2x, h2y = e2*c2y;
    atomicAdd(&hs[(size_t)t0*D + 2*lane  ], h1x);
    atomicAdd(&hs[(size_t)t0*D + 2*lane+1], h1y);
    atomicAdd(&hs[(size_t)t1*D + 2*lane  ], h2x);
    atomicAdd(&hs[(size_t)t1*D + 2*lane+1], h2y);
    atomicAdd(&rp[t2*D + 2*lane  ], h1x-h2x);
    atomicAdd(&rp[t2*D + 2*lane+1], h1y-h2y);
    if(lane==0){
      atomicAdd(&ebs[t0], e1);
      atomicAdd(&ebs[t1], e2);
    }
  }
}

// ------- K10: h_ent = hs / ebs (in place in d_out) --------------------------
__global__ __launch_bounds__(256) void k_hentfin(float* __restrict__ out,
    const float* __restrict__ ebs){
  size_t i = (size_t)blockIdx.x*256 + threadIdx.x;
  if(i >= (size_t)N_ENT*D/4) return;
  int e = (int)(i >> 5);
  float d = ebs[e];
  float inv = (d != 0.f) ? 1.0f/d : 0.0f;
  float4 v = ((float4*)out)[i];
  v.x *= inv; v.y *= inv; v.z *= inv; v.w *= inv;
  ((float4*)out)[i] = v;
}

// ------- K11: h_rel = (sum of NC partials) / cnt ----------------------------
__global__ __launch_bounds__(256) void k_hrelfin(const float* __restrict__ relpart,
    const int* __restrict__ cntr, float* __restrict__ out_hrel){
  int idx = blockIdx.x*256 + threadIdx.x;
  if(idx >= N_REL*D) return;
  int r = idx >> 7;
  float s = 0.f;
  for(int c=0;c<NC;c++) s += relpart[(size_t)c*N_REL*D + idx];
  int cn = cntr[r];
  float cf = cn > 0 ? (float)cn : 1.0f;
  out_hrel[idx] = s/cf;
}

// ------- K12: RotatE score --------------------------------------------------
__global__ __launch_bounds__(256) void k_score(const int* __restrict__ trip,
    const float* __restrict__ ent, const float* __restrict__ cosr,
    const float* __restrict__ sinr, float* __restrict__ score){
  int t = threadIdx.x, lane = t & 63;
  int gw = blockIdx.x*4 + (t>>6), nw = gridDim.x*4;
  for(int i=gw; i<N_TRIP; i+=nw){
    int t0 = trip[3*i], t1 = trip[3*i+1], t2 = trip[3*i+2];
    float re_h = ent[(size_t)t0*D + lane];
    float im_h = ent[(size_t)t0*D + 64 + lane];
    float re_t = ent[(size_t)t1*D + lane];
    float im_t = ent[(size_t)t1*D + 64 + lane];
    float cr = cosr[t2*64 + lane], sr = sinr[t2*64 + lane];
    float re_s = cr*re_t + sr*im_t - re_h;
    float im_s = cr*im_t - sr*re_t - im_h;
    float d = sqrtf(re_s*re_s + im_s*im_s);
    #pragma unroll
    for(int o=32;o>0;o>>=1) d += __shfl_xor(d,o,64);
    if(lane==0) score[i] = MARGINF - d;
  }
}

extern "C" void kernel_launch(void* const* d_in, const int* in_sizes, int n_in,
                              void* d_out, int out_size, void* d_ws, size_t ws_size,
                              hipStream_t stream){
  const int*   trip   = (const int*)  d_in[0];
  const float* ent    = (const float*)d_in[1];
  const float* rel    = (const float*)d_in[2];
  const float* W_a    = (const float*)d_in[3];
  const float* b_a    = (const float*)d_in[4];
  const float* W_a2   = (const float*)d_in[5];
  const float* b_a2   = (const float*)d_in[6];
  const float* gamma0 = (const float*)d_in[7];
  const float* beta0  = (const float*)d_in[8];
  const float* gamma1 = (const float*)d_in[9];
  const float* beta1  = (const float*)d_in[10];

  char* ws = (char*)d_ws;
  size_t off = 0;
  auto take = [&](size_t bytes)->void*{
    void* p = ws + off;
    off += (bytes + 255) & ~(size_t)255;
    return p;
  };
  // ---- zeroed scratch (contiguous from 0) ----
  int*   cnt0    = (int*)  take((size_t)N_ENT*4);
  int*   cnt1    = (int*)  take((size_t)N_ENT*4);
  int*   cntr    = (int*)  take((size_t)N_REL*4);
  float* stats   = (float*)take(640*4);
  float* sums    = (float*)take(256*4);
  float* ebs     = (float*)take((size_t)N_ENT*4);
  float* relpart = (float*)take((size_t)NC*N_REL*D*4);
  size_t zero_bytes = off;
  // ---- fully-overwritten scratch ----
  float* scale     = (float*)take((size_t)N_ENT*4);
  float* scale_rel = (float*)take((size_t)N_REL*4);
  float* WtT       = (float*)take(256*128*4);
  float* W2        = (float*)take(128*128*4);
  float* bprime    = (float*)take(128*4);
  float* a1c       = (float*)take(256*4);
  float* R         = (float*)take((size_t)N_REL*D*4);
  float* cosr      = (float*)take((size_t)N_REL*64*4);
  float* sinr      = (float*)take((size_t)N_REL*64*4);
  u16*   Abuf      = (u16*)  take((size_t)N_ENT*D*2);
  u16*   Bbuf      = (u16*)  take((size_t)N_ENT*D*2);
  (void)ws_size; (void)n_in; (void)in_sizes; (void)out_size;

  float* out_hent  = (float*)d_out;
  float* out_hrel  = out_hent + (size_t)N_ENT*D;
  float* out_score = out_hrel + (size_t)N_REL*D;

  hipMemsetAsync(d_ws, 0, zero_bytes, stream);
  hipMemsetAsync(d_out, 0, (size_t)N_ENT*D*4, stream);

  k_hist    <<<(N_TRIP+255)/256, 256, 0, stream>>>(trip, cnt0, cnt1, cntr);
  k_entstats<<<256, 256, 0, stream>>>(ent, cnt0, cnt1, scale, stats);
  k_relstats<<<(N_REL+3)/4, 256, 0, stream>>>(rel, cntr, scale_rel, stats, cosr, sinr);
  k_bn0fin  <<<1, 384, 0, stream>>>(stats, W_a, b_a, gamma0, beta0, WtT, W2, bprime);
  k_relproj <<<N_REL, 128, 0, stream>>>(rel, scale_rel, W2, R);
  k_ab      <<<N_ENT/32, 256, 0, stream>>>(ent, scale, WtT, Abuf, Bbuf);
  k_bn1stats<<<1024, 256, 0, stream>>>(trip, Abuf, Bbuf, R, bprime, sums);
  k_bn1fin  <<<1, 128, 0, stream>>>(sums, gamma1, beta1, a1c);
  k_main    <<<2048, 256, 0, stream>>>(trip, Abuf, Bbuf, R, bprime, a1c, W_a2, b_a2,
                                       out_hent, ebs, relpart);
  k_hentfin <<<(N_ENT*D/4+255)/256, 256, 0, stream>>>(out_hent, ebs);
  k_hrelfin <<<(N_REL*D+255)/256, 256, 0, stream>>>(relpart, cntr, out_hrel);
  k_score   <<<1024, 256, 0, stream>>>(trip, ent, cosr, sinr, out_score);
}

// Round 2
// 1121.450 us; speedup vs baseline: 1.4470x; 1.4470x over previous
//
#include <hip/hip_runtime.h>
#include <stdint.h>

#define N_TRIP 200000
#define N_ENT  200000
#define N_REL  500
#define D      128
#define MARGINF 6.0f
#define BN_EPSF 1e-5f
#define PHASE_C 50.26548245743669f   // PI / REL_RANGE, REL_RANGE = 8/128
#define NC 32                        // rel-partial contention-spreading copies

typedef unsigned short u16;
typedef unsigned int   u32;
typedef __attribute__((ext_vector_type(8))) short short8;
typedef __attribute__((ext_vector_type(4))) float f32x4;
typedef __attribute__((ext_vector_type(4))) unsigned short u16x4;

__device__ inline float bfl(u32 u){ return __uint_as_float(u<<16); }
__device__ inline float bfh(u32 u){ return __uint_as_float(u&0xffff0000u); }
__device__ inline u16 f2bf(float f){
  u32 u = __float_as_uint(f);
  u32 r = (u + 0x7fffu + ((u>>16)&1u))>>16;
  return (u16)r;
}

// ---------------- K1: histogram of head / tail / rel indices ----------------
__global__ __launch_bounds__(256) void k_hist(const int* __restrict__ trip,
    int* __restrict__ cnt0, int* __restrict__ cnt1, int* __restrict__ cntr){
  int i = blockIdx.x*256 + threadIdx.x;
  if(i < N_TRIP){
    atomicAdd(&cnt0[trip[3*i]],   1);
    atomicAdd(&cnt1[trip[3*i+1]], 1);
    atomicAdd(&cntr[trip[3*i+2]], 1);
  }
}

// ------- K2: per-entity norm scale + weighted column stats (S0,S1,Q0,Q1) ----
__global__ __launch_bounds__(256) void k_entstats(const float* __restrict__ ent,
    const int* __restrict__ cnt0, const int* __restrict__ cnt1,
    float* __restrict__ scale, float* __restrict__ stats){
  __shared__ float acc[512];
  int t = threadIdx.x;
  acc[t] = 0.f; acc[t+256] = 0.f;
  __syncthreads();
  int lane = t & 63;
  int gw = blockIdx.x*4 + (t>>6);
  int nw = gridDim.x*4;
  float p0=0,p1=0,p2=0,p3=0,p4=0,p5=0,p6=0,p7=0;
  for(int e=gw; e<N_ENT; e+=nw){
    float2 x = *(const float2*)(ent + (size_t)e*D + 2*lane);
    float ss = x.x*x.x + x.y*x.y;
    #pragma unroll
    for(int o=32;o>0;o>>=1) ss += __shfl_xor(ss,o,64);
    float nrm = sqrtf(ss);
    float sc = nrm > 1.0f ? 1.0f/nrm : 1.0f;
    if(lane==0) scale[e] = sc;
    float w0 = (float)cnt0[e];
    float w1 = (float)cnt1[e];
    float sx = x.x*sc, sy = x.y*sc;
    p0 += w0*sx;    p1 += w0*sy;
    p2 += w1*sx;    p3 += w1*sy;
    p4 += w0*sx*sx; p5 += w0*sy*sy;
    p6 += w1*sx*sx; p7 += w1*sy*sy;
  }
  atomicAdd(&acc[      2*lane  ], p0);
  atomicAdd(&acc[      2*lane+1], p1);
  atomicAdd(&acc[128 + 2*lane  ], p2);
  atomicAdd(&acc[128 + 2*lane+1], p3);
  atomicAdd(&acc[256 + 2*lane  ], p4);
  atomicAdd(&acc[256 + 2*lane+1], p5);
  atomicAdd(&acc[384 + 2*lane  ], p6);
  atomicAdd(&acc[384 + 2*lane+1], p7);
  __syncthreads();
  atomicAdd(&stats[t],     acc[t]);
  atomicAdd(&stats[t+256], acc[t+256]);
}

// ------- K3: per-rel scale + Qr stats + cos/sin phase tables ---------------
__global__ __launch_bounds__(256) void k_relstats(const float* __restrict__ rel,
    const int* __restrict__ cntr, float* __restrict__ scale_rel,
    float* __restrict__ stats, float* __restrict__ cosr, float* __restrict__ sinr){
  int t = threadIdx.x, lane = t & 63;
  int r = blockIdx.x*4 + (t>>6);
  if(r >= N_REL) return;
  float2 x = *(const float2*)(rel + (size_t)r*D + 2*lane);
  float ss = x.x*x.x + x.y*x.y;
  #pragma unroll
  for(int o=32;o>0;o>>=1) ss += __shfl_xor(ss,o,64);
  float nrm = sqrtf(ss);
  float sc = nrm > 1.0f ? 1.0f/nrm : 1.0f;
  if(lane==0) scale_rel[r] = sc;
  float w = (float)cntr[r];
  float sx = x.x*sc, sy = x.y*sc;
  atomicAdd(&stats[512 + 2*lane  ], w*sx*sx);
  atomicAdd(&stats[512 + 2*lane+1], w*sy*sy);
  if(lane < 32){   // raw (unnormalized) coords 0..63 feed the phases
    cosr[r*64 + 2*lane  ] = cosf(x.x*PHASE_C);
    sinr[r*64 + 2*lane  ] = sinf(x.x*PHASE_C);
    cosr[r*64 + 2*lane+1] = cosf(x.y*PHASE_C);
    sinr[r*64 + 2*lane+1] = sinf(x.y*PHASE_C);
  }
}

// ------- K4: finalize BN0, build folded bf16 weights Wbf, W2 and b' ---------
__global__ __launch_bounds__(384) void k_bn0fin(const float* __restrict__ stats,
    const float* __restrict__ W_a, const float* __restrict__ b_a,
    const float* __restrict__ gamma0, const float* __restrict__ beta0,
    u16* __restrict__ Wbf, float* __restrict__ W2, float* __restrict__ bprime){
  __shared__ float a0[384], c0[384];
  int t = threadIdx.x;
  {
    int j = t & 127;
    float mu, ex2;
    if(t < 256){
      mu  = (stats[j]     + stats[128+j]) * (1.0f/(2.0f*N_TRIP));
      ex2 = (stats[256+j] + stats[384+j]) * (1.0f/(2.0f*N_TRIP));
    } else {
      mu  = 0.0f;
      ex2 = stats[512+j] * (1.0f/N_TRIP);
    }
    float var = ex2 - mu*mu;
    float a = gamma0[t]*rsqrtf(var + BN_EPSF);
    a0[t] = a;
    c0[t] = beta0[t] - mu*a;
  }
  __syncthreads();
  // Wbf[j][k] (bf16): j<128 -> A proj (W cols 0..127), j>=128 -> B proj (cols 128..255)
  for(int idx=t; idx<256*128; idx+=384){
    int j = idx>>7, k = idx&127;
    int ko = ((j>>7)<<7) + k;
    Wbf[idx] = f2bf(W_a[(j&127)*384 + ko]*a0[ko]);
  }
  // W2[k][j] = W_a[j][256+k]*a0[256+k]   (rel slot, coalesced for k_relproj)
  for(int idx=t; idx<128*128; idx+=384){
    int k = idx>>7, j = idx&127;
    W2[idx] = W_a[j*384 + 256 + k]*a0[256+k];
  }
  if(t < 128){
    float s = b_a[t];
    for(int k=0;k<384;k++) s += W_a[t*384+k]*c0[k];
    bprime[t] = s;
  }
}

// ------- K5: R[r] = rel_n[r] @ W2 ------------------------------------------
__global__ __launch_bounds__(128) void k_relproj(const float* __restrict__ rel,
    const float* __restrict__ scale_rel, const float* __restrict__ W2,
    float* __restrict__ R){
  int r = blockIdx.x, j = threadIdx.x;
  __shared__ float x[128];
  x[j] = rel[(size_t)r*D + j]*scale_rel[r];
  __syncthreads();
  float s = 0.f;
  for(int k=0;k<128;k++) s += x[k]*W2[k*128+j];
  R[r*128+j] = s;
}

// ------- K6: A/B projection via MFMA (200000x128 @ 128x256 -> bf16) ---------
// Per wave: 16 entities x 256 outputs. Operands swapped (A=W', B=X^T) so the
// C/D mapping col=lane&15,row=(lane>>4)*4+reg gives 4 consecutive out-cols
// per lane -> one 8B store per 16x16 tile.
__global__ __launch_bounds__(256) void k_ab(const float* __restrict__ ent,
    const float* __restrict__ scale, const u16* __restrict__ Wbf,
    u16* __restrict__ Abuf, u16* __restrict__ Bbuf){
  int t = threadIdx.x;
  int lane = t & 63;
  int wm = t >> 6;
  int e0 = blockIdx.x*64 + wm*16;
  int erow = e0 + (lane & 15);
  int kgrp = (lane >> 4) << 3;     // 0,8,16,24
  float sc = scale[erow];
  const float* xp = ent + (size_t)erow*D + kgrp;
  short8 xf[4];
  #pragma unroll
  for(int kt=0;kt<4;kt++){
    float4 x0 = *(const float4*)(xp + kt*32);
    float4 x1 = *(const float4*)(xp + kt*32 + 4);
    short8 v;
    v[0]=(short)f2bf(x0.x*sc); v[1]=(short)f2bf(x0.y*sc);
    v[2]=(short)f2bf(x0.z*sc); v[3]=(short)f2bf(x0.w*sc);
    v[4]=(short)f2bf(x1.x*sc); v[5]=(short)f2bf(x1.y*sc);
    v[6]=(short)f2bf(x1.z*sc); v[7]=(short)f2bf(x1.w*sc);
    xf[kt]=v;
  }
  const u16* wp0 = Wbf + (size_t)(lane&15)*D + kgrp;
  int rgrp = (lane>>4)<<2;         // output-col group within a 16-tile
  #pragma unroll
  for(int jt=0;jt<16;jt++){
    const u16* wp = wp0 + (size_t)jt*16*D;
    f32x4 acc = {0.f,0.f,0.f,0.f};
    #pragma unroll
    for(int kt=0;kt<4;kt++){
      short8 wf = *(const short8*)(wp + kt*32);
      acc = __builtin_amdgcn_mfma_f32_16x16x32_bf16(wf, xf[kt], acc, 0,0,0);
    }
    int jbase = jt*16 + rgrp;      // 4 consecutive output cols jbase..jbase+3
    u16x4 pk;
    pk.x=f2bf(acc[0]); pk.y=f2bf(acc[1]); pk.z=f2bf(acc[2]); pk.w=f2bf(acc[3]);
    u16* dst = (jbase < 128) ? (Abuf + (size_t)erow*D + jbase)
                             : (Bbuf + (size_t)erow*D + (jbase-128));
    *(u16x4*)dst = pk;
  }
}

// ------- K7: BN1 statistics over the 2n virtual rows ------------------------
__global__ __launch_bounds__(256) void k_bn1stats(const int* __restrict__ trip,
    const u16* __restrict__ A, const u16* __restrict__ B,
    const float* __restrict__ R, const float* __restrict__ bprime,
    float* __restrict__ sums){
  __shared__ float acc[256];
  int t = threadIdx.x;
  acc[t] = 0.f;
  __syncthreads();
  int lane = t & 63;
  int gw = blockIdx.x*4 + (t>>6), nw = gridDim.x*4;
  float bp0 = bprime[2*lane], bp1 = bprime[2*lane+1];
  float s0=0,s1=0,q0=0,q1=0;
  for(int i=gw; i<N_TRIP; i+=nw){
    int t0 = trip[3*i], t1 = trip[3*i+1], t2 = trip[3*i+2];
    u32 ua0 = *(const u32*)(A + (size_t)t0*D + 2*lane);
    u32 ua1 = *(const u32*)(A + (size_t)t1*D + 2*lane);
    u32 ub0 = *(const u32*)(B + (size_t)t0*D + 2*lane);
    u32 ub1 = *(const u32*)(B + (size_t)t1*D + 2*lane);
    float2 r = *(const float2*)(R + (size_t)t2*D + 2*lane);
    float y1x = bfl(ua0)+bfl(ub1)+r.x+bp0;
    float y1y = bfh(ua0)+bfh(ub1)+r.y+bp1;
    float y2x = bfl(ua1)+bfl(ub0)-r.x+bp0;
    float y2y = bfh(ua1)+bfh(ub0)-r.y+bp1;
    s0 += y1x+y2x; s1 += y1y+y2y;
    q0 += y1x*y1x + y2x*y2x; q1 += y1y*y1y + y2y*y2y;
  }
  atomicAdd(&acc[      2*lane  ], s0);
  atomicAdd(&acc[      2*lane+1], s1);
  atomicAdd(&acc[128 + 2*lane  ], q0);
  atomicAdd(&acc[128 + 2*lane+1], q1);
  __syncthreads();
  atomicAdd(&sums[t], acc[t]);
}

// ------- K8: finalize BN1 ---------------------------------------------------
__global__ __launch_bounds__(128) void k_bn1fin(const float* __restrict__ sums,
    const float* __restrict__ gamma1, const float* __restrict__ beta1,
    float* __restrict__ a1c){
  int j = threadIdx.x;
  float mu  = sums[j]    *(1.0f/(2.0f*N_TRIP));
  float var = sums[128+j]*(1.0f/(2.0f*N_TRIP)) - mu*mu;
  float a = gamma1[j]*rsqrtf(var + BN_EPSF);
  a1c[j]     = a;
  a1c[128+j] = beta1[j] - mu*a;
}

// ------- K9: main per-triplet pass (c, s, e_b, scatter-adds) ----------------
__global__ __launch_bounds__(256) void k_main(const int* __restrict__ trip,
    const u16* __restrict__ A, const u16* __restrict__ B,
    const float* __restrict__ R, const float* __restrict__ bprime,
    const float* __restrict__ a1c, const float* __restrict__ W_a2,
    const float* __restrict__ b_a2,
    float* __restrict__ hs, float* __restrict__ ebs, float* __restrict__ relpart){
  int t = threadIdx.x, lane = t & 63;
  int gw = blockIdx.x*4 + (t>>6), nw = gridDim.x*4;
  float bp0 = bprime[2*lane], bp1 = bprime[2*lane+1];
  float a1x = a1c[2*lane],     a1y = a1c[2*lane+1];
  float ccx = a1c[128+2*lane], ccy = a1c[128+2*lane+1];
  float wvx = W_a2[2*lane],    wvy = W_a2[2*lane+1];
  float ba2 = b_a2[0];
  float* rp = relpart + (size_t)(blockIdx.x & (NC-1))*N_REL*D;
  for(int i=gw; i<N_TRIP; i+=nw){
    int t0 = trip[3*i], t1 = trip[3*i+1], t2 = trip[3*i+2];
    u32 ua0 = *(const u32*)(A + (size_t)t0*D + 2*lane);
    u32 ua1 = *(const u32*)(A + (size_t)t1*D + 2*lane);
    u32 ub0 = *(const u32*)(B + (size_t)t0*D + 2*lane);
    u32 ub1 = *(const u32*)(B + (size_t)t1*D + 2*lane);
    float2 r = *(const float2*)(R + (size_t)t2*D + 2*lane);
    float y1x = bfl(ua0)+bfl(ub1)+r.x+bp0;
    float y1y = bfh(ua0)+bfh(ub1)+r.y+bp1;
    float y2x = bfl(ua1)+bfl(ub0)-r.x+bp0;
    float y2y = bfh(ua1)+bfh(ub0)-r.y+bp1;
    float c1x = y1x*a1x+ccx, c1y = y1y*a1y+ccy;
    float c2x = y2x*a1x+ccx, c2y = y2y*a1y+ccy;
    float r1 = c1x*wvx + c1y*wvy;
    float r2 = c2x*wvx + c2y*wvy;
    #pragma unroll
    for(int o=32;o>0;o>>=1){ r1 += __shfl_xor(r1,o,64); r2 += __shfl_xor(r2,o,64); }
    float s1 = r1 + ba2, s2 = r2 + ba2;
    float e1 = expf(s1 >= 0.f ? -s1 : -0.01f*s1);
    float e2 = expf(s2 >= 0.f ? -s2 : -0.01f*s2);
    float h1x = e1*c1x, h1y = e1*c1y;
    float h2x = e2*c2x, h2y = e2*c2y;
    atomicAdd(&hs[(size_t)t0*D + 2*lane  ], h1x);
    atomicAdd(&hs[(size_t)t0*D + 2*lane+1], h1y);
    atomicAdd(&hs[(size_t)t1*D + 2*lane  ], h2x);
    atomicAdd(&hs[(size_t)t1*D + 2*lane+1], h2y);
    atomicAdd(&rp[t2*D + 2*lane  ], h1x-h2x);
    atomicAdd(&rp[t2*D + 2*lane+1], h1y-h2y);
    if(lane==0){
      atomicAdd(&ebs[t0], e1);
      atomicAdd(&ebs[t1], e2);
    }
  }
}

// ------- K10: h_ent = hs / ebs (in place in d_out) --------------------------
__global__ __launch_bounds__(256) void k_hentfin(float* __restrict__ out,
    const float* __restrict__ ebs){
  size_t i = (size_t)blockIdx.x*256 + threadIdx.x;
  if(i >= (size_t)N_ENT*D/4) return;
  int e = (int)(i >> 5);
  float d = ebs[e];
  float inv = (d != 0.f) ? 1.0f/d : 0.0f;
  float4 v = ((float4*)out)[i];
  v.x *= inv; v.y *= inv; v.z *= inv; v.w *= inv;
  ((float4*)out)[i] = v;
}

// ------- K11: h_rel = (sum of NC partials) / cnt ----------------------------
__global__ __launch_bounds__(256) void k_hrelfin(const float* __restrict__ relpart,
    const int* __restrict__ cntr, float* __restrict__ out_hrel){
  int idx = blockIdx.x*256 + threadIdx.x;
  if(idx >= N_REL*D) return;
  int r = idx >> 7;
  float s = 0.f;
  for(int c=0;c<NC;c++) s += relpart[(size_t)c*N_REL*D + idx];
  int cn = cntr[r];
  float cf = cn > 0 ? (float)cn : 1.0f;
  out_hrel[idx] = s/cf;
}

// ------- K12: RotatE score --------------------------------------------------
__global__ __launch_bounds__(256) void k_score(const int* __restrict__ trip,
    const float* __restrict__ ent, const float* __restrict__ cosr,
    const float* __restrict__ sinr, float* __restrict__ score){
  int t = threadIdx.x, lane = t & 63;
  int gw = blockIdx.x*4 + (t>>6), nw = gridDim.x*4;
  for(int i=gw; i<N_TRIP; i+=nw){
    int t0 = trip[3*i], t1 = trip[3*i+1], t2 = trip[3*i+2];
    float re_h = ent[(size_t)t0*D + lane];
    float im_h = ent[(size_t)t0*D + 64 + lane];
    float re_t = ent[(size_t)t1*D + lane];
    float im_t = ent[(size_t)t1*D + 64 + lane];
    float cr = cosr[t2*64 + lane], sr = sinr[t2*64 + lane];
    float re_s = cr*re_t + sr*im_t - re_h;
    float im_s = cr*im_t - sr*re_t - im_h;
    float d = sqrtf(re_s*re_s + im_s*im_s);
    #pragma unroll
    for(int o=32;o>0;o>>=1) d += __shfl_xor(d,o,64);
    if(lane==0) score[i] = MARGINF - d;
  }
}

extern "C" void kernel_launch(void* const* d_in, const int* in_sizes, int n_in,
                              void* d_out, int out_size, void* d_ws, size_t ws_size,
                              hipStream_t stream){
  const int*   trip   = (const int*)  d_in[0];
  const float* ent    = (const float*)d_in[1];
  const float* rel    = (const float*)d_in[2];
  const float* W_a    = (const float*)d_in[3];
  const float* b_a    = (const float*)d_in[4];
  const float* W_a2   = (const float*)d_in[5];
  const float* b_a2   = (const float*)d_in[6];
  const float* gamma0 = (const float*)d_in[7];
  const float* beta0  = (const float*)d_in[8];
  const float* gamma1 = (const float*)d_in[9];
  const float* beta1  = (const float*)d_in[10];

  char* ws = (char*)d_ws;
  size_t off = 0;
  auto take = [&](size_t bytes)->void*{
    void* p = ws + off;
    off += (bytes + 255) & ~(size_t)255;
    return p;
  };
  // ---- zeroed scratch (contiguous from 0) ----
  int*   cnt0    = (int*)  take((size_t)N_ENT*4);
  int*   cnt1    = (int*)  take((size_t)N_ENT*4);
  int*   cntr    = (int*)  take((size_t)N_REL*4);
  float* stats   = (float*)take(640*4);
  float* sums    = (float*)take(256*4);
  float* ebs     = (float*)take((size_t)N_ENT*4);
  float* relpart = (float*)take((size_t)NC*N_REL*D*4);
  size_t zero_bytes = off;
  // ---- fully-overwritten scratch ----
  float* scale     = (float*)take((size_t)N_ENT*4);
  float* scale_rel = (float*)take((size_t)N_REL*4);
  u16*   Wbf       = (u16*)  take(256*128*2);
  float* W2        = (float*)take(128*128*4);
  float* bprime    = (float*)take(128*4);
  float* a1c       = (float*)take(256*4);
  float* R         = (float*)take((size_t)N_REL*D*4);
  float* cosr      = (float*)take((size_t)N_REL*64*4);
  float* sinr      = (float*)take((size_t)N_REL*64*4);
  u16*   Abuf      = (u16*)  take((size_t)N_ENT*D*2);
  u16*   Bbuf      = (u16*)  take((size_t)N_ENT*D*2);
  (void)ws_size; (void)n_in; (void)in_sizes; (void)out_size;

  float* out_hent  = (float*)d_out;
  float* out_hrel  = out_hent + (size_t)N_ENT*D;
  float* out_score = out_hrel + (size_t)N_REL*D;

  hipMemsetAsync(d_ws, 0, zero_bytes, stream);
  hipMemsetAsync(d_out, 0, (size_t)N_ENT*D*4, stream);

  k_hist    <<<(N_TRIP+255)/256, 256, 0, stream>>>(trip, cnt0, cnt1, cntr);
  k_entstats<<<256, 256, 0, stream>>>(ent, cnt0, cnt1, scale, stats);
  k_relstats<<<(N_REL+3)/4, 256, 0, stream>>>(rel, cntr, scale_rel, stats, cosr, sinr);
  k_bn0fin  <<<1, 384, 0, stream>>>(stats, W_a, b_a, gamma0, beta0, Wbf, W2, bprime);
  k_relproj <<<N_REL, 128, 0, stream>>>(rel, scale_rel, W2, R);
  k_ab      <<<N_ENT/64, 256, 0, stream>>>(ent, scale, Wbf, Abuf, Bbuf);
  k_bn1stats<<<1024, 256, 0, stream>>>(trip, Abuf, Bbuf, R, bprime, sums);
  k_bn1fin  <<<1, 128, 0, stream>>>(sums, gamma1, beta1, a1c);
  k_main    <<<2048, 256, 0, stream>>>(trip, Abuf, Bbuf, R, bprime, a1c, W_a2, b_a2,
                                       out_hent, ebs, relpart);
  k_hentfin <<<(N_ENT*D/4+255)/256, 256, 0, stream>>>(out_hent, ebs);
  k_hrelfin <<<(N_REL*D+255)/256, 256, 0, stream>>>(relpart, cntr, out_hrel);
  k_score   <<<1024, 256, 0, stream>>>(trip, ent, cosr, sinr, out_score);
}

// Round 3
// 819.300 us; speedup vs baseline: 1.9807x; 1.3688x over previous
//
#include <hip/hip_runtime.h>
#include <stdint.h>

#define N_TRIP 200000
#define N_ENT  200000
#define N_REL  500
#define D      128
#define MARGINF 6.0f
#define BN_EPSF 1e-5f
#define PHASE_C 50.26548245743669f   // PI / REL_RANGE, REL_RANGE = 8/128

typedef unsigned short u16;
typedef unsigned int   u32;
typedef __attribute__((ext_vector_type(8))) short short8;
typedef __attribute__((ext_vector_type(4))) float f32x4;
typedef __attribute__((ext_vector_type(4))) unsigned short u16x4;

__device__ inline float bfl(u32 u){ return __uint_as_float(u<<16); }
__device__ inline float bfh(u32 u){ return __uint_as_float(u&0xffff0000u); }
__device__ inline u16 f2bf(float f){
  u32 u = __float_as_uint(f);
  u32 r = (u + 0x7fffu + ((u>>16)&1u))>>16;
  return (u16)r;
}

// ---------------- K1: histogram of head / tail / rel indices ----------------
__global__ __launch_bounds__(256) void k_hist(const int* __restrict__ trip,
    int* __restrict__ cnt0, int* __restrict__ cnt1, int* __restrict__ cntr){
  int i = blockIdx.x*256 + threadIdx.x;
  if(i < N_TRIP){
    atomicAdd(&cnt0[trip[3*i]],   1);
    atomicAdd(&cnt1[trip[3*i+1]], 1);
    atomicAdd(&cntr[trip[3*i+2]], 1);
  }
}

// ---------------- CSR build: 3-kernel prefix scan + cursor scatter ----------
__global__ __launch_bounds__(1024) void k_scan1(const int* __restrict__ cnt0,
    const int* __restrict__ cnt1, int* __restrict__ offs, int* __restrict__ bsum){
  __shared__ int sh[1024];
  int t = threadIdx.x;
  int e = blockIdx.x*1024 + t;
  int d = (e < N_ENT) ? cnt0[e] + cnt1[e] : 0;
  sh[t] = d; __syncthreads();
  for(int st=1; st<1024; st<<=1){
    int x = (t>=st) ? sh[t-st] : 0;
    __syncthreads();
    sh[t] += x;
    __syncthreads();
  }
  if(e < N_ENT) offs[e] = sh[t] - d;          // block-local exclusive
  if(t == 1023) bsum[blockIdx.x] = sh[t];
}

__global__ __launch_bounds__(512) void k_scan2(const int* __restrict__ bsum,
    int* __restrict__ boffs, const int* __restrict__ cntr,
    int* __restrict__ roffs, int* __restrict__ rcur, int nblk){
  __shared__ int sh[512];
  int t = threadIdx.x;
  int v = (t < nblk) ? bsum[t] : 0;
  sh[t] = v; __syncthreads();
  for(int st=1; st<512; st<<=1){
    int x = (t>=st) ? sh[t-st] : 0;
    __syncthreads(); sh[t] += x; __syncthreads();
  }
  if(t < nblk) boffs[t] = sh[t] - v;
  __syncthreads();
  int w = (t < N_REL) ? cntr[t] : 0;
  sh[t] = w; __syncthreads();
  for(int st=1; st<512; st<<=1){
    int x = (t>=st) ? sh[t-st] : 0;
    __syncthreads(); sh[t] += x; __syncthreads();
  }
  if(t < N_REL){ roffs[t] = sh[t]-w; rcur[t] = sh[t]-w; }
}

__global__ __launch_bounds__(1024) void k_scan3(int* __restrict__ offs,
    const int* __restrict__ boffs, int* __restrict__ cur){
  int e = blockIdx.x*1024 + threadIdx.x;
  if(e < N_ENT){
    int o = offs[e] + boffs[blockIdx.x];
    offs[e] = o;
    cur[e] = o;
  }
}

__global__ __launch_bounds__(256) void k_edges(const int* __restrict__ trip,
    int* __restrict__ cur, int* __restrict__ rcur,
    u32* __restrict__ ebuf, u32* __restrict__ rbuf){
  int i = blockIdx.x*256 + threadIdx.x;
  if(i < N_TRIP){
    int t0 = trip[3*i], t1 = trip[3*i+1], t2 = trip[3*i+2];
    ebuf[atomicAdd(&cur[t0], 1)] = (u32)(2*i);
    ebuf[atomicAdd(&cur[t1], 1)] = (u32)(2*i+1);
    rbuf[atomicAdd(&rcur[t2], 1)] = (u32)i;
  }
}

// ------- K2: per-entity norm scale + weighted column stats (S0,S1,Q0,Q1) ----
__global__ __launch_bounds__(256) void k_entstats(const float* __restrict__ ent,
    const int* __restrict__ cnt0, const int* __restrict__ cnt1,
    float* __restrict__ scale, float* __restrict__ stats){
  __shared__ float acc[512];
  int t = threadIdx.x;
  acc[t] = 0.f; acc[t+256] = 0.f;
  __syncthreads();
  int lane = t & 63;
  int gw = blockIdx.x*4 + (t>>6);
  int nw = gridDim.x*4;
  float p0=0,p1=0,p2=0,p3=0,p4=0,p5=0,p6=0,p7=0;
  for(int e=gw; e<N_ENT; e+=nw){
    float2 x = *(const float2*)(ent + (size_t)e*D + 2*lane);
    float ss = x.x*x.x + x.y*x.y;
    #pragma unroll
    for(int o=32;o>0;o>>=1) ss += __shfl_xor(ss,o,64);
    float nrm = sqrtf(ss);
    float sc = nrm > 1.0f ? 1.0f/nrm : 1.0f;
    if(lane==0) scale[e] = sc;
    float w0 = (float)cnt0[e];
    float w1 = (float)cnt1[e];
    float sx = x.x*sc, sy = x.y*sc;
    p0 += w0*sx;    p1 += w0*sy;
    p2 += w1*sx;    p3 += w1*sy;
    p4 += w0*sx*sx; p5 += w0*sy*sy;
    p6 += w1*sx*sx; p7 += w1*sy*sy;
  }
  atomicAdd(&acc[      2*lane  ], p0);
  atomicAdd(&acc[      2*lane+1], p1);
  atomicAdd(&acc[128 + 2*lane  ], p2);
  atomicAdd(&acc[128 + 2*lane+1], p3);
  atomicAdd(&acc[256 + 2*lane  ], p4);
  atomicAdd(&acc[256 + 2*lane+1], p5);
  atomicAdd(&acc[384 + 2*lane  ], p6);
  atomicAdd(&acc[384 + 2*lane+1], p7);
  __syncthreads();
  atomicAdd(&stats[t],     acc[t]);
  atomicAdd(&stats[t+256], acc[t+256]);
}

// ------- K3: per-rel scale + Qr stats + cos/sin phase tables ---------------
__global__ __launch_bounds__(256) void k_relstats(const float* __restrict__ rel,
    const int* __restrict__ cntr, float* __restrict__ scale_rel,
    float* __restrict__ stats, float* __restrict__ cosr, float* __restrict__ sinr){
  int t = threadIdx.x, lane = t & 63;
  int r = blockIdx.x*4 + (t>>6);
  if(r >= N_REL) return;
  float2 x = *(const float2*)(rel + (size_t)r*D + 2*lane);
  float ss = x.x*x.x + x.y*x.y;
  #pragma unroll
  for(int o=32;o>0;o>>=1) ss += __shfl_xor(ss,o,64);
  float nrm = sqrtf(ss);
  float sc = nrm > 1.0f ? 1.0f/nrm : 1.0f;
  if(lane==0) scale_rel[r] = sc;
  float w = (float)cntr[r];
  float sx = x.x*sc, sy = x.y*sc;
  atomicAdd(&stats[512 + 2*lane  ], w*sx*sx);
  atomicAdd(&stats[512 + 2*lane+1], w*sy*sy);
  if(lane < 32){   // raw (unnormalized) coords 0..63 feed the phases
    cosr[r*64 + 2*lane  ] = cosf(x.x*PHASE_C);
    sinr[r*64 + 2*lane  ] = sinf(x.x*PHASE_C);
    cosr[r*64 + 2*lane+1] = cosf(x.y*PHASE_C);
    sinr[r*64 + 2*lane+1] = sinf(x.y*PHASE_C);
  }
}

// ------- K4: finalize BN0, build folded bf16 weights Wbf, W2 and b' ---------
__global__ __launch_bounds__(384) void k_bn0fin(const float* __restrict__ stats,
    const float* __restrict__ W_a, const float* __restrict__ b_a,
    const float* __restrict__ gamma0, const float* __restrict__ beta0,
    u16* __restrict__ Wbf, float* __restrict__ W2, float* __restrict__ bprime){
  __shared__ float a0[384], c0[384];
  int t = threadIdx.x;
  {
    int j = t & 127;
    float mu, ex2;
    if(t < 256){
      mu  = (stats[j]     + stats[128+j]) * (1.0f/(2.0f*N_TRIP));
      ex2 = (stats[256+j] + stats[384+j]) * (1.0f/(2.0f*N_TRIP));
    } else {
      mu  = 0.0f;
      ex2 = stats[512+j] * (1.0f/N_TRIP);
    }
    float var = ex2 - mu*mu;
    float a = gamma0[t]*rsqrtf(var + BN_EPSF);
    a0[t] = a;
    c0[t] = beta0[t] - mu*a;
  }
  __syncthreads();
  // Wbf[j][k] (bf16): j<128 -> A proj (W cols 0..127), j>=128 -> B proj (cols 128..255)
  for(int idx=t; idx<256*128; idx+=384){
    int j = idx>>7, k = idx&127;
    int ko = ((j>>7)<<7) + k;
    Wbf[idx] = f2bf(W_a[(j&127)*384 + ko]*a0[ko]);
  }
  // W2[k][j] = W_a[j][256+k]*a0[256+k]   (rel slot, coalesced for k_relproj)
  for(int idx=t; idx<128*128; idx+=384){
    int k = idx>>7, j = idx&127;
    W2[idx] = W_a[j*384 + 256 + k]*a0[256+k];
  }
  if(t < 128){
    float s = b_a[t];
    for(int k=0;k<384;k++) s += W_a[t*384+k]*c0[k];
    bprime[t] = s;
  }
}

// ------- K5: R[r] = rel_n[r] @ W2 ------------------------------------------
__global__ __launch_bounds__(128) void k_relproj(const float* __restrict__ rel,
    const float* __restrict__ scale_rel, const float* __restrict__ W2,
    float* __restrict__ R){
  int r = blockIdx.x, j = threadIdx.x;
  __shared__ float x[128];
  x[j] = rel[(size_t)r*D + j]*scale_rel[r];
  __syncthreads();
  float s = 0.f;
  for(int k=0;k<128;k++) s += x[k]*W2[k*128+j];
  R[r*128+j] = s;
}

// ------- K6: A/B projection via MFMA (200000x128 @ 128x256 -> bf16) ---------
__global__ __launch_bounds__(256) void k_ab(const float* __restrict__ ent,
    const float* __restrict__ scale, const u16* __restrict__ Wbf,
    u16* __restrict__ Abuf, u16* __restrict__ Bbuf){
  int t = threadIdx.x;
  int lane = t & 63;
  int wm = t >> 6;
  int e0 = blockIdx.x*64 + wm*16;
  int erow = e0 + (lane & 15);
  int kgrp = (lane >> 4) << 3;     // 0,8,16,24
  float sc = scale[erow];
  const float* xp = ent + (size_t)erow*D + kgrp;
  short8 xf[4];
  #pragma unroll
  for(int kt=0;kt<4;kt++){
    float4 x0 = *(const float4*)(xp + kt*32);
    float4 x1 = *(const float4*)(xp + kt*32 + 4);
    short8 v;
    v[0]=(short)f2bf(x0.x*sc); v[1]=(short)f2bf(x0.y*sc);
    v[2]=(short)f2bf(x0.z*sc); v[3]=(short)f2bf(x0.w*sc);
    v[4]=(short)f2bf(x1.x*sc); v[5]=(short)f2bf(x1.y*sc);
    v[6]=(short)f2bf(x1.z*sc); v[7]=(short)f2bf(x1.w*sc);
    xf[kt]=v;
  }
  const u16* wp0 = Wbf + (size_t)(lane&15)*D + kgrp;
  int rgrp = (lane>>4)<<2;
  #pragma unroll
  for(int jt=0;jt<16;jt++){
    const u16* wp = wp0 + (size_t)jt*16*D;
    f32x4 acc = {0.f,0.f,0.f,0.f};
    #pragma unroll
    for(int kt=0;kt<4;kt++){
      short8 wf = *(const short8*)(wp + kt*32);
      acc = __builtin_amdgcn_mfma_f32_16x16x32_bf16(wf, xf[kt], acc, 0,0,0);
    }
    int jbase = jt*16 + rgrp;
    u16x4 pk;
    pk.x=f2bf(acc[0]); pk.y=f2bf(acc[1]); pk.z=f2bf(acc[2]); pk.w=f2bf(acc[3]);
    u16* dst = (jbase < 128) ? (Abuf + (size_t)erow*D + jbase)
                             : (Bbuf + (size_t)erow*D + (jbase-128));
    *(u16x4*)dst = pk;
  }
}

// ------- K7: BN1 statistics over the 2n virtual rows ------------------------
__global__ __launch_bounds__(256) void k_bn1stats(const int* __restrict__ trip,
    const u16* __restrict__ A, const u16* __restrict__ B,
    const float* __restrict__ R, const float* __restrict__ bprime,
    float* __restrict__ sums){
  __shared__ float acc[256];
  int t = threadIdx.x;
  acc[t] = 0.f;
  __syncthreads();
  int lane = t & 63;
  int gw = blockIdx.x*4 + (t>>6), nw = gridDim.x*4;
  float bp0 = bprime[2*lane], bp1 = bprime[2*lane+1];
  float s0=0,s1=0,q0=0,q1=0;
  for(int i=gw; i<N_TRIP; i+=nw){
    int t0 = trip[3*i], t1 = trip[3*i+1], t2 = trip[3*i+2];
    u32 ua0 = *(const u32*)(A + (size_t)t0*D + 2*lane);
    u32 ua1 = *(const u32*)(A + (size_t)t1*D + 2*lane);
    u32 ub0 = *(const u32*)(B + (size_t)t0*D + 2*lane);
    u32 ub1 = *(const u32*)(B + (size_t)t1*D + 2*lane);
    float2 r = *(const float2*)(R + (size_t)t2*D + 2*lane);
    float y1x = bfl(ua0)+bfl(ub1)+r.x+bp0;
    float y1y = bfh(ua0)+bfh(ub1)+r.y+bp1;
    float y2x = bfl(ua1)+bfl(ub0)-r.x+bp0;
    float y2y = bfh(ua1)+bfh(ub0)-r.y+bp1;
    s0 += y1x+y2x; s1 += y1y+y2y;
    q0 += y1x*y1x + y2x*y2x; q1 += y1y*y1y + y2y*y2y;
  }
  atomicAdd(&acc[      2*lane  ], s0);
  atomicAdd(&acc[      2*lane+1], s1);
  atomicAdd(&acc[128 + 2*lane  ], q0);
  atomicAdd(&acc[128 + 2*lane+1], q1);
  __syncthreads();
  atomicAdd(&sums[t], acc[t]);
}

// ------- K8: finalize BN1 ---------------------------------------------------
__global__ __launch_bounds__(128) void k_bn1fin(const float* __restrict__ sums,
    const float* __restrict__ gamma1, const float* __restrict__ beta1,
    float* __restrict__ a1c){
  int j = threadIdx.x;
  float mu  = sums[j]    *(1.0f/(2.0f*N_TRIP));
  float var = sums[128+j]*(1.0f/(2.0f*N_TRIP)) - mu*mu;
  float a = gamma1[j]*rsqrtf(var + BN_EPSF);
  a1c[j]     = a;
  a1c[128+j] = beta1[j] - mu*a;
}

// ------- K9: per-entity gather pass: h_ent written directly, no atomics -----
__global__ __launch_bounds__(256) void k_ent(const int* __restrict__ trip,
    const int* __restrict__ offs, const int* __restrict__ endp,
    const u32* __restrict__ ebuf,
    const u16* __restrict__ A, const u16* __restrict__ B,
    const float* __restrict__ R, const float* __restrict__ bprime,
    const float* __restrict__ a1c, const float* __restrict__ W_a2,
    const float* __restrict__ b_a2, float* __restrict__ out_hent){
  int t = threadIdx.x, lane = t & 63;
  int gw = blockIdx.x*4 + (t>>6), nw = gridDim.x*4;
  float bp0 = bprime[2*lane], bp1 = bprime[2*lane+1];
  float a1x = a1c[2*lane],     a1y = a1c[2*lane+1];
  float ccx = a1c[128+2*lane], ccy = a1c[128+2*lane+1];
  float wvx = W_a2[2*lane],    wvy = W_a2[2*lane+1];
  float ba2 = b_a2[0];
  for(int e=gw; e<N_ENT; e+=nw){
    int s = offs[e], en = endp[e];
    u32 ua = *(const u32*)(A + (size_t)e*D + 2*lane);
    float ax = bfl(ua), ay = bfh(ua);
    float hx = 0.f, hy = 0.f, eb = 0.f;
    for(int o=s; o<en; o++){
      u32 id = ebuf[o];
      int i = id>>1, role = id&1;
      int t0 = trip[3*i], t1 = trip[3*i+1], t2 = trip[3*i+2];
      int other = role ? t0 : t1;
      float sg = role ? -1.f : 1.f;
      u32 ub = *(const u32*)(B + (size_t)other*D + 2*lane);
      float2 r = *(const float2*)(R + (size_t)t2*D + 2*lane);
      float yx = ax + bfl(ub) + sg*r.x + bp0;
      float yy = ay + bfh(ub) + sg*r.y + bp1;
      float cx = yx*a1x + ccx, cy = yy*a1y + ccy;
      float rd = cx*wvx + cy*wvy;
      #pragma unroll
      for(int of=32; of>0; of>>=1) rd += __shfl_xor(rd, of, 64);
      float sc = rd + ba2;
      float e_b = expf(sc >= 0.f ? -sc : -0.01f*sc);
      hx += e_b*cx; hy += e_b*cy; eb += e_b;
    }
    float inv = (en > s) ? 1.0f/eb : 0.0f;
    float2 o2; o2.x = hx*inv; o2.y = hy*inv;
    *(float2*)(out_hent + (size_t)e*D + 2*lane) = o2;
  }
}

// ------- K10: per-rel gather pass: h_rel written directly, no atomics -------
__global__ __launch_bounds__(512) void k_rel(const int* __restrict__ trip,
    const int* __restrict__ roffs, const int* __restrict__ cntr,
    const u32* __restrict__ rbuf,
    const u16* __restrict__ A, const u16* __restrict__ B,
    const float* __restrict__ R, const float* __restrict__ bprime,
    const float* __restrict__ a1c, const float* __restrict__ W_a2,
    const float* __restrict__ b_a2, float* __restrict__ out_hrel){
  __shared__ float red[8][128];
  int t = threadIdx.x, lane = t & 63, w = t >> 6;
  int r = blockIdx.x;
  int cnt = cntr[r], base = roffs[r];
  float2 rr = *(const float2*)(R + (size_t)r*D + 2*lane);
  float bp0 = bprime[2*lane], bp1 = bprime[2*lane+1];
  float a1x = a1c[2*lane],     a1y = a1c[2*lane+1];
  float ccx = a1c[128+2*lane], ccy = a1c[128+2*lane+1];
  float wvx = W_a2[2*lane],    wvy = W_a2[2*lane+1];
  float ba2 = b_a2[0];
  float sx = 0.f, sy = 0.f;
  for(int j=w; j<cnt; j+=8){
    int i = (int)rbuf[base+j];
    int t0 = trip[3*i], t1 = trip[3*i+1];
    u32 ua0 = *(const u32*)(A + (size_t)t0*D + 2*lane);
    u32 ua1 = *(const u32*)(A + (size_t)t1*D + 2*lane);
    u32 ub0 = *(const u32*)(B + (size_t)t0*D + 2*lane);
    u32 ub1 = *(const u32*)(B + (size_t)t1*D + 2*lane);
    float y1x = bfl(ua0)+bfl(ub1)+rr.x+bp0;
    float y1y = bfh(ua0)+bfh(ub1)+rr.y+bp1;
    float y2x = bfl(ua1)+bfl(ub0)-rr.x+bp0;
    float y2y = bfh(ua1)+bfh(ub0)-rr.y+bp1;
    float c1x = y1x*a1x+ccx, c1y = y1y*a1y+ccy;
    float c2x = y2x*a1x+ccx, c2y = y2y*a1y+ccy;
    float r1 = c1x*wvx + c1y*wvy;
    float r2 = c2x*wvx + c2y*wvy;
    #pragma unroll
    for(int o=32;o>0;o>>=1){ r1 += __shfl_xor(r1,o,64); r2 += __shfl_xor(r2,o,64); }
    float s1 = r1 + ba2, s2 = r2 + ba2;
    float e1 = expf(s1 >= 0.f ? -s1 : -0.01f*s1);
    float e2 = expf(s2 >= 0.f ? -s2 : -0.01f*s2);
    sx += e1*c1x - e2*c2x;
    sy += e1*c1y - e2*c2y;
  }
  float2 p; p.x = sx; p.y = sy;
  *(float2*)&red[w][2*lane] = p;
  __syncthreads();
  if(t < 128){
    float s = 0.f;
    #pragma unroll
    for(int k=0;k<8;k++) s += red[k][t];
    float cf = cnt > 0 ? (float)cnt : 1.0f;
    out_hrel[(size_t)r*D + t] = s/cf;
  }
}

// ------- K12: RotatE score --------------------------------------------------
__global__ __launch_bounds__(256) void k_score(const int* __restrict__ trip,
    const float* __restrict__ ent, const float* __restrict__ cosr,
    const float* __restrict__ sinr, float* __restrict__ score){
  int t = threadIdx.x, lane = t & 63;
  int gw = blockIdx.x*4 + (t>>6), nw = gridDim.x*4;
  for(int i=gw; i<N_TRIP; i+=nw){
    int t0 = trip[3*i], t1 = trip[3*i+1], t2 = trip[3*i+2];
    float re_h = ent[(size_t)t0*D + lane];
    float im_h = ent[(size_t)t0*D + 64 + lane];
    float re_t = ent[(size_t)t1*D + lane];
    float im_t = ent[(size_t)t1*D + 64 + lane];
    float cr = cosr[t2*64 + lane], sr = sinr[t2*64 + lane];
    float re_s = cr*re_t + sr*im_t - re_h;
    float im_s = cr*im_t - sr*re_t - im_h;
    float d = sqrtf(re_s*re_s + im_s*im_s);
    #pragma unroll
    for(int o=32;o>0;o>>=1) d += __shfl_xor(d,o,64);
    if(lane==0) score[i] = MARGINF - d;
  }
}

extern "C" void kernel_launch(void* const* d_in, const int* in_sizes, int n_in,
                              void* d_out, int out_size, void* d_ws, size_t ws_size,
                              hipStream_t stream){
  const int*   trip   = (const int*)  d_in[0];
  const float* ent    = (const float*)d_in[1];
  const float* rel    = (const float*)d_in[2];
  const float* W_a    = (const float*)d_in[3];
  const float* b_a    = (const float*)d_in[4];
  const float* W_a2   = (const float*)d_in[5];
  const float* b_a2   = (const float*)d_in[6];
  const float* gamma0 = (const float*)d_in[7];
  const float* beta0  = (const float*)d_in[8];
  const float* gamma1 = (const float*)d_in[9];
  const float* beta1  = (const float*)d_in[10];

  char* ws = (char*)d_ws;
  size_t off = 0;
  auto take = [&](size_t bytes)->void*{
    void* p = ws + off;
    off += (bytes + 255) & ~(size_t)255;
    return p;
  };
  // ---- zeroed scratch (contiguous from 0) ----
  int*   cnt0    = (int*)  take((size_t)N_ENT*4);
  int*   cnt1    = (int*)  take((size_t)N_ENT*4);
  int*   cntr    = (int*)  take((size_t)N_REL*4);
  float* stats   = (float*)take(640*4);
  float* sums    = (float*)take(256*4);
  size_t zero_bytes = off;
  // ---- fully-overwritten scratch ----
  int*   offs      = (int*)  take((size_t)N_ENT*4);
  int*   cur       = (int*)  take((size_t)N_ENT*4);
  int*   bsum      = (int*)  take(512*4);
  int*   boffs     = (int*)  take(512*4);
  int*   roffs     = (int*)  take(512*4);
  int*   rcur      = (int*)  take(512*4);
  u32*   ebuf      = (u32*)  take((size_t)2*N_TRIP*4);
  u32*   rbuf      = (u32*)  take((size_t)N_TRIP*4);
  float* scale     = (float*)take((size_t)N_ENT*4);
  float* scale_rel = (float*)take((size_t)N_REL*4);
  u16*   Wbf       = (u16*)  take(256*128*2);
  float* W2        = (float*)take(128*128*4);
  float* bprime    = (float*)take(128*4);
  float* a1c       = (float*)take(256*4);
  float* R         = (float*)take((size_t)N_REL*D*4);
  float* cosr      = (float*)take((size_t)N_REL*64*4);
  float* sinr      = (float*)take((size_t)N_REL*64*4);
  u16*   Abuf      = (u16*)  take((size_t)N_ENT*D*2);
  u16*   Bbuf      = (u16*)  take((size_t)N_ENT*D*2);
  (void)ws_size; (void)n_in; (void)in_sizes; (void)out_size;

  float* out_hent  = (float*)d_out;
  float* out_hrel  = out_hent + (size_t)N_ENT*D;
  float* out_score = out_hrel + (size_t)N_REL*D;

  hipMemsetAsync(d_ws, 0, zero_bytes, stream);

  const int SCAN_BLKS = (N_ENT + 1023)/1024;   // 196
  k_hist    <<<(N_TRIP+255)/256, 256, 0, stream>>>(trip, cnt0, cnt1, cntr);
  k_scan1   <<<SCAN_BLKS, 1024, 0, stream>>>(cnt0, cnt1, offs, bsum);
  k_scan2   <<<1, 512, 0, stream>>>(bsum, boffs, cntr, roffs, rcur, SCAN_BLKS);
  k_scan3   <<<SCAN_BLKS, 1024, 0, stream>>>(offs, boffs, cur);
  k_edges   <<<(N_TRIP+255)/256, 256, 0, stream>>>(trip, cur, rcur, ebuf, rbuf);
  k_entstats<<<256, 256, 0, stream>>>(ent, cnt0, cnt1, scale, stats);
  k_relstats<<<(N_REL+3)/4, 256, 0, stream>>>(rel, cntr, scale_rel, stats, cosr, sinr);
  k_bn0fin  <<<1, 384, 0, stream>>>(stats, W_a, b_a, gamma0, beta0, Wbf, W2, bprime);
  k_relproj <<<N_REL, 128, 0, stream>>>(rel, scale_rel, W2, R);
  k_ab      <<<N_ENT/64, 256, 0, stream>>>(ent, scale, Wbf, Abuf, Bbuf);
  k_bn1stats<<<1024, 256, 0, stream>>>(trip, Abuf, Bbuf, R, bprime, sums);
  k_bn1fin  <<<1, 128, 0, stream>>>(sums, gamma1, beta1, a1c);
  k_ent     <<<2048, 256, 0, stream>>>(trip, offs, cur, ebuf, Abuf, Bbuf, R,
                                       bprime, a1c, W_a2, b_a2, out_hent);
  k_rel     <<<N_REL, 512, 0, stream>>>(trip, roffs, cntr, rbuf, Abuf, Bbuf, R,
                                        bprime, a1c, W_a2, b_a2, out_hrel);
  k_score   <<<1024, 256, 0, stream>>>(trip, ent, cosr, sinr, out_score);
}

// Round 4
// 728.852 us; speedup vs baseline: 2.2265x; 1.1241x over previous
//
#include <hip/hip_runtime.h>
#include <stdint.h>

#define N_TRIP 200000
#define N_ENT  200000
#define N_REL  500
#define D      128
#define MARGINF 6.0f
#define BN_EPSF 1e-5f
#define PHASE_C 50.26548245743669f   // PI / REL_RANGE, REL_RANGE = 8/128

typedef unsigned short u16;
typedef unsigned int   u32;
typedef __attribute__((ext_vector_type(8))) short short8;
typedef __attribute__((ext_vector_type(4))) float f32x4;
typedef __attribute__((ext_vector_type(4))) unsigned short u16x4;

__device__ inline float bfl(u32 u){ return __uint_as_float(u<<16); }
__device__ inline float bfh(u32 u){ return __uint_as_float(u&0xffff0000u); }
__device__ inline u16 f2bf(float f){
  u32 u = __float_as_uint(f);
  u32 r = (u + 0x7fffu + ((u>>16)&1u))>>16;
  return (u16)r;
}

// ---------------- K1: histogram of head / tail / rel indices ----------------
__global__ __launch_bounds__(256) void k_hist(const int* __restrict__ trip,
    int* __restrict__ cnt0, int* __restrict__ cnt1, int* __restrict__ cntr){
  int i = blockIdx.x*256 + threadIdx.x;
  if(i < N_TRIP){
    atomicAdd(&cnt0[trip[3*i]],   1);
    atomicAdd(&cnt1[trip[3*i+1]], 1);
    atomicAdd(&cntr[trip[3*i+2]], 1);
  }
}

// ---------------- CSR build: 3-kernel prefix scan + cursor scatter ----------
__global__ __launch_bounds__(1024) void k_scan1(const int* __restrict__ cnt0,
    const int* __restrict__ cnt1, int* __restrict__ offs, int* __restrict__ bsum){
  __shared__ int sh[1024];
  int t = threadIdx.x;
  int e = blockIdx.x*1024 + t;
  int d = (e < N_ENT) ? cnt0[e] + cnt1[e] : 0;
  sh[t] = d; __syncthreads();
  for(int st=1; st<1024; st<<=1){
    int x = (t>=st) ? sh[t-st] : 0;
    __syncthreads();
    sh[t] += x;
    __syncthreads();
  }
  if(e < N_ENT) offs[e] = sh[t] - d;          // block-local exclusive
  if(t == 1023) bsum[blockIdx.x] = sh[t];
}

__global__ __launch_bounds__(512) void k_scan2(const int* __restrict__ bsum,
    int* __restrict__ boffs, const int* __restrict__ cntr,
    int* __restrict__ roffs, int* __restrict__ rcur, int nblk){
  __shared__ int sh[512];
  int t = threadIdx.x;
  int v = (t < nblk) ? bsum[t] : 0;
  sh[t] = v; __syncthreads();
  for(int st=1; st<512; st<<=1){
    int x = (t>=st) ? sh[t-st] : 0;
    __syncthreads(); sh[t] += x; __syncthreads();
  }
  if(t < nblk) boffs[t] = sh[t] - v;
  __syncthreads();
  int w = (t < N_REL) ? cntr[t] : 0;
  sh[t] = w; __syncthreads();
  for(int st=1; st<512; st<<=1){
    int x = (t>=st) ? sh[t-st] : 0;
    __syncthreads(); sh[t] += x; __syncthreads();
  }
  if(t < N_REL){ roffs[t] = sh[t]-w; rcur[t] = sh[t]-w; }
}

__global__ __launch_bounds__(1024) void k_scan3(int* __restrict__ offs,
    const int* __restrict__ boffs, int* __restrict__ cur){
  int e = blockIdx.x*1024 + threadIdx.x;
  if(e < N_ENT){
    int o = offs[e] + boffs[blockIdx.x];
    offs[e] = o;
    cur[e] = o;
  }
}

__global__ __launch_bounds__(256) void k_edges(const int* __restrict__ trip,
    int* __restrict__ cur, int* __restrict__ rcur,
    u32* __restrict__ ebuf, u32* __restrict__ rbuf){
  int i = blockIdx.x*256 + threadIdx.x;
  if(i < N_TRIP){
    int t0 = trip[3*i], t1 = trip[3*i+1], t2 = trip[3*i+2];
    ebuf[atomicAdd(&cur[t0], 1)] = (u32)(2*i);
    ebuf[atomicAdd(&cur[t1], 1)] = (u32)(2*i+1);
    rbuf[atomicAdd(&rcur[t2], 1)] = (u32)i;
  }
}

// ------- K2: per-entity norm scale + weighted column stats (S0,S1,Q0,Q1) ----
__global__ __launch_bounds__(256) void k_entstats(const float* __restrict__ ent,
    const int* __restrict__ cnt0, const int* __restrict__ cnt1,
    float* __restrict__ scale, float* __restrict__ stats){
  __shared__ float acc[512];
  int t = threadIdx.x;
  acc[t] = 0.f; acc[t+256] = 0.f;
  __syncthreads();
  int lane = t & 63;
  int gw = blockIdx.x*4 + (t>>6);
  int nw = gridDim.x*4;
  float p0=0,p1=0,p2=0,p3=0,p4=0,p5=0,p6=0,p7=0;
  for(int e=gw; e<N_ENT; e+=nw){
    float2 x = *(const float2*)(ent + (size_t)e*D + 2*lane);
    float ss = x.x*x.x + x.y*x.y;
    #pragma unroll
    for(int o=32;o>0;o>>=1) ss += __shfl_xor(ss,o,64);
    float nrm = sqrtf(ss);
    float sc = nrm > 1.0f ? 1.0f/nrm : 1.0f;
    if(lane==0) scale[e] = sc;
    float w0 = (float)cnt0[e];
    float w1 = (float)cnt1[e];
    float sx = x.x*sc, sy = x.y*sc;
    p0 += w0*sx;    p1 += w0*sy;
    p2 += w1*sx;    p3 += w1*sy;
    p4 += w0*sx*sx; p5 += w0*sy*sy;
    p6 += w1*sx*sx; p7 += w1*sy*sy;
  }
  atomicAdd(&acc[      2*lane  ], p0);
  atomicAdd(&acc[      2*lane+1], p1);
  atomicAdd(&acc[128 + 2*lane  ], p2);
  atomicAdd(&acc[128 + 2*lane+1], p3);
  atomicAdd(&acc[256 + 2*lane  ], p4);
  atomicAdd(&acc[256 + 2*lane+1], p5);
  atomicAdd(&acc[384 + 2*lane  ], p6);
  atomicAdd(&acc[384 + 2*lane+1], p7);
  __syncthreads();
  atomicAdd(&stats[t],     acc[t]);
  atomicAdd(&stats[t+256], acc[t+256]);
}

// ------- K3: per-rel scale + Qr stats + cos/sin phase tables ---------------
__global__ __launch_bounds__(256) void k_relstats(const float* __restrict__ rel,
    const int* __restrict__ cntr, float* __restrict__ scale_rel,
    float* __restrict__ stats, float* __restrict__ cosr, float* __restrict__ sinr){
  int t = threadIdx.x, lane = t & 63;
  int r = blockIdx.x*4 + (t>>6);
  if(r >= N_REL) return;
  float2 x = *(const float2*)(rel + (size_t)r*D + 2*lane);
  float ss = x.x*x.x + x.y*x.y;
  #pragma unroll
  for(int o=32;o>0;o>>=1) ss += __shfl_xor(ss,o,64);
  float nrm = sqrtf(ss);
  float sc = nrm > 1.0f ? 1.0f/nrm : 1.0f;
  if(lane==0) scale_rel[r] = sc;
  float w = (float)cntr[r];
  float sx = x.x*sc, sy = x.y*sc;
  atomicAdd(&stats[512 + 2*lane  ], w*sx*sx);
  atomicAdd(&stats[512 + 2*lane+1], w*sy*sy);
  if(lane < 32){   // raw (unnormalized) coords 0..63 feed the phases
    cosr[r*64 + 2*lane  ] = cosf(x.x*PHASE_C);
    sinr[r*64 + 2*lane  ] = sinf(x.x*PHASE_C);
    cosr[r*64 + 2*lane+1] = cosf(x.y*PHASE_C);
    sinr[r*64 + 2*lane+1] = sinf(x.y*PHASE_C);
  }
}

// ------- K4: finalize BN0, build folded bf16 weights Wbf, W2 and b' ---------
__global__ __launch_bounds__(384) void k_bn0fin(const float* __restrict__ stats,
    const float* __restrict__ W_a, const float* __restrict__ b_a,
    const float* __restrict__ gamma0, const float* __restrict__ beta0,
    u16* __restrict__ Wbf, float* __restrict__ W2, float* __restrict__ bprime){
  __shared__ float a0[384], c0[384];
  int t = threadIdx.x;
  {
    int j = t & 127;
    float mu, ex2;
    if(t < 256){
      mu  = (stats[j]     + stats[128+j]) * (1.0f/(2.0f*N_TRIP));
      ex2 = (stats[256+j] + stats[384+j]) * (1.0f/(2.0f*N_TRIP));
    } else {
      mu  = 0.0f;
      ex2 = stats[512+j] * (1.0f/N_TRIP);
    }
    float var = ex2 - mu*mu;
    float a = gamma0[t]*rsqrtf(var + BN_EPSF);
    a0[t] = a;
    c0[t] = beta0[t] - mu*a;
  }
  __syncthreads();
  // Wbf[j][k] (bf16): j<128 -> A proj (W cols 0..127), j>=128 -> B proj (cols 128..255)
  for(int idx=t; idx<256*128; idx+=384){
    int j = idx>>7, k = idx&127;
    int ko = ((j>>7)<<7) + k;
    Wbf[idx] = f2bf(W_a[(j&127)*384 + ko]*a0[ko]);
  }
  // W2[k][j] = W_a[j][256+k]*a0[256+k]   (rel slot, coalesced for k_relproj)
  for(int idx=t; idx<128*128; idx+=384){
    int k = idx>>7, j = idx&127;
    W2[idx] = W_a[j*384 + 256 + k]*a0[256+k];
  }
  if(t < 128){
    float s = b_a[t];
    for(int k=0;k<384;k++) s += W_a[t*384+k]*c0[k];
    bprime[t] = s;
  }
}

// ------- K5: R[r] = rel_n[r] @ W2 ------------------------------------------
__global__ __launch_bounds__(128) void k_relproj(const float* __restrict__ rel,
    const float* __restrict__ scale_rel, const float* __restrict__ W2,
    float* __restrict__ R){
  int r = blockIdx.x, j = threadIdx.x;
  __shared__ float x[128];
  x[j] = rel[(size_t)r*D + j]*scale_rel[r];
  __syncthreads();
  float s = 0.f;
  for(int k=0;k<128;k++) s += x[k]*W2[k*128+j];
  R[r*128+j] = s;
}

// ------- K6: A/B projection via MFMA (200000x128 @ 128x256 -> bf16) ---------
__global__ __launch_bounds__(256) void k_ab(const float* __restrict__ ent,
    const float* __restrict__ scale, const u16* __restrict__ Wbf,
    u16* __restrict__ Abuf, u16* __restrict__ Bbuf){
  int t = threadIdx.x;
  int lane = t & 63;
  int wm = t >> 6;
  int e0 = blockIdx.x*64 + wm*16;
  int erow = e0 + (lane & 15);
  int kgrp = (lane >> 4) << 3;     // 0,8,16,24
  float sc = scale[erow];
  const float* xp = ent + (size_t)erow*D + kgrp;
  short8 xf[4];
  #pragma unroll
  for(int kt=0;kt<4;kt++){
    float4 x0 = *(const float4*)(xp + kt*32);
    float4 x1 = *(const float4*)(xp + kt*32 + 4);
    short8 v;
    v[0]=(short)f2bf(x0.x*sc); v[1]=(short)f2bf(x0.y*sc);
    v[2]=(short)f2bf(x0.z*sc); v[3]=(short)f2bf(x0.w*sc);
    v[4]=(short)f2bf(x1.x*sc); v[5]=(short)f2bf(x1.y*sc);
    v[6]=(short)f2bf(x1.z*sc); v[7]=(short)f2bf(x1.w*sc);
    xf[kt]=v;
  }
  const u16* wp0 = Wbf + (size_t)(lane&15)*D + kgrp;
  int rgrp = (lane>>4)<<2;
  #pragma unroll
  for(int jt=0;jt<16;jt++){
    const u16* wp = wp0 + (size_t)jt*16*D;
    f32x4 acc = {0.f,0.f,0.f,0.f};
    #pragma unroll
    for(int kt=0;kt<4;kt++){
      short8 wf = *(const short8*)(wp + kt*32);
      acc = __builtin_amdgcn_mfma_f32_16x16x32_bf16(wf, xf[kt], acc, 0,0,0);
    }
    int jbase = jt*16 + rgrp;
    u16x4 pk;
    pk.x=f2bf(acc[0]); pk.y=f2bf(acc[1]); pk.z=f2bf(acc[2]); pk.w=f2bf(acc[3]);
    u16* dst = (jbase < 128) ? (Abuf + (size_t)erow*D + jbase)
                             : (Bbuf + (size_t)erow*D + (jbase-128));
    *(u16x4*)dst = pk;
  }
}

// ------- K7: BN1 statistics over the 2n virtual rows ------------------------
__global__ __launch_bounds__(256) void k_bn1stats(const int* __restrict__ trip,
    const u16* __restrict__ A, const u16* __restrict__ B,
    const float* __restrict__ R, const float* __restrict__ bprime,
    float* __restrict__ sums){
  __shared__ float acc[256];
  int t = threadIdx.x;
  acc[t] = 0.f;
  __syncthreads();
  int lane = t & 63;
  int gw = blockIdx.x*4 + (t>>6), nw = gridDim.x*4;
  float bp0 = bprime[2*lane], bp1 = bprime[2*lane+1];
  float s0=0,s1=0,q0=0,q1=0;
  for(int i=gw; i<N_TRIP; i+=nw){
    int t0 = trip[3*i], t1 = trip[3*i+1], t2 = trip[3*i+2];
    u32 ua0 = *(const u32*)(A + (size_t)t0*D + 2*lane);
    u32 ua1 = *(const u32*)(A + (size_t)t1*D + 2*lane);
    u32 ub0 = *(const u32*)(B + (size_t)t0*D + 2*lane);
    u32 ub1 = *(const u32*)(B + (size_t)t1*D + 2*lane);
    float2 r = *(const float2*)(R + (size_t)t2*D + 2*lane);
    float y1x = bfl(ua0)+bfl(ub1)+r.x+bp0;
    float y1y = bfh(ua0)+bfh(ub1)+r.y+bp1;
    float y2x = bfl(ua1)+bfl(ub0)-r.x+bp0;
    float y2y = bfh(ua1)+bfh(ub0)-r.y+bp1;
    s0 += y1x+y2x; s1 += y1y+y2y;
    q0 += y1x*y1x + y2x*y2x; q1 += y1y*y1y + y2y*y2y;
  }
  atomicAdd(&acc[      2*lane  ], s0);
  atomicAdd(&acc[      2*lane+1], s1);
  atomicAdd(&acc[128 + 2*lane  ], q0);
  atomicAdd(&acc[128 + 2*lane+1], q1);
  __syncthreads();
  atomicAdd(&sums[t], acc[t]);
}

// ------- K8: finalize BN1 ---------------------------------------------------
__global__ __launch_bounds__(128) void k_bn1fin(const float* __restrict__ sums,
    const float* __restrict__ gamma1, const float* __restrict__ beta1,
    float* __restrict__ a1c){
  int j = threadIdx.x;
  float mu  = sums[j]    *(1.0f/(2.0f*N_TRIP));
  float var = sums[128+j]*(1.0f/(2.0f*N_TRIP)) - mu*mu;
  float a = gamma1[j]*rsqrtf(var + BN_EPSF);
  a1c[j]     = a;
  a1c[128+j] = beta1[j] - mu*a;
}

// ------- K9: per-entity gather pass: h_ent written directly, no atomics -----
__global__ __launch_bounds__(256) void k_ent(const int* __restrict__ trip,
    const int* __restrict__ offs, const int* __restrict__ endp,
    const u32* __restrict__ ebuf,
    const u16* __restrict__ A, const u16* __restrict__ B,
    const float* __restrict__ R, const float* __restrict__ bprime,
    const float* __restrict__ a1c, const float* __restrict__ W_a2,
    const float* __restrict__ b_a2, float* __restrict__ out_hent){
  int t = threadIdx.x, lane = t & 63;
  int gw = blockIdx.x*4 + (t>>6), nw = gridDim.x*4;
  float bp0 = bprime[2*lane], bp1 = bprime[2*lane+1];
  float a1x = a1c[2*lane],     a1y = a1c[2*lane+1];
  float ccx = a1c[128+2*lane], ccy = a1c[128+2*lane+1];
  float wvx = W_a2[2*lane],    wvy = W_a2[2*lane+1];
  float ba2 = b_a2[0];
  for(int e=gw; e<N_ENT; e+=nw){
    int s = offs[e], en = endp[e];
    u32 ua = *(const u32*)(A + (size_t)e*D + 2*lane);
    float ax = bfl(ua), ay = bfh(ua);
    float hx = 0.f, hy = 0.f, eb = 0.f;
    for(int o=s; o<en; o++){
      u32 id = ebuf[o];
      int i = id>>1, role = id&1;
      int t0 = trip[3*i], t1 = trip[3*i+1], t2 = trip[3*i+2];
      int other = role ? t0 : t1;
      float sg = role ? -1.f : 1.f;
      u32 ub = *(const u32*)(B + (size_t)other*D + 2*lane);
      float2 r = *(const float2*)(R + (size_t)t2*D + 2*lane);
      float yx = ax + bfl(ub) + sg*r.x + bp0;
      float yy = ay + bfh(ub) + sg*r.y + bp1;
      float cx = yx*a1x + ccx, cy = yy*a1y + ccy;
      float rd = cx*wvx + cy*wvy;
      #pragma unroll
      for(int of=32; of>0; of>>=1) rd += __shfl_xor(rd, of, 64);
      float sc = rd + ba2;
      float e_b = expf(sc >= 0.f ? -sc : -0.01f*sc);
      hx += e_b*cx; hy += e_b*cy; eb += e_b;
    }
    float inv = (en > s) ? 1.0f/eb : 0.0f;
    float2 o2; o2.x = hx*inv; o2.y = hy*inv;
    *(float2*)(out_hent + (size_t)e*D + 2*lane) = o2;
  }
}

// ------- K10: per-rel gather pass: h_rel written directly, no atomics -------
__global__ __launch_bounds__(512) void k_rel(const int* __restrict__ trip,
    const int* __restrict__ roffs, const int* __restrict__ cntr,
    const u32* __restrict__ rbuf,
    const u16* __restrict__ A, const u16* __restrict__ B,
    const float* __restrict__ R, const float* __restrict__ bprime,
    const float* __restrict__ a1c, const float* __restrict__ W_a2,
    const float* __restrict__ b_a2, float* __restrict__ out_hrel){
  __shared__ float red[8][128];
  int t = threadIdx.x, lane = t & 63, w = t >> 6;
  int r = blockIdx.x;
  int cnt = cntr[r], base = roffs[r];
  float2 rr = *(const float2*)(R + (size_t)r*D + 2*lane);
  float bp0 = bprime[2*lane], bp1 = bprime[2*lane+1];
  float a1x = a1c[2*lane],     a1y = a1c[2*lane+1];
  float ccx = a1c[128+2*lane], ccy = a1c[128+2*lane+1];
  float wvx = W_a2[2*lane],    wvy = W_a2[2*lane+1];
  float ba2 = b_a2[0];
  float sx = 0.f, sy = 0.f;
  for(int j=w; j<cnt; j+=8){
    int i = (int)rbuf[base+j];
    int t0 = trip[3*i], t1 = trip[3*i+1];
    u32 ua0 = *(const u32*)(A + (size_t)t0*D + 2*lane);
    u32 ua1 = *(const u32*)(A + (size_t)t1*D + 2*lane);
    u32 ub0 = *(const u32*)(B + (size_t)t0*D + 2*lane);
    u32 ub1 = *(const u32*)(B + (size_t)t1*D + 2*lane);
    float y1x = bfl(ua0)+bfl(ub1)+rr.x+bp0;
    float y1y = bfh(ua0)+bfh(ub1)+rr.y+bp1;
    float y2x = bfl(ua1)+bfl(ub0)-rr.x+bp0;
    float y2y = bfh(ua1)+bfh(ub0)-rr.y+bp1;
    float c1x = y1x*a1x+ccx, c1y = y1y*a1y+ccy;
    float c2x = y2x*a1x+ccx, c2y = y2y*a1y+ccy;
    float r1 = c1x*wvx + c1y*wvy;
    float r2 = c2x*wvx + c2y*wvy;
    #pragma unroll
    for(int o=32;o>0;o>>=1){ r1 += __shfl_xor(r1,o,64); r2 += __shfl_xor(r2,o,64); }
    float s1 = r1 + ba2, s2 = r2 + ba2;
    float e1 = expf(s1 >= 0.f ? -s1 : -0.01f*s1);
    float e2 = expf(s2 >= 0.f ? -s2 : -0.01f*s2);
    sx += e1*c1x - e2*c2x;
    sy += e1*c1y - e2*c2y;
  }
  float2 p; p.x = sx; p.y = sy;
  *(float2*)&red[w][2*lane] = p;
  __syncthreads();
  if(t < 128){
    float s = 0.f;
    #pragma unroll
    for(int k=0;k<8;k++) s += red[k][t];
    float cf = cnt > 0 ? (float)cnt : 1.0f;
    out_hrel[(size_t)r*D + t] = s/cf;
  }
}

// ------- K12: RotatE score --------------------------------------------------
__global__ __launch_bounds__(256) void k_score(const int* __restrict__ trip,
    const float* __restrict__ ent, const float* __restrict__ cosr,
    const float* __restrict__ sinr, float* __restrict__ score){
  int t = threadIdx.x, lane = t & 63;
  int gw = blockIdx.x*4 + (t>>6), nw = gridDim.x*4;
  for(int i=gw; i<N_TRIP; i+=nw){
    int t0 = trip[3*i], t1 = trip[3*i+1], t2 = trip[3*i+2];
    float re_h = ent[(size_t)t0*D + lane];
    float im_h = ent[(size_t)t0*D + 64 + lane];
    float re_t = ent[(size_t)t1*D + lane];
    float im_t = ent[(size_t)t1*D + 64 + lane];
    float cr = cosr[t2*64 + lane], sr = sinr[t2*64 + lane];
    float re_s = cr*re_t + sr*im_t - re_h;
    float im_s = cr*im_t - sr*re_t - im_h;
    float d = sqrtf(re_s*re_s + im_s*im_s);
    #pragma unroll
    for(int o=32;o>0;o>>=1) d += __shfl_xor(d,o,64);
    if(lane==0) score[i] = MARGINF - d;
  }
}

extern "C" void kernel_launch(void* const* d_in, const int* in_sizes, int n_in,
                              void* d_out, int out_size, void* d_ws, size_t ws_size,
                              hipStream_t stream){
  const int*   trip   = (const int*)  d_in[0];
  const float* ent    = (const float*)d_in[1];
  const float* rel    = (const float*)d_in[2];
  const float* W_a    = (const float*)d_in[3];
  const float* b_a    = (const float*)d_in[4];
  const float* W_a2   = (const float*)d_in[5];
  const float* b_a2   = (const float*)d_in[6];
  const float* gamma0 = (const float*)d_in[7];
  const float* beta0  = (const float*)d_in[8];
  const float* gamma1 = (const float*)d_in[9];
  const float* beta1  = (const float*)d_in[10];

  char* ws = (char*)d_ws;
  size_t off = 0;
  auto take = [&](size_t bytes)->void*{
    void* p = ws + off;
    off += (bytes + 255) & ~(size_t)255;
    return p;
  };
  // ---- zeroed scratch (contiguous from 0) ----
  int*   cnt0    = (int*)  take((size_t)N_ENT*4);
  int*   cnt1    = (int*)  take((size_t)N_ENT*4);
  int*   cntr    = (int*)  take((size_t)N_REL*4);
  float* stats   = (float*)take(640*4);
  float* sums    = (float*)take(256*4);
  size_t zero_bytes = off;
  // ---- fully-overwritten scratch ----
  int*   offs      = (int*)  take((size_t)N_ENT*4);
  int*   cur       = (int*)  take((size_t)N_ENT*4);
  int*   bsum      = (int*)  take(512*4);
  int*   boffs     = (int*)  take(512*4);
  int*   roffs     = (int*)  take(512*4);
  int*   rcur      = (int*)  take(512*4);
  u32*   ebuf      = (u32*)  take((size_t)2*N_TRIP*4);
  u32*   rbuf      = (u32*)  take((size_t)N_TRIP*4);
  float* scale     = (float*)take((size_t)N_ENT*4);
  float* scale_rel = (float*)take((size_t)N_REL*4);
  u16*   Wbf       = (u16*)  take(256*128*2);
  float* W2        = (float*)take(128*128*4);
  float* bprime    = (float*)take(128*4);
  float* a1c       = (float*)take(256*4);
  float* R         = (float*)take((size_t)N_REL*D*4);
  float* cosr      = (float*)take((size_t)N_REL*64*4);
  float* sinr      = (float*)take((size_t)N_REL*64*4);
  u16*   Abuf      = (u16*)  take((size_t)N_ENT*D*2);
  u16*   Bbuf      = (u16*)  take((size_t)N_ENT*D*2);
  (void)ws_size; (void)n_in; (void)in_sizes; (void)out_size;

  float* out_hent  = (float*)d_out;
  float* out_hrel  = out_hent + (size_t)N_ENT*D;
  float* out_score = out_hrel + (size_t)N_REL*D;

  hipMemsetAsync(d_ws, 0, zero_bytes, stream);

  const int SCAN_BLKS = (N_ENT + 1023)/1024;   // 196
  k_hist    <<<(N_TRIP+255)/256, 256, 0, stream>>>(trip, cnt0, cnt1, cntr);
  k_scan1   <<<SCAN_BLKS, 1024, 0, stream>>>(cnt0, cnt1, offs, bsum);
  k_scan2   <<<1, 512, 0, stream>>>(bsum, boffs, cntr, roffs, rcur, SCAN_BLKS);
  k_scan3   <<<SCAN_BLKS, 1024, 0, stream>>>(offs, boffs, cur);
  k_edges   <<<(N_TRIP+255)/256, 256, 0, stream>>>(trip, cur, rcur, ebuf, rbuf);
  k_entstats<<<2048, 256, 0, stream>>>(ent, cnt0, cnt1, scale, stats);
  k_relstats<<<(N_REL+3)/4, 256, 0, stream>>>(rel, cntr, scale_rel, stats, cosr, sinr);
  k_bn0fin  <<<1, 384, 0, stream>>>(stats, W_a, b_a, gamma0, beta0, Wbf, W2, bprime);
  k_relproj <<<N_REL, 128, 0, stream>>>(rel, scale_rel, W2, R);
  k_ab      <<<N_ENT/64, 256, 0, stream>>>(ent, scale, Wbf, Abuf, Bbuf);
  k_bn1stats<<<2048, 256, 0, stream>>>(trip, Abuf, Bbuf, R, bprime, sums);
  k_bn1fin  <<<1, 128, 0, stream>>>(sums, gamma1, beta1, a1c);
  k_ent     <<<2048, 256, 0, stream>>>(trip, offs, cur, ebuf, Abuf, Bbuf, R,
                                       bprime, a1c, W_a2, b_a2, out_hent);
  k_rel     <<<N_REL, 512, 0, stream>>>(trip, roffs, cntr, rbuf, Abuf, Bbuf, R,
                                        bprime, a1c, W_a2, b_a2, out_hrel);
  k_score   <<<2048, 256, 0, stream>>>(trip, ent, cosr, sinr, out_score);
}

// Round 5
// 677.646 us; speedup vs baseline: 2.3948x; 1.0756x over previous
//
#include <hip/hip_runtime.h>
#include <stdint.h>

#define N_TRIP 200000
#define N_ENT  200000
#define N_REL  500
#define D      128
#define MARGINF 6.0f
#define BN_EPSF 1e-5f
#define PHASE_C 50.26548245743669f   // PI / REL_RANGE, REL_RANGE = 8/128

typedef unsigned short u16;
typedef unsigned int   u32;
typedef __attribute__((ext_vector_type(8))) short short8;
typedef __attribute__((ext_vector_type(4))) float f32x4;
typedef __attribute__((ext_vector_type(4))) unsigned short u16x4;

__device__ inline float bfl(u32 u){ return __uint_as_float(u<<16); }
__device__ inline float bfh(u32 u){ return __uint_as_float(u&0xffff0000u); }
__device__ inline u16 f2bf(float f){
  u32 u = __float_as_uint(f);
  u32 r = (u + 0x7fffu + ((u>>16)&1u))>>16;
  return (u16)r;
}

// ---------------- K1: histogram of head / tail / rel indices ----------------
__global__ __launch_bounds__(256) void k_hist(const int* __restrict__ trip,
    int* __restrict__ cnt0, int* __restrict__ cnt1, int* __restrict__ cntr){
  int i = blockIdx.x*256 + threadIdx.x;
  if(i < N_TRIP){
    atomicAdd(&cnt0[trip[3*i]],   1);
    atomicAdd(&cnt1[trip[3*i+1]], 1);
    atomicAdd(&cntr[trip[3*i+2]], 1);
  }
}

// ---------------- CSR build: 3-kernel prefix scan + cursor scatter ----------
__global__ __launch_bounds__(1024) void k_scan1(const int* __restrict__ cnt0,
    const int* __restrict__ cnt1, int* __restrict__ offs, int* __restrict__ bsum){
  __shared__ int sh[1024];
  int t = threadIdx.x;
  int e = blockIdx.x*1024 + t;
  int d = (e < N_ENT) ? cnt0[e] + cnt1[e] : 0;
  sh[t] = d; __syncthreads();
  for(int st=1; st<1024; st<<=1){
    int x = (t>=st) ? sh[t-st] : 0;
    __syncthreads();
    sh[t] += x;
    __syncthreads();
  }
  if(e < N_ENT) offs[e] = sh[t] - d;          // block-local exclusive
  if(t == 1023) bsum[blockIdx.x] = sh[t];
}

__global__ __launch_bounds__(512) void k_scan2(const int* __restrict__ bsum,
    int* __restrict__ boffs, const int* __restrict__ cntr,
    int* __restrict__ roffs, int* __restrict__ rcur, int nblk){
  __shared__ int sh[512];
  int t = threadIdx.x;
  int v = (t < nblk) ? bsum[t] : 0;
  sh[t] = v; __syncthreads();
  for(int st=1; st<512; st<<=1){
    int x = (t>=st) ? sh[t-st] : 0;
    __syncthreads(); sh[t] += x; __syncthreads();
  }
  if(t < nblk) boffs[t] = sh[t] - v;
  __syncthreads();
  int w = (t < N_REL) ? cntr[t] : 0;
  sh[t] = w; __syncthreads();
  for(int st=1; st<512; st<<=1){
    int x = (t>=st) ? sh[t-st] : 0;
    __syncthreads(); sh[t] += x; __syncthreads();
  }
  if(t < N_REL){ roffs[t] = sh[t]-w; rcur[t] = sh[t]-w; }
}

__global__ __launch_bounds__(1024) void k_scan3(int* __restrict__ offs,
    const int* __restrict__ boffs, int* __restrict__ cur){
  int e = blockIdx.x*1024 + threadIdx.x;
  if(e < N_ENT){
    int o = offs[e] + boffs[blockIdx.x];
    offs[e] = o;
    cur[e] = o;
  }
}

__global__ __launch_bounds__(256) void k_edges(const int* __restrict__ trip,
    int* __restrict__ cur, int* __restrict__ rcur,
    u32* __restrict__ ebuf, u32* __restrict__ rbuf){
  int i = blockIdx.x*256 + threadIdx.x;
  if(i < N_TRIP){
    int t0 = trip[3*i], t1 = trip[3*i+1], t2 = trip[3*i+2];
    ebuf[atomicAdd(&cur[t0], 1)] = (u32)(2*i);
    ebuf[atomicAdd(&cur[t1], 1)] = (u32)(2*i+1);
    rbuf[atomicAdd(&rcur[t2], 1)] = (u32)i;
  }
}

// ------- K2: per-entity norm scale + weighted column stats (S0,S1,Q0,Q1) ----
__global__ __launch_bounds__(256) void k_entstats(const float* __restrict__ ent,
    const int* __restrict__ cnt0, const int* __restrict__ cnt1,
    float* __restrict__ scale, float* __restrict__ stats){
  __shared__ float acc[512];
  int t = threadIdx.x;
  acc[t] = 0.f; acc[t+256] = 0.f;
  __syncthreads();
  int lane = t & 63;
  int gw = blockIdx.x*4 + (t>>6);
  int nw = gridDim.x*4;
  float p0=0,p1=0,p2=0,p3=0,p4=0,p5=0,p6=0,p7=0;
  for(int e=gw; e<N_ENT; e+=nw){
    float2 x = *(const float2*)(ent + (size_t)e*D + 2*lane);
    float ss = x.x*x.x + x.y*x.y;
    #pragma unroll
    for(int o=32;o>0;o>>=1) ss += __shfl_xor(ss,o,64);
    float nrm = sqrtf(ss);
    float sc = nrm > 1.0f ? 1.0f/nrm : 1.0f;
    if(lane==0) scale[e] = sc;
    float w0 = (float)cnt0[e];
    float w1 = (float)cnt1[e];
    float sx = x.x*sc, sy = x.y*sc;
    p0 += w0*sx;    p1 += w0*sy;
    p2 += w1*sx;    p3 += w1*sy;
    p4 += w0*sx*sx; p5 += w0*sy*sy;
    p6 += w1*sx*sx; p7 += w1*sy*sy;
  }
  atomicAdd(&acc[      2*lane  ], p0);
  atomicAdd(&acc[      2*lane+1], p1);
  atomicAdd(&acc[128 + 2*lane  ], p2);
  atomicAdd(&acc[128 + 2*lane+1], p3);
  atomicAdd(&acc[256 + 2*lane  ], p4);
  atomicAdd(&acc[256 + 2*lane+1], p5);
  atomicAdd(&acc[384 + 2*lane  ], p6);
  atomicAdd(&acc[384 + 2*lane+1], p7);
  __syncthreads();
  atomicAdd(&stats[t],     acc[t]);
  atomicAdd(&stats[t+256], acc[t+256]);
}

// ------- K3: per-rel scale + Qr stats + cos/sin phase tables ---------------
__global__ __launch_bounds__(256) void k_relstats(const float* __restrict__ rel,
    const int* __restrict__ cntr, float* __restrict__ scale_rel,
    float* __restrict__ stats, float* __restrict__ cosr, float* __restrict__ sinr){
  int t = threadIdx.x, lane = t & 63;
  int r = blockIdx.x*4 + (t>>6);
  if(r >= N_REL) return;
  float2 x = *(const float2*)(rel + (size_t)r*D + 2*lane);
  float ss = x.x*x.x + x.y*x.y;
  #pragma unroll
  for(int o=32;o>0;o>>=1) ss += __shfl_xor(ss,o,64);
  float nrm = sqrtf(ss);
  float sc = nrm > 1.0f ? 1.0f/nrm : 1.0f;
  if(lane==0) scale_rel[r] = sc;
  float w = (float)cntr[r];
  float sx = x.x*sc, sy = x.y*sc;
  atomicAdd(&stats[512 + 2*lane  ], w*sx*sx);
  atomicAdd(&stats[512 + 2*lane+1], w*sy*sy);
  if(lane < 32){   // raw (unnormalized) coords 0..63 feed the phases
    cosr[r*64 + 2*lane  ] = cosf(x.x*PHASE_C);
    sinr[r*64 + 2*lane  ] = sinf(x.x*PHASE_C);
    cosr[r*64 + 2*lane+1] = cosf(x.y*PHASE_C);
    sinr[r*64 + 2*lane+1] = sinf(x.y*PHASE_C);
  }
}

// ------- K4: finalize BN0, build folded bf16 weights Wbf, W2 and b' ---------
__global__ __launch_bounds__(384) void k_bn0fin(const float* __restrict__ stats,
    const float* __restrict__ W_a, const float* __restrict__ b_a,
    const float* __restrict__ gamma0, const float* __restrict__ beta0,
    u16* __restrict__ Wbf, float* __restrict__ W2, float* __restrict__ bprime){
  __shared__ float a0[384], c0[384];
  int t = threadIdx.x;
  {
    int j = t & 127;
    float mu, ex2;
    if(t < 256){
      mu  = (stats[j]     + stats[128+j]) * (1.0f/(2.0f*N_TRIP));
      ex2 = (stats[256+j] + stats[384+j]) * (1.0f/(2.0f*N_TRIP));
    } else {
      mu  = 0.0f;
      ex2 = stats[512+j] * (1.0f/N_TRIP);
    }
    float var = ex2 - mu*mu;
    float a = gamma0[t]*rsqrtf(var + BN_EPSF);
    a0[t] = a;
    c0[t] = beta0[t] - mu*a;
  }
  __syncthreads();
  // Wbf[j][k] (bf16): j<128 -> A proj (W cols 0..127), j>=128 -> B proj (cols 128..255)
  for(int idx=t; idx<256*128; idx+=384){
    int j = idx>>7, k = idx&127;
    int ko = ((j>>7)<<7) + k;
    Wbf[idx] = f2bf(W_a[(j&127)*384 + ko]*a0[ko]);
  }
  // W2[k][j] = W_a[j][256+k]*a0[256+k]   (rel slot, coalesced for k_relproj)
  for(int idx=t; idx<128*128; idx+=384){
    int k = idx>>7, j = idx&127;
    W2[idx] = W_a[j*384 + 256 + k]*a0[256+k];
  }
  if(t < 128){
    float s = b_a[t];
    for(int k=0;k<384;k++) s += W_a[t*384+k]*c0[k];
    bprime[t] = s;
  }
}

// ------- K5: R[r] = rel_n[r] @ W2 ------------------------------------------
__global__ __launch_bounds__(128) void k_relproj(const float* __restrict__ rel,
    const float* __restrict__ scale_rel, const float* __restrict__ W2,
    float* __restrict__ R){
  int r = blockIdx.x, j = threadIdx.x;
  __shared__ float x[128];
  x[j] = rel[(size_t)r*D + j]*scale_rel[r];
  __syncthreads();
  float s = 0.f;
  for(int k=0;k<128;k++) s += x[k]*W2[k*128+j];
  R[r*128+j] = s;
}

// ------- K6: A/B projection via MFMA, weights in registers ------------------
// Block = 4 waves; wave q owns output cols [q*64, q*64+64) with its 16 weight
// fragments preloaded in VGPRs. 16-entity X tile staged in 4KB LDS (bf16,
// XOR-swizzled byte^=(row&7)<<4 to break the 256B-stride bank conflict).
__global__ __launch_bounds__(256) void k_ab(const float* __restrict__ ent,
    const float* __restrict__ scale, const u16* __restrict__ Wbf,
    u16* __restrict__ Abuf, u16* __restrict__ Bbuf){
  __shared__ u16 xlds[16*128];
  int t = threadIdx.x, lane = t & 63, q = t >> 6;
  int kgrp = (lane>>4)<<3;
  int rgrp = (lane>>4)<<2;
  int frow = lane & 15;
  short8 wf[4][4];
  #pragma unroll
  for(int jt=0;jt<4;jt++){
    #pragma unroll
    for(int kt=0;kt<4;kt++)
      wf[jt][kt] = *(const short8*)(Wbf + (size_t)(q*64 + jt*16 + frow)*D + kgrp + kt*32);
  }
  int srow = t>>4;                  // staging: thread -> (row, 8 cols)
  int scol = (t&15)<<3;
  char* swp = (char*)xlds + srow*256 + ((scol<<1) ^ ((srow&7)<<4));
  const char* rdp = (const char*)xlds + frow*256;
  int rbase0 = (lane>>4)<<4;
  int fsw = (frow&7)<<4;
  for(int chunk = blockIdx.x; chunk < N_ENT/16; chunk += gridDim.x){
    const float* xp = ent + (size_t)(chunk*16 + srow)*D + scol;
    float sc = scale[chunk*16 + srow];
    float4 x0 = *(const float4*)xp;
    float4 x1 = *(const float4*)(xp+4);
    uint4 pk;
    pk.x = (u32)f2bf(x0.x*sc) | ((u32)f2bf(x0.y*sc)<<16);
    pk.y = (u32)f2bf(x0.z*sc) | ((u32)f2bf(x0.w*sc)<<16);
    pk.z = (u32)f2bf(x1.x*sc) | ((u32)f2bf(x1.y*sc)<<16);
    pk.w = (u32)f2bf(x1.z*sc) | ((u32)f2bf(x1.w*sc)<<16);
    __syncthreads();                // prev iteration's reads done
    *(uint4*)swp = pk;
    __syncthreads();                // tile visible
    short8 xf[4];
    #pragma unroll
    for(int kt=0;kt<4;kt++)
      xf[kt] = *(const short8*)(rdp + ((rbase0 + kt*64) ^ fsw));
    int erow = chunk*16 + frow;
    #pragma unroll
    for(int jt=0;jt<4;jt++){
      f32x4 acc = {0.f,0.f,0.f,0.f};
      #pragma unroll
      for(int kt=0;kt<4;kt++)
        acc = __builtin_amdgcn_mfma_f32_16x16x32_bf16(wf[jt][kt], xf[kt], acc, 0,0,0);
      int jbase = q*64 + jt*16 + rgrp;
      u16x4 opk;
      opk.x=f2bf(acc[0]); opk.y=f2bf(acc[1]); opk.z=f2bf(acc[2]); opk.w=f2bf(acc[3]);
      u16* dst = (jbase < 128) ? (Abuf + (size_t)erow*D + jbase)
                               : (Bbuf + (size_t)erow*D + (jbase-128));
      *(u16x4*)dst = opk;
    }
  }
}

// ------- K7: BN1 statistics over the 2n virtual rows ------------------------
__global__ __launch_bounds__(256) void k_bn1stats(const int* __restrict__ trip,
    const u16* __restrict__ A, const u16* __restrict__ B,
    const float* __restrict__ R, const float* __restrict__ bprime,
    float* __restrict__ sums){
  __shared__ float acc[256];
  int t = threadIdx.x;
  acc[t] = 0.f;
  __syncthreads();
  int lane = t & 63;
  int gw = blockIdx.x*4 + (t>>6), nw = gridDim.x*4;
  float bp0 = bprime[2*lane], bp1 = bprime[2*lane+1];
  float s0=0,s1=0,q0=0,q1=0;
  for(int i=gw; i<N_TRIP; i+=nw){
    int t0 = trip[3*i], t1 = trip[3*i+1], t2 = trip[3*i+2];
    u32 ua0 = *(const u32*)(A + (size_t)t0*D + 2*lane);
    u32 ua1 = *(const u32*)(A + (size_t)t1*D + 2*lane);
    u32 ub0 = *(const u32*)(B + (size_t)t0*D + 2*lane);
    u32 ub1 = *(const u32*)(B + (size_t)t1*D + 2*lane);
    float2 r = *(const float2*)(R + (size_t)t2*D + 2*lane);
    float y1x = bfl(ua0)+bfl(ub1)+r.x+bp0;
    float y1y = bfh(ua0)+bfh(ub1)+r.y+bp1;
    float y2x = bfl(ua1)+bfl(ub0)-r.x+bp0;
    float y2y = bfh(ua1)+bfh(ub0)-r.y+bp1;
    s0 += y1x+y2x; s1 += y1y+y2y;
    q0 += y1x*y1x + y2x*y2x; q1 += y1y*y1y + y2y*y2y;
  }
  atomicAdd(&acc[      2*lane  ], s0);
  atomicAdd(&acc[      2*lane+1], s1);
  atomicAdd(&acc[128 + 2*lane  ], q0);
  atomicAdd(&acc[128 + 2*lane+1], q1);
  __syncthreads();
  atomicAdd(&sums[t], acc[t]);
}

// ------- K8: finalize BN1 + wa1 = W_a2 .* a1 + kappa ------------------------
__global__ __launch_bounds__(128) void k_bn1fin(const float* __restrict__ sums,
    const float* __restrict__ gamma1, const float* __restrict__ beta1,
    const float* __restrict__ W_a2, const float* __restrict__ b_a2,
    const float* __restrict__ bprime, float* __restrict__ a1c){
  __shared__ float red[128];
  int j = threadIdx.x;
  float mu  = sums[j]    *(1.0f/(2.0f*N_TRIP));
  float var = sums[128+j]*(1.0f/(2.0f*N_TRIP)) - mu*mu;
  float a = gamma1[j]*rsqrtf(var + BN_EPSF);
  float cc = beta1[j] - mu*a;
  float wa1 = W_a2[j]*a;
  a1c[j]     = a;
  a1c[128+j] = cc;
  a1c[256+j] = wa1;
  red[j] = W_a2[j]*cc + wa1*bprime[j];
  __syncthreads();
  #pragma unroll
  for(int s=64; s>0; s>>=1){
    if(j < s) red[j] += red[j+s];
    __syncthreads();
  }
  if(j==0) a1c[384] = red[0] + b_a2[0];
}

// ------- K8b: per-entity scalars alpha = wa1.A[e], beta = wa1.B[e], rho -----
__global__ __launch_bounds__(256) void k_alphabeta(const u16* __restrict__ A,
    const u16* __restrict__ B, const float* __restrict__ R,
    const float* __restrict__ a1c, float* __restrict__ alpha,
    float* __restrict__ beta, float* __restrict__ rho){
  int t = threadIdx.x, lane = t & 63;
  int gw = blockIdx.x*4 + (t>>6), nw = gridDim.x*4;
  float wx = a1c[256+2*lane], wy = a1c[256+2*lane+1];
  for(int e=gw; e<N_ENT; e+=nw){
    u32 ua = *(const u32*)(A + (size_t)e*D + 2*lane);
    u32 ub = *(const u32*)(B + (size_t)e*D + 2*lane);
    float da = wx*bfl(ua) + wy*bfh(ua);
    float db = wx*bfl(ub) + wy*bfh(ub);
    #pragma unroll
    for(int o=32;o>0;o>>=1){ da += __shfl_xor(da,o,64); db += __shfl_xor(db,o,64); }
    if(lane==0){ alpha[e]=da; beta[e]=db; }
  }
  for(int r=gw; r<N_REL; r+=nw){
    float2 rr = *(const float2*)(R + (size_t)r*D + 2*lane);
    float dr = wx*rr.x + wy*rr.y;
    #pragma unroll
    for(int o=32;o>0;o>>=1) dr += __shfl_xor(dr,o,64);
    if(lane==0) rho[r]=dr;
  }
}

// ------- K9: per-entity gather pass: h_ent written directly, no atomics -----
__global__ __launch_bounds__(256) void k_ent(const int* __restrict__ trip,
    const int* __restrict__ offs, const int* __restrict__ endp,
    const u32* __restrict__ ebuf,
    const u16* __restrict__ A, const u16* __restrict__ B,
    const float* __restrict__ R, const float* __restrict__ bprime,
    const float* __restrict__ a1c, const float* __restrict__ alpha,
    const float* __restrict__ beta, const float* __restrict__ rho,
    float* __restrict__ out_hent){
  int t = threadIdx.x, lane = t & 63;
  int gw = blockIdx.x*4 + (t>>6), nw = gridDim.x*4;
  float bp0 = bprime[2*lane], bp1 = bprime[2*lane+1];
  float a1x = a1c[2*lane],     a1y = a1c[2*lane+1];
  float ccx = a1c[128+2*lane], ccy = a1c[128+2*lane+1];
  float kap = a1c[384];
  for(int e=gw; e<N_ENT; e+=nw){
    int s = offs[e], en = endp[e];
    u32 ua = *(const u32*)(A + (size_t)e*D + 2*lane);
    float ax = bfl(ua), ay = bfh(ua);
    float al = alpha[e];
    float hx = 0.f, hy = 0.f, eb = 0.f;
    for(int o=s; o<en; o++){
      u32 id = ebuf[o];
      int i = id>>1, role = id&1;
      int t0 = trip[3*i], t1 = trip[3*i+1], t2 = trip[3*i+2];
      int other = role ? t0 : t1;
      float sg = role ? -1.f : 1.f;
      float sv = al + beta[other] + sg*rho[t2] + kap;
      float e_b = expf(sv >= 0.f ? -sv : -0.01f*sv);
      u32 ub = *(const u32*)(B + (size_t)other*D + 2*lane);
      float2 r = *(const float2*)(R + (size_t)t2*D + 2*lane);
      float yx = ax + bfl(ub) + sg*r.x + bp0;
      float yy = ay + bfh(ub) + sg*r.y + bp1;
      float cx = yx*a1x + ccx, cy = yy*a1y + ccy;
      hx += e_b*cx; hy += e_b*cy; eb += e_b;
    }
    float inv = (en > s) ? 1.0f/eb : 0.0f;
    float2 o2; o2.x = hx*inv; o2.y = hy*inv;
    *(float2*)(out_hent + (size_t)e*D + 2*lane) = o2;
  }
}

// ------- K10: per-rel gather pass: h_rel written directly, no atomics -------
__global__ __launch_bounds__(512) void k_rel(const int* __restrict__ trip,
    const int* __restrict__ roffs, const int* __restrict__ cntr,
    const u32* __restrict__ rbuf,
    const u16* __restrict__ A, const u16* __restrict__ B,
    const float* __restrict__ R, const float* __restrict__ bprime,
    const float* __restrict__ a1c, const float* __restrict__ alpha,
    const float* __restrict__ beta, const float* __restrict__ rho,
    float* __restrict__ out_hrel){
  __shared__ float red[8][128];
  int t = threadIdx.x, lane = t & 63, w = t >> 6;
  int r = blockIdx.x;
  int cnt = cntr[r], base = roffs[r];
  float2 rr = *(const float2*)(R + (size_t)r*D + 2*lane);
  float bp0 = bprime[2*lane], bp1 = bprime[2*lane+1];
  float a1x = a1c[2*lane],     a1y = a1c[2*lane+1];
  float ccx = a1c[128+2*lane], ccy = a1c[128+2*lane+1];
  float kap = a1c[384];
  float rhor = rho[r];
  float sx = 0.f, sy = 0.f;
  for(int j=w; j<cnt; j+=8){
    int i = (int)rbuf[base+j];
    int t0 = trip[3*i], t1 = trip[3*i+1];
    float s1 = alpha[t0] + beta[t1] + rhor + kap;
    float s2 = alpha[t1] + beta[t0] - rhor + kap;
    float e1 = expf(s1 >= 0.f ? -s1 : -0.01f*s1);
    float e2 = expf(s2 >= 0.f ? -s2 : -0.01f*s2);
    u32 ua0 = *(const u32*)(A + (size_t)t0*D + 2*lane);
    u32 ua1 = *(const u32*)(A + (size_t)t1*D + 2*lane);
    u32 ub0 = *(const u32*)(B + (size_t)t0*D + 2*lane);
    u32 ub1 = *(const u32*)(B + (size_t)t1*D + 2*lane);
    float y1x = bfl(ua0)+bfl(ub1)+rr.x+bp0;
    float y1y = bfh(ua0)+bfh(ub1)+rr.y+bp1;
    float y2x = bfl(ua1)+bfl(ub0)-rr.x+bp0;
    float y2y = bfh(ua1)+bfh(ub0)-rr.y+bp1;
    float c1x = y1x*a1x+ccx, c1y = y1y*a1y+ccy;
    float c2x = y2x*a1x+ccx, c2y = y2y*a1y+ccy;
    sx += e1*c1x - e2*c2x;
    sy += e1*c1y - e2*c2y;
  }
  float2 p; p.x = sx; p.y = sy;
  *(float2*)&red[w][2*lane] = p;
  __syncthreads();
  if(t < 128){
    float s = 0.f;
    #pragma unroll
    for(int k=0;k<8;k++) s += red[k][t];
    float cf = cnt > 0 ? (float)cnt : 1.0f;
    out_hrel[(size_t)r*D + t] = s/cf;
  }
}

// ------- K12: RotatE score --------------------------------------------------
__global__ __launch_bounds__(256) void k_score(const int* __restrict__ trip,
    const float* __restrict__ ent, const float* __restrict__ cosr,
    const float* __restrict__ sinr, float* __restrict__ score){
  int t = threadIdx.x, lane = t & 63;
  int gw = blockIdx.x*4 + (t>>6), nw = gridDim.x*4;
  for(int i=gw; i<N_TRIP; i+=nw){
    int t0 = trip[3*i], t1 = trip[3*i+1], t2 = trip[3*i+2];
    float re_h = ent[(size_t)t0*D + lane];
    float im_h = ent[(size_t)t0*D + 64 + lane];
    float re_t = ent[(size_t)t1*D + lane];
    float im_t = ent[(size_t)t1*D + 64 + lane];
    float cr = cosr[t2*64 + lane], sr = sinr[t2*64 + lane];
    float re_s = cr*re_t + sr*im_t - re_h;
    float im_s = cr*im_t - sr*re_t - im_h;
    float d = sqrtf(re_s*re_s + im_s*im_s);
    #pragma unroll
    for(int o=32;o>0;o>>=1) d += __shfl_xor(d,o,64);
    if(lane==0) score[i] = MARGINF - d;
  }
}

extern "C" void kernel_launch(void* const* d_in, const int* in_sizes, int n_in,
                              void* d_out, int out_size, void* d_ws, size_t ws_size,
                              hipStream_t stream){
  const int*   trip   = (const int*)  d_in[0];
  const float* ent    = (const float*)d_in[1];
  const float* rel    = (const float*)d_in[2];
  const float* W_a    = (const float*)d_in[3];
  const float* b_a    = (const float*)d_in[4];
  const float* W_a2   = (const float*)d_in[5];
  const float* b_a2   = (const float*)d_in[6];
  const float* gamma0 = (const float*)d_in[7];
  const float* beta0  = (const float*)d_in[8];
  const float* gamma1 = (const float*)d_in[9];
  const float* beta1  = (const float*)d_in[10];

  char* ws = (char*)d_ws;
  size_t off = 0;
  auto take = [&](size_t bytes)->void*{
    void* p = ws + off;
    off += (bytes + 255) & ~(size_t)255;
    return p;
  };
  // ---- zeroed scratch (contiguous from 0) ----
  int*   cnt0    = (int*)  take((size_t)N_ENT*4);
  int*   cnt1    = (int*)  take((size_t)N_ENT*4);
  int*   cntr    = (int*)  take((size_t)N_REL*4);
  float* stats   = (float*)take(640*4);
  float* sums    = (float*)take(256*4);
  size_t zero_bytes = off;
  // ---- fully-overwritten scratch ----
  int*   offs      = (int*)  take((size_t)N_ENT*4);
  int*   cur       = (int*)  take((size_t)N_ENT*4);
  int*   bsum      = (int*)  take(512*4);
  int*   boffs     = (int*)  take(512*4);
  int*   roffs     = (int*)  take(512*4);
  int*   rcur      = (int*)  take(512*4);
  u32*   ebuf      = (u32*)  take((size_t)2*N_TRIP*4);
  u32*   rbuf      = (u32*)  take((size_t)N_TRIP*4);
  float* scale     = (float*)take((size_t)N_ENT*4);
  float* scale_rel = (float*)take((size_t)N_REL*4);
  u16*   Wbf       = (u16*)  take(256*128*2);
  float* W2        = (float*)take(128*128*4);
  float* bprime    = (float*)take(128*4);
  float* a1c       = (float*)take(512*4);
  float* R         = (float*)take((size_t)N_REL*D*4);
  float* cosr      = (float*)take((size_t)N_REL*64*4);
  float* sinr      = (float*)take((size_t)N_REL*64*4);
  float* alpha     = (float*)take((size_t)N_ENT*4);
  float* betab     = (float*)take((size_t)N_ENT*4);
  float* rho       = (float*)take(512*4);
  u16*   Abuf      = (u16*)  take((size_t)N_ENT*D*2);
  u16*   Bbuf      = (u16*)  take((size_t)N_ENT*D*2);
  (void)ws_size; (void)n_in; (void)in_sizes; (void)out_size;

  float* out_hent  = (float*)d_out;
  float* out_hrel  = out_hent + (size_t)N_ENT*D;
  float* out_score = out_hrel + (size_t)N_REL*D;

  hipMemsetAsync(d_ws, 0, zero_bytes, stream);

  const int SCAN_BLKS = (N_ENT + 1023)/1024;   // 196
  k_hist     <<<(N_TRIP+255)/256, 256, 0, stream>>>(trip, cnt0, cnt1, cntr);
  k_scan1    <<<SCAN_BLKS, 1024, 0, stream>>>(cnt0, cnt1, offs, bsum);
  k_scan2    <<<1, 512, 0, stream>>>(bsum, boffs, cntr, roffs, rcur, SCAN_BLKS);
  k_scan3    <<<SCAN_BLKS, 1024, 0, stream>>>(offs, boffs, cur);
  k_edges    <<<(N_TRIP+255)/256, 256, 0, stream>>>(trip, cur, rcur, ebuf, rbuf);
  k_entstats <<<2048, 256, 0, stream>>>(ent, cnt0, cnt1, scale, stats);
  k_relstats <<<(N_REL+3)/4, 256, 0, stream>>>(rel, cntr, scale_rel, stats, cosr, sinr);
  k_bn0fin   <<<1, 384, 0, stream>>>(stats, W_a, b_a, gamma0, beta0, Wbf, W2, bprime);
  k_relproj  <<<N_REL, 128, 0, stream>>>(rel, scale_rel, W2, R);
  k_ab       <<<2048, 256, 0, stream>>>(ent, scale, Wbf, Abuf, Bbuf);
  k_bn1stats <<<2048, 256, 0, stream>>>(trip, Abuf, Bbuf, R, bprime, sums);
  k_bn1fin   <<<1, 128, 0, stream>>>(sums, gamma1, beta1, W_a2, b_a2, bprime, a1c);
  k_alphabeta<<<2048, 256, 0, stream>>>(Abuf, Bbuf, R, a1c, alpha, betab, rho);
  k_ent      <<<2048, 256, 0, stream>>>(trip, offs, cur, ebuf, Abuf, Bbuf, R,
                                        bprime, a1c, alpha, betab, rho, out_hent);
  k_rel      <<<N_REL, 512, 0, stream>>>(trip, roffs, cntr, rbuf, Abuf, Bbuf, R,
                                         bprime, a1c, alpha, betab, rho, out_hrel);
  k_score    <<<2048, 256, 0, stream>>>(trip, ent, cosr, sinr, out_score);
}

// Round 6
// 640.651 us; speedup vs baseline: 2.5330x; 1.0577x over previous
//
#include <hip/hip_runtime.h>
#include <stdint.h>

#define N_TRIP 200000
#define N_ENT  200000
#define N_REL  500
#define D      128
#define MARGINF 6.0f
#define BN_EPSF 1e-5f
#define PHASE_C 50.26548245743669f   // PI / REL_RANGE, REL_RANGE = 8/128

typedef unsigned short u16;
typedef unsigned int   u32;
typedef unsigned long long u64;
typedef __attribute__((ext_vector_type(8))) short short8;
typedef __attribute__((ext_vector_type(4))) float f32x4;
typedef __attribute__((ext_vector_type(4))) unsigned short u16x4;

__device__ inline float bfl(u32 u){ return __uint_as_float(u<<16); }
__device__ inline float bfh(u32 u){ return __uint_as_float(u&0xffff0000u); }
__device__ inline u16 f2bf(float f){
  u32 u = __float_as_uint(f);
  u32 r = (u + 0x7fffu + ((u>>16)&1u))>>16;
  return (u16)r;
}

// ---------------- K1: histogram of head / tail / rel indices ----------------
__global__ __launch_bounds__(256) void k_hist(const int* __restrict__ trip,
    int* __restrict__ cnt0, int* __restrict__ cnt1, int* __restrict__ cntr){
  int i = blockIdx.x*256 + threadIdx.x;
  if(i < N_TRIP){
    atomicAdd(&cnt0[trip[3*i]],   1);
    atomicAdd(&cnt1[trip[3*i+1]], 1);
    atomicAdd(&cntr[trip[3*i+2]], 1);
  }
}

// ---------------- CSR build: 3-kernel prefix scan + cursor scatter ----------
__global__ __launch_bounds__(1024) void k_scan1(const int* __restrict__ cnt0,
    const int* __restrict__ cnt1, int* __restrict__ offs, int* __restrict__ bsum){
  __shared__ int sh[1024];
  int t = threadIdx.x;
  int e = blockIdx.x*1024 + t;
  int d = (e < N_ENT) ? cnt0[e] + cnt1[e] : 0;
  sh[t] = d; __syncthreads();
  for(int st=1; st<1024; st<<=1){
    int x = (t>=st) ? sh[t-st] : 0;
    __syncthreads();
    sh[t] += x;
    __syncthreads();
  }
  if(e < N_ENT) offs[e] = sh[t] - d;          // block-local exclusive
  if(t == 1023) bsum[blockIdx.x] = sh[t];
}

__global__ __launch_bounds__(512) void k_scan2(const int* __restrict__ bsum,
    int* __restrict__ boffs, const int* __restrict__ cntr,
    int* __restrict__ roffs, int* __restrict__ rcur, int nblk){
  __shared__ int sh[512];
  int t = threadIdx.x;
  int v = (t < nblk) ? bsum[t] : 0;
  sh[t] = v; __syncthreads();
  for(int st=1; st<512; st<<=1){
    int x = (t>=st) ? sh[t-st] : 0;
    __syncthreads(); sh[t] += x; __syncthreads();
  }
  if(t < nblk) boffs[t] = sh[t] - v;
  __syncthreads();
  int w = (t < N_REL) ? cntr[t] : 0;
  sh[t] = w; __syncthreads();
  for(int st=1; st<512; st<<=1){
    int x = (t>=st) ? sh[t-st] : 0;
    __syncthreads(); sh[t] += x; __syncthreads();
  }
  if(t < N_REL){ roffs[t] = sh[t]-w; rcur[t] = sh[t]-w; }
}

__global__ __launch_bounds__(1024) void k_scan3(int* __restrict__ offs,
    const int* __restrict__ boffs, int* __restrict__ cur){
  int e = blockIdx.x*1024 + threadIdx.x;
  if(e < N_ENT){
    int o = offs[e] + boffs[blockIdx.x];
    offs[e] = o;
    cur[e] = o;
  }
}

// edge records: ebuf = other<<10 | t2<<1 | role ; rpair = t0 | t1<<18
// pair64 (linear) = t0 | t1<<18 | t2<<36
__global__ __launch_bounds__(256) void k_edges(const int* __restrict__ trip,
    int* __restrict__ cur, int* __restrict__ rcur,
    u32* __restrict__ ebuf, u64* __restrict__ pair64, u64* __restrict__ rpair){
  int i = blockIdx.x*256 + threadIdx.x;
  if(i < N_TRIP){
    int t0 = trip[3*i], t1 = trip[3*i+1], t2 = trip[3*i+2];
    u64 pr = ((u64)t2<<36) | ((u64)t1<<18) | (u64)t0;
    pair64[i] = pr;
    ebuf[atomicAdd(&cur[t0], 1)] = ((u32)t1<<10) | ((u32)t2<<1);
    ebuf[atomicAdd(&cur[t1], 1)] = ((u32)t0<<10) | ((u32)t2<<1) | 1u;
    rpair[atomicAdd(&rcur[t2], 1)] = pr;
  }
}

// ------- K2: per-entity norm scale + weighted column stats + bf16 ent copy --
__global__ __launch_bounds__(256) void k_entstats(const float* __restrict__ ent,
    const int* __restrict__ cnt0, const int* __restrict__ cnt1,
    float* __restrict__ scale, float* __restrict__ stats, u32* entbf){
  __shared__ float acc[512];
  int t = threadIdx.x;
  acc[t] = 0.f; acc[t+256] = 0.f;
  __syncthreads();
  int lane = t & 63;
  int gw = blockIdx.x*4 + (t>>6);
  int nw = gridDim.x*4;
  float p0=0,p1=0,p2=0,p3=0,p4=0,p5=0,p6=0,p7=0;
  for(int e=gw; e<N_ENT; e+=nw){
    float2 x = *(const float2*)(ent + (size_t)e*D + 2*lane);
    if(entbf) entbf[(size_t)e*64 + lane] = (u32)f2bf(x.x) | ((u32)f2bf(x.y)<<16);
    float ss = x.x*x.x + x.y*x.y;
    #pragma unroll
    for(int o=32;o>0;o>>=1) ss += __shfl_xor(ss,o,64);
    float nrm = sqrtf(ss);
    float sc = nrm > 1.0f ? 1.0f/nrm : 1.0f;
    if(lane==0) scale[e] = sc;
    float w0 = (float)cnt0[e];
    float w1 = (float)cnt1[e];
    float sx = x.x*sc, sy = x.y*sc;
    p0 += w0*sx;    p1 += w0*sy;
    p2 += w1*sx;    p3 += w1*sy;
    p4 += w0*sx*sx; p5 += w0*sy*sy;
    p6 += w1*sx*sx; p7 += w1*sy*sy;
  }
  atomicAdd(&acc[      2*lane  ], p0);
  atomicAdd(&acc[      2*lane+1], p1);
  atomicAdd(&acc[128 + 2*lane  ], p2);
  atomicAdd(&acc[128 + 2*lane+1], p3);
  atomicAdd(&acc[256 + 2*lane  ], p4);
  atomicAdd(&acc[256 + 2*lane+1], p5);
  atomicAdd(&acc[384 + 2*lane  ], p6);
  atomicAdd(&acc[384 + 2*lane+1], p7);
  __syncthreads();
  atomicAdd(&stats[t],     acc[t]);
  atomicAdd(&stats[t+256], acc[t+256]);
}

// ------- K3: per-rel scale + Qr stats + cos/sin phase tables ---------------
__global__ __launch_bounds__(256) void k_relstats(const float* __restrict__ rel,
    const int* __restrict__ cntr, float* __restrict__ scale_rel,
    float* __restrict__ stats, float* __restrict__ cosr, float* __restrict__ sinr){
  int t = threadIdx.x, lane = t & 63;
  int r = blockIdx.x*4 + (t>>6);
  if(r >= N_REL) return;
  float2 x = *(const float2*)(rel + (size_t)r*D + 2*lane);
  float ss = x.x*x.x + x.y*x.y;
  #pragma unroll
  for(int o=32;o>0;o>>=1) ss += __shfl_xor(ss,o,64);
  float nrm = sqrtf(ss);
  float sc = nrm > 1.0f ? 1.0f/nrm : 1.0f;
  if(lane==0) scale_rel[r] = sc;
  float w = (float)cntr[r];
  float sx = x.x*sc, sy = x.y*sc;
  atomicAdd(&stats[512 + 2*lane  ], w*sx*sx);
  atomicAdd(&stats[512 + 2*lane+1], w*sy*sy);
  if(lane < 32){   // raw (unnormalized) coords 0..63 feed the phases
    cosr[r*64 + 2*lane  ] = cosf(x.x*PHASE_C);
    sinr[r*64 + 2*lane  ] = sinf(x.x*PHASE_C);
    cosr[r*64 + 2*lane+1] = cosf(x.y*PHASE_C);
    sinr[r*64 + 2*lane+1] = sinf(x.y*PHASE_C);
  }
}

// ------- K4: finalize BN0, build folded bf16 weights Wbf, W2 and b' ---------
__global__ __launch_bounds__(384) void k_bn0fin(const float* __restrict__ stats,
    const float* __restrict__ W_a, const float* __restrict__ b_a,
    const float* __restrict__ gamma0, const float* __restrict__ beta0,
    u16* __restrict__ Wbf, float* __restrict__ W2, float* __restrict__ bprime){
  __shared__ float a0[384], c0[384];
  int t = threadIdx.x;
  {
    int j = t & 127;
    float mu, ex2;
    if(t < 256){
      mu  = (stats[j]     + stats[128+j]) * (1.0f/(2.0f*N_TRIP));
      ex2 = (stats[256+j] + stats[384+j]) * (1.0f/(2.0f*N_TRIP));
    } else {
      mu  = 0.0f;
      ex2 = stats[512+j] * (1.0f/N_TRIP);
    }
    float var = ex2 - mu*mu;
    float a = gamma0[t]*rsqrtf(var + BN_EPSF);
    a0[t] = a;
    c0[t] = beta0[t] - mu*a;
  }
  __syncthreads();
  for(int idx=t; idx<256*128; idx+=384){
    int j = idx>>7, k = idx&127;
    int ko = ((j>>7)<<7) + k;
    Wbf[idx] = f2bf(W_a[(j&127)*384 + ko]*a0[ko]);
  }
  for(int idx=t; idx<128*128; idx+=384){
    int k = idx>>7, j = idx&127;
    W2[idx] = W_a[j*384 + 256 + k]*a0[256+k];
  }
  if(t < 128){
    float s = b_a[t];
    for(int k=0;k<384;k++) s += W_a[t*384+k]*c0[k];
    bprime[t] = s;
  }
}

// ------- K5: R[r] = rel_n[r] @ W2 ------------------------------------------
__global__ __launch_bounds__(128) void k_relproj(const float* __restrict__ rel,
    const float* __restrict__ scale_rel, const float* __restrict__ W2,
    float* __restrict__ R){
  int r = blockIdx.x, j = threadIdx.x;
  __shared__ float x[128];
  x[j] = rel[(size_t)r*D + j]*scale_rel[r];
  __syncthreads();
  float s = 0.f;
  for(int k=0;k<128;k++) s += x[k]*W2[k*128+j];
  R[r*128+j] = s;
}

// ------- K6: A/B projection via MFMA, weights in registers ------------------
__global__ __launch_bounds__(256) void k_ab(const float* __restrict__ ent,
    const float* __restrict__ scale, const u16* __restrict__ Wbf,
    u16* __restrict__ Abuf, u16* __restrict__ Bbuf){
  __shared__ u16 xlds[16*128];
  int t = threadIdx.x, lane = t & 63, q = t >> 6;
  int kgrp = (lane>>4)<<3;
  int rgrp = (lane>>4)<<2;
  int frow = lane & 15;
  short8 wf[4][4];
  #pragma unroll
  for(int jt=0;jt<4;jt++){
    #pragma unroll
    for(int kt=0;kt<4;kt++)
      wf[jt][kt] = *(const short8*)(Wbf + (size_t)(q*64 + jt*16 + frow)*D + kgrp + kt*32);
  }
  int srow = t>>4;
  int scol = (t&15)<<3;
  char* swp = (char*)xlds + srow*256 + ((scol<<1) ^ ((srow&7)<<4));
  const char* rdp = (const char*)xlds + frow*256;
  int rbase0 = (lane>>4)<<4;
  int fsw = (frow&7)<<4;
  for(int chunk = blockIdx.x; chunk < N_ENT/16; chunk += gridDim.x){
    const float* xp = ent + (size_t)(chunk*16 + srow)*D + scol;
    float sc = scale[chunk*16 + srow];
    float4 x0 = *(const float4*)xp;
    float4 x1 = *(const float4*)(xp+4);
    uint4 pk;
    pk.x = (u32)f2bf(x0.x*sc) | ((u32)f2bf(x0.y*sc)<<16);
    pk.y = (u32)f2bf(x0.z*sc) | ((u32)f2bf(x0.w*sc)<<16);
    pk.z = (u32)f2bf(x1.x*sc) | ((u32)f2bf(x1.y*sc)<<16);
    pk.w = (u32)f2bf(x1.z*sc) | ((u32)f2bf(x1.w*sc)<<16);
    __syncthreads();
    *(uint4*)swp = pk;
    __syncthreads();
    short8 xf[4];
    #pragma unroll
    for(int kt=0;kt<4;kt++)
      xf[kt] = *(const short8*)(rdp + ((rbase0 + kt*64) ^ fsw));
    int erow = chunk*16 + frow;
    #pragma unroll
    for(int jt=0;jt<4;jt++){
      f32x4 acc = {0.f,0.f,0.f,0.f};
      #pragma unroll
      for(int kt=0;kt<4;kt++)
        acc = __builtin_amdgcn_mfma_f32_16x16x32_bf16(wf[jt][kt], xf[kt], acc, 0,0,0);
      int jbase = q*64 + jt*16 + rgrp;
      u16x4 opk;
      opk.x=f2bf(acc[0]); opk.y=f2bf(acc[1]); opk.z=f2bf(acc[2]); opk.w=f2bf(acc[3]);
      u16* dst = (jbase < 128) ? (Abuf + (size_t)erow*D + jbase)
                               : (Bbuf + (size_t)erow*D + (jbase-128));
      *(u16x4*)dst = opk;
    }
  }
}

// ------- K7: BN1 statistics, deterministic 1/2 subsample (even triplets) ----
__global__ __launch_bounds__(256) void k_bn1stats(const u64* __restrict__ pair64,
    const u16* __restrict__ A, const u16* __restrict__ B,
    const float* __restrict__ R, const float* __restrict__ bprime,
    float* __restrict__ sums){
  __shared__ float acc[256];
  int t = threadIdx.x;
  acc[t] = 0.f;
  __syncthreads();
  int lane = t & 63;
  int gw = blockIdx.x*4 + (t>>6), nw = gridDim.x*4;
  float bp0 = bprime[2*lane], bp1 = bprime[2*lane+1];
  float s0=0,s1=0,q0=0,q1=0;
  for(int i=2*gw; i<N_TRIP; i+=2*nw){
    u64 pr = pair64[i];
    int t0 = (int)(pr & 0x3FFFF);
    int t1 = (int)((pr>>18) & 0x3FFFF);
    int t2 = (int)(pr>>36);
    u32 ua0 = *(const u32*)(A + (size_t)t0*D + 2*lane);
    u32 ua1 = *(const u32*)(A + (size_t)t1*D + 2*lane);
    u32 ub0 = *(const u32*)(B + (size_t)t0*D + 2*lane);
    u32 ub1 = *(const u32*)(B + (size_t)t1*D + 2*lane);
    float2 r = *(const float2*)(R + (size_t)t2*D + 2*lane);
    float y1x = bfl(ua0)+bfl(ub1)+r.x+bp0;
    float y1y = bfh(ua0)+bfh(ub1)+r.y+bp1;
    float y2x = bfl(ua1)+bfl(ub0)-r.x+bp0;
    float y2y = bfh(ua1)+bfh(ub0)-r.y+bp1;
    s0 += y1x+y2x; s1 += y1y+y2y;
    q0 += y1x*y1x + y2x*y2x; q1 += y1y*y1y + y2y*y2y;
  }
  atomicAdd(&acc[      2*lane  ], s0);
  atomicAdd(&acc[      2*lane+1], s1);
  atomicAdd(&acc[128 + 2*lane  ], q0);
  atomicAdd(&acc[128 + 2*lane+1], q1);
  __syncthreads();
  atomicAdd(&sums[t], acc[t]);
}

// ------- K8: finalize BN1 + wa1 = W_a2 .* a1 + kappa ------------------------
// subsample: N_TRIP/2 triplets * 2 rows = N_TRIP samples
__global__ __launch_bounds__(128) void k_bn1fin(const float* __restrict__ sums,
    const float* __restrict__ gamma1, const float* __restrict__ beta1,
    const float* __restrict__ W_a2, const float* __restrict__ b_a2,
    const float* __restrict__ bprime, float* __restrict__ a1c){
  __shared__ float red[128];
  int j = threadIdx.x;
  float mu  = sums[j]    *(1.0f/(float)N_TRIP);
  float var = sums[128+j]*(1.0f/(float)N_TRIP) - mu*mu;
  float a = gamma1[j]*rsqrtf(var + BN_EPSF);
  float cc = beta1[j] - mu*a;
  float wa1 = W_a2[j]*a;
  a1c[j]     = a;
  a1c[128+j] = cc;
  a1c[256+j] = wa1;
  red[j] = W_a2[j]*cc + wa1*bprime[j];
  __syncthreads();
  #pragma unroll
  for(int s=64; s>0; s>>=1){
    if(j < s) red[j] += red[j+s];
    __syncthreads();
  }
  if(j==0) a1c[384] = red[0] + b_a2[0];
}

// ------- K8b: per-entity scalars alpha = wa1.A[e], beta = wa1.B[e], rho -----
__global__ __launch_bounds__(256) void k_alphabeta(const u16* __restrict__ A,
    const u16* __restrict__ B, const float* __restrict__ R,
    const float* __restrict__ a1c, float* __restrict__ alpha,
    float* __restrict__ beta, float* __restrict__ rho){
  int t = threadIdx.x, lane = t & 63;
  int gw = blockIdx.x*4 + (t>>6), nw = gridDim.x*4;
  float wx = a1c[256+2*lane], wy = a1c[256+2*lane+1];
  for(int e=gw; e<N_ENT; e+=nw){
    u32 ua = *(const u32*)(A + (size_t)e*D + 2*lane);
    u32 ub = *(const u32*)(B + (size_t)e*D + 2*lane);
    float da = wx*bfl(ua) + wy*bfh(ua);
    float db = wx*bfl(ub) + wy*bfh(ub);
    #pragma unroll
    for(int o=32;o>0;o>>=1){ da += __shfl_xor(da,o,64); db += __shfl_xor(db,o,64); }
    if(lane==0){ alpha[e]=da; beta[e]=db; }
  }
  for(int r=gw; r<N_REL; r+=nw){
    float2 rr = *(const float2*)(R + (size_t)r*D + 2*lane);
    float dr = wx*rr.x + wy*rr.y;
    #pragma unroll
    for(int o=32;o>0;o>>=1) dr += __shfl_xor(dr,o,64);
    if(lane==0) rho[r]=dr;
  }
}

// ------- K9: per-entity gather pass, packed edges, 2-way unrolled -----------
__global__ __launch_bounds__(256) void k_ent(
    const int* __restrict__ offs, const int* __restrict__ endp,
    const u32* __restrict__ ebuf,
    const u16* __restrict__ A, const u16* __restrict__ B,
    const float* __restrict__ R, const float* __restrict__ bprime,
    const float* __restrict__ a1c, const float* __restrict__ alpha,
    const float* __restrict__ beta, const float* __restrict__ rho,
    float* __restrict__ out_hent){
  int t = threadIdx.x, lane = t & 63;
  int gw = blockIdx.x*4 + (t>>6), nw = gridDim.x*4;
  float bp0 = bprime[2*lane], bp1 = bprime[2*lane+1];
  float a1x = a1c[2*lane],     a1y = a1c[2*lane+1];
  float ccx = a1c[128+2*lane], ccy = a1c[128+2*lane+1];
  float kap = a1c[384];
  for(int e=gw; e<N_ENT; e+=nw){
    int s = offs[e], en = endp[e];
    u32 ua = *(const u32*)(A + (size_t)e*D + 2*lane);
    float ax = bfl(ua), ay = bfh(ua);
    float al = alpha[e];
    float hx = 0.f, hy = 0.f, eb = 0.f;
    int o = s;
    for(; o+1<en; o+=2){
      u32 id0 = ebuf[o], id1 = ebuf[o+1];
      int ot0 = id0>>10,          ot1 = id1>>10;
      int r20 = (id0>>1)&511,     r21 = (id1>>1)&511;
      float sg0 = (id0&1)?-1.f:1.f, sg1 = (id1&1)?-1.f:1.f;
      u32 ub0 = *(const u32*)(B + (size_t)ot0*D + 2*lane);
      u32 ub1 = *(const u32*)(B + (size_t)ot1*D + 2*lane);
      float2 r0 = *(const float2*)(R + (size_t)r20*D + 2*lane);
      float2 r1 = *(const float2*)(R + (size_t)r21*D + 2*lane);
      float be0 = beta[ot0], be1 = beta[ot1];
      float ro0 = rho[r20],  ro1 = rho[r21];
      float sv0 = al + be0 + sg0*ro0 + kap;
      float sv1 = al + be1 + sg1*ro1 + kap;
      float e0 = expf(sv0 >= 0.f ? -sv0 : -0.01f*sv0);
      float e1 = expf(sv1 >= 0.f ? -sv1 : -0.01f*sv1);
      float y0x = ax + bfl(ub0) + sg0*r0.x + bp0;
      float y0y = ay + bfh(ub0) + sg0*r0.y + bp1;
      float y1x = ax + bfl(ub1) + sg1*r1.x + bp0;
      float y1y = ay + bfh(ub1) + sg1*r1.y + bp1;
      float c0x = y0x*a1x + ccx, c0y = y0y*a1y + ccy;
      float c1x = y1x*a1x + ccx, c1y = y1y*a1y + ccy;
      hx += e0*c0x + e1*c1x; hy += e0*c0y + e1*c1y; eb += e0 + e1;
    }
    if(o < en){
      u32 id = ebuf[o];
      int ot = id>>10;
      int r2 = (id>>1)&511;
      float sg = (id&1)?-1.f:1.f;
      u32 ub = *(const u32*)(B + (size_t)ot*D + 2*lane);
      float2 r = *(const float2*)(R + (size_t)r2*D + 2*lane);
      float sv = al + beta[ot] + sg*rho[r2] + kap;
      float e_b = expf(sv >= 0.f ? -sv : -0.01f*sv);
      float yx = ax + bfl(ub) + sg*r.x + bp0;
      float yy = ay + bfh(ub) + sg*r.y + bp1;
      float cx = yx*a1x + ccx, cy = yy*a1y + ccy;
      hx += e_b*cx; hy += e_b*cy; eb += e_b;
    }
    float inv = (en > s) ? 1.0f/eb : 0.0f;
    float2 o2; o2.x = hx*inv; o2.y = hy*inv;
    *(float2*)(out_hent + (size_t)e*D + 2*lane) = o2;
  }
}

// ------- K10: per-rel gather pass, packed pairs -----------------------------
__global__ __launch_bounds__(512) void k_rel(
    const int* __restrict__ roffs, const int* __restrict__ cntr,
    const u64* __restrict__ rpair,
    const u16* __restrict__ A, const u16* __restrict__ B,
    const float* __restrict__ R, const float* __restrict__ bprime,
    const float* __restrict__ a1c, const float* __restrict__ alpha,
    const float* __restrict__ beta, const float* __restrict__ rho,
    float* __restrict__ out_hrel){
  __shared__ float red[8][128];
  int t = threadIdx.x, lane = t & 63, w = t >> 6;
  int r = blockIdx.x;
  int cnt = cntr[r], base = roffs[r];
  float2 rr = *(const float2*)(R + (size_t)r*D + 2*lane);
  float bp0 = bprime[2*lane], bp1 = bprime[2*lane+1];
  float a1x = a1c[2*lane],     a1y = a1c[2*lane+1];
  float ccx = a1c[128+2*lane], ccy = a1c[128+2*lane+1];
  float kap = a1c[384];
  float rhor = rho[r];
  float sx = 0.f, sy = 0.f;
  for(int j=w; j<cnt; j+=8){
    u64 pr = rpair[base+j];
    int t0 = (int)(pr & 0x3FFFF);
    int t1 = (int)((pr>>18) & 0x3FFFF);
    float s1 = alpha[t0] + beta[t1] + rhor + kap;
    float s2 = alpha[t1] + beta[t0] - rhor + kap;
    float e1 = expf(s1 >= 0.f ? -s1 : -0.01f*s1);
    float e2 = expf(s2 >= 0.f ? -s2 : -0.01f*s2);
    u32 ua0 = *(const u32*)(A + (size_t)t0*D + 2*lane);
    u32 ua1 = *(const u32*)(A + (size_t)t1*D + 2*lane);
    u32 ub0 = *(const u32*)(B + (size_t)t0*D + 2*lane);
    u32 ub1 = *(const u32*)(B + (size_t)t1*D + 2*lane);
    float y1x = bfl(ua0)+bfl(ub1)+rr.x+bp0;
    float y1y = bfh(ua0)+bfh(ub1)+rr.y+bp1;
    float y2x = bfl(ua1)+bfl(ub0)-rr.x+bp0;
    float y2y = bfh(ua1)+bfh(ub0)-rr.y+bp1;
    float c1x = y1x*a1x+ccx, c1y = y1y*a1y+ccy;
    float c2x = y2x*a1x+ccx, c2y = y2y*a1y+ccy;
    sx += e1*c1x - e2*c2x;
    sy += e1*c1y - e2*c2y;
  }
  float2 p; p.x = sx; p.y = sy;
  *(float2*)&red[w][2*lane] = p;
  __syncthreads();
  if(t < 128){
    float s = 0.f;
    #pragma unroll
    for(int k=0;k<8;k++) s += red[k][t];
    float cf = cnt > 0 ? (float)cnt : 1.0f;
    out_hrel[(size_t)r*D + t] = s/cf;
  }
}

// ------- K12: RotatE score (bf16 gathers) -----------------------------------
__global__ __launch_bounds__(256) void k_score_bf(const u64* __restrict__ pair64,
    const u32* __restrict__ entbf, const float* __restrict__ cosr,
    const float* __restrict__ sinr, float* __restrict__ score){
  int t = threadIdx.x, lane = t & 63;
  int gw = blockIdx.x*4 + (t>>6), nw = gridDim.x*4;
  int half = lane & 1;
  int pidx = lane >> 1;
  for(int i=gw; i<N_TRIP; i+=nw){
    u64 pr = pair64[i];
    int t0 = (int)(pr & 0x3FFFF);
    int t1 = (int)((pr>>18) & 0x3FFFF);
    int t2 = (int)(pr>>36);
    u32 ph0 = entbf[(size_t)t0*64 + pidx];
    u32 pi0 = entbf[(size_t)t0*64 + 32 + pidx];
    u32 ph1 = entbf[(size_t)t1*64 + pidx];
    u32 pi1 = entbf[(size_t)t1*64 + 32 + pidx];
    float re_h = half ? bfh(ph0) : bfl(ph0);
    float im_h = half ? bfh(pi0) : bfl(pi0);
    float re_t = half ? bfh(ph1) : bfl(ph1);
    float im_t = half ? bfh(pi1) : bfl(pi1);
    float cr = cosr[t2*64 + lane], sr = sinr[t2*64 + lane];
    float re_s = cr*re_t + sr*im_t - re_h;
    float im_s = cr*im_t - sr*re_t - im_h;
    float d = sqrtf(re_s*re_s + im_s*im_s);
    #pragma unroll
    for(int o=32;o>0;o>>=1) d += __shfl_xor(d,o,64);
    if(lane==0) score[i] = MARGINF - d;
  }
}

// fp32 fallback if workspace too small for entbf
__global__ __launch_bounds__(256) void k_score_fp(const u64* __restrict__ pair64,
    const float* __restrict__ ent, const float* __restrict__ cosr,
    const float* __restrict__ sinr, float* __restrict__ score){
  int t = threadIdx.x, lane = t & 63;
  int gw = blockIdx.x*4 + (t>>6), nw = gridDim.x*4;
  for(int i=gw; i<N_TRIP; i+=nw){
    u64 pr = pair64[i];
    int t0 = (int)(pr & 0x3FFFF);
    int t1 = (int)((pr>>18) & 0x3FFFF);
    int t2 = (int)(pr>>36);
    float re_h = ent[(size_t)t0*D + lane];
    float im_h = ent[(size_t)t0*D + 64 + lane];
    float re_t = ent[(size_t)t1*D + lane];
    float im_t = ent[(size_t)t1*D + 64 + lane];
    float cr = cosr[t2*64 + lane], sr = sinr[t2*64 + lane];
    float re_s = cr*re_t + sr*im_t - re_h;
    float im_s = cr*im_t - sr*re_t - im_h;
    float d = sqrtf(re_s*re_s + im_s*im_s);
    #pragma unroll
    for(int o=32;o>0;o>>=1) d += __shfl_xor(d,o,64);
    if(lane==0) score[i] = MARGINF - d;
  }
}

extern "C" void kernel_launch(void* const* d_in, const int* in_sizes, int n_in,
                              void* d_out, int out_size, void* d_ws, size_t ws_size,
                              hipStream_t stream){
  const int*   trip   = (const int*)  d_in[0];
  const float* ent    = (const float*)d_in[1];
  const float* rel    = (const float*)d_in[2];
  const float* W_a    = (const float*)d_in[3];
  const float* b_a    = (const float*)d_in[4];
  const float* W_a2   = (const float*)d_in[5];
  const float* b_a2   = (const float*)d_in[6];
  const float* gamma0 = (const float*)d_in[7];
  const float* beta0  = (const float*)d_in[8];
  const float* gamma1 = (const float*)d_in[9];
  const float* beta1  = (const float*)d_in[10];

  char* ws = (char*)d_ws;
  size_t off = 0;
  auto take = [&](size_t bytes)->void*{
    void* p = ws + off;
    off += (bytes + 255) & ~(size_t)255;
    return p;
  };
  // ---- zeroed scratch (contiguous from 0) ----
  int*   cnt0    = (int*)  take((size_t)N_ENT*4);
  int*   cnt1    = (int*)  take((size_t)N_ENT*4);
  int*   cntr    = (int*)  take((size_t)N_REL*4);
  float* stats   = (float*)take(640*4);
  float* sums    = (float*)take(256*4);
  size_t zero_bytes = off;
  // ---- fully-overwritten scratch ----
  int*   offs      = (int*)  take((size_t)N_ENT*4);
  int*   cur       = (int*)  take((size_t)N_ENT*4);
  int*   bsum      = (int*)  take(512*4);
  int*   boffs     = (int*)  take(512*4);
  int*   roffs     = (int*)  take(512*4);
  int*   rcur      = (int*)  take(512*4);
  u32*   ebuf      = (u32*)  take((size_t)2*N_TRIP*4);
  u64*   pair64    = (u64*)  take((size_t)N_TRIP*8);
  u64*   rpair     = (u64*)  take((size_t)N_TRIP*8);
  float* scale     = (float*)take((size_t)N_ENT*4);
  float* scale_rel = (float*)take((size_t)N_REL*4);
  u16*   Wbf       = (u16*)  take(256*128*2);
  float* W2        = (float*)take(128*128*4);
  float* bprime    = (float*)take(128*4);
  float* a1c       = (float*)take(512*4);
  float* R         = (float*)take((size_t)N_REL*D*4);
  float* cosr      = (float*)take((size_t)N_REL*64*4);
  float* sinr      = (float*)take((size_t)N_REL*64*4);
  float* alpha     = (float*)take((size_t)N_ENT*4);
  float* betab     = (float*)take((size_t)N_ENT*4);
  float* rho       = (float*)take(512*4);
  u16*   Abuf      = (u16*)  take((size_t)N_ENT*D*2);
  u16*   Bbuf      = (u16*)  take((size_t)N_ENT*D*2);
  u32*   entbf     = (u32*)  take((size_t)N_ENT*64*4);
  bool use_bf = (off <= ws_size);
  (void)n_in; (void)in_sizes; (void)out_size;

  float* out_hent  = (float*)d_out;
  float* out_hrel  = out_hent + (size_t)N_ENT*D;
  float* out_score = out_hrel + (size_t)N_REL*D;

  hipMemsetAsync(d_ws, 0, zero_bytes, stream);

  const int SCAN_BLKS = (N_ENT + 1023)/1024;   // 196
  k_hist     <<<(N_TRIP+255)/256, 256, 0, stream>>>(trip, cnt0, cnt1, cntr);
  k_scan1    <<<SCAN_BLKS, 1024, 0, stream>>>(cnt0, cnt1, offs, bsum);
  k_scan2    <<<1, 512, 0, stream>>>(bsum, boffs, cntr, roffs, rcur, SCAN_BLKS);
  k_scan3    <<<SCAN_BLKS, 1024, 0, stream>>>(offs, boffs, cur);
  k_edges    <<<(N_TRIP+255)/256, 256, 0, stream>>>(trip, cur, rcur, ebuf, pair64, rpair);
  k_entstats <<<2048, 256, 0, stream>>>(ent, cnt0, cnt1, scale, stats,
                                        use_bf ? entbf : (u32*)nullptr);
  k_relstats <<<(N_REL+3)/4, 256, 0, stream>>>(rel, cntr, scale_rel, stats, cosr, sinr);
  k_bn0fin   <<<1, 384, 0, stream>>>(stats, W_a, b_a, gamma0, beta0, Wbf, W2, bprime);
  k_relproj  <<<N_REL, 128, 0, stream>>>(rel, scale_rel, W2, R);
  k_ab       <<<2048, 256, 0, stream>>>(ent, scale, Wbf, Abuf, Bbuf);
  k_bn1stats <<<2048, 256, 0, stream>>>(pair64, Abuf, Bbuf, R, bprime, sums);
  k_bn1fin   <<<1, 128, 0, stream>>>(sums, gamma1, beta1, W_a2, b_a2, bprime, a1c);
  k_alphabeta<<<2048, 256, 0, stream>>>(Abuf, Bbuf, R, a1c, alpha, betab, rho);
  k_ent      <<<2048, 256, 0, stream>>>(offs, cur, ebuf, Abuf, Bbuf, R,
                                        bprime, a1c, alpha, betab, rho, out_hent);
  k_rel      <<<N_REL, 512, 0, stream>>>(roffs, cntr, rpair, Abuf, Bbuf, R,
                                         bprime, a1c, alpha, betab, rho, out_hrel);
  if(use_bf)
    k_score_bf<<<2048, 256, 0, stream>>>(pair64, entbf, cosr, sinr, out_score);
  else
    k_score_fp<<<2048, 256, 0, stream>>>(pair64, ent, cosr, sinr, out_score);
}

// Round 7
// 608.068 us; speedup vs baseline: 2.6688x; 1.0536x over previous
//
#include <hip/hip_runtime.h>
#include <stdint.h>

#define N_TRIP 200000
#define N_ENT  200000
#define N_REL  500
#define D      128
#define MARGINF 6.0f
#define BN_EPSF 1e-5f
#define PHASE_C 50.26548245743669f   // PI / REL_RANGE, REL_RANGE = 8/128

typedef unsigned short u16;
typedef unsigned int   u32;
typedef unsigned long long u64;
typedef __attribute__((ext_vector_type(8))) short short8;
typedef __attribute__((ext_vector_type(4))) float f32x4;
typedef __attribute__((ext_vector_type(4))) unsigned short u16x4;

__device__ inline float bfl(u32 u){ return __uint_as_float(u<<16); }
__device__ inline float bfh(u32 u){ return __uint_as_float(u&0xffff0000u); }
__device__ inline u16 f2bf(float f){
  u32 u = __float_as_uint(f);
  u32 r = (u + 0x7fffu + ((u>>16)&1u))>>16;
  return (u16)r;
}

// ---------------- K1: histogram of head / tail / rel indices ----------------
__global__ __launch_bounds__(256) void k_hist(const int* __restrict__ trip,
    int* __restrict__ cnt0, int* __restrict__ cnt1, int* __restrict__ cntr){
  int i = blockIdx.x*256 + threadIdx.x;
  if(i < N_TRIP){
    atomicAdd(&cnt0[trip[3*i]],   1);
    atomicAdd(&cnt1[trip[3*i+1]], 1);
    atomicAdd(&cntr[trip[3*i+2]], 1);
  }
}

// ---------------- CSR build: 3-kernel prefix scan + cursor scatter ----------
__global__ __launch_bounds__(1024) void k_scan1(const int* __restrict__ cnt0,
    const int* __restrict__ cnt1, int* __restrict__ offs, int* __restrict__ bsum){
  __shared__ int sh[1024];
  int t = threadIdx.x;
  int e = blockIdx.x*1024 + t;
  int d = (e < N_ENT) ? cnt0[e] + cnt1[e] : 0;
  sh[t] = d; __syncthreads();
  for(int st=1; st<1024; st<<=1){
    int x = (t>=st) ? sh[t-st] : 0;
    __syncthreads();
    sh[t] += x;
    __syncthreads();
  }
  if(e < N_ENT) offs[e] = sh[t] - d;
  if(t == 1023) bsum[blockIdx.x] = sh[t];
}

__global__ __launch_bounds__(512) void k_scan2(const int* __restrict__ bsum,
    int* __restrict__ boffs, const int* __restrict__ cntr,
    int* __restrict__ roffs, int* __restrict__ rcur, int nblk){
  __shared__ int sh[512];
  int t = threadIdx.x;
  int v = (t < nblk) ? bsum[t] : 0;
  sh[t] = v; __syncthreads();
  for(int st=1; st<512; st<<=1){
    int x = (t>=st) ? sh[t-st] : 0;
    __syncthreads(); sh[t] += x; __syncthreads();
  }
  if(t < nblk) boffs[t] = sh[t] - v;
  __syncthreads();
  int w = (t < N_REL) ? cntr[t] : 0;
  sh[t] = w; __syncthreads();
  for(int st=1; st<512; st<<=1){
    int x = (t>=st) ? sh[t-st] : 0;
    __syncthreads(); sh[t] += x; __syncthreads();
  }
  if(t < N_REL){ roffs[t] = sh[t]-w; rcur[t] = sh[t]-w; }
}

__global__ __launch_bounds__(1024) void k_scan3(int* __restrict__ offs,
    const int* __restrict__ boffs, int* __restrict__ cur){
  int e = blockIdx.x*1024 + threadIdx.x;
  if(e < N_ENT){
    int o = offs[e] + boffs[blockIdx.x];
    offs[e] = o;
    cur[e] = o;
  }
}

// edge records: ebuf = other<<10 | t2<<1 | role ; pair64 = t0 | t1<<18 | t2<<36
__global__ __launch_bounds__(256) void k_edges(const int* __restrict__ trip,
    int* __restrict__ cur, int* __restrict__ rcur,
    u32* __restrict__ ebuf, u64* __restrict__ pair64, u64* __restrict__ rpair){
  int i = blockIdx.x*256 + threadIdx.x;
  if(i < N_TRIP){
    int t0 = trip[3*i], t1 = trip[3*i+1], t2 = trip[3*i+2];
    u64 pr = ((u64)t2<<36) | ((u64)t1<<18) | (u64)t0;
    pair64[i] = pr;
    ebuf[atomicAdd(&cur[t0], 1)] = ((u32)t1<<10) | ((u32)t2<<1);
    ebuf[atomicAdd(&cur[t1], 1)] = ((u32)t0<<10) | ((u32)t2<<1) | 1u;
    rpair[atomicAdd(&rcur[t2], 1)] = pr;
  }
}

// ------- K2: per-entity norm scale + weighted column stats + bf16 ent copy --
// 32-lane groups (2 rows/wave), float4 loads, manual x2 unroll -> 4 chains.
__global__ __launch_bounds__(256) void k_entstats(const float* __restrict__ ent,
    const int* __restrict__ cnt0, const int* __restrict__ cnt1,
    float* __restrict__ scale, float* __restrict__ stats, u32* entbf){
  __shared__ float acc[512];
  int t = threadIdx.x;
  acc[t] = 0.f; acc[t+256] = 0.f;
  __syncthreads();
  int lane = t & 63;
  int l32 = lane & 31, grp = lane >> 5;
  int wid = blockIdx.x*4 + (t>>6);
  int nw = gridDim.x*4;
  float s0[4]={0,0,0,0}, s1[4]={0,0,0,0}, q0[4]={0,0,0,0}, q1[4]={0,0,0,0};
  for(int e4 = wid*4; e4 < N_ENT; e4 += nw*4){
    int eA = e4 + grp;
    int eB = e4 + 2 + grp;
    float4 xA = *(const float4*)(ent + (size_t)eA*D + l32*4);
    float4 xB = *(const float4*)(ent + (size_t)eB*D + l32*4);
    float wA0 = (float)cnt0[eA], wA1 = (float)cnt1[eA];
    float wB0 = (float)cnt0[eB], wB1 = (float)cnt1[eB];
    float ssA = xA.x*xA.x + xA.y*xA.y + xA.z*xA.z + xA.w*xA.w;
    float ssB = xB.x*xB.x + xB.y*xB.y + xB.z*xB.z + xB.w*xB.w;
    #pragma unroll
    for(int o=16;o>0;o>>=1){
      ssA += __shfl_xor(ssA,o,64);
      ssB += __shfl_xor(ssB,o,64);
    }
    float nA = sqrtf(ssA), nB = sqrtf(ssB);
    float scA = nA > 1.0f ? 1.0f/nA : 1.0f;
    float scB = nB > 1.0f ? 1.0f/nB : 1.0f;
    if(l32==0){ scale[eA] = scA; scale[eB] = scB; }
    if(entbf){
      uint2 pA, pB;
      pA.x = (u32)f2bf(xA.x) | ((u32)f2bf(xA.y)<<16);
      pA.y = (u32)f2bf(xA.z) | ((u32)f2bf(xA.w)<<16);
      pB.x = (u32)f2bf(xB.x) | ((u32)f2bf(xB.y)<<16);
      pB.y = (u32)f2bf(xB.z) | ((u32)f2bf(xB.w)<<16);
      *(uint2*)(entbf + (size_t)eA*64 + l32*2) = pA;
      *(uint2*)(entbf + (size_t)eB*64 + l32*2) = pB;
    }
    float vA[4] = {xA.x*scA, xA.y*scA, xA.z*scA, xA.w*scA};
    float vB[4] = {xB.x*scB, xB.y*scB, xB.z*scB, xB.w*scB};
    #pragma unroll
    for(int k=0;k<4;k++){
      s0[k] += wA0*vA[k] + wB0*vB[k];
      s1[k] += wA1*vA[k] + wB1*vB[k];
      q0[k] += wA0*vA[k]*vA[k] + wB0*vB[k]*vB[k];
      q1[k] += wA1*vA[k]*vA[k] + wB1*vB[k]*vB[k];
    }
  }
  #pragma unroll
  for(int k=0;k<4;k++){
    int c = l32*4 + k;
    atomicAdd(&acc[c],     s0[k]);
    atomicAdd(&acc[128+c], s1[k]);
    atomicAdd(&acc[256+c], q0[k]);
    atomicAdd(&acc[384+c], q1[k]);
  }
  __syncthreads();
  atomicAdd(&stats[t],     acc[t]);
  atomicAdd(&stats[t+256], acc[t+256]);
}

// ------- K3: per-rel scale + Qr stats + cos/sin phase tables ---------------
__global__ __launch_bounds__(256) void k_relstats(const float* __restrict__ rel,
    const int* __restrict__ cntr, float* __restrict__ scale_rel,
    float* __restrict__ stats, float* __restrict__ cosr, float* __restrict__ sinr){
  int t = threadIdx.x, lane = t & 63;
  int r = blockIdx.x*4 + (t>>6);
  if(r >= N_REL) return;
  float2 x = *(const float2*)(rel + (size_t)r*D + 2*lane);
  float ss = x.x*x.x + x.y*x.y;
  #pragma unroll
  for(int o=32;o>0;o>>=1) ss += __shfl_xor(ss,o,64);
  float nrm = sqrtf(ss);
  float sc = nrm > 1.0f ? 1.0f/nrm : 1.0f;
  if(lane==0) scale_rel[r] = sc;
  float w = (float)cntr[r];
  float sx = x.x*sc, sy = x.y*sc;
  atomicAdd(&stats[512 + 2*lane  ], w*sx*sx);
  atomicAdd(&stats[512 + 2*lane+1], w*sy*sy);
  if(lane < 32){
    cosr[r*64 + 2*lane  ] = cosf(x.x*PHASE_C);
    sinr[r*64 + 2*lane  ] = sinf(x.x*PHASE_C);
    cosr[r*64 + 2*lane+1] = cosf(x.y*PHASE_C);
    sinr[r*64 + 2*lane+1] = sinf(x.y*PHASE_C);
  }
}

// ------- K4: finalize BN0, build folded bf16 weights Wbf, W2 and b' ---------
__global__ __launch_bounds__(384) void k_bn0fin(const float* __restrict__ stats,
    const float* __restrict__ W_a, const float* __restrict__ b_a,
    const float* __restrict__ gamma0, const float* __restrict__ beta0,
    u16* __restrict__ Wbf, float* __restrict__ W2, float* __restrict__ bprime){
  __shared__ float a0[384], c0[384];
  int t = threadIdx.x;
  {
    int j = t & 127;
    float mu, ex2;
    if(t < 256){
      mu  = (stats[j]     + stats[128+j]) * (1.0f/(2.0f*N_TRIP));
      ex2 = (stats[256+j] + stats[384+j]) * (1.0f/(2.0f*N_TRIP));
    } else {
      mu  = 0.0f;
      ex2 = stats[512+j] * (1.0f/N_TRIP);
    }
    float var = ex2 - mu*mu;
    float a = gamma0[t]*rsqrtf(var + BN_EPSF);
    a0[t] = a;
    c0[t] = beta0[t] - mu*a;
  }
  __syncthreads();
  for(int idx=t; idx<256*128; idx+=384){
    int j = idx>>7, k = idx&127;
    int ko = ((j>>7)<<7) + k;
    Wbf[idx] = f2bf(W_a[(j&127)*384 + ko]*a0[ko]);
  }
  for(int idx=t; idx<128*128; idx+=384){
    int k = idx>>7, j = idx&127;
    W2[idx] = W_a[j*384 + 256 + k]*a0[256+k];
  }
  if(t < 128){
    float s = b_a[t];
    for(int k=0;k<384;k++) s += W_a[t*384+k]*c0[k];
    bprime[t] = s;
  }
}

// ------- K5: R[r] = rel_n[r] @ W2 ------------------------------------------
__global__ __launch_bounds__(128) void k_relproj(const float* __restrict__ rel,
    const float* __restrict__ scale_rel, const float* __restrict__ W2,
    float* __restrict__ R){
  int r = blockIdx.x, j = threadIdx.x;
  __shared__ float x[128];
  x[j] = rel[(size_t)r*D + j]*scale_rel[r];
  __syncthreads();
  float s = 0.f;
  for(int k=0;k<128;k++) s += x[k]*W2[k*128+j];
  R[r*128+j] = s;
}

// ------- K6: A/B projection via MFMA, weights in registers ------------------
__global__ __launch_bounds__(256) void k_ab(const float* __restrict__ ent,
    const float* __restrict__ scale, const u16* __restrict__ Wbf,
    u16* __restrict__ Abuf, u16* __restrict__ Bbuf){
  __shared__ u16 xlds[16*128];
  int t = threadIdx.x, lane = t & 63, q = t >> 6;
  int kgrp = (lane>>4)<<3;
  int rgrp = (lane>>4)<<2;
  int frow = lane & 15;
  short8 wf[4][4];
  #pragma unroll
  for(int jt=0;jt<4;jt++){
    #pragma unroll
    for(int kt=0;kt<4;kt++)
      wf[jt][kt] = *(const short8*)(Wbf + (size_t)(q*64 + jt*16 + frow)*D + kgrp + kt*32);
  }
  int srow = t>>4;
  int scol = (t&15)<<3;
  char* swp = (char*)xlds + srow*256 + ((scol<<1) ^ ((srow&7)<<4));
  const char* rdp = (const char*)xlds + frow*256;
  int rbase0 = (lane>>4)<<4;
  int fsw = (frow&7)<<4;
  for(int chunk = blockIdx.x; chunk < N_ENT/16; chunk += gridDim.x){
    const float* xp = ent + (size_t)(chunk*16 + srow)*D + scol;
    float sc = scale[chunk*16 + srow];
    float4 x0 = *(const float4*)xp;
    float4 x1 = *(const float4*)(xp+4);
    uint4 pk;
    pk.x = (u32)f2bf(x0.x*sc) | ((u32)f2bf(x0.y*sc)<<16);
    pk.y = (u32)f2bf(x0.z*sc) | ((u32)f2bf(x0.w*sc)<<16);
    pk.z = (u32)f2bf(x1.x*sc) | ((u32)f2bf(x1.y*sc)<<16);
    pk.w = (u32)f2bf(x1.z*sc) | ((u32)f2bf(x1.w*sc)<<16);
    __syncthreads();
    *(uint4*)swp = pk;
    __syncthreads();
    short8 xf[4];
    #pragma unroll
    for(int kt=0;kt<4;kt++)
      xf[kt] = *(const short8*)(rdp + ((rbase0 + kt*64) ^ fsw));
    int erow = chunk*16 + frow;
    #pragma unroll
    for(int jt=0;jt<4;jt++){
      f32x4 acc = {0.f,0.f,0.f,0.f};
      #pragma unroll
      for(int kt=0;kt<4;kt++)
        acc = __builtin_amdgcn_mfma_f32_16x16x32_bf16(wf[jt][kt], xf[kt], acc, 0,0,0);
      int jbase = q*64 + jt*16 + rgrp;
      u16x4 opk;
      opk.x=f2bf(acc[0]); opk.y=f2bf(acc[1]); opk.z=f2bf(acc[2]); opk.w=f2bf(acc[3]);
      u16* dst = (jbase < 128) ? (Abuf + (size_t)erow*D + jbase)
                               : (Bbuf + (size_t)erow*D + (jbase-128));
      *(u16x4*)dst = opk;
    }
  }
}

// ------- K7: BN1 statistics, 1/2 subsample, x2 unrolled ----------------------
__global__ __launch_bounds__(256) void k_bn1stats(const u64* __restrict__ pair64,
    const u16* __restrict__ A, const u16* __restrict__ B,
    const float* __restrict__ R, const float* __restrict__ bprime,
    float* __restrict__ sums){
  __shared__ float acc[256];
  int t = threadIdx.x;
  acc[t] = 0.f;
  __syncthreads();
  int lane = t & 63;
  int gw = blockIdx.x*4 + (t>>6), nw = gridDim.x*4;
  float bp0 = bprime[2*lane], bp1 = bprime[2*lane+1];
  float s0=0,s1=0,q0=0,q1=0;
  for(int i=2*gw; i<N_TRIP; i+=4*nw){
    {
      u64 pr = pair64[i];
      int t0 = (int)(pr & 0x3FFFF);
      int t1 = (int)((pr>>18) & 0x3FFFF);
      int t2 = (int)(pr>>36);
      u32 ua0 = *(const u32*)(A + (size_t)t0*D + 2*lane);
      u32 ua1 = *(const u32*)(A + (size_t)t1*D + 2*lane);
      u32 ub0 = *(const u32*)(B + (size_t)t0*D + 2*lane);
      u32 ub1 = *(const u32*)(B + (size_t)t1*D + 2*lane);
      float2 r = *(const float2*)(R + (size_t)t2*D + 2*lane);
      float y1x = bfl(ua0)+bfl(ub1)+r.x+bp0;
      float y1y = bfh(ua0)+bfh(ub1)+r.y+bp1;
      float y2x = bfl(ua1)+bfl(ub0)-r.x+bp0;
      float y2y = bfh(ua1)+bfh(ub0)-r.y+bp1;
      s0 += y1x+y2x; s1 += y1y+y2y;
      q0 += y1x*y1x + y2x*y2x; q1 += y1y*y1y + y2y*y2y;
    }
    int i2 = i + 2*nw;
    if(i2 < N_TRIP){
      u64 pr = pair64[i2];
      int t0 = (int)(pr & 0x3FFFF);
      int t1 = (int)((pr>>18) & 0x3FFFF);
      int t2 = (int)(pr>>36);
      u32 ua0 = *(const u32*)(A + (size_t)t0*D + 2*lane);
      u32 ua1 = *(const u32*)(A + (size_t)t1*D + 2*lane);
      u32 ub0 = *(const u32*)(B + (size_t)t0*D + 2*lane);
      u32 ub1 = *(const u32*)(B + (size_t)t1*D + 2*lane);
      float2 r = *(const float2*)(R + (size_t)t2*D + 2*lane);
      float y1x = bfl(ua0)+bfl(ub1)+r.x+bp0;
      float y1y = bfh(ua0)+bfh(ub1)+r.y+bp1;
      float y2x = bfl(ua1)+bfl(ub0)-r.x+bp0;
      float y2y = bfh(ua1)+bfh(ub0)-r.y+bp1;
      s0 += y1x+y2x; s1 += y1y+y2y;
      q0 += y1x*y1x + y2x*y2x; q1 += y1y*y1y + y2y*y2y;
    }
  }
  atomicAdd(&acc[      2*lane  ], s0);
  atomicAdd(&acc[      2*lane+1], s1);
  atomicAdd(&acc[128 + 2*lane  ], q0);
  atomicAdd(&acc[128 + 2*lane+1], q1);
  __syncthreads();
  atomicAdd(&sums[t], acc[t]);
}

// ------- K8: finalize BN1 + wa1 = W_a2 .* a1 + kappa ------------------------
__global__ __launch_bounds__(128) void k_bn1fin(const float* __restrict__ sums,
    const float* __restrict__ gamma1, const float* __restrict__ beta1,
    const float* __restrict__ W_a2, const float* __restrict__ b_a2,
    const float* __restrict__ bprime, float* __restrict__ a1c){
  __shared__ float red[128];
  int j = threadIdx.x;
  float mu  = sums[j]    *(1.0f/(float)N_TRIP);
  float var = sums[128+j]*(1.0f/(float)N_TRIP) - mu*mu;
  float a = gamma1[j]*rsqrtf(var + BN_EPSF);
  float cc = beta1[j] - mu*a;
  float wa1 = W_a2[j]*a;
  a1c[j]     = a;
  a1c[128+j] = cc;
  a1c[256+j] = wa1;
  red[j] = W_a2[j]*cc + wa1*bprime[j];
  __syncthreads();
  #pragma unroll
  for(int s=64; s>0; s>>=1){
    if(j < s) red[j] += red[j+s];
    __syncthreads();
  }
  if(j==0) a1c[384] = red[0] + b_a2[0];
}

// ------- K8b: per-entity scalars alpha/beta/rho, 32-lane groups, x2 unroll --
__global__ __launch_bounds__(256) void k_alphabeta(const u16* __restrict__ A,
    const u16* __restrict__ B, const float* __restrict__ R,
    const float* __restrict__ a1c, float* __restrict__ alpha,
    float* __restrict__ beta, float* __restrict__ rho){
  int t = threadIdx.x, lane = t & 63;
  int l32 = lane & 31, grp = lane >> 5;
  int wid = blockIdx.x*4 + (t>>6), nw = gridDim.x*4;
  float4 wa = *(const float4*)(a1c + 256 + l32*4);
  for(int e4 = wid*4; e4 < N_ENT; e4 += nw*4){
    int eA = e4 + grp, eB = e4 + 2 + grp;
    uint2 uaA = *(const uint2*)(A + (size_t)eA*D + l32*4);
    uint2 ubA = *(const uint2*)(B + (size_t)eA*D + l32*4);
    uint2 uaB = *(const uint2*)(A + (size_t)eB*D + l32*4);
    uint2 ubB = *(const uint2*)(B + (size_t)eB*D + l32*4);
    float daA = wa.x*bfl(uaA.x) + wa.y*bfh(uaA.x) + wa.z*bfl(uaA.y) + wa.w*bfh(uaA.y);
    float dbA = wa.x*bfl(ubA.x) + wa.y*bfh(ubA.x) + wa.z*bfl(ubA.y) + wa.w*bfh(ubA.y);
    float daB = wa.x*bfl(uaB.x) + wa.y*bfh(uaB.x) + wa.z*bfl(uaB.y) + wa.w*bfh(uaB.y);
    float dbB = wa.x*bfl(ubB.x) + wa.y*bfh(ubB.x) + wa.z*bfl(ubB.y) + wa.w*bfh(ubB.y);
    #pragma unroll
    for(int o=16;o>0;o>>=1){
      daA += __shfl_xor(daA,o,64); dbA += __shfl_xor(dbA,o,64);
      daB += __shfl_xor(daB,o,64); dbB += __shfl_xor(dbB,o,64);
    }
    if(l32==0){ alpha[eA]=daA; beta[eA]=dbA; alpha[eB]=daB; beta[eB]=dbB; }
  }
  for(int r2 = wid*2 + grp; r2 < N_REL; r2 += nw*2){
    float4 rr = *(const float4*)(R + (size_t)r2*D + l32*4);
    float dr = wa.x*rr.x + wa.y*rr.y + wa.z*rr.z + wa.w*rr.w;
    #pragma unroll
    for(int o=16;o>0;o>>=1) dr += __shfl_xor(dr,o,64);
    if(l32==0) rho[r2]=dr;
  }
}

// ------- K9: per-entity gather, 16-lane groups (4 entities/wave) ------------
__global__ __launch_bounds__(256) void k_ent(
    const int* __restrict__ offs, const int* __restrict__ endp,
    const u32* __restrict__ ebuf,
    const u16* __restrict__ A, const u16* __restrict__ B,
    const float* __restrict__ R, const float* __restrict__ bprime,
    const float* __restrict__ a1c, const float* __restrict__ alpha,
    const float* __restrict__ beta, const float* __restrict__ rho,
    float* __restrict__ out_hent){
  int t = threadIdx.x, lane = t & 63;
  int l16 = lane & 15, g = lane >> 4;
  int wid = blockIdx.x*4 + (t>>6), nw = gridDim.x*4;
  int cb = l16*8;
  float4 bpA = *(const float4*)(bprime + cb);
  float4 bpB = *(const float4*)(bprime + cb + 4);
  float4 a1A = *(const float4*)(a1c + cb);
  float4 a1B = *(const float4*)(a1c + cb + 4);
  float4 ccA = *(const float4*)(a1c + 128 + cb);
  float4 ccB = *(const float4*)(a1c + 128 + cb + 4);
  float kap = a1c[384];
  for(int e4 = wid*4; e4 < N_ENT; e4 += nw*4){
    int e = e4 + g;
    int s = offs[e], en = endp[e];
    uint4 ua = *(const uint4*)(A + (size_t)e*D + cb);
    float ax0 = bfl(ua.x), ax1 = bfh(ua.x), ax2 = bfl(ua.y), ax3 = bfh(ua.y);
    float ax4 = bfl(ua.z), ax5 = bfh(ua.z), ax6 = bfl(ua.w), ax7 = bfh(ua.w);
    float al = alpha[e];
    float h0=0,h1=0,h2=0,h3=0,h4=0,h5=0,h6=0,h7=0, eb=0;
    for(int o=s; o<en; o++){
      u32 id = ebuf[o];
      int ot = id>>10, r2 = (id>>1)&511;
      float sg = (id&1) ? -1.f : 1.f;
      uint4 ub = *(const uint4*)(B + (size_t)ot*D + cb);
      float4 rA = *(const float4*)(R + (size_t)r2*D + cb);
      float4 rB = *(const float4*)(R + (size_t)r2*D + cb + 4);
      float sv = al + beta[ot] + sg*rho[r2] + kap;
      float e_b = expf(sv >= 0.f ? -sv : -0.01f*sv);
      float y, c;
      y = ax0 + bfl(ub.x) + sg*rA.x + bpA.x; c = y*a1A.x + ccA.x; h0 += e_b*c;
      y = ax1 + bfh(ub.x) + sg*rA.y + bpA.y; c = y*a1A.y + ccA.y; h1 += e_b*c;
      y = ax2 + bfl(ub.y) + sg*rA.z + bpA.z; c = y*a1A.z + ccA.z; h2 += e_b*c;
      y = ax3 + bfh(ub.y) + sg*rA.w + bpA.w; c = y*a1A.w + ccA.w; h3 += e_b*c;
      y = ax4 + bfl(ub.z) + sg*rB.x + bpB.x; c = y*a1B.x + ccB.x; h4 += e_b*c;
      y = ax5 + bfh(ub.z) + sg*rB.y + bpB.y; c = y*a1B.y + ccB.y; h5 += e_b*c;
      y = ax6 + bfl(ub.w) + sg*rB.z + bpB.z; c = y*a1B.z + ccB.z; h6 += e_b*c;
      y = ax7 + bfh(ub.w) + sg*rB.w + bpB.w; c = y*a1B.w + ccB.w; h7 += e_b*c;
      eb += e_b;
    }
    float inv = (en > s) ? 1.0f/eb : 0.0f;
    float4 o0; o0.x=h0*inv; o0.y=h1*inv; o0.z=h2*inv; o0.w=h3*inv;
    float4 o1; o1.x=h4*inv; o1.y=h5*inv; o1.z=h6*inv; o1.w=h7*inv;
    *(float4*)(out_hent + (size_t)e*D + cb)     = o0;
    *(float4*)(out_hent + (size_t)e*D + cb + 4) = o1;
  }
}

// ------- K10: per-rel gather pass, packed pairs -----------------------------
__global__ __launch_bounds__(512) void k_rel(
    const int* __restrict__ roffs, const int* __restrict__ cntr,
    const u64* __restrict__ rpair,
    const u16* __restrict__ A, const u16* __restrict__ B,
    const float* __restrict__ R, const float* __restrict__ bprime,
    const float* __restrict__ a1c, const float* __restrict__ alpha,
    const float* __restrict__ beta, const float* __restrict__ rho,
    float* __restrict__ out_hrel){
  __shared__ float red[8][128];
  int t = threadIdx.x, lane = t & 63, w = t >> 6;
  int r = blockIdx.x;
  int cnt = cntr[r], base = roffs[r];
  float2 rr = *(const float2*)(R + (size_t)r*D + 2*lane);
  float bp0 = bprime[2*lane], bp1 = bprime[2*lane+1];
  float a1x = a1c[2*lane],     a1y = a1c[2*lane+1];
  float ccx = a1c[128+2*lane], ccy = a1c[128+2*lane+1];
  float kap = a1c[384];
  float rhor = rho[r];
  float sx = 0.f, sy = 0.f;
  for(int j=w; j<cnt; j+=8){
    u64 pr = rpair[base+j];
    int t0 = (int)(pr & 0x3FFFF);
    int t1 = (int)((pr>>18) & 0x3FFFF);
    float s1 = alpha[t0] + beta[t1] + rhor + kap;
    float s2 = alpha[t1] + beta[t0] - rhor + kap;
    float e1 = expf(s1 >= 0.f ? -s1 : -0.01f*s1);
    float e2 = expf(s2 >= 0.f ? -s2 : -0.01f*s2);
    u32 ua0 = *(const u32*)(A + (size_t)t0*D + 2*lane);
    u32 ua1 = *(const u32*)(A + (size_t)t1*D + 2*lane);
    u32 ub0 = *(const u32*)(B + (size_t)t0*D + 2*lane);
    u32 ub1 = *(const u32*)(B + (size_t)t1*D + 2*lane);
    float y1x = bfl(ua0)+bfl(ub1)+rr.x+bp0;
    float y1y = bfh(ua0)+bfh(ub1)+rr.y+bp1;
    float y2x = bfl(ua1)+bfl(ub0)-rr.x+bp0;
    float y2y = bfh(ua1)+bfh(ub0)-rr.y+bp1;
    float c1x = y1x*a1x+ccx, c1y = y1y*a1y+ccy;
    float c2x = y2x*a1x+ccx, c2y = y2y*a1y+ccy;
    sx += e1*c1x - e2*c2x;
    sy += e1*c1y - e2*c2y;
  }
  float2 p; p.x = sx; p.y = sy;
  *(float2*)&red[w][2*lane] = p;
  __syncthreads();
  if(t < 128){
    float s = 0.f;
    #pragma unroll
    for(int k=0;k<8;k++) s += red[k][t];
    float cf = cnt > 0 ? (float)cnt : 1.0f;
    out_hrel[(size_t)r*D + t] = s/cf;
  }
}

// ------- K12: RotatE score (bf16 gathers), x2 unrolled -----------------------
__global__ __launch_bounds__(256) void k_score_bf(const u64* __restrict__ pair64,
    const u32* __restrict__ entbf, const float* __restrict__ cosr,
    const float* __restrict__ sinr, float* __restrict__ score){
  int t = threadIdx.x, lane = t & 63;
  int gw = blockIdx.x*4 + (t>>6), nw = gridDim.x*4;
  int half = lane & 1;
  int pidx = lane >> 1;
  for(int i=gw; i<N_TRIP; i+=2*nw){
    u64 prA = pair64[i];
    int a0 = (int)(prA & 0x3FFFF);
    int a1 = (int)((prA>>18) & 0x3FFFF);
    int a2 = (int)(prA>>36);
    u32 ph0A = entbf[(size_t)a0*64 + pidx];
    u32 pi0A = entbf[(size_t)a0*64 + 32 + pidx];
    u32 ph1A = entbf[(size_t)a1*64 + pidx];
    u32 pi1A = entbf[(size_t)a1*64 + 32 + pidx];
    int i2 = i + nw;
    bool hasB = (i2 < N_TRIP);
    u64 prB = hasB ? pair64[i2] : prA;
    int b0 = (int)(prB & 0x3FFFF);
    int b1 = (int)((prB>>18) & 0x3FFFF);
    int b2 = (int)(prB>>36);
    u32 ph0B = entbf[(size_t)b0*64 + pidx];
    u32 pi0B = entbf[(size_t)b0*64 + 32 + pidx];
    u32 ph1B = entbf[(size_t)b1*64 + pidx];
    u32 pi1B = entbf[(size_t)b1*64 + 32 + pidx];
    float crA = cosr[a2*64 + lane], srA = sinr[a2*64 + lane];
    float crB = cosr[b2*64 + lane], srB = sinr[b2*64 + lane];
    float re_hA = half ? bfh(ph0A) : bfl(ph0A);
    float im_hA = half ? bfh(pi0A) : bfl(pi0A);
    float re_tA = half ? bfh(ph1A) : bfl(ph1A);
    float im_tA = half ? bfh(pi1A) : bfl(pi1A);
    float re_hB = half ? bfh(ph0B) : bfl(ph0B);
    float im_hB = half ? bfh(pi0B) : bfl(pi0B);
    float re_tB = half ? bfh(ph1B) : bfl(ph1B);
    float im_tB = half ? bfh(pi1B) : bfl(pi1B);
    float re_sA = crA*re_tA + srA*im_tA - re_hA;
    float im_sA = crA*im_tA - srA*re_tA - im_hA;
    float re_sB = crB*re_tB + srB*im_tB - re_hB;
    float im_sB = crB*im_tB - srB*re_tB - im_hB;
    float dA = sqrtf(re_sA*re_sA + im_sA*im_sA);
    float dB = sqrtf(re_sB*re_sB + im_sB*im_sB);
    #pragma unroll
    for(int o=32;o>0;o>>=1){
      dA += __shfl_xor(dA,o,64);
      dB += __shfl_xor(dB,o,64);
    }
    if(lane==0){
      score[i] = MARGINF - dA;
      if(hasB) score[i2] = MARGINF - dB;
    }
  }
}

// fp32 fallback if workspace too small for entbf
__global__ __launch_bounds__(256) void k_score_fp(const u64* __restrict__ pair64,
    const float* __restrict__ ent, const float* __restrict__ cosr,
    const float* __restrict__ sinr, float* __restrict__ score){
  int t = threadIdx.x, lane = t & 63;
  int gw = blockIdx.x*4 + (t>>6), nw = gridDim.x*4;
  for(int i=gw; i<N_TRIP; i+=nw){
    u64 pr = pair64[i];
    int t0 = (int)(pr & 0x3FFFF);
    int t1 = (int)((pr>>18) & 0x3FFFF);
    int t2 = (int)(pr>>36);
    float re_h = ent[(size_t)t0*D + lane];
    float im_h = ent[(size_t)t0*D + 64 + lane];
    float re_t = ent[(size_t)t1*D + lane];
    float im_t = ent[(size_t)t1*D + 64 + lane];
    float cr = cosr[t2*64 + lane], sr = sinr[t2*64 + lane];
    float re_s = cr*re_t + sr*im_t - re_h;
    float im_s = cr*im_t - sr*re_t - im_h;
    float d = sqrtf(re_s*re_s + im_s*im_s);
    #pragma unroll
    for(int o=32;o>0;o>>=1) d += __shfl_xor(d,o,64);
    if(lane==0) score[i] = MARGINF - d;
  }
}

extern "C" void kernel_launch(void* const* d_in, const int* in_sizes, int n_in,
                              void* d_out, int out_size, void* d_ws, size_t ws_size,
                              hipStream_t stream){
  const int*   trip   = (const int*)  d_in[0];
  const float* ent    = (const float*)d_in[1];
  const float* rel    = (const float*)d_in[2];
  const float* W_a    = (const float*)d_in[3];
  const float* b_a    = (const float*)d_in[4];
  const float* W_a2   = (const float*)d_in[5];
  const float* b_a2   = (const float*)d_in[6];
  const float* gamma0 = (const float*)d_in[7];
  const float* beta0  = (const float*)d_in[8];
  const float* gamma1 = (const float*)d_in[9];
  const float* beta1  = (const float*)d_in[10];

  char* ws = (char*)d_ws;
  size_t off = 0;
  auto take = [&](size_t bytes)->void*{
    void* p = ws + off;
    off += (bytes + 255) & ~(size_t)255;
    return p;
  };
  // ---- zeroed scratch (contiguous from 0) ----
  int*   cnt0    = (int*)  take((size_t)N_ENT*4);
  int*   cnt1    = (int*)  take((size_t)N_ENT*4);
  int*   cntr    = (int*)  take((size_t)N_REL*4);
  float* stats   = (float*)take(640*4);
  float* sums    = (float*)take(256*4);
  size_t zero_bytes = off;
  // ---- fully-overwritten scratch ----
  int*   offs      = (int*)  take((size_t)N_ENT*4);
  int*   cur       = (int*)  take((size_t)N_ENT*4);
  int*   bsum      = (int*)  take(512*4);
  int*   boffs     = (int*)  take(512*4);
  int*   roffs     = (int*)  take(512*4);
  int*   rcur      = (int*)  take(512*4);
  u32*   ebuf      = (u32*)  take((size_t)2*N_TRIP*4);
  u64*   pair64    = (u64*)  take((size_t)N_TRIP*8);
  u64*   rpair     = (u64*)  take((size_t)N_TRIP*8);
  float* scale     = (float*)take((size_t)N_ENT*4);
  float* scale_rel = (float*)take((size_t)N_REL*4);
  u16*   Wbf       = (u16*)  take(256*128*2);
  float* W2        = (float*)take(128*128*4);
  float* bprime    = (float*)take(128*4);
  float* a1c       = (float*)take(512*4);
  float* R         = (float*)take((size_t)N_REL*D*4);
  float* cosr      = (float*)take((size_t)N_REL*64*4);
  float* sinr      = (float*)take((size_t)N_REL*64*4);
  float* alpha     = (float*)take((size_t)N_ENT*4);
  float* betab     = (float*)take((size_t)N_ENT*4);
  float* rho       = (float*)take(512*4);
  u16*   Abuf      = (u16*)  take((size_t)N_ENT*D*2);
  u16*   Bbuf      = (u16*)  take((size_t)N_ENT*D*2);
  u32*   entbf     = (u32*)  take((size_t)N_ENT*64*4);
  bool use_bf = (off <= ws_size);
  (void)n_in; (void)in_sizes; (void)out_size;

  float* out_hent  = (float*)d_out;
  float* out_hrel  = out_hent + (size_t)N_ENT*D;
  float* out_score = out_hrel + (size_t)N_REL*D;

  hipMemsetAsync(d_ws, 0, zero_bytes, stream);

  const int SCAN_BLKS = (N_ENT + 1023)/1024;   // 196
  k_hist     <<<(N_TRIP+255)/256, 256, 0, stream>>>(trip, cnt0, cnt1, cntr);
  k_scan1    <<<SCAN_BLKS, 1024, 0, stream>>>(cnt0, cnt1, offs, bsum);
  k_scan2    <<<1, 512, 0, stream>>>(bsum, boffs, cntr, roffs, rcur, SCAN_BLKS);
  k_scan3    <<<SCAN_BLKS, 1024, 0, stream>>>(offs, boffs, cur);
  k_edges    <<<(N_TRIP+255)/256, 256, 0, stream>>>(trip, cur, rcur, ebuf, pair64, rpair);
  k_entstats <<<2048, 256, 0, stream>>>(ent, cnt0, cnt1, scale, stats,
                                        use_bf ? entbf : (u32*)nullptr);
  k_relstats <<<(N_REL+3)/4, 256, 0, stream>>>(rel, cntr, scale_rel, stats, cosr, sinr);
  k_bn0fin   <<<1, 384, 0, stream>>>(stats, W_a, b_a, gamma0, beta0, Wbf, W2, bprime);
  k_relproj  <<<N_REL, 128, 0, stream>>>(rel, scale_rel, W2, R);
  k_ab       <<<2048, 256, 0, stream>>>(ent, scale, Wbf, Abuf, Bbuf);
  k_bn1stats <<<2048, 256, 0, stream>>>(pair64, Abuf, Bbuf, R, bprime, sums);
  k_bn1fin   <<<1, 128, 0, stream>>>(sums, gamma1, beta1, W_a2, b_a2, bprime, a1c);
  k_alphabeta<<<2048, 256, 0, stream>>>(Abuf, Bbuf, R, a1c, alpha, betab, rho);
  k_ent      <<<2048, 256, 0, stream>>>(offs, cur, ebuf, Abuf, Bbuf, R,
                                        bprime, a1c, alpha, betab, rho, out_hent);
  k_rel      <<<N_REL, 512, 0, stream>>>(roffs, cntr, rpair, Abuf, Bbuf, R,
                                         bprime, a1c, alpha, betab, rho, out_hrel);
  if(use_bf)
    k_score_bf<<<2048, 256, 0, stream>>>(pair64, entbf, cosr, sinr, out_score);
  else
    k_score_fp<<<2048, 256, 0, stream>>>(pair64, ent, cosr, sinr, out_score);
}

// Round 8
// 591.656 us; speedup vs baseline: 2.7428x; 1.0277x over previous
//
#include <hip/hip_runtime.h>
#include <stdint.h>

#define N_TRIP 200000
#define N_ENT  200000
#define N_REL  500
#define D      128
#define MARGINF 6.0f
#define BN_EPSF 1e-5f
#define PHASE_C 50.26548245743669f   // PI / REL_RANGE, REL_RANGE = 8/128

typedef unsigned short u16;
typedef unsigned int   u32;
typedef unsigned long long u64;
typedef __attribute__((ext_vector_type(8))) short short8;
typedef __attribute__((ext_vector_type(4))) float f32x4;
typedef __attribute__((ext_vector_type(4))) unsigned short u16x4;

__device__ inline float bfl(u32 u){ return __uint_as_float(u<<16); }
__device__ inline float bfh(u32 u){ return __uint_as_float(u&0xffff0000u); }
__device__ inline u16 f2bf(float f){
  u32 u = __float_as_uint(f);
  u32 r = (u + 0x7fffu + ((u>>16)&1u))>>16;
  return (u16)r;
}

// ---------------- K1: histogram of head / tail / rel indices ----------------
__global__ __launch_bounds__(256) void k_hist(const int* __restrict__ trip,
    int* __restrict__ cnt0, int* __restrict__ cnt1, int* __restrict__ cntr){
  int i = blockIdx.x*256 + threadIdx.x;
  if(i < N_TRIP){
    atomicAdd(&cnt0[trip[3*i]],   1);
    atomicAdd(&cnt1[trip[3*i+1]], 1);
    atomicAdd(&cntr[trip[3*i+2]], 1);
  }
}

// ---------------- CSR build: 3-kernel prefix scan + cursor scatter ----------
__global__ __launch_bounds__(1024) void k_scan1(const int* __restrict__ cnt0,
    const int* __restrict__ cnt1, int* __restrict__ offs, int* __restrict__ bsum){
  __shared__ int sh[1024];
  int t = threadIdx.x;
  int e = blockIdx.x*1024 + t;
  int d = (e < N_ENT) ? cnt0[e] + cnt1[e] : 0;
  sh[t] = d; __syncthreads();
  for(int st=1; st<1024; st<<=1){
    int x = (t>=st) ? sh[t-st] : 0;
    __syncthreads();
    sh[t] += x;
    __syncthreads();
  }
  if(e < N_ENT) offs[e] = sh[t] - d;
  if(t == 1023) bsum[blockIdx.x] = sh[t];
}

__global__ __launch_bounds__(512) void k_scan2(const int* __restrict__ bsum,
    int* __restrict__ boffs, const int* __restrict__ cntr,
    int* __restrict__ roffs, int* __restrict__ rcur, int nblk){
  __shared__ int sh[512];
  int t = threadIdx.x;
  int v = (t < nblk) ? bsum[t] : 0;
  sh[t] = v; __syncthreads();
  for(int st=1; st<512; st<<=1){
    int x = (t>=st) ? sh[t-st] : 0;
    __syncthreads(); sh[t] += x; __syncthreads();
  }
  if(t < nblk) boffs[t] = sh[t] - v;
  __syncthreads();
  int w = (t < N_REL) ? cntr[t] : 0;
  sh[t] = w; __syncthreads();
  for(int st=1; st<512; st<<=1){
    int x = (t>=st) ? sh[t-st] : 0;
    __syncthreads(); sh[t] += x; __syncthreads();
  }
  if(t < N_REL){ roffs[t] = sh[t]-w; rcur[t] = sh[t]-w; }
}

__global__ __launch_bounds__(1024) void k_scan3(int* __restrict__ offs,
    const int* __restrict__ boffs, int* __restrict__ cur){
  int e = blockIdx.x*1024 + threadIdx.x;
  if(e < N_ENT){
    int o = offs[e] + boffs[blockIdx.x];
    offs[e] = o;
    cur[e] = o;
  }
}

// edge records: ebuf = other<<10 | t2<<1 | role ; pair64 = t0 | t1<<18 | t2<<36
__global__ __launch_bounds__(256) void k_edges(const int* __restrict__ trip,
    int* __restrict__ cur, int* __restrict__ rcur,
    u32* __restrict__ ebuf, u64* __restrict__ pair64, u64* __restrict__ rpair){
  int i = blockIdx.x*256 + threadIdx.x;
  if(i < N_TRIP){
    int t0 = trip[3*i], t1 = trip[3*i+1], t2 = trip[3*i+2];
    u64 pr = ((u64)t2<<36) | ((u64)t1<<18) | (u64)t0;
    pair64[i] = pr;
    ebuf[atomicAdd(&cur[t0], 1)] = ((u32)t1<<10) | ((u32)t2<<1);
    ebuf[atomicAdd(&cur[t1], 1)] = ((u32)t0<<10) | ((u32)t2<<1) | 1u;
    rpair[atomicAdd(&rcur[t2], 1)] = pr;
  }
}

// ------- K2a: pure-streaming prep: entnbf (normalized bf16) + entbf (raw) ---
// 16-lane groups: 4 rows/wave, each lane owns 8 contiguous cols. No atomics.
__global__ __launch_bounds__(256) void k_prep(const float* __restrict__ ent,
    u32* __restrict__ entnbf, u32* entbf){
  int t = threadIdx.x, lane = t & 63;
  int l16 = lane & 15, g = lane >> 4;
  int wid = blockIdx.x*4 + (t>>6), nw = gridDim.x*4;
  for(int e4 = wid*4; e4 < N_ENT; e4 += nw*4){
    int e = e4 + g;
    const float* xp = ent + (size_t)e*D + l16*8;
    float4 x0 = *(const float4*)xp;
    float4 x1 = *(const float4*)(xp+4);
    if(entbf){
      uint4 pk;
      pk.x = (u32)f2bf(x0.x) | ((u32)f2bf(x0.y)<<16);
      pk.y = (u32)f2bf(x0.z) | ((u32)f2bf(x0.w)<<16);
      pk.z = (u32)f2bf(x1.x) | ((u32)f2bf(x1.y)<<16);
      pk.w = (u32)f2bf(x1.z) | ((u32)f2bf(x1.w)<<16);
      *(uint4*)(entbf + (size_t)e*64 + l16*4) = pk;
    }
    float ss = x0.x*x0.x + x0.y*x0.y + x0.z*x0.z + x0.w*x0.w
             + x1.x*x1.x + x1.y*x1.y + x1.z*x1.z + x1.w*x1.w;
    #pragma unroll
    for(int o=8;o>0;o>>=1) ss += __shfl_xor(ss,o,64);
    float nrm = sqrtf(ss);
    float sc = nrm > 1.0f ? 1.0f/nrm : 1.0f;
    uint4 pn;
    pn.x = (u32)f2bf(x0.x*sc) | ((u32)f2bf(x0.y*sc)<<16);
    pn.y = (u32)f2bf(x0.z*sc) | ((u32)f2bf(x0.w*sc)<<16);
    pn.z = (u32)f2bf(x1.x*sc) | ((u32)f2bf(x1.y*sc)<<16);
    pn.w = (u32)f2bf(x1.z*sc) | ((u32)f2bf(x1.w*sc)<<16);
    *(uint4*)(entnbf + (size_t)e*64 + l16*4) = pn;
  }
}

// ------- K2b: BN0 column stats from L3-hot entnbf; per-lane col accumulators -
__global__ __launch_bounds__(256) void k_stats(const u32* __restrict__ entnbf,
    const int* __restrict__ cnt0, const int* __restrict__ cnt1,
    float* __restrict__ stats){
  __shared__ float acc[512];
  int t = threadIdx.x;
  acc[t] = 0.f; acc[t+256] = 0.f;
  __syncthreads();
  int lane = t & 63;
  int l16 = lane & 15, g = lane >> 4;
  int wid = blockIdx.x*4 + (t>>6), nw = gridDim.x*4;
  float s0[8]={0,0,0,0,0,0,0,0}, s1[8]={0,0,0,0,0,0,0,0};
  float q0[8]={0,0,0,0,0,0,0,0}, q1[8]={0,0,0,0,0,0,0,0};
  for(int e4 = wid*4; e4 < N_ENT; e4 += nw*4){
    int e = e4 + g;
    uint4 u = *(const uint4*)(entnbf + (size_t)e*64 + l16*4);
    float w0 = (float)cnt0[e], w1 = (float)cnt1[e];
    float v[8] = {bfl(u.x),bfh(u.x),bfl(u.y),bfh(u.y),
                  bfl(u.z),bfh(u.z),bfl(u.w),bfh(u.w)};
    #pragma unroll
    for(int k=0;k<8;k++){
      s0[k] += w0*v[k]; s1[k] += w1*v[k];
      q0[k] += w0*v[k]*v[k]; q1[k] += w1*v[k]*v[k];
    }
  }
  #pragma unroll
  for(int k=0;k<8;k++){
    int c = l16*8 + k;
    atomicAdd(&acc[c],     s0[k]);
    atomicAdd(&acc[128+c], s1[k]);
    atomicAdd(&acc[256+c], q0[k]);
    atomicAdd(&acc[384+c], q1[k]);
  }
  __syncthreads();
  atomicAdd(&stats[t],     acc[t]);
  atomicAdd(&stats[t+256], acc[t+256]);
}

// ------- K3: per-rel scale + Qr stats + cos/sin phase tables ---------------
__global__ __launch_bounds__(256) void k_relstats(const float* __restrict__ rel,
    const int* __restrict__ cntr, float* __restrict__ scale_rel,
    float* __restrict__ stats, float* __restrict__ cosr, float* __restrict__ sinr){
  int t = threadIdx.x, lane = t & 63;
  int r = blockIdx.x*4 + (t>>6);
  if(r >= N_REL) return;
  float2 x = *(const float2*)(rel + (size_t)r*D + 2*lane);
  float ss = x.x*x.x + x.y*x.y;
  #pragma unroll
  for(int o=32;o>0;o>>=1) ss += __shfl_xor(ss,o,64);
  float nrm = sqrtf(ss);
  float sc = nrm > 1.0f ? 1.0f/nrm : 1.0f;
  if(lane==0) scale_rel[r] = sc;
  float w = (float)cntr[r];
  float sx = x.x*sc, sy = x.y*sc;
  atomicAdd(&stats[512 + 2*lane  ], w*sx*sx);
  atomicAdd(&stats[512 + 2*lane+1], w*sy*sy);
  if(lane < 32){
    cosr[r*64 + 2*lane  ] = cosf(x.x*PHASE_C);
    sinr[r*64 + 2*lane  ] = sinf(x.x*PHASE_C);
    cosr[r*64 + 2*lane+1] = cosf(x.y*PHASE_C);
    sinr[r*64 + 2*lane+1] = sinf(x.y*PHASE_C);
  }
}

// ------- K4: finalize BN0, build folded bf16 weights Wbf, W2 and b' ---------
__global__ __launch_bounds__(384) void k_bn0fin(const float* __restrict__ stats,
    const float* __restrict__ W_a, const float* __restrict__ b_a,
    const float* __restrict__ gamma0, const float* __restrict__ beta0,
    u16* __restrict__ Wbf, float* __restrict__ W2, float* __restrict__ bprime){
  __shared__ float a0[384], c0[384];
  int t = threadIdx.x;
  {
    int j = t & 127;
    float mu, ex2;
    if(t < 256){
      mu  = (stats[j]     + stats[128+j]) * (1.0f/(2.0f*N_TRIP));
      ex2 = (stats[256+j] + stats[384+j]) * (1.0f/(2.0f*N_TRIP));
    } else {
      mu  = 0.0f;
      ex2 = stats[512+j] * (1.0f/N_TRIP);
    }
    float var = ex2 - mu*mu;
    float a = gamma0[t]*rsqrtf(var + BN_EPSF);
    a0[t] = a;
    c0[t] = beta0[t] - mu*a;
  }
  __syncthreads();
  for(int idx=t; idx<256*128; idx+=384){
    int j = idx>>7, k = idx&127;
    int ko = ((j>>7)<<7) + k;
    Wbf[idx] = f2bf(W_a[(j&127)*384 + ko]*a0[ko]);
  }
  for(int idx=t; idx<128*128; idx+=384){
    int k = idx>>7, j = idx&127;
    W2[idx] = W_a[j*384 + 256 + k]*a0[256+k];
  }
  if(t < 128){
    float s = b_a[t];
    for(int k=0;k<384;k++) s += W_a[t*384+k]*c0[k];
    bprime[t] = s;
  }
}

// ------- K5: R[r] = rel_n[r] @ W2 ------------------------------------------
__global__ __launch_bounds__(128) void k_relproj(const float* __restrict__ rel,
    const float* __restrict__ scale_rel, const float* __restrict__ W2,
    float* __restrict__ R){
  int r = blockIdx.x, j = threadIdx.x;
  __shared__ float x[128];
  x[j] = rel[(size_t)r*D + j]*scale_rel[r];
  __syncthreads();
  float s = 0.f;
  for(int k=0;k<128;k++) s += x[k]*W2[k*128+j];
  R[r*128+j] = s;
}

// ------- K6: A/B projection via MFMA; input is pre-normalized bf16 ----------
__global__ __launch_bounds__(256) void k_ab(const u32* __restrict__ entnbf,
    const u16* __restrict__ Wbf, u16* __restrict__ Abuf, u16* __restrict__ Bbuf){
  __shared__ u16 xlds[16*128];
  int t = threadIdx.x, lane = t & 63, q = t >> 6;
  int kgrp = (lane>>4)<<3;
  int rgrp = (lane>>4)<<2;
  int frow = lane & 15;
  short8 wf[4][4];
  #pragma unroll
  for(int jt=0;jt<4;jt++){
    #pragma unroll
    for(int kt=0;kt<4;kt++)
      wf[jt][kt] = *(const short8*)(Wbf + (size_t)(q*64 + jt*16 + frow)*D + kgrp + kt*32);
  }
  int srow = t>>4;
  int scol16 = t&15;                 // uint4 index within row (8 bf16 cols)
  char* swp = (char*)xlds + srow*256 + ((scol16<<4) ^ ((srow&7)<<4));
  const char* rdp = (const char*)xlds + frow*256;
  int rbase0 = (lane>>4)<<4;
  int fsw = (frow&7)<<4;
  for(int chunk = blockIdx.x; chunk < N_ENT/16; chunk += gridDim.x){
    uint4 pk = *(const uint4*)(entnbf + (size_t)(chunk*16 + srow)*64 + scol16*4);
    __syncthreads();
    *(uint4*)swp = pk;
    __syncthreads();
    short8 xf[4];
    #pragma unroll
    for(int kt=0;kt<4;kt++)
      xf[kt] = *(const short8*)(rdp + ((rbase0 + kt*64) ^ fsw));
    int erow = chunk*16 + frow;
    #pragma unroll
    for(int jt=0;jt<4;jt++){
      f32x4 acc = {0.f,0.f,0.f,0.f};
      #pragma unroll
      for(int kt=0;kt<4;kt++)
        acc = __builtin_amdgcn_mfma_f32_16x16x32_bf16(wf[jt][kt], xf[kt], acc, 0,0,0);
      int jbase = q*64 + jt*16 + rgrp;
      u16x4 opk;
      opk.x=f2bf(acc[0]); opk.y=f2bf(acc[1]); opk.z=f2bf(acc[2]); opk.w=f2bf(acc[3]);
      u16* dst = (jbase < 128) ? (Abuf + (size_t)erow*D + jbase)
                               : (Bbuf + (size_t)erow*D + (jbase-128));
      *(u16x4*)dst = opk;
    }
  }
}

// ------- K7: BN1 statistics, 1/2 subsample, x2 unrolled ----------------------
__global__ __launch_bounds__(256) void k_bn1stats(const u64* __restrict__ pair64,
    const u16* __restrict__ A, const u16* __restrict__ B,
    const float* __restrict__ R, const float* __restrict__ bprime,
    float* __restrict__ sums){
  __shared__ float acc[256];
  int t = threadIdx.x;
  acc[t] = 0.f;
  __syncthreads();
  int lane = t & 63;
  int gw = blockIdx.x*4 + (t>>6), nw = gridDim.x*4;
  float bp0 = bprime[2*lane], bp1 = bprime[2*lane+1];
  float s0=0,s1=0,q0=0,q1=0;
  for(int i=2*gw; i<N_TRIP; i+=4*nw){
    {
      u64 pr = pair64[i];
      int t0 = (int)(pr & 0x3FFFF);
      int t1 = (int)((pr>>18) & 0x3FFFF);
      int t2 = (int)(pr>>36);
      u32 ua0 = *(const u32*)(A + (size_t)t0*D + 2*lane);
      u32 ua1 = *(const u32*)(A + (size_t)t1*D + 2*lane);
      u32 ub0 = *(const u32*)(B + (size_t)t0*D + 2*lane);
      u32 ub1 = *(const u32*)(B + (size_t)t1*D + 2*lane);
      float2 r = *(const float2*)(R + (size_t)t2*D + 2*lane);
      float y1x = bfl(ua0)+bfl(ub1)+r.x+bp0;
      float y1y = bfh(ua0)+bfh(ub1)+r.y+bp1;
      float y2x = bfl(ua1)+bfl(ub0)-r.x+bp0;
      float y2y = bfh(ua1)+bfh(ub0)-r.y+bp1;
      s0 += y1x+y2x; s1 += y1y+y2y;
      q0 += y1x*y1x + y2x*y2x; q1 += y1y*y1y + y2y*y2y;
    }
    int i2 = i + 2*nw;
    if(i2 < N_TRIP){
      u64 pr = pair64[i2];
      int t0 = (int)(pr & 0x3FFFF);
      int t1 = (int)((pr>>18) & 0x3FFFF);
      int t2 = (int)(pr>>36);
      u32 ua0 = *(const u32*)(A + (size_t)t0*D + 2*lane);
      u32 ua1 = *(const u32*)(A + (size_t)t1*D + 2*lane);
      u32 ub0 = *(const u32*)(B + (size_t)t0*D + 2*lane);
      u32 ub1 = *(const u32*)(B + (size_t)t1*D + 2*lane);
      float2 r = *(const float2*)(R + (size_t)t2*D + 2*lane);
      float y1x = bfl(ua0)+bfl(ub1)+r.x+bp0;
      float y1y = bfh(ua0)+bfh(ub1)+r.y+bp1;
      float y2x = bfl(ua1)+bfl(ub0)-r.x+bp0;
      float y2y = bfh(ua1)+bfh(ub0)-r.y+bp1;
      s0 += y1x+y2x; s1 += y1y+y2y;
      q0 += y1x*y1x + y2x*y2x; q1 += y1y*y1y + y2y*y2y;
    }
  }
  atomicAdd(&acc[      2*lane  ], s0);
  atomicAdd(&acc[      2*lane+1], s1);
  atomicAdd(&acc[128 + 2*lane  ], q0);
  atomicAdd(&acc[128 + 2*lane+1], q1);
  __syncthreads();
  atomicAdd(&sums[t], acc[t]);
}

// ------- K8: finalize BN1 + wa1 = W_a2 .* a1 + kappa ------------------------
__global__ __launch_bounds__(128) void k_bn1fin(const float* __restrict__ sums,
    const float* __restrict__ gamma1, const float* __restrict__ beta1,
    const float* __restrict__ W_a2, const float* __restrict__ b_a2,
    const float* __restrict__ bprime, float* __restrict__ a1c){
  __shared__ float red[128];
  int j = threadIdx.x;
  float mu  = sums[j]    *(1.0f/(float)N_TRIP);
  float var = sums[128+j]*(1.0f/(float)N_TRIP) - mu*mu;
  float a = gamma1[j]*rsqrtf(var + BN_EPSF);
  float cc = beta1[j] - mu*a;
  float wa1 = W_a2[j]*a;
  a1c[j]     = a;
  a1c[128+j] = cc;
  a1c[256+j] = wa1;
  red[j] = W_a2[j]*cc + wa1*bprime[j];
  __syncthreads();
  #pragma unroll
  for(int s=64; s>0; s>>=1){
    if(j < s) red[j] += red[j+s];
    __syncthreads();
  }
  if(j==0) a1c[384] = red[0] + b_a2[0];
}

// ------- K8b: per-entity scalars alpha/beta/rho, 32-lane groups, x2 unroll --
__global__ __launch_bounds__(256) void k_alphabeta(const u16* __restrict__ A,
    const u16* __restrict__ B, const float* __restrict__ R,
    const float* __restrict__ a1c, float* __restrict__ alpha,
    float* __restrict__ beta, float* __restrict__ rho){
  int t = threadIdx.x, lane = t & 63;
  int l32 = lane & 31, grp = lane >> 5;
  int wid = blockIdx.x*4 + (t>>6), nw = gridDim.x*4;
  float4 wa = *(const float4*)(a1c + 256 + l32*4);
  for(int e4 = wid*4; e4 < N_ENT; e4 += nw*4){
    int eA = e4 + grp, eB = e4 + 2 + grp;
    uint2 uaA = *(const uint2*)(A + (size_t)eA*D + l32*4);
    uint2 ubA = *(const uint2*)(B + (size_t)eA*D + l32*4);
    uint2 uaB = *(const uint2*)(A + (size_t)eB*D + l32*4);
    uint2 ubB = *(const uint2*)(B + (size_t)eB*D + l32*4);
    float daA = wa.x*bfl(uaA.x) + wa.y*bfh(uaA.x) + wa.z*bfl(uaA.y) + wa.w*bfh(uaA.y);
    float dbA = wa.x*bfl(ubA.x) + wa.y*bfh(ubA.x) + wa.z*bfl(ubA.y) + wa.w*bfh(ubA.y);
    float daB = wa.x*bfl(uaB.x) + wa.y*bfh(uaB.x) + wa.z*bfl(uaB.y) + wa.w*bfh(uaB.y);
    float dbB = wa.x*bfl(ubB.x) + wa.y*bfh(ubB.x) + wa.z*bfl(ubB.y) + wa.w*bfh(ubB.y);
    #pragma unroll
    for(int o=16;o>0;o>>=1){
      daA += __shfl_xor(daA,o,64); dbA += __shfl_xor(dbA,o,64);
      daB += __shfl_xor(daB,o,64); dbB += __shfl_xor(dbB,o,64);
    }
    if(l32==0){ alpha[eA]=daA; beta[eA]=dbA; alpha[eB]=daB; beta[eB]=dbB; }
  }
  for(int r2 = wid*2 + grp; r2 < N_REL; r2 += nw*2){
    float4 rr = *(const float4*)(R + (size_t)r2*D + l32*4);
    float dr = wa.x*rr.x + wa.y*rr.y + wa.z*rr.z + wa.w*rr.w;
    #pragma unroll
    for(int o=16;o>0;o>>=1) dr += __shfl_xor(dr,o,64);
    if(l32==0) rho[r2]=dr;
  }
}

// ------- K9: per-entity gather, 16-lane groups (4 entities/wave) ------------
__global__ __launch_bounds__(256) void k_ent(
    const int* __restrict__ offs, const int* __restrict__ endp,
    const u32* __restrict__ ebuf,
    const u16* __restrict__ A, const u16* __restrict__ B,
    const float* __restrict__ R, const float* __restrict__ bprime,
    const float* __restrict__ a1c, const float* __restrict__ alpha,
    const float* __restrict__ beta, const float* __restrict__ rho,
    float* __restrict__ out_hent){
  int t = threadIdx.x, lane = t & 63;
  int l16 = lane & 15, g = lane >> 4;
  int wid = blockIdx.x*4 + (t>>6), nw = gridDim.x*4;
  int cb = l16*8;
  float4 bpA = *(const float4*)(bprime + cb);
  float4 bpB = *(const float4*)(bprime + cb + 4);
  float4 a1A = *(const float4*)(a1c + cb);
  float4 a1B = *(const float4*)(a1c + cb + 4);
  float4 ccA = *(const float4*)(a1c + 128 + cb);
  float4 ccB = *(const float4*)(a1c + 128 + cb + 4);
  float kap = a1c[384];
  for(int e4 = wid*4; e4 < N_ENT; e4 += nw*4){
    int e = e4 + g;
    int s = offs[e], en = endp[e];
    uint4 ua = *(const uint4*)(A + (size_t)e*D + cb);
    float ax0 = bfl(ua.x), ax1 = bfh(ua.x), ax2 = bfl(ua.y), ax3 = bfh(ua.y);
    float ax4 = bfl(ua.z), ax5 = bfh(ua.z), ax6 = bfl(ua.w), ax7 = bfh(ua.w);
    float al = alpha[e];
    float h0=0,h1=0,h2=0,h3=0,h4=0,h5=0,h6=0,h7=0, eb=0;
    for(int o=s; o<en; o++){
      u32 id = ebuf[o];
      int ot = id>>10, r2 = (id>>1)&511;
      float sg = (id&1) ? -1.f : 1.f;
      uint4 ub = *(const uint4*)(B + (size_t)ot*D + cb);
      float4 rA = *(const float4*)(R + (size_t)r2*D + cb);
      float4 rB = *(const float4*)(R + (size_t)r2*D + cb + 4);
      float sv = al + beta[ot] + sg*rho[r2] + kap;
      float e_b = expf(sv >= 0.f ? -sv : -0.01f*sv);
      float y, c;
      y = ax0 + bfl(ub.x) + sg*rA.x + bpA.x; c = y*a1A.x + ccA.x; h0 += e_b*c;
      y = ax1 + bfh(ub.x) + sg*rA.y + bpA.y; c = y*a1A.y + ccA.y; h1 += e_b*c;
      y = ax2 + bfl(ub.y) + sg*rA.z + bpA.z; c = y*a1A.z + ccA.z; h2 += e_b*c;
      y = ax3 + bfh(ub.y) + sg*rA.w + bpA.w; c = y*a1A.w + ccA.w; h3 += e_b*c;
      y = ax4 + bfl(ub.z) + sg*rB.x + bpB.x; c = y*a1B.x + ccB.x; h4 += e_b*c;
      y = ax5 + bfh(ub.z) + sg*rB.y + bpB.y; c = y*a1B.y + ccB.y; h5 += e_b*c;
      y = ax6 + bfl(ub.w) + sg*rB.z + bpB.z; c = y*a1B.z + ccB.z; h6 += e_b*c;
      y = ax7 + bfh(ub.w) + sg*rB.w + bpB.w; c = y*a1B.w + ccB.w; h7 += e_b*c;
      eb += e_b;
    }
    float inv = (en > s) ? 1.0f/eb : 0.0f;
    float4 o0; o0.x=h0*inv; o0.y=h1*inv; o0.z=h2*inv; o0.w=h3*inv;
    float4 o1; o1.x=h4*inv; o1.y=h5*inv; o1.z=h6*inv; o1.w=h7*inv;
    *(float4*)(out_hent + (size_t)e*D + cb)     = o0;
    *(float4*)(out_hent + (size_t)e*D + cb + 4) = o1;
  }
}

// ------- K10: per-rel gather pass, packed pairs -----------------------------
__global__ __launch_bounds__(512) void k_rel(
    const int* __restrict__ roffs, const int* __restrict__ cntr,
    const u64* __restrict__ rpair,
    const u16* __restrict__ A, const u16* __restrict__ B,
    const float* __restrict__ R, const float* __restrict__ bprime,
    const float* __restrict__ a1c, const float* __restrict__ alpha,
    const float* __restrict__ beta, const float* __restrict__ rho,
    float* __restrict__ out_hrel){
  __shared__ float red[8][128];
  int t = threadIdx.x, lane = t & 63, w = t >> 6;
  int r = blockIdx.x;
  int cnt = cntr[r], base = roffs[r];
  float2 rr = *(const float2*)(R + (size_t)r*D + 2*lane);
  float bp0 = bprime[2*lane], bp1 = bprime[2*lane+1];
  float a1x = a1c[2*lane],     a1y = a1c[2*lane+1];
  float ccx = a1c[128+2*lane], ccy = a1c[128+2*lane+1];
  float kap = a1c[384];
  float rhor = rho[r];
  float sx = 0.f, sy = 0.f;
  for(int j=w; j<cnt; j+=8){
    u64 pr = rpair[base+j];
    int t0 = (int)(pr & 0x3FFFF);
    int t1 = (int)((pr>>18) & 0x3FFFF);
    float s1 = alpha[t0] + beta[t1] + rhor + kap;
    float s2 = alpha[t1] + beta[t0] - rhor + kap;
    float e1 = expf(s1 >= 0.f ? -s1 : -0.01f*s1);
    float e2 = expf(s2 >= 0.f ? -s2 : -0.01f*s2);
    u32 ua0 = *(const u32*)(A + (size_t)t0*D + 2*lane);
    u32 ua1 = *(const u32*)(A + (size_t)t1*D + 2*lane);
    u32 ub0 = *(const u32*)(B + (size_t)t0*D + 2*lane);
    u32 ub1 = *(const u32*)(B + (size_t)t1*D + 2*lane);
    float y1x = bfl(ua0)+bfl(ub1)+rr.x+bp0;
    float y1y = bfh(ua0)+bfh(ub1)+rr.y+bp1;
    float y2x = bfl(ua1)+bfl(ub0)-rr.x+bp0;
    float y2y = bfh(ua1)+bfh(ub0)-rr.y+bp1;
    float c1x = y1x*a1x+ccx, c1y = y1y*a1y+ccy;
    float c2x = y2x*a1x+ccx, c2y = y2y*a1y+ccy;
    sx += e1*c1x - e2*c2x;
    sy += e1*c1y - e2*c2y;
  }
  float2 p; p.x = sx; p.y = sy;
  *(float2*)&red[w][2*lane] = p;
  __syncthreads();
  if(t < 128){
    float s = 0.f;
    #pragma unroll
    for(int k=0;k<8;k++) s += red[k][t];
    float cf = cnt > 0 ? (float)cnt : 1.0f;
    out_hrel[(size_t)r*D + t] = s/cf;
  }
}

// ------- K12: RotatE score (bf16 gathers), x2 unrolled -----------------------
__global__ __launch_bounds__(256) void k_score_bf(const u64* __restrict__ pair64,
    const u32* __restrict__ entbf, const float* __restrict__ cosr,
    const float* __restrict__ sinr, float* __restrict__ score){
  int t = threadIdx.x, lane = t & 63;
  int gw = blockIdx.x*4 + (t>>6), nw = gridDim.x*4;
  int half = lane & 1;
  int pidx = lane >> 1;
  for(int i=gw; i<N_TRIP; i+=2*nw){
    u64 prA = pair64[i];
    int a0 = (int)(prA & 0x3FFFF);
    int a1 = (int)((prA>>18) & 0x3FFFF);
    int a2 = (int)(prA>>36);
    u32 ph0A = entbf[(size_t)a0*64 + pidx];
    u32 pi0A = entbf[(size_t)a0*64 + 32 + pidx];
    u32 ph1A = entbf[(size_t)a1*64 + pidx];
    u32 pi1A = entbf[(size_t)a1*64 + 32 + pidx];
    int i2 = i + nw;
    bool hasB = (i2 < N_TRIP);
    u64 prB = hasB ? pair64[i2] : prA;
    int b0 = (int)(prB & 0x3FFFF);
    int b1 = (int)((prB>>18) & 0x3FFFF);
    int b2 = (int)(prB>>36);
    u32 ph0B = entbf[(size_t)b0*64 + pidx];
    u32 pi0B = entbf[(size_t)b0*64 + 32 + pidx];
    u32 ph1B = entbf[(size_t)b1*64 + pidx];
    u32 pi1B = entbf[(size_t)b1*64 + 32 + pidx];
    float crA = cosr[a2*64 + lane], srA = sinr[a2*64 + lane];
    float crB = cosr[b2*64 + lane], srB = sinr[b2*64 + lane];
    float re_hA = half ? bfh(ph0A) : bfl(ph0A);
    float im_hA = half ? bfh(pi0A) : bfl(pi0A);
    float re_tA = half ? bfh(ph1A) : bfl(ph1A);
    float im_tA = half ? bfh(pi1A) : bfl(pi1A);
    float re_hB = half ? bfh(ph0B) : bfl(ph0B);
    float im_hB = half ? bfh(pi0B) : bfl(pi0B);
    float re_tB = half ? bfh(ph1B) : bfl(ph1B);
    float im_tB = half ? bfh(pi1B) : bfl(pi1B);
    float re_sA = crA*re_tA + srA*im_tA - re_hA;
    float im_sA = crA*im_tA - srA*re_tA - im_hA;
    float re_sB = crB*re_tB + srB*im_tB - re_hB;
    float im_sB = crB*im_tB - srB*re_tB - im_hB;
    float dA = sqrtf(re_sA*re_sA + im_sA*im_sA);
    float dB = sqrtf(re_sB*re_sB + im_sB*im_sB);
    #pragma unroll
    for(int o=32;o>0;o>>=1){
      dA += __shfl_xor(dA,o,64);
      dB += __shfl_xor(dB,o,64);
    }
    if(lane==0){
      score[i] = MARGINF - dA;
      if(hasB) score[i2] = MARGINF - dB;
    }
  }
}

// fp32 fallback if workspace too small for entbf
__global__ __launch_bounds__(256) void k_score_fp(const u64* __restrict__ pair64,
    const float* __restrict__ ent, const float* __restrict__ cosr,
    const float* __restrict__ sinr, float* __restrict__ score){
  int t = threadIdx.x, lane = t & 63;
  int gw = blockIdx.x*4 + (t>>6), nw = gridDim.x*4;
  for(int i=gw; i<N_TRIP; i+=nw){
    u64 pr = pair64[i];
    int t0 = (int)(pr & 0x3FFFF);
    int t1 = (int)((pr>>18) & 0x3FFFF);
    int t2 = (int)(pr>>36);
    float re_h = ent[(size_t)t0*D + lane];
    float im_h = ent[(size_t)t0*D + 64 + lane];
    float re_t = ent[(size_t)t1*D + lane];
    float im_t = ent[(size_t)t1*D + 64 + lane];
    float cr = cosr[t2*64 + lane], sr = sinr[t2*64 + lane];
    float re_s = cr*re_t + sr*im_t - re_h;
    float im_s = cr*im_t - sr*re_t - im_h;
    float d = sqrtf(re_s*re_s + im_s*im_s);
    #pragma unroll
    for(int o=32;o>0;o>>=1) d += __shfl_xor(d,o,64);
    if(lane==0) score[i] = MARGINF - d;
  }
}

extern "C" void kernel_launch(void* const* d_in, const int* in_sizes, int n_in,
                              void* d_out, int out_size, void* d_ws, size_t ws_size,
                              hipStream_t stream){
  const int*   trip   = (const int*)  d_in[0];
  const float* ent    = (const float*)d_in[1];
  const float* rel    = (const float*)d_in[2];
  const float* W_a    = (const float*)d_in[3];
  const float* b_a    = (const float*)d_in[4];
  const float* W_a2   = (const float*)d_in[5];
  const float* b_a2   = (const float*)d_in[6];
  const float* gamma0 = (const float*)d_in[7];
  const float* beta0  = (const float*)d_in[8];
  const float* gamma1 = (const float*)d_in[9];
  const float* beta1  = (const float*)d_in[10];

  char* ws = (char*)d_ws;
  size_t off = 0;
  auto take = [&](size_t bytes)->void*{
    void* p = ws + off;
    off += (bytes + 255) & ~(size_t)255;
    return p;
  };
  // ---- zeroed scratch (contiguous from 0) ----
  int*   cnt0    = (int*)  take((size_t)N_ENT*4);
  int*   cnt1    = (int*)  take((size_t)N_ENT*4);
  int*   cntr    = (int*)  take((size_t)N_REL*4);
  float* stats   = (float*)take(640*4);
  float* sums    = (float*)take(256*4);
  size_t zero_bytes = off;
  // ---- fully-overwritten scratch (required) ----
  int*   offs      = (int*)  take((size_t)N_ENT*4);
  int*   cur       = (int*)  take((size_t)N_ENT*4);
  int*   bsum      = (int*)  take(512*4);
  int*   boffs     = (int*)  take(512*4);
  int*   roffs     = (int*)  take(512*4);
  int*   rcur      = (int*)  take(512*4);
  u32*   ebuf      = (u32*)  take((size_t)2*N_TRIP*4);
  u64*   pair64    = (u64*)  take((size_t)N_TRIP*8);
  u64*   rpair     = (u64*)  take((size_t)N_TRIP*8);
  float* scale_rel = (float*)take((size_t)N_REL*4);
  u16*   Wbf       = (u16*)  take(256*128*2);
  float* W2        = (float*)take(128*128*4);
  float* bprime    = (float*)take(128*4);
  float* a1c       = (float*)take(512*4);
  float* R         = (float*)take((size_t)N_REL*D*4);
  float* cosr      = (float*)take((size_t)N_REL*64*4);
  float* sinr      = (float*)take((size_t)N_REL*64*4);
  float* alpha     = (float*)take((size_t)N_ENT*4);
  float* betab     = (float*)take((size_t)N_ENT*4);
  float* rho       = (float*)take(512*4);
  u16*   Abuf      = (u16*)  take((size_t)N_ENT*D*2);
  u16*   Bbuf      = (u16*)  take((size_t)N_ENT*D*2);
  u32*   entnbf    = (u32*)  take((size_t)N_ENT*64*4);   // required (<=165MB, proven fit)
  // ---- optional: raw bf16 copy for k_score ----
  u32*   entbf     = (u32*)  take((size_t)N_ENT*64*4);
  bool use_bf = (off <= ws_size);
  (void)n_in; (void)in_sizes; (void)out_size;

  float* out_hent  = (float*)d_out;
  float* out_hrel  = out_hent + (size_t)N_ENT*D;
  float* out_score = out_hrel + (size_t)N_REL*D;

  hipMemsetAsync(d_ws, 0, zero_bytes, stream);

  const int SCAN_BLKS = (N_ENT + 1023)/1024;   // 196
  k_prep     <<<2048, 256, 0, stream>>>(ent, entnbf, use_bf ? entbf : (u32*)nullptr);
  k_hist     <<<(N_TRIP+255)/256, 256, 0, stream>>>(trip, cnt0, cnt1, cntr);
  k_scan1    <<<SCAN_BLKS, 1024, 0, stream>>>(cnt0, cnt1, offs, bsum);
  k_scan2    <<<1, 512, 0, stream>>>(bsum, boffs, cntr, roffs, rcur, SCAN_BLKS);
  k_scan3    <<<SCAN_BLKS, 1024, 0, stream>>>(offs, boffs, cur);
  k_edges    <<<(N_TRIP+255)/256, 256, 0, stream>>>(trip, cur, rcur, ebuf, pair64, rpair);
  k_stats    <<<640, 256, 0, stream>>>(entnbf, cnt0, cnt1, stats);
  k_relstats <<<(N_REL+3)/4, 256, 0, stream>>>(rel, cntr, scale_rel, stats, cosr, sinr);
  k_bn0fin   <<<1, 384, 0, stream>>>(stats, W_a, b_a, gamma0, beta0, Wbf, W2, bprime);
  k_relproj  <<<N_REL, 128, 0, stream>>>(rel, scale_rel, W2, R);
  k_ab       <<<2048, 256, 0, stream>>>(entnbf, Wbf, Abuf, Bbuf);
  k_bn1stats <<<2048, 256, 0, stream>>>(pair64, Abuf, Bbuf, R, bprime, sums);
  k_bn1fin   <<<1, 128, 0, stream>>>(sums, gamma1, beta1, W_a2, b_a2, bprime, a1c);
  k_alphabeta<<<2048, 256, 0, stream>>>(Abuf, Bbuf, R, a1c, alpha, betab, rho);
  k_ent      <<<2048, 256, 0, stream>>>(offs, cur, ebuf, Abuf, Bbuf, R,
                                        bprime, a1c, alpha, betab, rho, out_hent);
  k_rel      <<<N_REL, 512, 0, stream>>>(roffs, cntr, rpair, Abuf, Bbuf, R,
                                         bprime, a1c, alpha, betab, rho, out_hrel);
  if(use_bf)
    k_score_bf<<<2048, 256, 0, stream>>>(pair64, entbf, cosr, sinr, out_score);
  else
    k_score_fp<<<2048, 256, 0, stream>>>(pair64, ent, cosr, sinr, out_score);
}

// Round 9
// 469.508 us; speedup vs baseline: 3.4564x; 1.2602x over previous
//
#include <hip/hip_runtime.h>
#include <stdint.h>

#define N_TRIP 200000
#define N_ENT  200000
#define N_REL  500
#define D      128
#define MARGINF 6.0f
#define BN_EPSF 1e-5f
#define PHASE_C 50.26548245743669f   // PI / REL_RANGE, REL_RANGE = 8/128

typedef unsigned short u16;
typedef unsigned int   u32;
typedef unsigned long long u64;
typedef __attribute__((ext_vector_type(8))) short short8;
typedef __attribute__((ext_vector_type(4))) float f32x4;
typedef __attribute__((ext_vector_type(4))) unsigned short u16x4;

__device__ inline float bfl(u32 u){ return __uint_as_float(u<<16); }
__device__ inline float bfh(u32 u){ return __uint_as_float(u&0xffff0000u); }
__device__ inline u16 f2bf(float f){
  u32 u = __float_as_uint(f);
  u32 r = (u + 0x7fffu + ((u>>16)&1u))>>16;
  return (u16)r;
}

// ------- K1: histogram; rel counts aggregated in LDS (contention fix) -------
__global__ __launch_bounds__(256) void k_hist(const int* __restrict__ trip,
    int* __restrict__ cnt0, int* __restrict__ cnt1, int* __restrict__ cntr){
  __shared__ int rc[N_REL];
  int t = threadIdx.x;
  for(int r=t; r<N_REL; r+=256) rc[r]=0;
  __syncthreads();
  #pragma unroll
  for(int k=0;k<8;k++){
    int i = blockIdx.x*2048 + t + k*256;
    if(i < N_TRIP){
      atomicAdd(&cnt0[trip[3*i]],   1);
      atomicAdd(&cnt1[trip[3*i+1]], 1);
      atomicAdd(&rc[trip[3*i+2]],   1);
    }
  }
  __syncthreads();
  for(int r=t; r<N_REL; r+=256){
    int c = rc[r];
    if(c) atomicAdd(&cntr[r], c);
  }
}

// ---------------- CSR build: 3-kernel prefix scan + cursor scatter ----------
__global__ __launch_bounds__(1024) void k_scan1(const int* __restrict__ cnt0,
    const int* __restrict__ cnt1, int* __restrict__ offs, int* __restrict__ bsum){
  __shared__ int sh[1024];
  int t = threadIdx.x;
  int e = blockIdx.x*1024 + t;
  int d = (e < N_ENT) ? cnt0[e] + cnt1[e] : 0;
  sh[t] = d; __syncthreads();
  for(int st=1; st<1024; st<<=1){
    int x = (t>=st) ? sh[t-st] : 0;
    __syncthreads();
    sh[t] += x;
    __syncthreads();
  }
  if(e < N_ENT) offs[e] = sh[t] - d;
  if(t == 1023) bsum[blockIdx.x] = sh[t];
}

__global__ __launch_bounds__(512) void k_scan2(const int* __restrict__ bsum,
    int* __restrict__ boffs, const int* __restrict__ cntr,
    int* __restrict__ roffs, int* __restrict__ rcur, int nblk){
  __shared__ int sh[512];
  int t = threadIdx.x;
  int v = (t < nblk) ? bsum[t] : 0;
  sh[t] = v; __syncthreads();
  for(int st=1; st<512; st<<=1){
    int x = (t>=st) ? sh[t-st] : 0;
    __syncthreads(); sh[t] += x; __syncthreads();
  }
  if(t < nblk) boffs[t] = sh[t] - v;
  __syncthreads();
  int w = (t < N_REL) ? cntr[t] : 0;
  sh[t] = w; __syncthreads();
  for(int st=1; st<512; st<<=1){
    int x = (t>=st) ? sh[t-st] : 0;
    __syncthreads(); sh[t] += x; __syncthreads();
  }
  if(t < N_REL){ roffs[t] = sh[t]-w; rcur[t] = sh[t]-w; }
}

__global__ __launch_bounds__(1024) void k_scan3(int* __restrict__ offs,
    const int* __restrict__ boffs, int* __restrict__ cur){
  int e = blockIdx.x*1024 + threadIdx.x;
  if(e < N_ENT){
    int o = offs[e] + boffs[blockIdx.x];
    offs[e] = o;
    cur[e] = o;
  }
}

// ------- K-edges: chunked scatter; rel cursors via LDS + bulk alloc ---------
// ebuf = other<<10 | t2<<1 | role ; pair64/rpair = t0 | t1<<18 | t2<<36
__global__ __launch_bounds__(256) void k_edges(const int* __restrict__ trip,
    int* __restrict__ cur, int* __restrict__ rcur,
    u32* __restrict__ ebuf, u64* __restrict__ pair64, u64* __restrict__ rpair){
  __shared__ int rcnt[N_REL];
  __shared__ int rbase[N_REL];
  int t = threadIdx.x;
  for(int r=t; r<N_REL; r+=256) rcnt[r]=0;
  __syncthreads();
  int i0 = blockIdx.x*2048;
  int lt0[8], lt1[8], lt2[8], lp[8];
  #pragma unroll
  for(int k=0;k<8;k++){
    int i = i0 + t + k*256;
    lt2[k] = -1;
    if(i < N_TRIP){
      int t0 = trip[3*i], t1 = trip[3*i+1], t2 = trip[3*i+2];
      lt0[k]=t0; lt1[k]=t1; lt2[k]=t2;
      lp[k] = atomicAdd(&rcnt[t2], 1);
      pair64[i] = ((u64)t2<<36) | ((u64)t1<<18) | (u64)t0;
      ebuf[atomicAdd(&cur[t0], 1)] = ((u32)t1<<10) | ((u32)t2<<1);
      ebuf[atomicAdd(&cur[t1], 1)] = ((u32)t0<<10) | ((u32)t2<<1) | 1u;
    }
  }
  __syncthreads();
  for(int r=t; r<N_REL; r+=256){
    int c = rcnt[r];
    rbase[r] = c ? atomicAdd(&rcur[r], c) : 0;
  }
  __syncthreads();
  #pragma unroll
  for(int k=0;k<8;k++){
    if(lt2[k] >= 0)
      rpair[rbase[lt2[k]] + lp[k]] =
        ((u64)lt2[k]<<36) | ((u64)lt1[k]<<18) | (u64)lt0[k];
  }
}

// ------- K2a: pure-streaming prep: entnbf (normalized bf16) + entbf (raw) ---
__global__ __launch_bounds__(256) void k_prep(const float* __restrict__ ent,
    u32* __restrict__ entnbf, u32* entbf){
  int t = threadIdx.x, lane = t & 63;
  int l16 = lane & 15, g = lane >> 4;
  int wid = blockIdx.x*4 + (t>>6), nw = gridDim.x*4;
  for(int e4 = wid*4; e4 < N_ENT; e4 += nw*4){
    int e = e4 + g;
    const float* xp = ent + (size_t)e*D + l16*8;
    float4 x0 = *(const float4*)xp;
    float4 x1 = *(const float4*)(xp+4);
    if(entbf){
      uint4 pk;
      pk.x = (u32)f2bf(x0.x) | ((u32)f2bf(x0.y)<<16);
      pk.y = (u32)f2bf(x0.z) | ((u32)f2bf(x0.w)<<16);
      pk.z = (u32)f2bf(x1.x) | ((u32)f2bf(x1.y)<<16);
      pk.w = (u32)f2bf(x1.z) | ((u32)f2bf(x1.w)<<16);
      *(uint4*)(entbf + (size_t)e*64 + l16*4) = pk;
    }
    float ss = x0.x*x0.x + x0.y*x0.y + x0.z*x0.z + x0.w*x0.w
             + x1.x*x1.x + x1.y*x1.y + x1.z*x1.z + x1.w*x1.w;
    #pragma unroll
    for(int o=8;o>0;o>>=1) ss += __shfl_xor(ss,o,64);
    float nrm = sqrtf(ss);
    float sc = nrm > 1.0f ? 1.0f/nrm : 1.0f;
    uint4 pn;
    pn.x = (u32)f2bf(x0.x*sc) | ((u32)f2bf(x0.y*sc)<<16);
    pn.y = (u32)f2bf(x0.z*sc) | ((u32)f2bf(x0.w*sc)<<16);
    pn.z = (u32)f2bf(x1.x*sc) | ((u32)f2bf(x1.y*sc)<<16);
    pn.w = (u32)f2bf(x1.z*sc) | ((u32)f2bf(x1.w*sc)<<16);
    *(uint4*)(entnbf + (size_t)e*64 + l16*4) = pn;
  }
}

// ------- K2b: BN0 column stats from L3-hot entnbf ---------------------------
__global__ __launch_bounds__(256) void k_stats(const u32* __restrict__ entnbf,
    const int* __restrict__ cnt0, const int* __restrict__ cnt1,
    float* __restrict__ stats){
  __shared__ float acc[512];
  int t = threadIdx.x;
  acc[t] = 0.f; acc[t+256] = 0.f;
  __syncthreads();
  int lane = t & 63;
  int l16 = lane & 15, g = lane >> 4;
  int wid = blockIdx.x*4 + (t>>6), nw = gridDim.x*4;
  float s0[8]={0,0,0,0,0,0,0,0}, s1[8]={0,0,0,0,0,0,0,0};
  float q0[8]={0,0,0,0,0,0,0,0}, q1[8]={0,0,0,0,0,0,0,0};
  for(int e4 = wid*4; e4 < N_ENT; e4 += nw*4){
    int e = e4 + g;
    uint4 u = *(const uint4*)(entnbf + (size_t)e*64 + l16*4);
    float w0 = (float)cnt0[e], w1 = (float)cnt1[e];
    float v[8] = {bfl(u.x),bfh(u.x),bfl(u.y),bfh(u.y),
                  bfl(u.z),bfh(u.z),bfl(u.w),bfh(u.w)};
    #pragma unroll
    for(int k=0;k<8;k++){
      s0[k] += w0*v[k]; s1[k] += w1*v[k];
      q0[k] += w0*v[k]*v[k]; q1[k] += w1*v[k]*v[k];
    }
  }
  #pragma unroll
  for(int k=0;k<8;k++){
    int c = l16*8 + k;
    atomicAdd(&acc[c],     s0[k]);
    atomicAdd(&acc[128+c], s1[k]);
    atomicAdd(&acc[256+c], q0[k]);
    atomicAdd(&acc[384+c], q1[k]);
  }
  __syncthreads();
  atomicAdd(&stats[t],     acc[t]);
  atomicAdd(&stats[t+256], acc[t+256]);
}

// ------- K3: per-rel scale + Qr stats + cos/sin phase tables ---------------
__global__ __launch_bounds__(256) void k_relstats(const float* __restrict__ rel,
    const int* __restrict__ cntr, float* __restrict__ scale_rel,
    float* __restrict__ stats, float* __restrict__ cosr, float* __restrict__ sinr){
  int t = threadIdx.x, lane = t & 63;
  int r = blockIdx.x*4 + (t>>6);
  if(r >= N_REL) return;
  float2 x = *(const float2*)(rel + (size_t)r*D + 2*lane);
  float ss = x.x*x.x + x.y*x.y;
  #pragma unroll
  for(int o=32;o>0;o>>=1) ss += __shfl_xor(ss,o,64);
  float nrm = sqrtf(ss);
  float sc = nrm > 1.0f ? 1.0f/nrm : 1.0f;
  if(lane==0) scale_rel[r] = sc;
  float w = (float)cntr[r];
  float sx = x.x*sc, sy = x.y*sc;
  atomicAdd(&stats[512 + 2*lane  ], w*sx*sx);
  atomicAdd(&stats[512 + 2*lane+1], w*sy*sy);
  if(lane < 32){
    cosr[r*64 + 2*lane  ] = cosf(x.x*PHASE_C);
    sinr[r*64 + 2*lane  ] = sinf(x.x*PHASE_C);
    cosr[r*64 + 2*lane+1] = cosf(x.y*PHASE_C);
    sinr[r*64 + 2*lane+1] = sinf(x.y*PHASE_C);
  }
}

// ------- K4: finalize BN0, build folded bf16 weights Wbf, W2 and b' ---------
__global__ __launch_bounds__(384) void k_bn0fin(const float* __restrict__ stats,
    const float* __restrict__ W_a, const float* __restrict__ b_a,
    const float* __restrict__ gamma0, const float* __restrict__ beta0,
    u16* __restrict__ Wbf, float* __restrict__ W2, float* __restrict__ bprime){
  __shared__ float a0[384], c0[384];
  int t = threadIdx.x;
  {
    int j = t & 127;
    float mu, ex2;
    if(t < 256){
      mu  = (stats[j]     + stats[128+j]) * (1.0f/(2.0f*N_TRIP));
      ex2 = (stats[256+j] + stats[384+j]) * (1.0f/(2.0f*N_TRIP));
    } else {
      mu  = 0.0f;
      ex2 = stats[512+j] * (1.0f/N_TRIP);
    }
    float var = ex2 - mu*mu;
    float a = gamma0[t]*rsqrtf(var + BN_EPSF);
    a0[t] = a;
    c0[t] = beta0[t] - mu*a;
  }
  __syncthreads();
  for(int idx=t; idx<256*128; idx+=384){
    int j = idx>>7, k = idx&127;
    int ko = ((j>>7)<<7) + k;
    Wbf[idx] = f2bf(W_a[(j&127)*384 + ko]*a0[ko]);
  }
  for(int idx=t; idx<128*128; idx+=384){
    int k = idx>>7, j = idx&127;
    W2[idx] = W_a[j*384 + 256 + k]*a0[256+k];
  }
  if(t < 128){
    float s = b_a[t];
    for(int k=0;k<384;k++) s += W_a[t*384+k]*c0[k];
    bprime[t] = s;
  }
}

// ------- K5: R[r] = rel_n[r] @ W2 ------------------------------------------
__global__ __launch_bounds__(128) void k_relproj(const float* __restrict__ rel,
    const float* __restrict__ scale_rel, const float* __restrict__ W2,
    float* __restrict__ R){
  int r = blockIdx.x, j = threadIdx.x;
  __shared__ float x[128];
  x[j] = rel[(size_t)r*D + j]*scale_rel[r];
  __syncthreads();
  float s = 0.f;
  for(int k=0;k<128;k++) s += x[k]*W2[k*128+j];
  R[r*128+j] = s;
}

// ------- K6: A/B projection via MFMA; input is pre-normalized bf16 ----------
__global__ __launch_bounds__(256) void k_ab(const u32* __restrict__ entnbf,
    const u16* __restrict__ Wbf, u16* __restrict__ Abuf, u16* __restrict__ Bbuf){
  __shared__ u16 xlds[16*128];
  int t = threadIdx.x, lane = t & 63, q = t >> 6;
  int kgrp = (lane>>4)<<3;
  int rgrp = (lane>>4)<<2;
  int frow = lane & 15;
  short8 wf[4][4];
  #pragma unroll
  for(int jt=0;jt<4;jt++){
    #pragma unroll
    for(int kt=0;kt<4;kt++)
      wf[jt][kt] = *(const short8*)(Wbf + (size_t)(q*64 + jt*16 + frow)*D + kgrp + kt*32);
  }
  int srow = t>>4;
  int scol16 = t&15;
  char* swp = (char*)xlds + srow*256 + ((scol16<<4) ^ ((srow&7)<<4));
  const char* rdp = (const char*)xlds + frow*256;
  int rbase0 = (lane>>4)<<4;
  int fsw = (frow&7)<<4;
  for(int chunk = blockIdx.x; chunk < N_ENT/16; chunk += gridDim.x){
    uint4 pk = *(const uint4*)(entnbf + (size_t)(chunk*16 + srow)*64 + scol16*4);
    __syncthreads();
    *(uint4*)swp = pk;
    __syncthreads();
    short8 xf[4];
    #pragma unroll
    for(int kt=0;kt<4;kt++)
      xf[kt] = *(const short8*)(rdp + ((rbase0 + kt*64) ^ fsw));
    int erow = chunk*16 + frow;
    #pragma unroll
    for(int jt=0;jt<4;jt++){
      f32x4 acc = {0.f,0.f,0.f,0.f};
      #pragma unroll
      for(int kt=0;kt<4;kt++)
        acc = __builtin_amdgcn_mfma_f32_16x16x32_bf16(wf[jt][kt], xf[kt], acc, 0,0,0);
      int jbase = q*64 + jt*16 + rgrp;
      u16x4 opk;
      opk.x=f2bf(acc[0]); opk.y=f2bf(acc[1]); opk.z=f2bf(acc[2]); opk.w=f2bf(acc[3]);
      u16* dst = (jbase < 128) ? (Abuf + (size_t)erow*D + jbase)
                               : (Bbuf + (size_t)erow*D + (jbase-128));
      *(u16x4*)dst = opk;
    }
  }
}

// ------- K7: BN1 statistics, 1/4 subsample, x2 unrolled ----------------------
__global__ __launch_bounds__(256) void k_bn1stats(const u64* __restrict__ pair64,
    const u16* __restrict__ A, const u16* __restrict__ B,
    const float* __restrict__ R, const float* __restrict__ bprime,
    float* __restrict__ sums){
  __shared__ float acc[256];
  int t = threadIdx.x;
  acc[t] = 0.f;
  __syncthreads();
  int lane = t & 63;
  int gw = blockIdx.x*4 + (t>>6), nw = gridDim.x*4;
  float bp0 = bprime[2*lane], bp1 = bprime[2*lane+1];
  float s0=0,s1=0,q0=0,q1=0;
  for(int i=4*gw; i<N_TRIP; i+=8*nw){
    {
      u64 pr = pair64[i];
      int t0 = (int)(pr & 0x3FFFF);
      int t1 = (int)((pr>>18) & 0x3FFFF);
      int t2 = (int)(pr>>36);
      u32 ua0 = *(const u32*)(A + (size_t)t0*D + 2*lane);
      u32 ua1 = *(const u32*)(A + (size_t)t1*D + 2*lane);
      u32 ub0 = *(const u32*)(B + (size_t)t0*D + 2*lane);
      u32 ub1 = *(const u32*)(B + (size_t)t1*D + 2*lane);
      float2 r = *(const float2*)(R + (size_t)t2*D + 2*lane);
      float y1x = bfl(ua0)+bfl(ub1)+r.x+bp0;
      float y1y = bfh(ua0)+bfh(ub1)+r.y+bp1;
      float y2x = bfl(ua1)+bfl(ub0)-r.x+bp0;
      float y2y = bfh(ua1)+bfh(ub0)-r.y+bp1;
      s0 += y1x+y2x; s1 += y1y+y2y;
      q0 += y1x*y1x + y2x*y2x; q1 += y1y*y1y + y2y*y2y;
    }
    int i2 = i + 4*nw;
    if(i2 < N_TRIP){
      u64 pr = pair64[i2];
      int t0 = (int)(pr & 0x3FFFF);
      int t1 = (int)((pr>>18) & 0x3FFFF);
      int t2 = (int)(pr>>36);
      u32 ua0 = *(const u32*)(A + (size_t)t0*D + 2*lane);
      u32 ua1 = *(const u32*)(A + (size_t)t1*D + 2*lane);
      u32 ub0 = *(const u32*)(B + (size_t)t0*D + 2*lane);
      u32 ub1 = *(const u32*)(B + (size_t)t1*D + 2*lane);
      float2 r = *(const float2*)(R + (size_t)t2*D + 2*lane);
      float y1x = bfl(ua0)+bfl(ub1)+r.x+bp0;
      float y1y = bfh(ua0)+bfh(ub1)+r.y+bp1;
      float y2x = bfl(ua1)+bfl(ub0)-r.x+bp0;
      float y2y = bfh(ua1)+bfh(ub0)-r.y+bp1;
      s0 += y1x+y2x; s1 += y1y+y2y;
      q0 += y1x*y1x + y2x*y2x; q1 += y1y*y1y + y2y*y2y;
    }
  }
  atomicAdd(&acc[      2*lane  ], s0);
  atomicAdd(&acc[      2*lane+1], s1);
  atomicAdd(&acc[128 + 2*lane  ], q0);
  atomicAdd(&acc[128 + 2*lane+1], q1);
  __syncthreads();
  atomicAdd(&sums[t], acc[t]);
}

// ------- K8: finalize BN1 (1/4 subsample: N_TRIP/2 samples) -----------------
__global__ __launch_bounds__(128) void k_bn1fin(const float* __restrict__ sums,
    const float* __restrict__ gamma1, const float* __restrict__ beta1,
    const float* __restrict__ W_a2, const float* __restrict__ b_a2,
    const float* __restrict__ bprime, float* __restrict__ a1c){
  __shared__ float red[128];
  int j = threadIdx.x;
  float mu  = sums[j]    *(2.0f/(float)N_TRIP);
  float var = sums[128+j]*(2.0f/(float)N_TRIP) - mu*mu;
  float a = gamma1[j]*rsqrtf(var + BN_EPSF);
  float cc = beta1[j] - mu*a;
  float wa1 = W_a2[j]*a;
  a1c[j]     = a;
  a1c[128+j] = cc;
  a1c[256+j] = wa1;
  red[j] = W_a2[j]*cc + wa1*bprime[j];
  __syncthreads();
  #pragma unroll
  for(int s=64; s>0; s>>=1){
    if(j < s) red[j] += red[j+s];
    __syncthreads();
  }
  if(j==0) a1c[384] = red[0] + b_a2[0];
}

// ------- K8b: per-entity scalars alpha/beta/rho, 32-lane groups, x2 unroll --
__global__ __launch_bounds__(256) void k_alphabeta(const u16* __restrict__ A,
    const u16* __restrict__ B, const float* __restrict__ R,
    const float* __restrict__ a1c, float* __restrict__ alpha,
    float* __restrict__ beta, float* __restrict__ rho){
  int t = threadIdx.x, lane = t & 63;
  int l32 = lane & 31, grp = lane >> 5;
  int wid = blockIdx.x*4 + (t>>6), nw = gridDim.x*4;
  float4 wa = *(const float4*)(a1c + 256 + l32*4);
  for(int e4 = wid*4; e4 < N_ENT; e4 += nw*4){
    int eA = e4 + grp, eB = e4 + 2 + grp;
    uint2 uaA = *(const uint2*)(A + (size_t)eA*D + l32*4);
    uint2 ubA = *(const uint2*)(B + (size_t)eA*D + l32*4);
    uint2 uaB = *(const uint2*)(A + (size_t)eB*D + l32*4);
    uint2 ubB = *(const uint2*)(B + (size_t)eB*D + l32*4);
    float daA = wa.x*bfl(uaA.x) + wa.y*bfh(uaA.x) + wa.z*bfl(uaA.y) + wa.w*bfh(uaA.y);
    float dbA = wa.x*bfl(ubA.x) + wa.y*bfh(ubA.x) + wa.z*bfl(ubA.y) + wa.w*bfh(ubA.y);
    float daB = wa.x*bfl(uaB.x) + wa.y*bfh(uaB.x) + wa.z*bfl(uaB.y) + wa.w*bfh(uaB.y);
    float dbB = wa.x*bfl(ubB.x) + wa.y*bfh(ubB.x) + wa.z*bfl(ubB.y) + wa.w*bfh(ubB.y);
    #pragma unroll
    for(int o=16;o>0;o>>=1){
      daA += __shfl_xor(daA,o,64); dbA += __shfl_xor(dbA,o,64);
      daB += __shfl_xor(daB,o,64); dbB += __shfl_xor(dbB,o,64);
    }
    if(l32==0){ alpha[eA]=daA; beta[eA]=dbA; alpha[eB]=daB; beta[eB]=dbB; }
  }
  for(int r2 = wid*2 + grp; r2 < N_REL; r2 += nw*2){
    float4 rr = *(const float4*)(R + (size_t)r2*D + l32*4);
    float dr = wa.x*rr.x + wa.y*rr.y + wa.z*rr.z + wa.w*rr.w;
    #pragma unroll
    for(int o=16;o>0;o>>=1) dr += __shfl_xor(dr,o,64);
    if(l32==0) rho[r2]=dr;
  }
}

// ------- K9: per-entity gather, 16-lane groups (4 entities/wave) ------------
__global__ __launch_bounds__(256) void k_ent(
    const int* __restrict__ offs, const int* __restrict__ endp,
    const u32* __restrict__ ebuf,
    const u16* __restrict__ A, const u16* __restrict__ B,
    const float* __restrict__ R, const float* __restrict__ bprime,
    const float* __restrict__ a1c, const float* __restrict__ alpha,
    const float* __restrict__ beta, const float* __restrict__ rho,
    float* __restrict__ out_hent){
  int t = threadIdx.x, lane = t & 63;
  int l16 = lane & 15, g = lane >> 4;
  int wid = blockIdx.x*4 + (t>>6), nw = gridDim.x*4;
  int cb = l16*8;
  float4 bpA = *(const float4*)(bprime + cb);
  float4 bpB = *(const float4*)(bprime + cb + 4);
  float4 a1A = *(const float4*)(a1c + cb);
  float4 a1B = *(const float4*)(a1c + cb + 4);
  float4 ccA = *(const float4*)(a1c + 128 + cb);
  float4 ccB = *(const float4*)(a1c + 128 + cb + 4);
  float kap = a1c[384];
  for(int e4 = wid*4; e4 < N_ENT; e4 += nw*4){
    int e = e4 + g;
    int s = offs[e], en = endp[e];
    uint4 ua = *(const uint4*)(A + (size_t)e*D + cb);
    float ax0 = bfl(ua.x), ax1 = bfh(ua.x), ax2 = bfl(ua.y), ax3 = bfh(ua.y);
    float ax4 = bfl(ua.z), ax5 = bfh(ua.z), ax6 = bfl(ua.w), ax7 = bfh(ua.w);
    float al = alpha[e];
    float h0=0,h1=0,h2=0,h3=0,h4=0,h5=0,h6=0,h7=0, eb=0;
    for(int o=s; o<en; o++){
      u32 id = ebuf[o];
      int ot = id>>10, r2 = (id>>1)&511;
      float sg = (id&1) ? -1.f : 1.f;
      uint4 ub = *(const uint4*)(B + (size_t)ot*D + cb);
      float4 rA = *(const float4*)(R + (size_t)r2*D + cb);
      float4 rB = *(const float4*)(R + (size_t)r2*D + cb + 4);
      float sv = al + beta[ot] + sg*rho[r2] + kap;
      float e_b = expf(sv >= 0.f ? -sv : -0.01f*sv);
      float y, c;
      y = ax0 + bfl(ub.x) + sg*rA.x + bpA.x; c = y*a1A.x + ccA.x; h0 += e_b*c;
      y = ax1 + bfh(ub.x) + sg*rA.y + bpA.y; c = y*a1A.y + ccA.y; h1 += e_b*c;
      y = ax2 + bfl(ub.y) + sg*rA.z + bpA.z; c = y*a1A.z + ccA.z; h2 += e_b*c;
      y = ax3 + bfh(ub.y) + sg*rA.w + bpA.w; c = y*a1A.w + ccA.w; h3 += e_b*c;
      y = ax4 + bfl(ub.z) + sg*rB.x + bpB.x; c = y*a1B.x + ccB.x; h4 += e_b*c;
      y = ax5 + bfh(ub.z) + sg*rB.y + bpB.y; c = y*a1B.y + ccB.y; h5 += e_b*c;
      y = ax6 + bfl(ub.w) + sg*rB.z + bpB.z; c = y*a1B.z + ccB.z; h6 += e_b*c;
      y = ax7 + bfh(ub.w) + sg*rB.w + bpB.w; c = y*a1B.w + ccB.w; h7 += e_b*c;
      eb += e_b;
    }
    float inv = (en > s) ? 1.0f/eb : 0.0f;
    float4 o0; o0.x=h0*inv; o0.y=h1*inv; o0.z=h2*inv; o0.w=h3*inv;
    float4 o1; o1.x=h4*inv; o1.y=h5*inv; o1.z=h6*inv; o1.w=h7*inv;
    *(float4*)(out_hent + (size_t)e*D + cb)     = o0;
    *(float4*)(out_hent + (size_t)e*D + cb + 4) = o1;
  }
}

// ------- K10: per-rel gather pass, packed pairs -----------------------------
__global__ __launch_bounds__(512) void k_rel(
    const int* __restrict__ roffs, const int* __restrict__ cntr,
    const u64* __restrict__ rpair,
    const u16* __restrict__ A, const u16* __restrict__ B,
    const float* __restrict__ R, const float* __restrict__ bprime,
    const float* __restrict__ a1c, const float* __restrict__ alpha,
    const float* __restrict__ beta, const float* __restrict__ rho,
    float* __restrict__ out_hrel){
  __shared__ float red[8][128];
  int t = threadIdx.x, lane = t & 63, w = t >> 6;
  int r = blockIdx.x;
  int cnt = cntr[r], base = roffs[r];
  float2 rr = *(const float2*)(R + (size_t)r*D + 2*lane);
  float bp0 = bprime[2*lane], bp1 = bprime[2*lane+1];
  float a1x = a1c[2*lane],     a1y = a1c[2*lane+1];
  float ccx = a1c[128+2*lane], ccy = a1c[128+2*lane+1];
  float kap = a1c[384];
  float rhor = rho[r];
  float sx = 0.f, sy = 0.f;
  for(int j=w; j<cnt; j+=8){
    u64 pr = rpair[base+j];
    int t0 = (int)(pr & 0x3FFFF);
    int t1 = (int)((pr>>18) & 0x3FFFF);
    float s1 = alpha[t0] + beta[t1] + rhor + kap;
    float s2 = alpha[t1] + beta[t0] - rhor + kap;
    float e1 = expf(s1 >= 0.f ? -s1 : -0.01f*s1);
    float e2 = expf(s2 >= 0.f ? -s2 : -0.01f*s2);
    u32 ua0 = *(const u32*)(A + (size_t)t0*D + 2*lane);
    u32 ua1 = *(const u32*)(A + (size_t)t1*D + 2*lane);
    u32 ub0 = *(const u32*)(B + (size_t)t0*D + 2*lane);
    u32 ub1 = *(const u32*)(B + (size_t)t1*D + 2*lane);
    float y1x = bfl(ua0)+bfl(ub1)+rr.x+bp0;
    float y1y = bfh(ua0)+bfh(ub1)+rr.y+bp1;
    float y2x = bfl(ua1)+bfl(ub0)-rr.x+bp0;
    float y2y = bfh(ua1)+bfh(ub0)-rr.y+bp1;
    float c1x = y1x*a1x+ccx, c1y = y1y*a1y+ccy;
    float c2x = y2x*a1x+ccx, c2y = y2y*a1y+ccy;
    sx += e1*c1x - e2*c2x;
    sy += e1*c1y - e2*c2y;
  }
  float2 p; p.x = sx; p.y = sy;
  *(float2*)&red[w][2*lane] = p;
  __syncthreads();
  if(t < 128){
    float s = 0.f;
    #pragma unroll
    for(int k=0;k<8;k++) s += red[k][t];
    float cf = cnt > 0 ? (float)cnt : 1.0f;
    out_hrel[(size_t)r*D + t] = s/cf;
  }
}

// ------- K12: RotatE score (bf16 gathers), x2 unrolled -----------------------
__global__ __launch_bounds__(256) void k_score_bf(const u64* __restrict__ pair64,
    const u32* __restrict__ entbf, const float* __restrict__ cosr,
    const float* __restrict__ sinr, float* __restrict__ score){
  int t = threadIdx.x, lane = t & 63;
  int gw = blockIdx.x*4 + (t>>6), nw = gridDim.x*4;
  int half = lane & 1;
  int pidx = lane >> 1;
  for(int i=gw; i<N_TRIP; i+=2*nw){
    u64 prA = pair64[i];
    int a0 = (int)(prA & 0x3FFFF);
    int a1 = (int)((prA>>18) & 0x3FFFF);
    int a2 = (int)(prA>>36);
    u32 ph0A = entbf[(size_t)a0*64 + pidx];
    u32 pi0A = entbf[(size_t)a0*64 + 32 + pidx];
    u32 ph1A = entbf[(size_t)a1*64 + pidx];
    u32 pi1A = entbf[(size_t)a1*64 + 32 + pidx];
    int i2 = i + nw;
    bool hasB = (i2 < N_TRIP);
    u64 prB = hasB ? pair64[i2] : prA;
    int b0 = (int)(prB & 0x3FFFF);
    int b1 = (int)((prB>>18) & 0x3FFFF);
    int b2 = (int)(prB>>36);
    u32 ph0B = entbf[(size_t)b0*64 + pidx];
    u32 pi0B = entbf[(size_t)b0*64 + 32 + pidx];
    u32 ph1B = entbf[(size_t)b1*64 + pidx];
    u32 pi1B = entbf[(size_t)b1*64 + 32 + pidx];
    float crA = cosr[a2*64 + lane], srA = sinr[a2*64 + lane];
    float crB = cosr[b2*64 + lane], srB = sinr[b2*64 + lane];
    float re_hA = half ? bfh(ph0A) : bfl(ph0A);
    float im_hA = half ? bfh(pi0A) : bfl(pi0A);
    float re_tA = half ? bfh(ph1A) : bfl(ph1A);
    float im_tA = half ? bfh(pi1A) : bfl(pi1A);
    float re_hB = half ? bfh(ph0B) : bfl(ph0B);
    float im_hB = half ? bfh(pi0B) : bfl(pi0B);
    float re_tB = half ? bfh(ph1B) : bfl(ph1B);
    float im_tB = half ? bfh(pi1B) : bfl(pi1B);
    float re_sA = crA*re_tA + srA*im_tA - re_hA;
    float im_sA = crA*im_tA - srA*re_tA - im_hA;
    float re_sB = crB*re_tB + srB*im_tB - re_hB;
    float im_sB = crB*im_tB - srB*re_tB - im_hB;
    float dA = sqrtf(re_sA*re_sA + im_sA*im_sA);
    float dB = sqrtf(re_sB*re_sB + im_sB*im_sB);
    #pragma unroll
    for(int o=32;o>0;o>>=1){
      dA += __shfl_xor(dA,o,64);
      dB += __shfl_xor(dB,o,64);
    }
    if(lane==0){
      score[i] = MARGINF - dA;
      if(hasB) score[i2] = MARGINF - dB;
    }
  }
}

// fp32 fallback if workspace too small for entbf
__global__ __launch_bounds__(256) void k_score_fp(const u64* __restrict__ pair64,
    const float* __restrict__ ent, const float* __restrict__ cosr,
    const float* __restrict__ sinr, float* __restrict__ score){
  int t = threadIdx.x, lane = t & 63;
  int gw = blockIdx.x*4 + (t>>6), nw = gridDim.x*4;
  for(int i=gw; i<N_TRIP; i+=nw){
    u64 pr = pair64[i];
    int t0 = (int)(pr & 0x3FFFF);
    int t1 = (int)((pr>>18) & 0x3FFFF);
    int t2 = (int)(pr>>36);
    float re_h = ent[(size_t)t0*D + lane];
    float im_h = ent[(size_t)t0*D + 64 + lane];
    float re_t = ent[(size_t)t1*D + lane];
    float im_t = ent[(size_t)t1*D + 64 + lane];
    float cr = cosr[t2*64 + lane], sr = sinr[t2*64 + lane];
    float re_s = cr*re_t + sr*im_t - re_h;
    float im_s = cr*im_t - sr*re_t - im_h;
    float d = sqrtf(re_s*re_s + im_s*im_s);
    #pragma unroll
    for(int o=32;o>0;o>>=1) d += __shfl_xor(d,o,64);
    if(lane==0) score[i] = MARGINF - d;
  }
}

extern "C" void kernel_launch(void* const* d_in, const int* in_sizes, int n_in,
                              void* d_out, int out_size, void* d_ws, size_t ws_size,
                              hipStream_t stream){
  const int*   trip   = (const int*)  d_in[0];
  const float* ent    = (const float*)d_in[1];
  const float* rel    = (const float*)d_in[2];
  const float* W_a    = (const float*)d_in[3];
  const float* b_a    = (const float*)d_in[4];
  const float* W_a2   = (const float*)d_in[5];
  const float* b_a2   = (const float*)d_in[6];
  const float* gamma0 = (const float*)d_in[7];
  const float* beta0  = (const float*)d_in[8];
  const float* gamma1 = (const float*)d_in[9];
  const float* beta1  = (const float*)d_in[10];

  char* ws = (char*)d_ws;
  size_t off = 0;
  auto take = [&](size_t bytes)->void*{
    void* p = ws + off;
    off += (bytes + 255) & ~(size_t)255;
    return p;
  };
  // ---- zeroed scratch (contiguous from 0) ----
  int*   cnt0    = (int*)  take((size_t)N_ENT*4);
  int*   cnt1    = (int*)  take((size_t)N_ENT*4);
  int*   cntr    = (int*)  take((size_t)N_REL*4);
  float* stats   = (float*)take(640*4);
  float* sums    = (float*)take(256*4);
  size_t zero_bytes = off;
  // ---- fully-overwritten scratch (required) ----
  int*   offs      = (int*)  take((size_t)N_ENT*4);
  int*   cur       = (int*)  take((size_t)N_ENT*4);
  int*   bsum      = (int*)  take(512*4);
  int*   boffs     = (int*)  take(512*4);
  int*   roffs     = (int*)  take(512*4);
  int*   rcur      = (int*)  take(512*4);
  u32*   ebuf      = (u32*)  take((size_t)2*N_TRIP*4);
  u64*   pair64    = (u64*)  take((size_t)N_TRIP*8);
  u64*   rpair     = (u64*)  take((size_t)N_TRIP*8);
  float* scale_rel = (float*)take((size_t)N_REL*4);
  u16*   Wbf       = (u16*)  take(256*128*2);
  float* W2        = (float*)take(128*128*4);
  float* bprime    = (float*)take(128*4);
  float* a1c       = (float*)take(512*4);
  float* R         = (float*)take((size_t)N_REL*D*4);
  float* cosr      = (float*)take((size_t)N_REL*64*4);
  float* sinr      = (float*)take((size_t)N_REL*64*4);
  float* alpha     = (float*)take((size_t)N_ENT*4);
  float* betab     = (float*)take((size_t)N_ENT*4);
  float* rho       = (float*)take(512*4);
  u16*   Abuf      = (u16*)  take((size_t)N_ENT*D*2);
  u16*   Bbuf      = (u16*)  take((size_t)N_ENT*D*2);
  u32*   entnbf    = (u32*)  take((size_t)N_ENT*64*4);
  // ---- optional: raw bf16 copy for k_score ----
  u32*   entbf     = (u32*)  take((size_t)N_ENT*64*4);
  bool use_bf = (off <= ws_size);
  (void)n_in; (void)in_sizes; (void)out_size;

  float* out_hent  = (float*)d_out;
  float* out_hrel  = out_hent + (size_t)N_ENT*D;
  float* out_score = out_hrel + (size_t)N_REL*D;

  hipMemsetAsync(d_ws, 0, zero_bytes, stream);

  const int SCAN_BLKS = (N_ENT + 1023)/1024;     // 196
  const int EDG_BLKS  = (N_TRIP + 2047)/2048;    // 98
  k_prep     <<<2048, 256, 0, stream>>>(ent, entnbf, use_bf ? entbf : (u32*)nullptr);
  k_hist     <<<EDG_BLKS, 256, 0, stream>>>(trip, cnt0, cnt1, cntr);
  k_scan1    <<<SCAN_BLKS, 1024, 0, stream>>>(cnt0, cnt1, offs, bsum);
  k_scan2    <<<1, 512, 0, stream>>>(bsum, boffs, cntr, roffs, rcur, SCAN_BLKS);
  k_scan3    <<<SCAN_BLKS, 1024, 0, stream>>>(offs, boffs, cur);
  k_edges    <<<EDG_BLKS, 256, 0, stream>>>(trip, cur, rcur, ebuf, pair64, rpair);
  k_stats    <<<640, 256, 0, stream>>>(entnbf, cnt0, cnt1, stats);
  k_relstats <<<(N_REL+3)/4, 256, 0, stream>>>(rel, cntr, scale_rel, stats, cosr, sinr);
  k_bn0fin   <<<1, 384, 0, stream>>>(stats, W_a, b_a, gamma0, beta0, Wbf, W2, bprime);
  k_relproj  <<<N_REL, 128, 0, stream>>>(rel, scale_rel, W2, R);
  k_ab       <<<2048, 256, 0, stream>>>(entnbf, Wbf, Abuf, Bbuf);
  k_bn1stats <<<2048, 256, 0, stream>>>(pair64, Abuf, Bbuf, R, bprime, sums);
  k_bn1fin   <<<1, 128, 0, stream>>>(sums, gamma1, beta1, W_a2, b_a2, bprime, a1c);
  k_alphabeta<<<2048, 256, 0, stream>>>(Abuf, Bbuf, R, a1c, alpha, betab, rho);
  k_ent      <<<2048, 256, 0, stream>>>(offs, cur, ebuf, Abuf, Bbuf, R,
                                        bprime, a1c, alpha, betab, rho, out_hent);
  k_rel      <<<N_REL, 512, 0, stream>>>(roffs, cntr, rpair, Abuf, Bbuf, R,
                                         bprime, a1c, alpha, betab, rho, out_hrel);
  if(use_bf)
    k_score_bf<<<2048, 256, 0, stream>>>(pair64, entbf, cosr, sinr, out_score);
  else
    k_score_fp<<<2048, 256, 0, stream>>>(pair64, ent, cosr, sinr, out_score);
}

// Round 10
// 454.150 us; speedup vs baseline: 3.5733x; 1.0338x over previous
//
#include <hip/hip_runtime.h>
#include <stdint.h>

#define N_TRIP 200000
#define N_ENT  200000
#define N_REL  500
#define D      128
#define MARGINF 6.0f
#define BN_EPSF 1e-5f
#define PHASE_C 50.26548245743669f   // PI / REL_RANGE, REL_RANGE = 8/128

typedef unsigned short u16;
typedef unsigned int   u32;
typedef unsigned long long u64;
typedef __attribute__((ext_vector_type(8))) short short8;
typedef __attribute__((ext_vector_type(4))) float f32x4;
typedef __attribute__((ext_vector_type(4))) unsigned short u16x4;

__device__ inline float bfl(u32 u){ return __uint_as_float(u<<16); }
__device__ inline float bfh(u32 u){ return __uint_as_float(u&0xffff0000u); }
__device__ inline u16 f2bf(float f){
  u32 u = __float_as_uint(f);
  u32 r = (u + 0x7fffu + ((u>>16)&1u))>>16;
  return (u16)r;
}

// ------- K1: histogram; rel counts aggregated in LDS ------------------------
__global__ __launch_bounds__(256) void k_hist(const int* __restrict__ trip,
    int* __restrict__ cnt0, int* __restrict__ cnt1, int* __restrict__ cntr){
  __shared__ int rc[N_REL];
  int t = threadIdx.x;
  for(int r=t; r<N_REL; r+=256) rc[r]=0;
  __syncthreads();
  #pragma unroll
  for(int k=0;k<8;k++){
    int i = blockIdx.x*2048 + t + k*256;
    if(i < N_TRIP){
      atomicAdd(&cnt0[trip[3*i]],   1);
      atomicAdd(&cnt1[trip[3*i+1]], 1);
      atomicAdd(&rc[trip[3*i+2]],   1);
    }
  }
  __syncthreads();
  for(int r=t; r<N_REL; r+=256){
    int c = rc[r];
    if(c) atomicAdd(&cntr[r], c);
  }
}

// ---------------- CSR build: 3-kernel prefix scan + cursor scatter ----------
__global__ __launch_bounds__(1024) void k_scan1(const int* __restrict__ cnt0,
    const int* __restrict__ cnt1, int* __restrict__ offs, int* __restrict__ bsum){
  __shared__ int sh[1024];
  int t = threadIdx.x;
  int e = blockIdx.x*1024 + t;
  int d = (e < N_ENT) ? cnt0[e] + cnt1[e] : 0;
  sh[t] = d; __syncthreads();
  for(int st=1; st<1024; st<<=1){
    int x = (t>=st) ? sh[t-st] : 0;
    __syncthreads();
    sh[t] += x;
    __syncthreads();
  }
  if(e < N_ENT) offs[e] = sh[t] - d;
  if(t == 1023) bsum[blockIdx.x] = sh[t];
}

__global__ __launch_bounds__(512) void k_scan2(const int* __restrict__ bsum,
    int* __restrict__ boffs, const int* __restrict__ cntr,
    int* __restrict__ roffs, int* __restrict__ rcur, int nblk){
  __shared__ int sh[512];
  int t = threadIdx.x;
  int v = (t < nblk) ? bsum[t] : 0;
  sh[t] = v; __syncthreads();
  for(int st=1; st<512; st<<=1){
    int x = (t>=st) ? sh[t-st] : 0;
    __syncthreads(); sh[t] += x; __syncthreads();
  }
  if(t < nblk) boffs[t] = sh[t] - v;
  __syncthreads();
  int w = (t < N_REL) ? cntr[t] : 0;
  sh[t] = w; __syncthreads();
  for(int st=1; st<512; st<<=1){
    int x = (t>=st) ? sh[t-st] : 0;
    __syncthreads(); sh[t] += x; __syncthreads();
  }
  if(t < N_REL){ roffs[t] = sh[t]-w; rcur[t] = sh[t]-w; }
}

__global__ __launch_bounds__(1024) void k_scan3(int* __restrict__ offs,
    const int* __restrict__ boffs, int* __restrict__ cur){
  int e = blockIdx.x*1024 + threadIdx.x;
  if(e < N_ENT){
    int o = offs[e] + boffs[blockIdx.x];
    offs[e] = o;
    cur[e] = o;
  }
}

// ------- K-edges: chunked scatter; rel cursors via LDS + bulk alloc ---------
__global__ __launch_bounds__(256) void k_edges(const int* __restrict__ trip,
    int* __restrict__ cur, int* __restrict__ rcur,
    u32* __restrict__ ebuf, u64* __restrict__ pair64, u64* __restrict__ rpair){
  __shared__ int rcnt[N_REL];
  __shared__ int rbase[N_REL];
  int t = threadIdx.x;
  for(int r=t; r<N_REL; r+=256) rcnt[r]=0;
  __syncthreads();
  int i0 = blockIdx.x*2048;
  int lt0[8], lt1[8], lt2[8], lp[8];
  #pragma unroll
  for(int k=0;k<8;k++){
    int i = i0 + t + k*256;
    lt2[k] = -1;
    if(i < N_TRIP){
      int t0 = trip[3*i], t1 = trip[3*i+1], t2 = trip[3*i+2];
      lt0[k]=t0; lt1[k]=t1; lt2[k]=t2;
      lp[k] = atomicAdd(&rcnt[t2], 1);
      pair64[i] = ((u64)t2<<36) | ((u64)t1<<18) | (u64)t0;
      ebuf[atomicAdd(&cur[t0], 1)] = ((u32)t1<<10) | ((u32)t2<<1);
      ebuf[atomicAdd(&cur[t1], 1)] = ((u32)t0<<10) | ((u32)t2<<1) | 1u;
    }
  }
  __syncthreads();
  for(int r=t; r<N_REL; r+=256){
    int c = rcnt[r];
    rbase[r] = c ? atomicAdd(&rcur[r], c) : 0;
  }
  __syncthreads();
  #pragma unroll
  for(int k=0;k<8;k++){
    if(lt2[k] >= 0)
      rpair[rbase[lt2[k]] + lp[k]] =
        ((u64)lt2[k]<<36) | ((u64)lt1[k]<<18) | (u64)lt0[k];
  }
}

// ------- K2a: pure-streaming prep, x2 row unroll (8 rows/wave) --------------
__global__ __launch_bounds__(256) void k_prep(const float* __restrict__ ent,
    u32* __restrict__ entnbf, u32* entbf){
  int t = threadIdx.x, lane = t & 63;
  int l16 = lane & 15, g = lane >> 4;
  int wid = blockIdx.x*4 + (t>>6), nw = gridDim.x*4;
  for(int e8 = wid*8; e8 < N_ENT; e8 += nw*8){
    int eA = e8 + g, eB = e8 + 4 + g;
    const float* xpA = ent + (size_t)eA*D + l16*8;
    const float* xpB = ent + (size_t)eB*D + l16*8;
    float4 a0 = *(const float4*)xpA;
    float4 a1 = *(const float4*)(xpA+4);
    float4 b0 = *(const float4*)xpB;
    float4 b1 = *(const float4*)(xpB+4);
    if(entbf){
      uint4 pa, pb;
      pa.x = (u32)f2bf(a0.x) | ((u32)f2bf(a0.y)<<16);
      pa.y = (u32)f2bf(a0.z) | ((u32)f2bf(a0.w)<<16);
      pa.z = (u32)f2bf(a1.x) | ((u32)f2bf(a1.y)<<16);
      pa.w = (u32)f2bf(a1.z) | ((u32)f2bf(a1.w)<<16);
      pb.x = (u32)f2bf(b0.x) | ((u32)f2bf(b0.y)<<16);
      pb.y = (u32)f2bf(b0.z) | ((u32)f2bf(b0.w)<<16);
      pb.z = (u32)f2bf(b1.x) | ((u32)f2bf(b1.y)<<16);
      pb.w = (u32)f2bf(b1.z) | ((u32)f2bf(b1.w)<<16);
      *(uint4*)(entbf + (size_t)eA*64 + l16*4) = pa;
      *(uint4*)(entbf + (size_t)eB*64 + l16*4) = pb;
    }
    float ssA = a0.x*a0.x + a0.y*a0.y + a0.z*a0.z + a0.w*a0.w
              + a1.x*a1.x + a1.y*a1.y + a1.z*a1.z + a1.w*a1.w;
    float ssB = b0.x*b0.x + b0.y*b0.y + b0.z*b0.z + b0.w*b0.w
              + b1.x*b1.x + b1.y*b1.y + b1.z*b1.z + b1.w*b1.w;
    #pragma unroll
    for(int o=8;o>0;o>>=1){
      ssA += __shfl_xor(ssA,o,64);
      ssB += __shfl_xor(ssB,o,64);
    }
    float nA = sqrtf(ssA), nB = sqrtf(ssB);
    float scA = nA > 1.0f ? 1.0f/nA : 1.0f;
    float scB = nB > 1.0f ? 1.0f/nB : 1.0f;
    uint4 na, nb;
    na.x = (u32)f2bf(a0.x*scA) | ((u32)f2bf(a0.y*scA)<<16);
    na.y = (u32)f2bf(a0.z*scA) | ((u32)f2bf(a0.w*scA)<<16);
    na.z = (u32)f2bf(a1.x*scA) | ((u32)f2bf(a1.y*scA)<<16);
    na.w = (u32)f2bf(a1.z*scA) | ((u32)f2bf(a1.w*scA)<<16);
    nb.x = (u32)f2bf(b0.x*scB) | ((u32)f2bf(b0.y*scB)<<16);
    nb.y = (u32)f2bf(b0.z*scB) | ((u32)f2bf(b0.w*scB)<<16);
    nb.z = (u32)f2bf(b1.x*scB) | ((u32)f2bf(b1.y*scB)<<16);
    nb.w = (u32)f2bf(b1.z*scB) | ((u32)f2bf(b1.w*scB)<<16);
    *(uint4*)(entnbf + (size_t)eA*64 + l16*4) = na;
    *(uint4*)(entnbf + (size_t)eB*64 + l16*4) = nb;
  }
}

// ------- K2b: BN0 column stats from L3-hot entnbf ---------------------------
__global__ __launch_bounds__(256) void k_stats(const u32* __restrict__ entnbf,
    const int* __restrict__ cnt0, const int* __restrict__ cnt1,
    float* __restrict__ stats){
  __shared__ float acc[512];
  int t = threadIdx.x;
  acc[t] = 0.f; acc[t+256] = 0.f;
  __syncthreads();
  int lane = t & 63;
  int l16 = lane & 15, g = lane >> 4;
  int wid = blockIdx.x*4 + (t>>6), nw = gridDim.x*4;
  float s0[8]={0,0,0,0,0,0,0,0}, s1[8]={0,0,0,0,0,0,0,0};
  float q0[8]={0,0,0,0,0,0,0,0}, q1[8]={0,0,0,0,0,0,0,0};
  for(int e4 = wid*4; e4 < N_ENT; e4 += nw*4){
    int e = e4 + g;
    uint4 u = *(const uint4*)(entnbf + (size_t)e*64 + l16*4);
    float w0 = (float)cnt0[e], w1 = (float)cnt1[e];
    float v[8] = {bfl(u.x),bfh(u.x),bfl(u.y),bfh(u.y),
                  bfl(u.z),bfh(u.z),bfl(u.w),bfh(u.w)};
    #pragma unroll
    for(int k=0;k<8;k++){
      s0[k] += w0*v[k]; s1[k] += w1*v[k];
      q0[k] += w0*v[k]*v[k]; q1[k] += w1*v[k]*v[k];
    }
  }
  #pragma unroll
  for(int k=0;k<8;k++){
    int c = l16*8 + k;
    atomicAdd(&acc[c],     s0[k]);
    atomicAdd(&acc[128+c], s1[k]);
    atomicAdd(&acc[256+c], q0[k]);
    atomicAdd(&acc[384+c], q1[k]);
  }
  __syncthreads();
  atomicAdd(&stats[t],     acc[t]);
  atomicAdd(&stats[t+256], acc[t+256]);
}

// ------- K3: per-rel scale + Qr stats + cos/sin phase tables ---------------
__global__ __launch_bounds__(256) void k_relstats(const float* __restrict__ rel,
    const int* __restrict__ cntr, float* __restrict__ scale_rel,
    float* __restrict__ stats, float* __restrict__ cosr, float* __restrict__ sinr){
  int t = threadIdx.x, lane = t & 63;
  int r = blockIdx.x*4 + (t>>6);
  if(r >= N_REL) return;
  float2 x = *(const float2*)(rel + (size_t)r*D + 2*lane);
  float ss = x.x*x.x + x.y*x.y;
  #pragma unroll
  for(int o=32;o>0;o>>=1) ss += __shfl_xor(ss,o,64);
  float nrm = sqrtf(ss);
  float sc = nrm > 1.0f ? 1.0f/nrm : 1.0f;
  if(lane==0) scale_rel[r] = sc;
  float w = (float)cntr[r];
  float sx = x.x*sc, sy = x.y*sc;
  atomicAdd(&stats[512 + 2*lane  ], w*sx*sx);
  atomicAdd(&stats[512 + 2*lane+1], w*sy*sy);
  if(lane < 32){
    cosr[r*64 + 2*lane  ] = cosf(x.x*PHASE_C);
    sinr[r*64 + 2*lane  ] = sinf(x.x*PHASE_C);
    cosr[r*64 + 2*lane+1] = cosf(x.y*PHASE_C);
    sinr[r*64 + 2*lane+1] = sinf(x.y*PHASE_C);
  }
}

// ------- K4: finalize BN0, build folded bf16 weights Wbf, W2 and b' ---------
__global__ __launch_bounds__(384) void k_bn0fin(const float* __restrict__ stats,
    const float* __restrict__ W_a, const float* __restrict__ b_a,
    const float* __restrict__ gamma0, const float* __restrict__ beta0,
    u16* __restrict__ Wbf, float* __restrict__ W2, float* __restrict__ bprime){
  __shared__ float a0[384], c0[384];
  int t = threadIdx.x;
  {
    int j = t & 127;
    float mu, ex2;
    if(t < 256){
      mu  = (stats[j]     + stats[128+j]) * (1.0f/(2.0f*N_TRIP));
      ex2 = (stats[256+j] + stats[384+j]) * (1.0f/(2.0f*N_TRIP));
    } else {
      mu  = 0.0f;
      ex2 = stats[512+j] * (1.0f/N_TRIP);
    }
    float var = ex2 - mu*mu;
    float a = gamma0[t]*rsqrtf(var + BN_EPSF);
    a0[t] = a;
    c0[t] = beta0[t] - mu*a;
  }
  __syncthreads();
  for(int idx=t; idx<256*128; idx+=384){
    int j = idx>>7, k = idx&127;
    int ko = ((j>>7)<<7) + k;
    Wbf[idx] = f2bf(W_a[(j&127)*384 + ko]*a0[ko]);
  }
  for(int idx=t; idx<128*128; idx+=384){
    int k = idx>>7, j = idx&127;
    W2[idx] = W_a[j*384 + 256 + k]*a0[256+k];
  }
  if(t < 128){
    float s = b_a[t];
    for(int k=0;k<384;k++) s += W_a[t*384+k]*c0[k];
    bprime[t] = s;
  }
}

// ------- K5: R[r] = rel_n[r] @ W2 ------------------------------------------
__global__ __launch_bounds__(128) void k_relproj(const float* __restrict__ rel,
    const float* __restrict__ scale_rel, const float* __restrict__ W2,
    float* __restrict__ R){
  int r = blockIdx.x, j = threadIdx.x;
  __shared__ float x[128];
  x[j] = rel[(size_t)r*D + j]*scale_rel[r];
  __syncthreads();
  float s = 0.f;
  for(int k=0;k<128;k++) s += x[k]*W2[k*128+j];
  R[r*128+j] = s;
}

// ------- K6: A/B projection via MFMA; input is pre-normalized bf16 ----------
__global__ __launch_bounds__(256) void k_ab(const u32* __restrict__ entnbf,
    const u16* __restrict__ Wbf, u16* __restrict__ Abuf, u16* __restrict__ Bbuf){
  __shared__ u16 xlds[16*128];
  int t = threadIdx.x, lane = t & 63, q = t >> 6;
  int kgrp = (lane>>4)<<3;
  int rgrp = (lane>>4)<<2;
  int frow = lane & 15;
  short8 wf[4][4];
  #pragma unroll
  for(int jt=0;jt<4;jt++){
    #pragma unroll
    for(int kt=0;kt<4;kt++)
      wf[jt][kt] = *(const short8*)(Wbf + (size_t)(q*64 + jt*16 + frow)*D + kgrp + kt*32);
  }
  int srow = t>>4;
  int scol16 = t&15;
  char* swp = (char*)xlds + srow*256 + ((scol16<<4) ^ ((srow&7)<<4));
  const char* rdp = (const char*)xlds + frow*256;
  int rbase0 = (lane>>4)<<4;
  int fsw = (frow&7)<<4;
  for(int chunk = blockIdx.x; chunk < N_ENT/16; chunk += gridDim.x){
    uint4 pk = *(const uint4*)(entnbf + (size_t)(chunk*16 + srow)*64 + scol16*4);
    __syncthreads();
    *(uint4*)swp = pk;
    __syncthreads();
    short8 xf[4];
    #pragma unroll
    for(int kt=0;kt<4;kt++)
      xf[kt] = *(const short8*)(rdp + ((rbase0 + kt*64) ^ fsw));
    int erow = chunk*16 + frow;
    #pragma unroll
    for(int jt=0;jt<4;jt++){
      f32x4 acc = {0.f,0.f,0.f,0.f};
      #pragma unroll
      for(int kt=0;kt<4;kt++)
        acc = __builtin_amdgcn_mfma_f32_16x16x32_bf16(wf[jt][kt], xf[kt], acc, 0,0,0);
      int jbase = q*64 + jt*16 + rgrp;
      u16x4 opk;
      opk.x=f2bf(acc[0]); opk.y=f2bf(acc[1]); opk.z=f2bf(acc[2]); opk.w=f2bf(acc[3]);
      u16* dst = (jbase < 128) ? (Abuf + (size_t)erow*D + jbase)
                               : (Bbuf + (size_t)erow*D + (jbase-128));
      *(u16x4*)dst = opk;
    }
  }
}

// ------- K7: BN1 statistics, 1/4 subsample, x2 unrolled ----------------------
__global__ __launch_bounds__(256) void k_bn1stats(const u64* __restrict__ pair64,
    const u16* __restrict__ A, const u16* __restrict__ B,
    const float* __restrict__ R, const float* __restrict__ bprime,
    float* __restrict__ sums){
  __shared__ float acc[256];
  int t = threadIdx.x;
  acc[t] = 0.f;
  __syncthreads();
  int lane = t & 63;
  int gw = blockIdx.x*4 + (t>>6), nw = gridDim.x*4;
  float bp0 = bprime[2*lane], bp1 = bprime[2*lane+1];
  float s0=0,s1=0,q0=0,q1=0;
  for(int i=4*gw; i<N_TRIP; i+=8*nw){
    {
      u64 pr = pair64[i];
      int t0 = (int)(pr & 0x3FFFF);
      int t1 = (int)((pr>>18) & 0x3FFFF);
      int t2 = (int)(pr>>36);
      u32 ua0 = *(const u32*)(A + (size_t)t0*D + 2*lane);
      u32 ua1 = *(const u32*)(A + (size_t)t1*D + 2*lane);
      u32 ub0 = *(const u32*)(B + (size_t)t0*D + 2*lane);
      u32 ub1 = *(const u32*)(B + (size_t)t1*D + 2*lane);
      float2 r = *(const float2*)(R + (size_t)t2*D + 2*lane);
      float y1x = bfl(ua0)+bfl(ub1)+r.x+bp0;
      float y1y = bfh(ua0)+bfh(ub1)+r.y+bp1;
      float y2x = bfl(ua1)+bfl(ub0)-r.x+bp0;
      float y2y = bfh(ua1)+bfh(ub0)-r.y+bp1;
      s0 += y1x+y2x; s1 += y1y+y2y;
      q0 += y1x*y1x + y2x*y2x; q1 += y1y*y1y + y2y*y2y;
    }
    int i2 = i + 4*nw;
    if(i2 < N_TRIP){
      u64 pr = pair64[i2];
      int t0 = (int)(pr & 0x3FFFF);
      int t1 = (int)((pr>>18) & 0x3FFFF);
      int t2 = (int)(pr>>36);
      u32 ua0 = *(const u32*)(A + (size_t)t0*D + 2*lane);
      u32 ua1 = *(const u32*)(A + (size_t)t1*D + 2*lane);
      u32 ub0 = *(const u32*)(B + (size_t)t0*D + 2*lane);
      u32 ub1 = *(const u32*)(B + (size_t)t1*D + 2*lane);
      float2 r = *(const float2*)(R + (size_t)t2*D + 2*lane);
      float y1x = bfl(ua0)+bfl(ub1)+r.x+bp0;
      float y1y = bfh(ua0)+bfh(ub1)+r.y+bp1;
      float y2x = bfl(ua1)+bfl(ub0)-r.x+bp0;
      float y2y = bfh(ua1)+bfh(ub0)-r.y+bp1;
      s0 += y1x+y2x; s1 += y1y+y2y;
      q0 += y1x*y1x + y2x*y2x; q1 += y1y*y1y + y2y*y2y;
    }
  }
  atomicAdd(&acc[      2*lane  ], s0);
  atomicAdd(&acc[      2*lane+1], s1);
  atomicAdd(&acc[128 + 2*lane  ], q0);
  atomicAdd(&acc[128 + 2*lane+1], q1);
  __syncthreads();
  atomicAdd(&sums[t], acc[t]);
}

// ------- K8: finalize BN1 (1/4 subsample: N_TRIP/2 samples) -----------------
__global__ __launch_bounds__(128) void k_bn1fin(const float* __restrict__ sums,
    const float* __restrict__ gamma1, const float* __restrict__ beta1,
    const float* __restrict__ W_a2, const float* __restrict__ b_a2,
    const float* __restrict__ bprime, float* __restrict__ a1c){
  __shared__ float red[128];
  int j = threadIdx.x;
  float mu  = sums[j]    *(2.0f/(float)N_TRIP);
  float var = sums[128+j]*(2.0f/(float)N_TRIP) - mu*mu;
  float a = gamma1[j]*rsqrtf(var + BN_EPSF);
  float cc = beta1[j] - mu*a;
  float wa1 = W_a2[j]*a;
  a1c[j]     = a;
  a1c[128+j] = cc;
  a1c[256+j] = wa1;
  red[j] = W_a2[j]*cc + wa1*bprime[j];
  __syncthreads();
  #pragma unroll
  for(int s=64; s>0; s>>=1){
    if(j < s) red[j] += red[j+s];
    __syncthreads();
  }
  if(j==0) a1c[384] = red[0] + b_a2[0];
}

// ------- K8b: per-entity scalars alpha/beta/rho -----------------------------
__global__ __launch_bounds__(256) void k_alphabeta(const u16* __restrict__ A,
    const u16* __restrict__ B, const float* __restrict__ R,
    const float* __restrict__ a1c, float* __restrict__ alpha,
    float* __restrict__ beta, float* __restrict__ rho){
  int t = threadIdx.x, lane = t & 63;
  int l32 = lane & 31, grp = lane >> 5;
  int wid = blockIdx.x*4 + (t>>6), nw = gridDim.x*4;
  float4 wa = *(const float4*)(a1c + 256 + l32*4);
  for(int e4 = wid*4; e4 < N_ENT; e4 += nw*4){
    int eA = e4 + grp, eB = e4 + 2 + grp;
    uint2 uaA = *(const uint2*)(A + (size_t)eA*D + l32*4);
    uint2 ubA = *(const uint2*)(B + (size_t)eA*D + l32*4);
    uint2 uaB = *(const uint2*)(A + (size_t)eB*D + l32*4);
    uint2 ubB = *(const uint2*)(B + (size_t)eB*D + l32*4);
    float daA = wa.x*bfl(uaA.x) + wa.y*bfh(uaA.x) + wa.z*bfl(uaA.y) + wa.w*bfh(uaA.y);
    float dbA = wa.x*bfl(ubA.x) + wa.y*bfh(ubA.x) + wa.z*bfl(ubA.y) + wa.w*bfh(ubA.y);
    float daB = wa.x*bfl(uaB.x) + wa.y*bfh(uaB.x) + wa.z*bfl(uaB.y) + wa.w*bfh(uaB.y);
    float dbB = wa.x*bfl(ubB.x) + wa.y*bfh(ubB.x) + wa.z*bfl(ubB.y) + wa.w*bfh(ubB.y);
    #pragma unroll
    for(int o=16;o>0;o>>=1){
      daA += __shfl_xor(daA,o,64); dbA += __shfl_xor(dbA,o,64);
      daB += __shfl_xor(daB,o,64); dbB += __shfl_xor(dbB,o,64);
    }
    if(l32==0){ alpha[eA]=daA; beta[eA]=dbA; alpha[eB]=daB; beta[eB]=dbB; }
  }
  for(int r2 = wid*2 + grp; r2 < N_REL; r2 += nw*2){
    float4 rr = *(const float4*)(R + (size_t)r2*D + l32*4);
    float dr = wa.x*rr.x + wa.y*rr.y + wa.z*rr.z + wa.w*rr.w;
    #pragma unroll
    for(int o=16;o>0;o>>=1) dr += __shfl_xor(dr,o,64);
    if(l32==0) rho[r2]=dr;
  }
}

// ------- K9: per-entity gather, 16-lane groups, x2 edge unroll --------------
__global__ __launch_bounds__(256) void k_ent(
    const int* __restrict__ offs, const int* __restrict__ endp,
    const u32* __restrict__ ebuf,
    const u16* __restrict__ A, const u16* __restrict__ B,
    const float* __restrict__ R, const float* __restrict__ bprime,
    const float* __restrict__ a1c, const float* __restrict__ alpha,
    const float* __restrict__ beta, const float* __restrict__ rho,
    float* __restrict__ out_hent){
  int t = threadIdx.x, lane = t & 63;
  int l16 = lane & 15, g = lane >> 4;
  int wid = blockIdx.x*4 + (t>>6), nw = gridDim.x*4;
  int cb = l16*8;
  float4 bpA = *(const float4*)(bprime + cb);
  float4 bpB = *(const float4*)(bprime + cb + 4);
  float4 a1A = *(const float4*)(a1c + cb);
  float4 a1B = *(const float4*)(a1c + cb + 4);
  float4 ccA = *(const float4*)(a1c + 128 + cb);
  float4 ccB = *(const float4*)(a1c + 128 + cb + 4);
  float kap = a1c[384];
  for(int e4 = wid*4; e4 < N_ENT; e4 += nw*4){
    int e = e4 + g;
    int s = offs[e], en = endp[e];
    uint4 ua = *(const uint4*)(A + (size_t)e*D + cb);
    float ax0 = bfl(ua.x), ax1 = bfh(ua.x), ax2 = bfl(ua.y), ax3 = bfh(ua.y);
    float ax4 = bfl(ua.z), ax5 = bfh(ua.z), ax6 = bfl(ua.w), ax7 = bfh(ua.w);
    float al = alpha[e];
    float h0=0,h1=0,h2=0,h3=0,h4=0,h5=0,h6=0,h7=0, eb=0;
    int o = s;
    for(; o+1<en; o+=2){
      u32 idX = ebuf[o], idY = ebuf[o+1];
      int otX = idX>>10, r2X = (idX>>1)&511;
      int otY = idY>>10, r2Y = (idY>>1)&511;
      float sgX = (idX&1) ? -1.f : 1.f;
      float sgY = (idY&1) ? -1.f : 1.f;
      uint4 ubX = *(const uint4*)(B + (size_t)otX*D + cb);
      uint4 ubY = *(const uint4*)(B + (size_t)otY*D + cb);
      float4 rAX = *(const float4*)(R + (size_t)r2X*D + cb);
      float4 rBX = *(const float4*)(R + (size_t)r2X*D + cb + 4);
      float4 rAY = *(const float4*)(R + (size_t)r2Y*D + cb);
      float4 rBY = *(const float4*)(R + (size_t)r2Y*D + cb + 4);
      float beX = beta[otX], beY = beta[otY];
      float roX = rho[r2X],  roY = rho[r2Y];
      float svX = al + beX + sgX*roX + kap;
      float svY = al + beY + sgY*roY + kap;
      float ebX = expf(svX >= 0.f ? -svX : -0.01f*svX);
      float ebY = expf(svY >= 0.f ? -svY : -0.01f*svY);
      float y, c;
      y = ax0 + bfl(ubX.x) + sgX*rAX.x + bpA.x; c = y*a1A.x + ccA.x; h0 += ebX*c;
      y = ax1 + bfh(ubX.x) + sgX*rAX.y + bpA.y; c = y*a1A.y + ccA.y; h1 += ebX*c;
      y = ax2 + bfl(ubX.y) + sgX*rAX.z + bpA.z; c = y*a1A.z + ccA.z; h2 += ebX*c;
      y = ax3 + bfh(ubX.y) + sgX*rAX.w + bpA.w; c = y*a1A.w + ccA.w; h3 += ebX*c;
      y = ax4 + bfl(ubX.z) + sgX*rBX.x + bpB.x; c = y*a1B.x + ccB.x; h4 += ebX*c;
      y = ax5 + bfh(ubX.z) + sgX*rBX.y + bpB.y; c = y*a1B.y + ccB.y; h5 += ebX*c;
      y = ax6 + bfl(ubX.w) + sgX*rBX.z + bpB.z; c = y*a1B.z + ccB.z; h6 += ebX*c;
      y = ax7 + bfh(ubX.w) + sgX*rBX.w + bpB.w; c = y*a1B.w + ccB.w; h7 += ebX*c;
      y = ax0 + bfl(ubY.x) + sgY*rAY.x + bpA.x; c = y*a1A.x + ccA.x; h0 += ebY*c;
      y = ax1 + bfh(ubY.x) + sgY*rAY.y + bpA.y; c = y*a1A.y + ccA.y; h1 += ebY*c;
      y = ax2 + bfl(ubY.y) + sgY*rAY.z + bpA.z; c = y*a1A.z + ccA.z; h2 += ebY*c;
      y = ax3 + bfh(ubY.y) + sgY*rAY.w + bpA.w; c = y*a1A.w + ccA.w; h3 += ebY*c;
      y = ax4 + bfl(ubY.z) + sgY*rBY.x + bpB.x; c = y*a1B.x + ccB.x; h4 += ebY*c;
      y = ax5 + bfh(ubY.z) + sgY*rBY.y + bpB.y; c = y*a1B.y + ccB.y; h5 += ebY*c;
      y = ax6 + bfl(ubY.w) + sgY*rBY.z + bpB.z; c = y*a1B.z + ccB.z; h6 += ebY*c;
      y = ax7 + bfh(ubY.w) + sgY*rBY.w + bpB.w; c = y*a1B.w + ccB.w; h7 += ebY*c;
      eb += ebX + ebY;
    }
    if(o < en){
      u32 id = ebuf[o];
      int ot = id>>10, r2 = (id>>1)&511;
      float sg = (id&1) ? -1.f : 1.f;
      uint4 ub = *(const uint4*)(B + (size_t)ot*D + cb);
      float4 rA = *(const float4*)(R + (size_t)r2*D + cb);
      float4 rB = *(const float4*)(R + (size_t)r2*D + cb + 4);
      float sv = al + beta[ot] + sg*rho[r2] + kap;
      float e_b = expf(sv >= 0.f ? -sv : -0.01f*sv);
      float y, c;
      y = ax0 + bfl(ub.x) + sg*rA.x + bpA.x; c = y*a1A.x + ccA.x; h0 += e_b*c;
      y = ax1 + bfh(ub.x) + sg*rA.y + bpA.y; c = y*a1A.y + ccA.y; h1 += e_b*c;
      y = ax2 + bfl(ub.y) + sg*rA.z + bpA.z; c = y*a1A.z + ccA.z; h2 += e_b*c;
      y = ax3 + bfh(ub.y) + sg*rA.w + bpA.w; c = y*a1A.w + ccA.w; h3 += e_b*c;
      y = ax4 + bfl(ub.z) + sg*rB.x + bpB.x; c = y*a1B.x + ccB.x; h4 += e_b*c;
      y = ax5 + bfh(ub.z) + sg*rB.y + bpB.y; c = y*a1B.y + ccB.y; h5 += e_b*c;
      y = ax6 + bfl(ub.w) + sg*rB.z + bpB.z; c = y*a1B.z + ccB.z; h6 += e_b*c;
      y = ax7 + bfh(ub.w) + sg*rB.w + bpB.w; c = y*a1B.w + ccB.w; h7 += e_b*c;
      eb += e_b;
    }
    float inv = (en > s) ? 1.0f/eb : 0.0f;
    float4 o0; o0.x=h0*inv; o0.y=h1*inv; o0.z=h2*inv; o0.w=h3*inv;
    float4 o1; o1.x=h4*inv; o1.y=h5*inv; o1.z=h6*inv; o1.w=h7*inv;
    *(float4*)(out_hent + (size_t)e*D + cb)     = o0;
    *(float4*)(out_hent + (size_t)e*D + cb + 4) = o1;
  }
}

// ------- K10: per-rel gather pass, packed pairs, x2 unrolled ----------------
__global__ __launch_bounds__(512) void k_rel(
    const int* __restrict__ roffs, const int* __restrict__ cntr,
    const u64* __restrict__ rpair,
    const u16* __restrict__ A, const u16* __restrict__ B,
    const float* __restrict__ R, const float* __restrict__ bprime,
    const float* __restrict__ a1c, const float* __restrict__ alpha,
    const float* __restrict__ beta, const float* __restrict__ rho,
    float* __restrict__ out_hrel){
  __shared__ float red[8][128];
  int t = threadIdx.x, lane = t & 63, w = t >> 6;
  int r = blockIdx.x;
  int cnt = cntr[r], base = roffs[r];
  float2 rr = *(const float2*)(R + (size_t)r*D + 2*lane);
  float bp0 = bprime[2*lane], bp1 = bprime[2*lane+1];
  float a1x = a1c[2*lane],     a1y = a1c[2*lane+1];
  float ccx = a1c[128+2*lane], ccy = a1c[128+2*lane+1];
  float kap = a1c[384];
  float rhor = rho[r];
  float sx = 0.f, sy = 0.f;
  for(int j=w; j<cnt; j+=16){
    {
      u64 pr = rpair[base+j];
      int t0 = (int)(pr & 0x3FFFF);
      int t1 = (int)((pr>>18) & 0x3FFFF);
      float s1 = alpha[t0] + beta[t1] + rhor + kap;
      float s2 = alpha[t1] + beta[t0] - rhor + kap;
      float e1 = expf(s1 >= 0.f ? -s1 : -0.01f*s1);
      float e2 = expf(s2 >= 0.f ? -s2 : -0.01f*s2);
      u32 ua0 = *(const u32*)(A + (size_t)t0*D + 2*lane);
      u32 ua1 = *(const u32*)(A + (size_t)t1*D + 2*lane);
      u32 ub0 = *(const u32*)(B + (size_t)t0*D + 2*lane);
      u32 ub1 = *(const u32*)(B + (size_t)t1*D + 2*lane);
      float y1x = bfl(ua0)+bfl(ub1)+rr.x+bp0;
      float y1y = bfh(ua0)+bfh(ub1)+rr.y+bp1;
      float y2x = bfl(ua1)+bfl(ub0)-rr.x+bp0;
      float y2y = bfh(ua1)+bfh(ub0)-rr.y+bp1;
      float c1x = y1x*a1x+ccx, c1y = y1y*a1y+ccy;
      float c2x = y2x*a1x+ccx, c2y = y2y*a1y+ccy;
      sx += e1*c1x - e2*c2x;
      sy += e1*c1y - e2*c2y;
    }
    int j2 = j + 8;
    if(j2 < cnt){
      u64 pr = rpair[base+j2];
      int t0 = (int)(pr & 0x3FFFF);
      int t1 = (int)((pr>>18) & 0x3FFFF);
      float s1 = alpha[t0] + beta[t1] + rhor + kap;
      float s2 = alpha[t1] + beta[t0] - rhor + kap;
      float e1 = expf(s1 >= 0.f ? -s1 : -0.01f*s1);
      float e2 = expf(s2 >= 0.f ? -s2 : -0.01f*s2);
      u32 ua0 = *(const u32*)(A + (size_t)t0*D + 2*lane);
      u32 ua1 = *(const u32*)(A + (size_t)t1*D + 2*lane);
      u32 ub0 = *(const u32*)(B + (size_t)t0*D + 2*lane);
      u32 ub1 = *(const u32*)(B + (size_t)t1*D + 2*lane);
      float y1x = bfl(ua0)+bfl(ub1)+rr.x+bp0;
      float y1y = bfh(ua0)+bfh(ub1)+rr.y+bp1;
      float y2x = bfl(ua1)+bfl(ub0)-rr.x+bp0;
      float y2y = bfh(ua1)+bfh(ub0)-rr.y+bp1;
      float c1x = y1x*a1x+ccx, c1y = y1y*a1y+ccy;
      float c2x = y2x*a1x+ccx, c2y = y2y*a1y+ccy;
      sx += e1*c1x - e2*c2x;
      sy += e1*c1y - e2*c2y;
    }
  }
  float2 p; p.x = sx; p.y = sy;
  *(float2*)&red[w][2*lane] = p;
  __syncthreads();
  if(t < 128){
    float s = 0.f;
    #pragma unroll
    for(int k=0;k<8;k++) s += red[k][t];
    float cf = cnt > 0 ? (float)cnt : 1.0f;
    out_hrel[(size_t)r*D + t] = s/cf;
  }
}

// ------- K12: RotatE score, 16-lane groups (4 triplets/wave) ----------------
__global__ __launch_bounds__(256) void k_score_bf(const u64* __restrict__ pair64,
    const u32* __restrict__ entbf, const float* __restrict__ cosr,
    const float* __restrict__ sinr, float* __restrict__ score){
  int t = threadIdx.x, lane = t & 63;
  int l16 = lane & 15, g = lane >> 4;
  int wid = blockIdx.x*4 + (t>>6), nw = gridDim.x*4;
  for(int i4 = wid*4; i4 < N_TRIP; i4 += nw*4){
    int i = i4 + g;
    u64 pr = pair64[i];
    int t0 = (int)(pr & 0x3FFFF);
    int t1 = (int)((pr>>18) & 0x3FFFF);
    int t2 = (int)(pr>>36);
    uint2 reh = *(const uint2*)(entbf + (size_t)t0*64 + l16*2);
    uint2 imh = *(const uint2*)(entbf + (size_t)t0*64 + 32 + l16*2);
    uint2 ret = *(const uint2*)(entbf + (size_t)t1*64 + l16*2);
    uint2 imt = *(const uint2*)(entbf + (size_t)t1*64 + 32 + l16*2);
    float4 cr = *(const float4*)(cosr + (size_t)t2*64 + l16*4);
    float4 sr = *(const float4*)(sinr + (size_t)t2*64 + l16*4);
    float rh[4] = {bfl(reh.x),bfh(reh.x),bfl(reh.y),bfh(reh.y)};
    float ih[4] = {bfl(imh.x),bfh(imh.x),bfl(imh.y),bfh(imh.y)};
    float rt[4] = {bfl(ret.x),bfh(ret.x),bfl(ret.y),bfh(ret.y)};
    float it[4] = {bfl(imt.x),bfh(imt.x),bfl(imt.y),bfh(imt.y)};
    float cc[4] = {cr.x,cr.y,cr.z,cr.w};
    float ss[4] = {sr.x,sr.y,sr.z,sr.w};
    float d = 0.f;
    #pragma unroll
    for(int k=0;k<4;k++){
      float res = cc[k]*rt[k] + ss[k]*it[k] - rh[k];
      float ims = cc[k]*it[k] - ss[k]*rt[k] - ih[k];
      d += sqrtf(res*res + ims*ims);
    }
    #pragma unroll
    for(int o=8;o>0;o>>=1) d += __shfl_xor(d,o,64);
    if(l16==0) score[i] = MARGINF - d;
  }
}

// fp32 fallback if workspace too small for entbf
__global__ __launch_bounds__(256) void k_score_fp(const u64* __restrict__ pair64,
    const float* __restrict__ ent, const float* __restrict__ cosr,
    const float* __restrict__ sinr, float* __restrict__ score){
  int t = threadIdx.x, lane = t & 63;
  int gw = blockIdx.x*4 + (t>>6), nw = gridDim.x*4;
  for(int i=gw; i<N_TRIP; i+=nw){
    u64 pr = pair64[i];
    int t0 = (int)(pr & 0x3FFFF);
    int t1 = (int)((pr>>18) & 0x3FFFF);
    int t2 = (int)(pr>>36);
    float re_h = ent[(size_t)t0*D + lane];
    float im_h = ent[(size_t)t0*D + 64 + lane];
    float re_t = ent[(size_t)t1*D + lane];
    float im_t = ent[(size_t)t1*D + 64 + lane];
    float cr = cosr[t2*64 + lane], sr = sinr[t2*64 + lane];
    float re_s = cr*re_t + sr*im_t - re_h;
    float im_s = cr*im_t - sr*re_t - im_h;
    float d = sqrtf(re_s*re_s + im_s*im_s);
    #pragma unroll
    for(int o=32;o>0;o>>=1) d += __shfl_xor(d,o,64);
    if(lane==0) score[i] = MARGINF - d;
  }
}

extern "C" void kernel_launch(void* const* d_in, const int* in_sizes, int n_in,
                              void* d_out, int out_size, void* d_ws, size_t ws_size,
                              hipStream_t stream){
  const int*   trip   = (const int*)  d_in[0];
  const float* ent    = (const float*)d_in[1];
  const float* rel    = (const float*)d_in[2];
  const float* W_a    = (const float*)d_in[3];
  const float* b_a    = (const float*)d_in[4];
  const float* W_a2   = (const float*)d_in[5];
  const float* b_a2   = (const float*)d_in[6];
  const float* gamma0 = (const float*)d_in[7];
  const float* beta0  = (const float*)d_in[8];
  const float* gamma1 = (const float*)d_in[9];
  const float* beta1  = (const float*)d_in[10];

  char* ws = (char*)d_ws;
  size_t off = 0;
  auto take = [&](size_t bytes)->void*{
    void* p = ws + off;
    off += (bytes + 255) & ~(size_t)255;
    return p;
  };
  // ---- zeroed scratch (contiguous from 0) ----
  int*   cnt0    = (int*)  take((size_t)N_ENT*4);
  int*   cnt1    = (int*)  take((size_t)N_ENT*4);
  int*   cntr    = (int*)  take((size_t)N_REL*4);
  float* stats   = (float*)take(640*4);
  float* sums    = (float*)take(256*4);
  size_t zero_bytes = off;
  // ---- fully-overwritten scratch (required) ----
  int*   offs      = (int*)  take((size_t)N_ENT*4);
  int*   cur       = (int*)  take((size_t)N_ENT*4);
  int*   bsum      = (int*)  take(512*4);
  int*   boffs     = (int*)  take(512*4);
  int*   roffs     = (int*)  take(512*4);
  int*   rcur      = (int*)  take(512*4);
  u32*   ebuf      = (u32*)  take((size_t)2*N_TRIP*4);
  u64*   pair64    = (u64*)  take((size_t)N_TRIP*8);
  u64*   rpair     = (u64*)  take((size_t)N_TRIP*8);
  float* scale_rel = (float*)take((size_t)N_REL*4);
  u16*   Wbf       = (u16*)  take(256*128*2);
  float* W2        = (float*)take(128*128*4);
  float* bprime    = (float*)take(128*4);
  float* a1c       = (float*)take(512*4);
  float* R         = (float*)take((size_t)N_REL*D*4);
  float* cosr      = (float*)take((size_t)N_REL*64*4);
  float* sinr      = (float*)take((size_t)N_REL*64*4);
  float* alpha     = (float*)take((size_t)N_ENT*4);
  float* betab     = (float*)take((size_t)N_ENT*4);
  float* rho       = (float*)take(512*4);
  u16*   Abuf      = (u16*)  take((size_t)N_ENT*D*2);
  u16*   Bbuf      = (u16*)  take((size_t)N_ENT*D*2);
  u32*   entnbf    = (u32*)  take((size_t)N_ENT*64*4);
  // ---- optional: raw bf16 copy for k_score ----
  u32*   entbf     = (u32*)  take((size_t)N_ENT*64*4);
  bool use_bf = (off <= ws_size);
  (void)n_in; (void)in_sizes; (void)out_size;

  float* out_hent  = (float*)d_out;
  float* out_hrel  = out_hent + (size_t)N_ENT*D;
  float* out_score = out_hrel + (size_t)N_REL*D;

  hipMemsetAsync(d_ws, 0, zero_bytes, stream);

  const int SCAN_BLKS = (N_ENT + 1023)/1024;     // 196
  const int EDG_BLKS  = (N_TRIP + 2047)/2048;    // 98
  k_prep     <<<2048, 256, 0, stream>>>(ent, entnbf, use_bf ? entbf : (u32*)nullptr);
  k_hist     <<<EDG_BLKS, 256, 0, stream>>>(trip, cnt0, cnt1, cntr);
  k_scan1    <<<SCAN_BLKS, 1024, 0, stream>>>(cnt0, cnt1, offs, bsum);
  k_scan2    <<<1, 512, 0, stream>>>(bsum, boffs, cntr, roffs, rcur, SCAN_BLKS);
  k_scan3    <<<SCAN_BLKS, 1024, 0, stream>>>(offs, boffs, cur);
  k_edges    <<<EDG_BLKS, 256, 0, stream>>>(trip, cur, rcur, ebuf, pair64, rpair);
  k_stats    <<<640, 256, 0, stream>>>(entnbf, cnt0, cnt1, stats);
  k_relstats <<<(N_REL+3)/4, 256, 0, stream>>>(rel, cntr, scale_rel, stats, cosr, sinr);
  k_bn0fin   <<<1, 384, 0, stream>>>(stats, W_a, b_a, gamma0, beta0, Wbf, W2, bprime);
  k_relproj  <<<N_REL, 128, 0, stream>>>(rel, scale_rel, W2, R);
  k_ab       <<<2048, 256, 0, stream>>>(entnbf, Wbf, Abuf, Bbuf);
  k_bn1stats <<<2048, 256, 0, stream>>>(pair64, Abuf, Bbuf, R, bprime, sums);
  k_bn1fin   <<<1, 128, 0, stream>>>(sums, gamma1, beta1, W_a2, b_a2, bprime, a1c);
  k_alphabeta<<<2048, 256, 0, stream>>>(Abuf, Bbuf, R, a1c, alpha, betab, rho);
  k_ent      <<<2048, 256, 0, stream>>>(offs, cur, ebuf, Abuf, Bbuf, R,
                                        bprime, a1c, alpha, betab, rho, out_hent);
  k_rel      <<<N_REL, 512, 0, stream>>>(roffs, cntr, rpair, Abuf, Bbuf, R,
                                         bprime, a1c, alpha, betab, rho, out_hrel);
  if(use_bf)
    k_score_bf<<<2048, 256, 0, stream>>>(pair64, entbf, cosr, sinr, out_score);
  else
    k_score_fp<<<2048, 256, 0, stream>>>(pair64, ent, cosr, sinr, out_score);
}

// Round 11
// 426.675 us; speedup vs baseline: 3.8033x; 1.0644x over previous
//
#include <hip/hip_runtime.h>
#include <stdint.h>

#define N_TRIP 200000
#define N_ENT  200000
#define N_REL  500
#define D      128
#define MARGINF 6.0f
#define BN_EPSF 1e-5f
#define PHASE_C 50.26548245743669f   // PI / REL_RANGE, REL_RANGE = 8/128
#define PREP_BLKS 384
#define BN1_BLKS  240

typedef unsigned short u16;
typedef unsigned int   u32;
typedef unsigned long long u64;
typedef __attribute__((ext_vector_type(8))) short short8;
typedef __attribute__((ext_vector_type(4))) float f32x4;
typedef __attribute__((ext_vector_type(4))) unsigned short u16x4;

__device__ inline float bfl(u32 u){ return __uint_as_float(u<<16); }
__device__ inline float bfh(u32 u){ return __uint_as_float(u&0xffff0000u); }
__device__ inline u16 f2bf(float f){
  u32 u = __float_as_uint(f);
  u32 r = (u + 0x7fffu + ((u>>16)&1u))>>16;
  return (u16)r;
}

// ------- K1: histogram; rel counts aggregated in LDS ------------------------
__global__ __launch_bounds__(256) void k_hist(const int* __restrict__ trip,
    int* __restrict__ cnt0, int* __restrict__ cnt1, int* __restrict__ cntr){
  __shared__ int rc[N_REL];
  int t = threadIdx.x;
  for(int r=t; r<N_REL; r+=256) rc[r]=0;
  __syncthreads();
  #pragma unroll
  for(int k=0;k<8;k++){
    int i = blockIdx.x*2048 + t + k*256;
    if(i < N_TRIP){
      atomicAdd(&cnt0[trip[3*i]],   1);
      atomicAdd(&cnt1[trip[3*i+1]], 1);
      atomicAdd(&rc[trip[3*i+2]],   1);
    }
  }
  __syncthreads();
  for(int r=t; r<N_REL; r+=256){
    int c = rc[r];
    if(c) atomicAdd(&cntr[r], c);
  }
}

// ---------------- CSR build: 3-kernel prefix scan + cursor scatter ----------
__global__ __launch_bounds__(1024) void k_scan1(const int* __restrict__ cnt0,
    const int* __restrict__ cnt1, int* __restrict__ offs, int* __restrict__ bsum){
  __shared__ int sh[1024];
  int t = threadIdx.x;
  int e = blockIdx.x*1024 + t;
  int d = (e < N_ENT) ? cnt0[e] + cnt1[e] : 0;
  sh[t] = d; __syncthreads();
  for(int st=1; st<1024; st<<=1){
    int x = (t>=st) ? sh[t-st] : 0;
    __syncthreads();
    sh[t] += x;
    __syncthreads();
  }
  if(e < N_ENT) offs[e] = sh[t] - d;
  if(t == 1023) bsum[blockIdx.x] = sh[t];
}

__global__ __launch_bounds__(512) void k_scan2(const int* __restrict__ bsum,
    int* __restrict__ boffs, const int* __restrict__ cntr,
    int* __restrict__ roffs, int* __restrict__ rcur, int nblk){
  __shared__ int sh[512];
  int t = threadIdx.x;
  int v = (t < nblk) ? bsum[t] : 0;
  sh[t] = v; __syncthreads();
  for(int st=1; st<512; st<<=1){
    int x = (t>=st) ? sh[t-st] : 0;
    __syncthreads(); sh[t] += x; __syncthreads();
  }
  if(t < nblk) boffs[t] = sh[t] - v;
  __syncthreads();
  int w = (t < N_REL) ? cntr[t] : 0;
  sh[t] = w; __syncthreads();
  for(int st=1; st<512; st<<=1){
    int x = (t>=st) ? sh[t-st] : 0;
    __syncthreads(); sh[t] += x; __syncthreads();
  }
  if(t < N_REL){ roffs[t] = sh[t]-w; rcur[t] = sh[t]-w; }
}

__global__ __launch_bounds__(1024) void k_scan3(int* __restrict__ offs,
    const int* __restrict__ boffs, int* __restrict__ cur){
  int e = blockIdx.x*1024 + threadIdx.x;
  if(e < N_ENT){
    int o = offs[e] + boffs[blockIdx.x];
    offs[e] = o;
    cur[e] = o;
  }
}

// ------- K-edges: chunked scatter; rel cursors via LDS + bulk alloc ---------
__global__ __launch_bounds__(256) void k_edges(const int* __restrict__ trip,
    int* __restrict__ cur, int* __restrict__ rcur,
    u32* __restrict__ ebuf, u64* __restrict__ pair64, u64* __restrict__ rpair){
  __shared__ int rcnt[N_REL];
  __shared__ int rbase[N_REL];
  int t = threadIdx.x;
  for(int r=t; r<N_REL; r+=256) rcnt[r]=0;
  __syncthreads();
  int i0 = blockIdx.x*2048;
  int lt0[8], lt1[8], lt2[8], lp[8];
  #pragma unroll
  for(int k=0;k<8;k++){
    int i = i0 + t + k*256;
    lt2[k] = -1;
    if(i < N_TRIP){
      int t0 = trip[3*i], t1 = trip[3*i+1], t2 = trip[3*i+2];
      lt0[k]=t0; lt1[k]=t1; lt2[k]=t2;
      lp[k] = atomicAdd(&rcnt[t2], 1);
      pair64[i] = ((u64)t2<<36) | ((u64)t1<<18) | (u64)t0;
      ebuf[atomicAdd(&cur[t0], 1)] = ((u32)t1<<10) | ((u32)t2<<1);
      ebuf[atomicAdd(&cur[t1], 1)] = ((u32)t0<<10) | ((u32)t2<<1) | 1u;
    }
  }
  __syncthreads();
  for(int r=t; r<N_REL; r+=256){
    int c = rcnt[r];
    rbase[r] = c ? atomicAdd(&rcur[r], c) : 0;
  }
  __syncthreads();
  #pragma unroll
  for(int k=0;k<8;k++){
    if(lt2[k] >= 0)
      rpair[rbase[lt2[k]] + lp[k]] =
        ((u64)lt2[k]<<36) | ((u64)lt1[k]<<18) | (u64)lt0[k];
  }
}

// ------- K2: streaming prep + fused BN0 stats (partials to scratch) ---------
// 16-lane groups, 8 rows/wave. Stats use fp32 normalized values; per-block
// LDS aggregation -> pstat[block][512] (NO global atomics).
__global__ __launch_bounds__(256) void k_prep(const float* __restrict__ ent,
    const int* __restrict__ cnt0, const int* __restrict__ cnt1,
    u32* __restrict__ entnbf, u32* entbf, float* __restrict__ pstat){
  __shared__ float acc[512];
  int t = threadIdx.x;
  acc[t] = 0.f; acc[t+256] = 0.f;
  __syncthreads();
  int lane = t & 63;
  int l16 = lane & 15, g = lane >> 4;
  int wid = blockIdx.x*4 + (t>>6), nw = gridDim.x*4;
  float s0[8]={0,0,0,0,0,0,0,0}, s1[8]={0,0,0,0,0,0,0,0};
  float q0[8]={0,0,0,0,0,0,0,0}, q1[8]={0,0,0,0,0,0,0,0};
  for(int e8 = wid*8; e8 < N_ENT; e8 += nw*8){
    int eA = e8 + g, eB = e8 + 4 + g;
    const float* xpA = ent + (size_t)eA*D + l16*8;
    const float* xpB = ent + (size_t)eB*D + l16*8;
    float4 a0 = *(const float4*)xpA;
    float4 a1 = *(const float4*)(xpA+4);
    float4 b0 = *(const float4*)xpB;
    float4 b1 = *(const float4*)(xpB+4);
    if(entbf){
      uint4 pa, pb;
      pa.x = (u32)f2bf(a0.x) | ((u32)f2bf(a0.y)<<16);
      pa.y = (u32)f2bf(a0.z) | ((u32)f2bf(a0.w)<<16);
      pa.z = (u32)f2bf(a1.x) | ((u32)f2bf(a1.y)<<16);
      pa.w = (u32)f2bf(a1.z) | ((u32)f2bf(a1.w)<<16);
      pb.x = (u32)f2bf(b0.x) | ((u32)f2bf(b0.y)<<16);
      pb.y = (u32)f2bf(b0.z) | ((u32)f2bf(b0.w)<<16);
      pb.z = (u32)f2bf(b1.x) | ((u32)f2bf(b1.y)<<16);
      pb.w = (u32)f2bf(b1.z) | ((u32)f2bf(b1.w)<<16);
      *(uint4*)(entbf + (size_t)eA*64 + l16*4) = pa;
      *(uint4*)(entbf + (size_t)eB*64 + l16*4) = pb;
    }
    float ssA = a0.x*a0.x + a0.y*a0.y + a0.z*a0.z + a0.w*a0.w
              + a1.x*a1.x + a1.y*a1.y + a1.z*a1.z + a1.w*a1.w;
    float ssB = b0.x*b0.x + b0.y*b0.y + b0.z*b0.z + b0.w*b0.w
              + b1.x*b1.x + b1.y*b1.y + b1.z*b1.z + b1.w*b1.w;
    #pragma unroll
    for(int o=8;o>0;o>>=1){
      ssA += __shfl_xor(ssA,o,64);
      ssB += __shfl_xor(ssB,o,64);
    }
    float nA = sqrtf(ssA), nB = sqrtf(ssB);
    float scA = nA > 1.0f ? 1.0f/nA : 1.0f;
    float scB = nB > 1.0f ? 1.0f/nB : 1.0f;
    float vA[8] = {a0.x*scA,a0.y*scA,a0.z*scA,a0.w*scA,
                   a1.x*scA,a1.y*scA,a1.z*scA,a1.w*scA};
    float vB[8] = {b0.x*scB,b0.y*scB,b0.z*scB,b0.w*scB,
                   b1.x*scB,b1.y*scB,b1.z*scB,b1.w*scB};
    uint4 na, nb;
    na.x = (u32)f2bf(vA[0]) | ((u32)f2bf(vA[1])<<16);
    na.y = (u32)f2bf(vA[2]) | ((u32)f2bf(vA[3])<<16);
    na.z = (u32)f2bf(vA[4]) | ((u32)f2bf(vA[5])<<16);
    na.w = (u32)f2bf(vA[6]) | ((u32)f2bf(vA[7])<<16);
    nb.x = (u32)f2bf(vB[0]) | ((u32)f2bf(vB[1])<<16);
    nb.y = (u32)f2bf(vB[2]) | ((u32)f2bf(vB[3])<<16);
    nb.z = (u32)f2bf(vB[4]) | ((u32)f2bf(vB[5])<<16);
    nb.w = (u32)f2bf(vB[6]) | ((u32)f2bf(vB[7])<<16);
    *(uint4*)(entnbf + (size_t)eA*64 + l16*4) = na;
    *(uint4*)(entnbf + (size_t)eB*64 + l16*4) = nb;
    float wA0 = (float)cnt0[eA], wA1 = (float)cnt1[eA];
    float wB0 = (float)cnt0[eB], wB1 = (float)cnt1[eB];
    #pragma unroll
    for(int k=0;k<8;k++){
      s0[k] += wA0*vA[k] + wB0*vB[k];
      s1[k] += wA1*vA[k] + wB1*vB[k];
      q0[k] += wA0*vA[k]*vA[k] + wB0*vB[k]*vB[k];
      q1[k] += wA1*vA[k]*vA[k] + wB1*vB[k]*vB[k];
    }
  }
  #pragma unroll
  for(int k=0;k<8;k++){
    int c = l16*8 + k;
    atomicAdd(&acc[c],     s0[k]);
    atomicAdd(&acc[128+c], s1[k]);
    atomicAdd(&acc[256+c], q0[k]);
    atomicAdd(&acc[384+c], q1[k]);
  }
  __syncthreads();
  pstat[(size_t)blockIdx.x*512 + t]       = acc[t];
  pstat[(size_t)blockIdx.x*512 + 256 + t] = acc[t+256];
}

// ------- K2c: reduce prep partials into stats[0..512) -----------------------
__global__ __launch_bounds__(512) void k_redstats(const float* __restrict__ pstat,
    float* __restrict__ stats){
  int j = threadIdx.x;
  float s = 0.f;
  for(int b=0;b<PREP_BLKS;b++) s += pstat[(size_t)b*512 + j];
  stats[j] = s;
}

// ------- K3: per-rel scale + Qr stats (LDS-aggregated) + phase tables -------
__global__ __launch_bounds__(256) void k_relstats(const float* __restrict__ rel,
    const int* __restrict__ cntr, float* __restrict__ scale_rel,
    float* __restrict__ stats, float* __restrict__ cosr, float* __restrict__ sinr){
  __shared__ float qacc[128];
  int t = threadIdx.x, lane = t & 63;
  if(t < 128) qacc[t] = 0.f;
  __syncthreads();
  int r = blockIdx.x*4 + (t>>6);
  if(r < N_REL){
    float2 x = *(const float2*)(rel + (size_t)r*D + 2*lane);
    float ss = x.x*x.x + x.y*x.y;
    #pragma unroll
    for(int o=32;o>0;o>>=1) ss += __shfl_xor(ss,o,64);
    float nrm = sqrtf(ss);
    float sc = nrm > 1.0f ? 1.0f/nrm : 1.0f;
    if(lane==0) scale_rel[r] = sc;
    float w = (float)cntr[r];
    float sx = x.x*sc, sy = x.y*sc;
    atomicAdd(&qacc[2*lane  ], w*sx*sx);
    atomicAdd(&qacc[2*lane+1], w*sy*sy);
    if(lane < 32){
      cosr[r*64 + 2*lane  ] = cosf(x.x*PHASE_C);
      sinr[r*64 + 2*lane  ] = sinf(x.x*PHASE_C);
      cosr[r*64 + 2*lane+1] = cosf(x.y*PHASE_C);
      sinr[r*64 + 2*lane+1] = sinf(x.y*PHASE_C);
    }
  }
  __syncthreads();
  if(t < 128) atomicAdd(&stats[512+t], qacc[t]);
}

// ------- K4: finalize BN0, build folded bf16 weights Wbf, W2 and b' ---------
__global__ __launch_bounds__(384) void k_bn0fin(const float* __restrict__ stats,
    const float* __restrict__ W_a, const float* __restrict__ b_a,
    const float* __restrict__ gamma0, const float* __restrict__ beta0,
    u16* __restrict__ Wbf, float* __restrict__ W2, float* __restrict__ bprime){
  __shared__ float a0[384], c0[384];
  int t = threadIdx.x;
  {
    int j = t & 127;
    float mu, ex2;
    if(t < 256){
      mu  = (stats[j]     + stats[128+j]) * (1.0f/(2.0f*N_TRIP));
      ex2 = (stats[256+j] + stats[384+j]) * (1.0f/(2.0f*N_TRIP));
    } else {
      mu  = 0.0f;
      ex2 = stats[512+j] * (1.0f/N_TRIP);
    }
    float var = ex2 - mu*mu;
    float a = gamma0[t]*rsqrtf(var + BN_EPSF);
    a0[t] = a;
    c0[t] = beta0[t] - mu*a;
  }
  __syncthreads();
  for(int idx=t; idx<256*128; idx+=384){
    int j = idx>>7, k = idx&127;
    int ko = ((j>>7)<<7) + k;
    Wbf[idx] = f2bf(W_a[(j&127)*384 + ko]*a0[ko]);
  }
  for(int idx=t; idx<128*128; idx+=384){
    int k = idx>>7, j = idx&127;
    W2[idx] = W_a[j*384 + 256 + k]*a0[256+k];
  }
  if(t < 128){
    float s = b_a[t];
    for(int k=0;k<384;k++) s += W_a[t*384+k]*c0[k];
    bprime[t] = s;
  }
}

// ------- K5: R[r] = rel_n[r] @ W2 ------------------------------------------
__global__ __launch_bounds__(128) void k_relproj(const float* __restrict__ rel,
    const float* __restrict__ scale_rel, const float* __restrict__ W2,
    float* __restrict__ R){
  int r = blockIdx.x, j = threadIdx.x;
  __shared__ float x[128];
  x[j] = rel[(size_t)r*D + j]*scale_rel[r];
  __syncthreads();
  float s = 0.f;
  for(int k=0;k<128;k++) s += x[k]*W2[k*128+j];
  R[r*128+j] = s;
}

// ------- K6: A/B projection via MFMA; input is pre-normalized bf16 ----------
__global__ __launch_bounds__(256) void k_ab(const u32* __restrict__ entnbf,
    const u16* __restrict__ Wbf, u16* __restrict__ Abuf, u16* __restrict__ Bbuf){
  __shared__ u16 xlds[16*128];
  int t = threadIdx.x, lane = t & 63, q = t >> 6;
  int kgrp = (lane>>4)<<3;
  int rgrp = (lane>>4)<<2;
  int frow = lane & 15;
  short8 wf[4][4];
  #pragma unroll
  for(int jt=0;jt<4;jt++){
    #pragma unroll
    for(int kt=0;kt<4;kt++)
      wf[jt][kt] = *(const short8*)(Wbf + (size_t)(q*64 + jt*16 + frow)*D + kgrp + kt*32);
  }
  int srow = t>>4;
  int scol16 = t&15;
  char* swp = (char*)xlds + srow*256 + ((scol16<<4) ^ ((srow&7)<<4));
  const char* rdp = (const char*)xlds + frow*256;
  int rbase0 = (lane>>4)<<4;
  int fsw = (frow&7)<<4;
  for(int chunk = blockIdx.x; chunk < N_ENT/16; chunk += gridDim.x){
    uint4 pk = *(const uint4*)(entnbf + (size_t)(chunk*16 + srow)*64 + scol16*4);
    __syncthreads();
    *(uint4*)swp = pk;
    __syncthreads();
    short8 xf[4];
    #pragma unroll
    for(int kt=0;kt<4;kt++)
      xf[kt] = *(const short8*)(rdp + ((rbase0 + kt*64) ^ fsw));
    int erow = chunk*16 + frow;
    #pragma unroll
    for(int jt=0;jt<4;jt++){
      f32x4 acc = {0.f,0.f,0.f,0.f};
      #pragma unroll
      for(int kt=0;kt<4;kt++)
        acc = __builtin_amdgcn_mfma_f32_16x16x32_bf16(wf[jt][kt], xf[kt], acc, 0,0,0);
      int jbase = q*64 + jt*16 + rgrp;
      u16x4 opk;
      opk.x=f2bf(acc[0]); opk.y=f2bf(acc[1]); opk.z=f2bf(acc[2]); opk.w=f2bf(acc[3]);
      u16* dst = (jbase < 128) ? (Abuf + (size_t)erow*D + jbase)
                               : (Bbuf + (size_t)erow*D + (jbase-128));
      *(u16x4*)dst = opk;
    }
  }
}

// ------- K7: BN1 stats, 1/4 subsample, partials to scratch (no atomics) -----
__global__ __launch_bounds__(256) void k_bn1stats(const u64* __restrict__ pair64,
    const u16* __restrict__ A, const u16* __restrict__ B,
    const float* __restrict__ R, const float* __restrict__ bprime,
    float* __restrict__ pstat1){
  __shared__ float acc[256];
  int t = threadIdx.x;
  acc[t] = 0.f;
  __syncthreads();
  int lane = t & 63;
  int gw = blockIdx.x*4 + (t>>6), nw = gridDim.x*4;
  float bp0 = bprime[2*lane], bp1 = bprime[2*lane+1];
  float s0=0,s1=0,q0=0,q1=0;
  for(int i=4*gw; i<N_TRIP; i+=8*nw){
    {
      u64 pr = pair64[i];
      int t0 = (int)(pr & 0x3FFFF);
      int t1 = (int)((pr>>18) & 0x3FFFF);
      int t2 = (int)(pr>>36);
      u32 ua0 = *(const u32*)(A + (size_t)t0*D + 2*lane);
      u32 ua1 = *(const u32*)(A + (size_t)t1*D + 2*lane);
      u32 ub0 = *(const u32*)(B + (size_t)t0*D + 2*lane);
      u32 ub1 = *(const u32*)(B + (size_t)t1*D + 2*lane);
      float2 r = *(const float2*)(R + (size_t)t2*D + 2*lane);
      float y1x = bfl(ua0)+bfl(ub1)+r.x+bp0;
      float y1y = bfh(ua0)+bfh(ub1)+r.y+bp1;
      float y2x = bfl(ua1)+bfl(ub0)-r.x+bp0;
      float y2y = bfh(ua1)+bfh(ub0)-r.y+bp1;
      s0 += y1x+y2x; s1 += y1y+y2y;
      q0 += y1x*y1x + y2x*y2x; q1 += y1y*y1y + y2y*y2y;
    }
    int i2 = i + 4*nw;
    if(i2 < N_TRIP){
      u64 pr = pair64[i2];
      int t0 = (int)(pr & 0x3FFFF);
      int t1 = (int)((pr>>18) & 0x3FFFF);
      int t2 = (int)(pr>>36);
      u32 ua0 = *(const u32*)(A + (size_t)t0*D + 2*lane);
      u32 ua1 = *(const u32*)(A + (size_t)t1*D + 2*lane);
      u32 ub0 = *(const u32*)(B + (size_t)t0*D + 2*lane);
      u32 ub1 = *(const u32*)(B + (size_t)t1*D + 2*lane);
      float2 r = *(const float2*)(R + (size_t)t2*D + 2*lane);
      float y1x = bfl(ua0)+bfl(ub1)+r.x+bp0;
      float y1y = bfh(ua0)+bfh(ub1)+r.y+bp1;
      float y2x = bfl(ua1)+bfl(ub0)-r.x+bp0;
      float y2y = bfh(ua1)+bfh(ub0)-r.y+bp1;
      s0 += y1x+y2x; s1 += y1y+y2y;
      q0 += y1x*y1x + y2x*y2x; q1 += y1y*y1y + y2y*y2y;
    }
  }
  atomicAdd(&acc[      2*lane  ], s0);
  atomicAdd(&acc[      2*lane+1], s1);
  atomicAdd(&acc[128 + 2*lane  ], q0);
  atomicAdd(&acc[128 + 2*lane+1], q1);
  __syncthreads();
  pstat1[(size_t)blockIdx.x*256 + t] = acc[t];
}

// ------- K8: reduce BN1 partials + finalize (1/4 subsample) -----------------
__global__ __launch_bounds__(128) void k_bn1fin(const float* __restrict__ pstat1,
    const float* __restrict__ gamma1, const float* __restrict__ beta1,
    const float* __restrict__ W_a2, const float* __restrict__ b_a2,
    const float* __restrict__ bprime, float* __restrict__ a1c){
  __shared__ float red[128];
  int j = threadIdx.x;
  float s = 0.f, q = 0.f;
  for(int b=0;b<BN1_BLKS;b++){
    s += pstat1[(size_t)b*256 + j];
    q += pstat1[(size_t)b*256 + 128 + j];
  }
  float mu  = s*(2.0f/(float)N_TRIP);
  float var = q*(2.0f/(float)N_TRIP) - mu*mu;
  float a = gamma1[j]*rsqrtf(var + BN_EPSF);
  float cc = beta1[j] - mu*a;
  float wa1 = W_a2[j]*a;
  a1c[j]     = a;
  a1c[128+j] = cc;
  a1c[256+j] = wa1;
  red[j] = W_a2[j]*cc + wa1*bprime[j];
  __syncthreads();
  #pragma unroll
  for(int st=64; st>0; st>>=1){
    if(j < st) red[j] += red[j+st];
    __syncthreads();
  }
  if(j==0) a1c[384] = red[0] + b_a2[0];
}

// ------- K8b: per-entity scalars alpha/beta/rho -----------------------------
__global__ __launch_bounds__(256) void k_alphabeta(const u16* __restrict__ A,
    const u16* __restrict__ B, const float* __restrict__ R,
    const float* __restrict__ a1c, float* __restrict__ alpha,
    float* __restrict__ beta, float* __restrict__ rho){
  int t = threadIdx.x, lane = t & 63;
  int l32 = lane & 31, grp = lane >> 5;
  int wid = blockIdx.x*4 + (t>>6), nw = gridDim.x*4;
  float4 wa = *(const float4*)(a1c + 256 + l32*4);
  for(int e4 = wid*4; e4 < N_ENT; e4 += nw*4){
    int eA = e4 + grp, eB = e4 + 2 + grp;
    uint2 uaA = *(const uint2*)(A + (size_t)eA*D + l32*4);
    uint2 ubA = *(const uint2*)(B + (size_t)eA*D + l32*4);
    uint2 uaB = *(const uint2*)(A + (size_t)eB*D + l32*4);
    uint2 ubB = *(const uint2*)(B + (size_t)eB*D + l32*4);
    float daA = wa.x*bfl(uaA.x) + wa.y*bfh(uaA.x) + wa.z*bfl(uaA.y) + wa.w*bfh(uaA.y);
    float dbA = wa.x*bfl(ubA.x) + wa.y*bfh(ubA.x) + wa.z*bfl(ubA.y) + wa.w*bfh(ubA.y);
    float daB = wa.x*bfl(uaB.x) + wa.y*bfh(uaB.x) + wa.z*bfl(uaB.y) + wa.w*bfh(uaB.y);
    float dbB = wa.x*bfl(ubB.x) + wa.y*bfh(ubB.x) + wa.z*bfl(ubB.y) + wa.w*bfh(ubB.y);
    #pragma unroll
    for(int o=16;o>0;o>>=1){
      daA += __shfl_xor(daA,o,64); dbA += __shfl_xor(dbA,o,64);
      daB += __shfl_xor(daB,o,64); dbB += __shfl_xor(dbB,o,64);
    }
    if(l32==0){ alpha[eA]=daA; beta[eA]=dbA; alpha[eB]=daB; beta[eB]=dbB; }
  }
  for(int r2 = wid*2 + grp; r2 < N_REL; r2 += nw*2){
    float4 rr = *(const float4*)(R + (size_t)r2*D + l32*4);
    float dr = wa.x*rr.x + wa.y*rr.y + wa.z*rr.z + wa.w*rr.w;
    #pragma unroll
    for(int o=16;o>0;o>>=1) dr += __shfl_xor(dr,o,64);
    if(l32==0) rho[r2]=dr;
  }
}

// ------- K9: per-entity gather, 16-lane groups, x2 edge unroll --------------
__global__ __launch_bounds__(256) void k_ent(
    const int* __restrict__ offs, const int* __restrict__ endp,
    const u32* __restrict__ ebuf,
    const u16* __restrict__ A, const u16* __restrict__ B,
    const float* __restrict__ R, const float* __restrict__ bprime,
    const float* __restrict__ a1c, const float* __restrict__ alpha,
    const float* __restrict__ beta, const float* __restrict__ rho,
    float* __restrict__ out_hent){
  int t = threadIdx.x, lane = t & 63;
  int l16 = lane & 15, g = lane >> 4;
  int wid = blockIdx.x*4 + (t>>6), nw = gridDim.x*4;
  int cb = l16*8;
  float4 bpA = *(const float4*)(bprime + cb);
  float4 bpB = *(const float4*)(bprime + cb + 4);
  float4 a1A = *(const float4*)(a1c + cb);
  float4 a1B = *(const float4*)(a1c + cb + 4);
  float4 ccA = *(const float4*)(a1c + 128 + cb);
  float4 ccB = *(const float4*)(a1c + 128 + cb + 4);
  float kap = a1c[384];
  for(int e4 = wid*4; e4 < N_ENT; e4 += nw*4){
    int e = e4 + g;
    int s = offs[e], en = endp[e];
    uint4 ua = *(const uint4*)(A + (size_t)e*D + cb);
    float ax0 = bfl(ua.x), ax1 = bfh(ua.x), ax2 = bfl(ua.y), ax3 = bfh(ua.y);
    float ax4 = bfl(ua.z), ax5 = bfh(ua.z), ax6 = bfl(ua.w), ax7 = bfh(ua.w);
    float al = alpha[e];
    float h0=0,h1=0,h2=0,h3=0,h4=0,h5=0,h6=0,h7=0, eb=0;
    int o = s;
    for(; o+1<en; o+=2){
      u32 idX = ebuf[o], idY = ebuf[o+1];
      int otX = idX>>10, r2X = (idX>>1)&511;
      int otY = idY>>10, r2Y = (idY>>1)&511;
      float sgX = (idX&1) ? -1.f : 1.f;
      float sgY = (idY&1) ? -1.f : 1.f;
      uint4 ubX = *(const uint4*)(B + (size_t)otX*D + cb);
      uint4 ubY = *(const uint4*)(B + (size_t)otY*D + cb);
      float4 rAX = *(const float4*)(R + (size_t)r2X*D + cb);
      float4 rBX = *(const float4*)(R + (size_t)r2X*D + cb + 4);
      float4 rAY = *(const float4*)(R + (size_t)r2Y*D + cb);
      float4 rBY = *(const float4*)(R + (size_t)r2Y*D + cb + 4);
      float beX = beta[otX], beY = beta[otY];
      float roX = rho[r2X],  roY = rho[r2Y];
      float svX = al + beX + sgX*roX + kap;
      float svY = al + beY + sgY*roY + kap;
      float ebX = expf(svX >= 0.f ? -svX : -0.01f*svX);
      float ebY = expf(svY >= 0.f ? -svY : -0.01f*svY);
      float y, c;
      y = ax0 + bfl(ubX.x) + sgX*rAX.x + bpA.x; c = y*a1A.x + ccA.x; h0 += ebX*c;
      y = ax1 + bfh(ubX.x) + sgX*rAX.y + bpA.y; c = y*a1A.y + ccA.y; h1 += ebX*c;
      y = ax2 + bfl(ubX.y) + sgX*rAX.z + bpA.z; c = y*a1A.z + ccA.z; h2 += ebX*c;
      y = ax3 + bfh(ubX.y) + sgX*rAX.w + bpA.w; c = y*a1A.w + ccA.w; h3 += ebX*c;
      y = ax4 + bfl(ubX.z) + sgX*rBX.x + bpB.x; c = y*a1B.x + ccB.x; h4 += ebX*c;
      y = ax5 + bfh(ubX.z) + sgX*rBX.y + bpB.y; c = y*a1B.y + ccB.y; h5 += ebX*c;
      y = ax6 + bfl(ubX.w) + sgX*rBX.z + bpB.z; c = y*a1B.z + ccB.z; h6 += ebX*c;
      y = ax7 + bfh(ubX.w) + sgX*rBX.w + bpB.w; c = y*a1B.w + ccB.w; h7 += ebX*c;
      y = ax0 + bfl(ubY.x) + sgY*rAY.x + bpA.x; c = y*a1A.x + ccA.x; h0 += ebY*c;
      y = ax1 + bfh(ubY.x) + sgY*rAY.y + bpA.y; c = y*a1A.y + ccA.y; h1 += ebY*c;
      y = ax2 + bfl(ubY.y) + sgY*rAY.z + bpA.z; c = y*a1A.z + ccA.z; h2 += ebY*c;
      y = ax3 + bfh(ubY.y) + sgY*rAY.w + bpA.w; c = y*a1A.w + ccA.w; h3 += ebY*c;
      y = ax4 + bfl(ubY.z) + sgY*rBY.x + bpB.x; c = y*a1B.x + ccB.x; h4 += ebY*c;
      y = ax5 + bfh(ubY.z) + sgY*rBY.y + bpB.y; c = y*a1B.y + ccB.y; h5 += ebY*c;
      y = ax6 + bfl(ubY.w) + sgY*rBY.z + bpB.z; c = y*a1B.z + ccB.z; h6 += ebY*c;
      y = ax7 + bfh(ubY.w) + sgY*rBY.w + bpB.w; c = y*a1B.w + ccB.w; h7 += ebY*c;
      eb += ebX + ebY;
    }
    if(o < en){
      u32 id = ebuf[o];
      int ot = id>>10, r2 = (id>>1)&511;
      float sg = (id&1) ? -1.f : 1.f;
      uint4 ub = *(const uint4*)(B + (size_t)ot*D + cb);
      float4 rA = *(const float4*)(R + (size_t)r2*D + cb);
      float4 rB = *(const float4*)(R + (size_t)r2*D + cb + 4);
      float sv = al + beta[ot] + sg*rho[r2] + kap;
      float e_b = expf(sv >= 0.f ? -sv : -0.01f*sv);
      float y, c;
      y = ax0 + bfl(ub.x) + sg*rA.x + bpA.x; c = y*a1A.x + ccA.x; h0 += e_b*c;
      y = ax1 + bfh(ub.x) + sg*rA.y + bpA.y; c = y*a1A.y + ccA.y; h1 += e_b*c;
      y = ax2 + bfl(ub.y) + sg*rA.z + bpA.z; c = y*a1A.z + ccA.z; h2 += e_b*c;
      y = ax3 + bfh(ub.y) + sg*rA.w + bpA.w; c = y*a1A.w + ccA.w; h3 += e_b*c;
      y = ax4 + bfl(ub.z) + sg*rB.x + bpB.x; c = y*a1B.x + ccB.x; h4 += e_b*c;
      y = ax5 + bfh(ub.z) + sg*rB.y + bpB.y; c = y*a1B.y + ccB.y; h5 += e_b*c;
      y = ax6 + bfl(ub.w) + sg*rB.z + bpB.z; c = y*a1B.z + ccB.z; h6 += e_b*c;
      y = ax7 + bfh(ub.w) + sg*rB.w + bpB.w; c = y*a1B.w + ccB.w; h7 += e_b*c;
      eb += e_b;
    }
    float inv = (en > s) ? 1.0f/eb : 0.0f;
    float4 o0; o0.x=h0*inv; o0.y=h1*inv; o0.z=h2*inv; o0.w=h3*inv;
    float4 o1; o1.x=h4*inv; o1.y=h5*inv; o1.z=h6*inv; o1.w=h7*inv;
    *(float4*)(out_hent + (size_t)e*D + cb)     = o0;
    *(float4*)(out_hent + (size_t)e*D + cb + 4) = o1;
  }
}

// ------- K10: per-rel gather pass, packed pairs, x2 unrolled ----------------
__global__ __launch_bounds__(512) void k_rel(
    const int* __restrict__ roffs, const int* __restrict__ cntr,
    const u64* __restrict__ rpair,
    const u16* __restrict__ A, const u16* __restrict__ B,
    const float* __restrict__ R, const float* __restrict__ bprime,
    const float* __restrict__ a1c, const float* __restrict__ alpha,
    const float* __restrict__ beta, const float* __restrict__ rho,
    float* __restrict__ out_hrel){
  __shared__ float red[8][128];
  int t = threadIdx.x, lane = t & 63, w = t >> 6;
  int r = blockIdx.x;
  int cnt = cntr[r], base = roffs[r];
  float2 rr = *(const float2*)(R + (size_t)r*D + 2*lane);
  float bp0 = bprime[2*lane], bp1 = bprime[2*lane+1];
  float a1x = a1c[2*lane],     a1y = a1c[2*lane+1];
  float ccx = a1c[128+2*lane], ccy = a1c[128+2*lane+1];
  float kap = a1c[384];
  float rhor = rho[r];
  float sx = 0.f, sy = 0.f;
  for(int j=w; j<cnt; j+=16){
    {
      u64 pr = rpair[base+j];
      int t0 = (int)(pr & 0x3FFFF);
      int t1 = (int)((pr>>18) & 0x3FFFF);
      float s1 = alpha[t0] + beta[t1] + rhor + kap;
      float s2 = alpha[t1] + beta[t0] - rhor + kap;
      float e1 = expf(s1 >= 0.f ? -s1 : -0.01f*s1);
      float e2 = expf(s2 >= 0.f ? -s2 : -0.01f*s2);
      u32 ua0 = *(const u32*)(A + (size_t)t0*D + 2*lane);
      u32 ua1 = *(const u32*)(A + (size_t)t1*D + 2*lane);
      u32 ub0 = *(const u32*)(B + (size_t)t0*D + 2*lane);
      u32 ub1 = *(const u32*)(B + (size_t)t1*D + 2*lane);
      float y1x = bfl(ua0)+bfl(ub1)+rr.x+bp0;
      float y1y = bfh(ua0)+bfh(ub1)+rr.y+bp1;
      float y2x = bfl(ua1)+bfl(ub0)-rr.x+bp0;
      float y2y = bfh(ua1)+bfh(ub0)-rr.y+bp1;
      float c1x = y1x*a1x+ccx, c1y = y1y*a1y+ccy;
      float c2x = y2x*a1x+ccx, c2y = y2y*a1y+ccy;
      sx += e1*c1x - e2*c2x;
      sy += e1*c1y - e2*c2y;
    }
    int j2 = j + 8;
    if(j2 < cnt){
      u64 pr = rpair[base+j2];
      int t0 = (int)(pr & 0x3FFFF);
      int t1 = (int)((pr>>18) & 0x3FFFF);
      float s1 = alpha[t0] + beta[t1] + rhor + kap;
      float s2 = alpha[t1] + beta[t0] - rhor + kap;
      float e1 = expf(s1 >= 0.f ? -s1 : -0.01f*s1);
      float e2 = expf(s2 >= 0.f ? -s2 : -0.01f*s2);
      u32 ua0 = *(const u32*)(A + (size_t)t0*D + 2*lane);
      u32 ua1 = *(const u32*)(A + (size_t)t1*D + 2*lane);
      u32 ub0 = *(const u32*)(B + (size_t)t0*D + 2*lane);
      u32 ub1 = *(const u32*)(B + (size_t)t1*D + 2*lane);
      float y1x = bfl(ua0)+bfl(ub1)+rr.x+bp0;
      float y1y = bfh(ua0)+bfh(ub1)+rr.y+bp1;
      float y2x = bfl(ua1)+bfl(ub0)-rr.x+bp0;
      float y2y = bfh(ua1)+bfh(ub0)-rr.y+bp1;
      float c1x = y1x*a1x+ccx, c1y = y1y*a1y+ccy;
      float c2x = y2x*a1x+ccx, c2y = y2y*a1y+ccy;
      sx += e1*c1x - e2*c2x;
      sy += e1*c1y - e2*c2y;
    }
  }
  float2 p; p.x = sx; p.y = sy;
  *(float2*)&red[w][2*lane] = p;
  __syncthreads();
  if(t < 128){
    float s = 0.f;
    #pragma unroll
    for(int k=0;k<8;k++) s += red[k][t];
    float cf = cnt > 0 ? (float)cnt : 1.0f;
    out_hrel[(size_t)r*D + t] = s/cf;
  }
}

// ------- K12: RotatE score, 16-lane groups (4 triplets/wave) ----------------
__global__ __launch_bounds__(256) void k_score_bf(const u64* __restrict__ pair64,
    const u32* __restrict__ entbf, const float* __restrict__ cosr,
    const float* __restrict__ sinr, float* __restrict__ score){
  int t = threadIdx.x, lane = t & 63;
  int l16 = lane & 15, g = lane >> 4;
  int wid = blockIdx.x*4 + (t>>6), nw = gridDim.x*4;
  for(int i4 = wid*4; i4 < N_TRIP; i4 += nw*4){
    int i = i4 + g;
    u64 pr = pair64[i];
    int t0 = (int)(pr & 0x3FFFF);
    int t1 = (int)((pr>>18) & 0x3FFFF);
    int t2 = (int)(pr>>36);
    uint2 reh = *(const uint2*)(entbf + (size_t)t0*64 + l16*2);
    uint2 imh = *(const uint2*)(entbf + (size_t)t0*64 + 32 + l16*2);
    uint2 ret = *(const uint2*)(entbf + (size_t)t1*64 + l16*2);
    uint2 imt = *(const uint2*)(entbf + (size_t)t1*64 + 32 + l16*2);
    float4 cr = *(const float4*)(cosr + (size_t)t2*64 + l16*4);
    float4 sr = *(const float4*)(sinr + (size_t)t2*64 + l16*4);
    float rh[4] = {bfl(reh.x),bfh(reh.x),bfl(reh.y),bfh(reh.y)};
    float ih[4] = {bfl(imh.x),bfh(imh.x),bfl(imh.y),bfh(imh.y)};
    float rt[4] = {bfl(ret.x),bfh(ret.x),bfl(ret.y),bfh(ret.y)};
    float it[4] = {bfl(imt.x),bfh(imt.x),bfl(imt.y),bfh(imt.y)};
    float cc[4] = {cr.x,cr.y,cr.z,cr.w};
    float ss[4] = {sr.x,sr.y,sr.z,sr.w};
    float d = 0.f;
    #pragma unroll
    for(int k=0;k<4;k++){
      float res = cc[k]*rt[k] + ss[k]*it[k] - rh[k];
      float ims = cc[k]*it[k] - ss[k]*rt[k] - ih[k];
      d += sqrtf(res*res + ims*ims);
    }
    #pragma unroll
    for(int o=8;o>0;o>>=1) d += __shfl_xor(d,o,64);
    if(l16==0) score[i] = MARGINF - d;
  }
}

// fp32 fallback if workspace too small for entbf
__global__ __launch_bounds__(256) void k_score_fp(const u64* __restrict__ pair64,
    const float* __restrict__ ent, const float* __restrict__ cosr,
    const float* __restrict__ sinr, float* __restrict__ score){
  int t = threadIdx.x, lane = t & 63;
  int gw = blockIdx.x*4 + (t>>6), nw = gridDim.x*4;
  for(int i=gw; i<N_TRIP; i+=nw){
    u64 pr = pair64[i];
    int t0 = (int)(pr & 0x3FFFF);
    int t1 = (int)((pr>>18) & 0x3FFFF);
    int t2 = (int)(pr>>36);
    float re_h = ent[(size_t)t0*D + lane];
    float im_h = ent[(size_t)t0*D + 64 + lane];
    float re_t = ent[(size_t)t1*D + lane];
    float im_t = ent[(size_t)t1*D + 64 + lane];
    float cr = cosr[t2*64 + lane], sr = sinr[t2*64 + lane];
    float re_s = cr*re_t + sr*im_t - re_h;
    float im_s = cr*im_t - sr*re_t - im_h;
    float d = sqrtf(re_s*re_s + im_s*im_s);
    #pragma unroll
    for(int o=32;o>0;o>>=1) d += __shfl_xor(d,o,64);
    if(lane==0) score[i] = MARGINF - d;
  }
}

extern "C" void kernel_launch(void* const* d_in, const int* in_sizes, int n_in,
                              void* d_out, int out_size, void* d_ws, size_t ws_size,
                              hipStream_t stream){
  const int*   trip   = (const int*)  d_in[0];
  const float* ent    = (const float*)d_in[1];
  const float* rel    = (const float*)d_in[2];
  const float* W_a    = (const float*)d_in[3];
  const float* b_a    = (const float*)d_in[4];
  const float* W_a2   = (const float*)d_in[5];
  const float* b_a2   = (const float*)d_in[6];
  const float* gamma0 = (const float*)d_in[7];
  const float* beta0  = (const float*)d_in[8];
  const float* gamma1 = (const float*)d_in[9];
  const float* beta1  = (const float*)d_in[10];

  char* ws = (char*)d_ws;
  size_t off = 0;
  auto take = [&](size_t bytes)->void*{
    void* p = ws + off;
    off += (bytes + 255) & ~(size_t)255;
    return p;
  };
  // ---- zeroed scratch (contiguous from 0) ----
  int*   cnt0    = (int*)  take((size_t)N_ENT*4);
  int*   cnt1    = (int*)  take((size_t)N_ENT*4);
  int*   cntr    = (int*)  take((size_t)N_REL*4);
  float* stats   = (float*)take(640*4);
  size_t zero_bytes = off;
  // ---- fully-overwritten scratch (required) ----
  int*   offs      = (int*)  take((size_t)N_ENT*4);
  int*   cur       = (int*)  take((size_t)N_ENT*4);
  int*   bsum      = (int*)  take(512*4);
  int*   boffs     = (int*)  take(512*4);
  int*   roffs     = (int*)  take(512*4);
  int*   rcur      = (int*)  take(512*4);
  u32*   ebuf      = (u32*)  take((size_t)2*N_TRIP*4);
  u64*   pair64    = (u64*)  take((size_t)N_TRIP*8);
  u64*   rpair     = (u64*)  take((size_t)N_TRIP*8);
  float* scale_rel = (float*)take((size_t)N_REL*4);
  u16*   Wbf       = (u16*)  take(256*128*2);
  float* W2        = (float*)take(128*128*4);
  float* bprime    = (float*)take(128*4);
  float* a1c       = (float*)take(512*4);
  float* R         = (float*)take((size_t)N_REL*D*4);
  float* cosr      = (float*)take((size_t)N_REL*64*4);
  float* sinr      = (float*)take((size_t)N_REL*64*4);
  float* alpha     = (float*)take((size_t)N_ENT*4);
  float* betab     = (float*)take((size_t)N_ENT*4);
  float* rho       = (float*)take(512*4);
  float* pstat     = (float*)take((size_t)PREP_BLKS*512*4);
  float* pstat1    = (float*)take((size_t)BN1_BLKS*256*4);
  u16*   Abuf      = (u16*)  take((size_t)N_ENT*D*2);
  u16*   Bbuf      = (u16*)  take((size_t)N_ENT*D*2);
  u32*   entnbf    = (u32*)  take((size_t)N_ENT*64*4);
  // ---- optional: raw bf16 copy for k_score ----
  u32*   entbf     = (u32*)  take((size_t)N_ENT*64*4);
  bool use_bf = (off <= ws_size);
  (void)n_in; (void)in_sizes; (void)out_size;

  float* out_hent  = (float*)d_out;
  float* out_hrel  = out_hent + (size_t)N_ENT*D;
  float* out_score = out_hrel + (size_t)N_REL*D;

  hipMemsetAsync(d_ws, 0, zero_bytes, stream);

  const int SCAN_BLKS = (N_ENT + 1023)/1024;     // 196
  const int EDG_BLKS  = (N_TRIP + 2047)/2048;    // 98
  k_hist     <<<EDG_BLKS, 256, 0, stream>>>(trip, cnt0, cnt1, cntr);
  k_prep     <<<PREP_BLKS, 256, 0, stream>>>(ent, cnt0, cnt1, entnbf,
                                             use_bf ? entbf : (u32*)nullptr, pstat);
  k_redstats <<<1, 512, 0, stream>>>(pstat, stats);
  k_scan1    <<<SCAN_BLKS, 1024, 0, stream>>>(cnt0, cnt1, offs, bsum);
  k_scan2    <<<1, 512, 0, stream>>>(bsum, boffs, cntr, roffs, rcur, SCAN_BLKS);
  k_scan3    <<<SCAN_BLKS, 1024, 0, stream>>>(offs, boffs, cur);
  k_edges    <<<EDG_BLKS, 256, 0, stream>>>(trip, cur, rcur, ebuf, pair64, rpair);
  k_relstats <<<(N_REL+3)/4, 256, 0, stream>>>(rel, cntr, scale_rel, stats, cosr, sinr);
  k_bn0fin   <<<1, 384, 0, stream>>>(stats, W_a, b_a, gamma0, beta0, Wbf, W2, bprime);
  k_relproj  <<<N_REL, 128, 0, stream>>>(rel, scale_rel, W2, R);
  k_ab       <<<2048, 256, 0, stream>>>(entnbf, Wbf, Abuf, Bbuf);
  k_bn1stats <<<BN1_BLKS, 256, 0, stream>>>(pair64, Abuf, Bbuf, R, bprime, pstat1);
  k_bn1fin   <<<1, 128, 0, stream>>>(pstat1, gamma1, beta1, W_a2, b_a2, bprime, a1c);
  k_alphabeta<<<2048, 256, 0, stream>>>(Abuf, Bbuf, R, a1c, alpha, betab, rho);
  k_ent      <<<2048, 256, 0, stream>>>(offs, cur, ebuf, Abuf, Bbuf, R,
                                        bprime, a1c, alpha, betab, rho, out_hent);
  k_rel      <<<N_REL, 512, 0, stream>>>(roffs, cntr, rpair, Abuf, Bbuf, R,
                                         bprime, a1c, alpha, betab, rho, out_hrel);
  if(use_bf)
    k_score_bf<<<2048, 256, 0, stream>>>(pair64, entbf, cosr, sinr, out_score);
  else
    k_score_fp<<<2048, 256, 0, stream>>>(pair64, ent, cosr, sinr, out_score);
}

// Round 12
// 425.529 us; speedup vs baseline: 3.8136x; 1.0027x over previous
//
#include <hip/hip_runtime.h>
#include <stdint.h>

#define N_TRIP 200000
#define N_ENT  200000
#define N_REL  500
#define D      128
#define MARGINF 6.0f
#define BN_EPSF 1e-5f
#define PHASE_C 50.26548245743669f   // PI / REL_RANGE, REL_RANGE = 8/128
#define PREP_BLKS 1024
#define BN1_BLKS  240

typedef unsigned short u16;
typedef unsigned int   u32;
typedef unsigned long long u64;
typedef __attribute__((ext_vector_type(8))) short short8;
typedef __attribute__((ext_vector_type(4))) float f32x4;
typedef __attribute__((ext_vector_type(4))) unsigned short u16x4;

__device__ inline float bfl(u32 u){ return __uint_as_float(u<<16); }
__device__ inline float bfh(u32 u){ return __uint_as_float(u&0xffff0000u); }
__device__ inline u16 f2bf(float f){
  u32 u = __float_as_uint(f);
  u32 r = (u + 0x7fffu + ((u>>16)&1u))>>16;
  return (u16)r;
}

// ------- K1: histogram; rel counts aggregated in LDS ------------------------
__global__ __launch_bounds__(256) void k_hist(const int* __restrict__ trip,
    int* __restrict__ cnt0, int* __restrict__ cnt1, int* __restrict__ cntr){
  __shared__ int rc[N_REL];
  int t = threadIdx.x;
  for(int r=t; r<N_REL; r+=256) rc[r]=0;
  __syncthreads();
  #pragma unroll
  for(int k=0;k<8;k++){
    int i = blockIdx.x*2048 + t + k*256;
    if(i < N_TRIP){
      atomicAdd(&cnt0[trip[3*i]],   1);
      atomicAdd(&cnt1[trip[3*i+1]], 1);
      atomicAdd(&rc[trip[3*i+2]],   1);
    }
  }
  __syncthreads();
  for(int r=t; r<N_REL; r+=256){
    int c = rc[r];
    if(c) atomicAdd(&cntr[r], c);
  }
}

// ---------------- CSR build: 3-kernel prefix scan + cursor scatter ----------
__global__ __launch_bounds__(1024) void k_scan1(const int* __restrict__ cnt0,
    const int* __restrict__ cnt1, int* __restrict__ offs, int* __restrict__ bsum){
  __shared__ int sh[1024];
  int t = threadIdx.x;
  int e = blockIdx.x*1024 + t;
  int d = (e < N_ENT) ? cnt0[e] + cnt1[e] : 0;
  sh[t] = d; __syncthreads();
  for(int st=1; st<1024; st<<=1){
    int x = (t>=st) ? sh[t-st] : 0;
    __syncthreads();
    sh[t] += x;
    __syncthreads();
  }
  if(e < N_ENT) offs[e] = sh[t] - d;
  if(t == 1023) bsum[blockIdx.x] = sh[t];
}

__global__ __launch_bounds__(512) void k_scan2(const int* __restrict__ bsum,
    int* __restrict__ boffs, const int* __restrict__ cntr,
    int* __restrict__ roffs, int* __restrict__ rcur, int nblk){
  __shared__ int sh[512];
  int t = threadIdx.x;
  int v = (t < nblk) ? bsum[t] : 0;
  sh[t] = v; __syncthreads();
  for(int st=1; st<512; st<<=1){
    int x = (t>=st) ? sh[t-st] : 0;
    __syncthreads(); sh[t] += x; __syncthreads();
  }
  if(t < nblk) boffs[t] = sh[t] - v;
  __syncthreads();
  int w = (t < N_REL) ? cntr[t] : 0;
  sh[t] = w; __syncthreads();
  for(int st=1; st<512; st<<=1){
    int x = (t>=st) ? sh[t-st] : 0;
    __syncthreads(); sh[t] += x; __syncthreads();
  }
  if(t < N_REL){ roffs[t] = sh[t]-w; rcur[t] = sh[t]-w; }
}

__global__ __launch_bounds__(1024) void k_scan3(int* __restrict__ offs,
    const int* __restrict__ boffs, int* __restrict__ cur){
  int e = blockIdx.x*1024 + threadIdx.x;
  if(e < N_ENT){
    int o = offs[e] + boffs[blockIdx.x];
    offs[e] = o;
    cur[e] = o;
  }
}

// ------- K-edges: chunked scatter; rel cursors via LDS + bulk alloc ---------
__global__ __launch_bounds__(256) void k_edges(const int* __restrict__ trip,
    int* __restrict__ cur, int* __restrict__ rcur,
    u32* __restrict__ ebuf, u64* __restrict__ pair64, u64* __restrict__ rpair){
  __shared__ int rcnt[N_REL];
  __shared__ int rbase[N_REL];
  int t = threadIdx.x;
  for(int r=t; r<N_REL; r+=256) rcnt[r]=0;
  __syncthreads();
  int i0 = blockIdx.x*2048;
  int lt0[8], lt1[8], lt2[8], lp[8];
  #pragma unroll
  for(int k=0;k<8;k++){
    int i = i0 + t + k*256;
    lt2[k] = -1;
    if(i < N_TRIP){
      int t0 = trip[3*i], t1 = trip[3*i+1], t2 = trip[3*i+2];
      lt0[k]=t0; lt1[k]=t1; lt2[k]=t2;
      lp[k] = atomicAdd(&rcnt[t2], 1);
      pair64[i] = ((u64)t2<<36) | ((u64)t1<<18) | (u64)t0;
      ebuf[atomicAdd(&cur[t0], 1)] = ((u32)t1<<10) | ((u32)t2<<1);
      ebuf[atomicAdd(&cur[t1], 1)] = ((u32)t0<<10) | ((u32)t2<<1) | 1u;
    }
  }
  __syncthreads();
  for(int r=t; r<N_REL; r+=256){
    int c = rcnt[r];
    rbase[r] = c ? atomicAdd(&rcur[r], c) : 0;
  }
  __syncthreads();
  #pragma unroll
  for(int k=0;k<8;k++){
    if(lt2[k] >= 0)
      rpair[rbase[lt2[k]] + lp[k]] =
        ((u64)lt2[k]<<36) | ((u64)lt1[k]<<18) | (u64)lt0[k];
  }
}

// ------- K2: streaming prep + fused BN0 stats (partials to scratch) ---------
__global__ __launch_bounds__(256) void k_prep(const float* __restrict__ ent,
    const int* __restrict__ cnt0, const int* __restrict__ cnt1,
    u32* __restrict__ entnbf, u32* entbf, float* __restrict__ pstat){
  __shared__ float acc[512];
  int t = threadIdx.x;
  acc[t] = 0.f; acc[t+256] = 0.f;
  __syncthreads();
  int lane = t & 63;
  int l16 = lane & 15, g = lane >> 4;
  int wid = blockIdx.x*4 + (t>>6), nw = gridDim.x*4;
  float s0[8]={0,0,0,0,0,0,0,0}, s1[8]={0,0,0,0,0,0,0,0};
  float q0[8]={0,0,0,0,0,0,0,0}, q1[8]={0,0,0,0,0,0,0,0};
  for(int e8 = wid*8; e8 < N_ENT; e8 += nw*8){
    int eA = e8 + g, eB = e8 + 4 + g;
    const float* xpA = ent + (size_t)eA*D + l16*8;
    const float* xpB = ent + (size_t)eB*D + l16*8;
    float4 a0 = *(const float4*)xpA;
    float4 a1 = *(const float4*)(xpA+4);
    float4 b0 = *(const float4*)xpB;
    float4 b1 = *(const float4*)(xpB+4);
    if(entbf){
      uint4 pa, pb;
      pa.x = (u32)f2bf(a0.x) | ((u32)f2bf(a0.y)<<16);
      pa.y = (u32)f2bf(a0.z) | ((u32)f2bf(a0.w)<<16);
      pa.z = (u32)f2bf(a1.x) | ((u32)f2bf(a1.y)<<16);
      pa.w = (u32)f2bf(a1.z) | ((u32)f2bf(a1.w)<<16);
      pb.x = (u32)f2bf(b0.x) | ((u32)f2bf(b0.y)<<16);
      pb.y = (u32)f2bf(b0.z) | ((u32)f2bf(b0.w)<<16);
      pb.z = (u32)f2bf(b1.x) | ((u32)f2bf(b1.y)<<16);
      pb.w = (u32)f2bf(b1.z) | ((u32)f2bf(b1.w)<<16);
      *(uint4*)(entbf + (size_t)eA*64 + l16*4) = pa;
      *(uint4*)(entbf + (size_t)eB*64 + l16*4) = pb;
    }
    float ssA = a0.x*a0.x + a0.y*a0.y + a0.z*a0.z + a0.w*a0.w
              + a1.x*a1.x + a1.y*a1.y + a1.z*a1.z + a1.w*a1.w;
    float ssB = b0.x*b0.x + b0.y*b0.y + b0.z*b0.z + b0.w*b0.w
              + b1.x*b1.x + b1.y*b1.y + b1.z*b1.z + b1.w*b1.w;
    #pragma unroll
    for(int o=8;o>0;o>>=1){
      ssA += __shfl_xor(ssA,o,64);
      ssB += __shfl_xor(ssB,o,64);
    }
    float nA = sqrtf(ssA), nB = sqrtf(ssB);
    float scA = nA > 1.0f ? 1.0f/nA : 1.0f;
    float scB = nB > 1.0f ? 1.0f/nB : 1.0f;
    float vA[8] = {a0.x*scA,a0.y*scA,a0.z*scA,a0.w*scA,
                   a1.x*scA,a1.y*scA,a1.z*scA,a1.w*scA};
    float vB[8] = {b0.x*scB,b0.y*scB,b0.z*scB,b0.w*scB,
                   b1.x*scB,b1.y*scB,b1.z*scB,b1.w*scB};
    uint4 na, nb;
    na.x = (u32)f2bf(vA[0]) | ((u32)f2bf(vA[1])<<16);
    na.y = (u32)f2bf(vA[2]) | ((u32)f2bf(vA[3])<<16);
    na.z = (u32)f2bf(vA[4]) | ((u32)f2bf(vA[5])<<16);
    na.w = (u32)f2bf(vA[6]) | ((u32)f2bf(vA[7])<<16);
    nb.x = (u32)f2bf(vB[0]) | ((u32)f2bf(vB[1])<<16);
    nb.y = (u32)f2bf(vB[2]) | ((u32)f2bf(vB[3])<<16);
    nb.z = (u32)f2bf(vB[4]) | ((u32)f2bf(vB[5])<<16);
    nb.w = (u32)f2bf(vB[6]) | ((u32)f2bf(vB[7])<<16);
    *(uint4*)(entnbf + (size_t)eA*64 + l16*4) = na;
    *(uint4*)(entnbf + (size_t)eB*64 + l16*4) = nb;
    float wA0 = (float)cnt0[eA], wA1 = (float)cnt1[eA];
    float wB0 = (float)cnt0[eB], wB1 = (float)cnt1[eB];
    #pragma unroll
    for(int k=0;k<8;k++){
      s0[k] += wA0*vA[k] + wB0*vB[k];
      s1[k] += wA1*vA[k] + wB1*vB[k];
      q0[k] += wA0*vA[k]*vA[k] + wB0*vB[k]*vB[k];
      q1[k] += wA1*vA[k]*vA[k] + wB1*vB[k]*vB[k];
    }
  }
  #pragma unroll
  for(int k=0;k<8;k++){
    int c = l16*8 + k;
    atomicAdd(&acc[c],     s0[k]);
    atomicAdd(&acc[128+c], s1[k]);
    atomicAdd(&acc[256+c], q0[k]);
    atomicAdd(&acc[384+c], q1[k]);
  }
  __syncthreads();
  pstat[(size_t)blockIdx.x*512 + t]       = acc[t];
  pstat[(size_t)blockIdx.x*512 + 256 + t] = acc[t+256];
}

// ------- K2c: reduce prep partials into stats[0..512): 64 blocks ------------
// thread -> (column c = tid&511, chunk = tid>>9); each sums 32 partial-blocks.
__global__ __launch_bounds__(256) void k_redstats(const float* __restrict__ pstat,
    float* __restrict__ stats){
  int tid = blockIdx.x*256 + threadIdx.x;     // 64*256 = 16384 threads
  int c = tid & 511;
  int chunk = tid >> 9;                       // 0..31
  float s = 0.f;
  #pragma unroll 4
  for(int k=0;k<PREP_BLKS/32;k++)
    s += pstat[(size_t)(chunk*(PREP_BLKS/32) + k)*512 + c];
  atomicAdd(&stats[c], s);
}

// ------- K3: per-rel scale + Qr stats (LDS-aggregated) + phase tables -------
__global__ __launch_bounds__(256) void k_relstats(const float* __restrict__ rel,
    const int* __restrict__ cntr, float* __restrict__ scale_rel,
    float* __restrict__ stats, float* __restrict__ cosr, float* __restrict__ sinr){
  __shared__ float qacc[128];
  int t = threadIdx.x, lane = t & 63;
  if(t < 128) qacc[t] = 0.f;
  __syncthreads();
  int r = blockIdx.x*4 + (t>>6);
  if(r < N_REL){
    float2 x = *(const float2*)(rel + (size_t)r*D + 2*lane);
    float ss = x.x*x.x + x.y*x.y;
    #pragma unroll
    for(int o=32;o>0;o>>=1) ss += __shfl_xor(ss,o,64);
    float nrm = sqrtf(ss);
    float sc = nrm > 1.0f ? 1.0f/nrm : 1.0f;
    if(lane==0) scale_rel[r] = sc;
    float w = (float)cntr[r];
    float sx = x.x*sc, sy = x.y*sc;
    atomicAdd(&qacc[2*lane  ], w*sx*sx);
    atomicAdd(&qacc[2*lane+1], w*sy*sy);
    if(lane < 32){
      cosr[r*64 + 2*lane  ] = cosf(x.x*PHASE_C);
      sinr[r*64 + 2*lane  ] = sinf(x.x*PHASE_C);
      cosr[r*64 + 2*lane+1] = cosf(x.y*PHASE_C);
      sinr[r*64 + 2*lane+1] = sinf(x.y*PHASE_C);
    }
  }
  __syncthreads();
  if(t < 128) atomicAdd(&stats[512+t], qacc[t]);
}

// ------- K4: finalize BN0, build folded bf16 weights Wbf, W2 and b' ---------
__global__ __launch_bounds__(384) void k_bn0fin(const float* __restrict__ stats,
    const float* __restrict__ W_a, const float* __restrict__ b_a,
    const float* __restrict__ gamma0, const float* __restrict__ beta0,
    u16* __restrict__ Wbf, float* __restrict__ W2, float* __restrict__ bprime){
  __shared__ float a0[384], c0[384];
  int t = threadIdx.x;
  {
    int j = t & 127;
    float mu, ex2;
    if(t < 256){
      mu  = (stats[j]     + stats[128+j]) * (1.0f/(2.0f*N_TRIP));
      ex2 = (stats[256+j] + stats[384+j]) * (1.0f/(2.0f*N_TRIP));
    } else {
      mu  = 0.0f;
      ex2 = stats[512+j] * (1.0f/N_TRIP);
    }
    float var = ex2 - mu*mu;
    float a = gamma0[t]*rsqrtf(var + BN_EPSF);
    a0[t] = a;
    c0[t] = beta0[t] - mu*a;
  }
  __syncthreads();
  for(int idx=t; idx<256*128; idx+=384){
    int j = idx>>7, k = idx&127;
    int ko = ((j>>7)<<7) + k;
    Wbf[idx] = f2bf(W_a[(j&127)*384 + ko]*a0[ko]);
  }
  for(int idx=t; idx<128*128; idx+=384){
    int k = idx>>7, j = idx&127;
    W2[idx] = W_a[j*384 + 256 + k]*a0[256+k];
  }
  if(t < 128){
    float s = b_a[t];
    for(int k=0;k<384;k++) s += W_a[t*384+k]*c0[k];
    bprime[t] = s;
  }
}

// ------- K5: R[r] = rel_n[r] @ W2 ------------------------------------------
__global__ __launch_bounds__(128) void k_relproj(const float* __restrict__ rel,
    const float* __restrict__ scale_rel, const float* __restrict__ W2,
    float* __restrict__ R){
  int r = blockIdx.x, j = threadIdx.x;
  __shared__ float x[128];
  x[j] = rel[(size_t)r*D + j]*scale_rel[r];
  __syncthreads();
  float s = 0.f;
  for(int k=0;k<128;k++) s += x[k]*W2[k*128+j];
  R[r*128+j] = s;
}

// ------- K6: A/B projection via MFMA; input is pre-normalized bf16 ----------
__global__ __launch_bounds__(256) void k_ab(const u32* __restrict__ entnbf,
    const u16* __restrict__ Wbf, u16* __restrict__ Abuf, u16* __restrict__ Bbuf){
  __shared__ u16 xlds[16*128];
  int t = threadIdx.x, lane = t & 63, q = t >> 6;
  int kgrp = (lane>>4)<<3;
  int rgrp = (lane>>4)<<2;
  int frow = lane & 15;
  short8 wf[4][4];
  #pragma unroll
  for(int jt=0;jt<4;jt++){
    #pragma unroll
    for(int kt=0;kt<4;kt++)
      wf[jt][kt] = *(const short8*)(Wbf + (size_t)(q*64 + jt*16 + frow)*D + kgrp + kt*32);
  }
  int srow = t>>4;
  int scol16 = t&15;
  char* swp = (char*)xlds + srow*256 + ((scol16<<4) ^ ((srow&7)<<4));
  const char* rdp = (const char*)xlds + frow*256;
  int rbase0 = (lane>>4)<<4;
  int fsw = (frow&7)<<4;
  for(int chunk = blockIdx.x; chunk < N_ENT/16; chunk += gridDim.x){
    uint4 pk = *(const uint4*)(entnbf + (size_t)(chunk*16 + srow)*64 + scol16*4);
    __syncthreads();
    *(uint4*)swp = pk;
    __syncthreads();
    short8 xf[4];
    #pragma unroll
    for(int kt=0;kt<4;kt++)
      xf[kt] = *(const short8*)(rdp + ((rbase0 + kt*64) ^ fsw));
    int erow = chunk*16 + frow;
    #pragma unroll
    for(int jt=0;jt<4;jt++){
      f32x4 acc = {0.f,0.f,0.f,0.f};
      #pragma unroll
      for(int kt=0;kt<4;kt++)
        acc = __builtin_amdgcn_mfma_f32_16x16x32_bf16(wf[jt][kt], xf[kt], acc, 0,0,0);
      int jbase = q*64 + jt*16 + rgrp;
      u16x4 opk;
      opk.x=f2bf(acc[0]); opk.y=f2bf(acc[1]); opk.z=f2bf(acc[2]); opk.w=f2bf(acc[3]);
      u16* dst = (jbase < 128) ? (Abuf + (size_t)erow*D + jbase)
                               : (Bbuf + (size_t)erow*D + (jbase-128));
      *(u16x4*)dst = opk;
    }
  }
}

// ------- K7: BN1 stats, 1/4 subsample, partials to scratch (no atomics) -----
__global__ __launch_bounds__(256) void k_bn1stats(const u64* __restrict__ pair64,
    const u16* __restrict__ A, const u16* __restrict__ B,
    const float* __restrict__ R, const float* __restrict__ bprime,
    float* __restrict__ pstat1){
  __shared__ float acc[256];
  int t = threadIdx.x;
  acc[t] = 0.f;
  __syncthreads();
  int lane = t & 63;
  int gw = blockIdx.x*4 + (t>>6), nw = gridDim.x*4;
  float bp0 = bprime[2*lane], bp1 = bprime[2*lane+1];
  float s0=0,s1=0,q0=0,q1=0;
  for(int i=4*gw; i<N_TRIP; i+=8*nw){
    {
      u64 pr = pair64[i];
      int t0 = (int)(pr & 0x3FFFF);
      int t1 = (int)((pr>>18) & 0x3FFFF);
      int t2 = (int)(pr>>36);
      u32 ua0 = *(const u32*)(A + (size_t)t0*D + 2*lane);
      u32 ua1 = *(const u32*)(A + (size_t)t1*D + 2*lane);
      u32 ub0 = *(const u32*)(B + (size_t)t0*D + 2*lane);
      u32 ub1 = *(const u32*)(B + (size_t)t1*D + 2*lane);
      float2 r = *(const float2*)(R + (size_t)t2*D + 2*lane);
      float y1x = bfl(ua0)+bfl(ub1)+r.x+bp0;
      float y1y = bfh(ua0)+bfh(ub1)+r.y+bp1;
      float y2x = bfl(ua1)+bfl(ub0)-r.x+bp0;
      float y2y = bfh(ua1)+bfh(ub0)-r.y+bp1;
      s0 += y1x+y2x; s1 += y1y+y2y;
      q0 += y1x*y1x + y2x*y2x; q1 += y1y*y1y + y2y*y2y;
    }
    int i2 = i + 4*nw;
    if(i2 < N_TRIP){
      u64 pr = pair64[i2];
      int t0 = (int)(pr & 0x3FFFF);
      int t1 = (int)((pr>>18) & 0x3FFFF);
      int t2 = (int)(pr>>36);
      u32 ua0 = *(const u32*)(A + (size_t)t0*D + 2*lane);
      u32 ua1 = *(const u32*)(A + (size_t)t1*D + 2*lane);
      u32 ub0 = *(const u32*)(B + (size_t)t0*D + 2*lane);
      u32 ub1 = *(const u32*)(B + (size_t)t1*D + 2*lane);
      float2 r = *(const float2*)(R + (size_t)t2*D + 2*lane);
      float y1x = bfl(ua0)+bfl(ub1)+r.x+bp0;
      float y1y = bfh(ua0)+bfh(ub1)+r.y+bp1;
      float y2x = bfl(ua1)+bfl(ub0)-r.x+bp0;
      float y2y = bfh(ua1)+bfh(ub0)-r.y+bp1;
      s0 += y1x+y2x; s1 += y1y+y2y;
      q0 += y1x*y1x + y2x*y2x; q1 += y1y*y1y + y2y*y2y;
    }
  }
  atomicAdd(&acc[      2*lane  ], s0);
  atomicAdd(&acc[      2*lane+1], s1);
  atomicAdd(&acc[128 + 2*lane  ], q0);
  atomicAdd(&acc[128 + 2*lane+1], q1);
  __syncthreads();
  pstat1[(size_t)blockIdx.x*256 + t] = acc[t];
}

// ------- K8: reduce BN1 partials + finalize (1/4 subsample) -----------------
__global__ __launch_bounds__(128) void k_bn1fin(const float* __restrict__ pstat1,
    const float* __restrict__ gamma1, const float* __restrict__ beta1,
    const float* __restrict__ W_a2, const float* __restrict__ b_a2,
    const float* __restrict__ bprime, float* __restrict__ a1c){
  __shared__ float red[128];
  int j = threadIdx.x;
  float s = 0.f, q = 0.f;
  for(int b=0;b<BN1_BLKS;b++){
    s += pstat1[(size_t)b*256 + j];
    q += pstat1[(size_t)b*256 + 128 + j];
  }
  float mu  = s*(2.0f/(float)N_TRIP);
  float var = q*(2.0f/(float)N_TRIP) - mu*mu;
  float a = gamma1[j]*rsqrtf(var + BN_EPSF);
  float cc = beta1[j] - mu*a;
  float wa1 = W_a2[j]*a;
  a1c[j]     = a;
  a1c[128+j] = cc;
  a1c[256+j] = wa1;
  red[j] = W_a2[j]*cc + wa1*bprime[j];
  __syncthreads();
  #pragma unroll
  for(int st=64; st>0; st>>=1){
    if(j < st) red[j] += red[j+st];
    __syncthreads();
  }
  if(j==0) a1c[384] = red[0] + b_a2[0];
}

// ------- K8b: per-entity scalars alpha/beta/rho -----------------------------
__global__ __launch_bounds__(256) void k_alphabeta(const u16* __restrict__ A,
    const u16* __restrict__ B, const float* __restrict__ R,
    const float* __restrict__ a1c, float* __restrict__ alpha,
    float* __restrict__ beta, float* __restrict__ rho){
  int t = threadIdx.x, lane = t & 63;
  int l32 = lane & 31, grp = lane >> 5;
  int wid = blockIdx.x*4 + (t>>6), nw = gridDim.x*4;
  float4 wa = *(const float4*)(a1c + 256 + l32*4);
  for(int e4 = wid*4; e4 < N_ENT; e4 += nw*4){
    int eA = e4 + grp, eB = e4 + 2 + grp;
    uint2 uaA = *(const uint2*)(A + (size_t)eA*D + l32*4);
    uint2 ubA = *(const uint2*)(B + (size_t)eA*D + l32*4);
    uint2 uaB = *(const uint2*)(A + (size_t)eB*D + l32*4);
    uint2 ubB = *(const uint2*)(B + (size_t)eB*D + l32*4);
    float daA = wa.x*bfl(uaA.x) + wa.y*bfh(uaA.x) + wa.z*bfl(uaA.y) + wa.w*bfh(uaA.y);
    float dbA = wa.x*bfl(ubA.x) + wa.y*bfh(ubA.x) + wa.z*bfl(ubA.y) + wa.w*bfh(ubA.y);
    float daB = wa.x*bfl(uaB.x) + wa.y*bfh(uaB.x) + wa.z*bfl(uaB.y) + wa.w*bfh(uaB.y);
    float dbB = wa.x*bfl(ubB.x) + wa.y*bfh(ubB.x) + wa.z*bfl(ubB.y) + wa.w*bfh(ubB.y);
    #pragma unroll
    for(int o=16;o>0;o>>=1){
      daA += __shfl_xor(daA,o,64); dbA += __shfl_xor(dbA,o,64);
      daB += __shfl_xor(daB,o,64); dbB += __shfl_xor(dbB,o,64);
    }
    if(l32==0){ alpha[eA]=daA; beta[eA]=dbA; alpha[eB]=daB; beta[eB]=dbB; }
  }
  for(int r2 = wid*2 + grp; r2 < N_REL; r2 += nw*2){
    float4 rr = *(const float4*)(R + (size_t)r2*D + l32*4);
    float dr = wa.x*rr.x + wa.y*rr.y + wa.z*rr.z + wa.w*rr.w;
    #pragma unroll
    for(int o=16;o>0;o>>=1) dr += __shfl_xor(dr,o,64);
    if(l32==0) rho[r2]=dr;
  }
}

// ------- K9: per-entity gather, 16-lane groups, x2 edge unroll --------------
__global__ __launch_bounds__(256) void k_ent(
    const int* __restrict__ offs, const int* __restrict__ endp,
    const u32* __restrict__ ebuf,
    const u16* __restrict__ A, const u16* __restrict__ B,
    const float* __restrict__ R, const float* __restrict__ bprime,
    const float* __restrict__ a1c, const float* __restrict__ alpha,
    const float* __restrict__ beta, const float* __restrict__ rho,
    float* __restrict__ out_hent){
  int t = threadIdx.x, lane = t & 63;
  int l16 = lane & 15, g = lane >> 4;
  int wid = blockIdx.x*4 + (t>>6), nw = gridDim.x*4;
  int cb = l16*8;
  float4 bpA = *(const float4*)(bprime + cb);
  float4 bpB = *(const float4*)(bprime + cb + 4);
  float4 a1A = *(const float4*)(a1c + cb);
  float4 a1B = *(const float4*)(a1c + cb + 4);
  float4 ccA = *(const float4*)(a1c + 128 + cb);
  float4 ccB = *(const float4*)(a1c + 128 + cb + 4);
  float kap = a1c[384];
  for(int e4 = wid*4; e4 < N_ENT; e4 += nw*4){
    int e = e4 + g;
    int s = offs[e], en = endp[e];
    uint4 ua = *(const uint4*)(A + (size_t)e*D + cb);
    float ax0 = bfl(ua.x), ax1 = bfh(ua.x), ax2 = bfl(ua.y), ax3 = bfh(ua.y);
    float ax4 = bfl(ua.z), ax5 = bfh(ua.z), ax6 = bfl(ua.w), ax7 = bfh(ua.w);
    float al = alpha[e];
    float h0=0,h1=0,h2=0,h3=0,h4=0,h5=0,h6=0,h7=0, eb=0;
    int o = s;
    for(; o+1<en; o+=2){
      u32 idX = ebuf[o], idY = ebuf[o+1];
      int otX = idX>>10, r2X = (idX>>1)&511;
      int otY = idY>>10, r2Y = (idY>>1)&511;
      float sgX = (idX&1) ? -1.f : 1.f;
      float sgY = (idY&1) ? -1.f : 1.f;
      uint4 ubX = *(const uint4*)(B + (size_t)otX*D + cb);
      uint4 ubY = *(const uint4*)(B + (size_t)otY*D + cb);
      float4 rAX = *(const float4*)(R + (size_t)r2X*D + cb);
      float4 rBX = *(const float4*)(R + (size_t)r2X*D + cb + 4);
      float4 rAY = *(const float4*)(R + (size_t)r2Y*D + cb);
      float4 rBY = *(const float4*)(R + (size_t)r2Y*D + cb + 4);
      float beX = beta[otX], beY = beta[otY];
      float roX = rho[r2X],  roY = rho[r2Y];
      float svX = al + beX + sgX*roX + kap;
      float svY = al + beY + sgY*roY + kap;
      float ebX = expf(svX >= 0.f ? -svX : -0.01f*svX);
      float ebY = expf(svY >= 0.f ? -svY : -0.01f*svY);
      float y, c;
      y = ax0 + bfl(ubX.x) + sgX*rAX.x + bpA.x; c = y*a1A.x + ccA.x; h0 += ebX*c;
      y = ax1 + bfh(ubX.x) + sgX*rAX.y + bpA.y; c = y*a1A.y + ccA.y; h1 += ebX*c;
      y = ax2 + bfl(ubX.y) + sgX*rAX.z + bpA.z; c = y*a1A.z + ccA.z; h2 += ebX*c;
      y = ax3 + bfh(ubX.y) + sgX*rAX.w + bpA.w; c = y*a1A.w + ccA.w; h3 += ebX*c;
      y = ax4 + bfl(ubX.z) + sgX*rBX.x + bpB.x; c = y*a1B.x + ccB.x; h4 += ebX*c;
      y = ax5 + bfh(ubX.z) + sgX*rBX.y + bpB.y; c = y*a1B.y + ccB.y; h5 += ebX*c;
      y = ax6 + bfl(ubX.w) + sgX*rBX.z + bpB.z; c = y*a1B.z + ccB.z; h6 += ebX*c;
      y = ax7 + bfh(ubX.w) + sgX*rBX.w + bpB.w; c = y*a1B.w + ccB.w; h7 += ebX*c;
      y = ax0 + bfl(ubY.x) + sgY*rAY.x + bpA.x; c = y*a1A.x + ccA.x; h0 += ebY*c;
      y = ax1 + bfh(ubY.x) + sgY*rAY.y + bpA.y; c = y*a1A.y + ccA.y; h1 += ebY*c;
      y = ax2 + bfl(ubY.y) + sgY*rAY.z + bpA.z; c = y*a1A.z + ccA.z; h2 += ebY*c;
      y = ax3 + bfh(ubY.y) + sgY*rAY.w + bpA.w; c = y*a1A.w + ccA.w; h3 += ebY*c;
      y = ax4 + bfl(ubY.z) + sgY*rBY.x + bpB.x; c = y*a1B.x + ccB.x; h4 += ebY*c;
      y = ax5 + bfh(ubY.z) + sgY*rBY.y + bpB.y; c = y*a1B.y + ccB.y; h5 += ebY*c;
      y = ax6 + bfl(ubY.w) + sgY*rBY.z + bpB.z; c = y*a1B.z + ccB.z; h6 += ebY*c;
      y = ax7 + bfh(ubY.w) + sgY*rBY.w + bpB.w; c = y*a1B.w + ccB.w; h7 += ebY*c;
      eb += ebX + ebY;
    }
    if(o < en){
      u32 id = ebuf[o];
      int ot = id>>10, r2 = (id>>1)&511;
      float sg = (id&1) ? -1.f : 1.f;
      uint4 ub = *(const uint4*)(B + (size_t)ot*D + cb);
      float4 rA = *(const float4*)(R + (size_t)r2*D + cb);
      float4 rB = *(const float4*)(R + (size_t)r2*D + cb + 4);
      float sv = al + beta[ot] + sg*rho[r2] + kap;
      float e_b = expf(sv >= 0.f ? -sv : -0.01f*sv);
      float y, c;
      y = ax0 + bfl(ub.x) + sg*rA.x + bpA.x; c = y*a1A.x + ccA.x; h0 += e_b*c;
      y = ax1 + bfh(ub.x) + sg*rA.y + bpA.y; c = y*a1A.y + ccA.y; h1 += e_b*c;
      y = ax2 + bfl(ub.y) + sg*rA.z + bpA.z; c = y*a1A.z + ccA.z; h2 += e_b*c;
      y = ax3 + bfh(ub.y) + sg*rA.w + bpA.w; c = y*a1A.w + ccA.w; h3 += e_b*c;
      y = ax4 + bfl(ub.z) + sg*rB.x + bpB.x; c = y*a1B.x + ccB.x; h4 += e_b*c;
      y = ax5 + bfh(ub.z) + sg*rB.y + bpB.y; c = y*a1B.y + ccB.y; h5 += e_b*c;
      y = ax6 + bfl(ub.w) + sg*rB.z + bpB.z; c = y*a1B.z + ccB.z; h6 += e_b*c;
      y = ax7 + bfh(ub.w) + sg*rB.w + bpB.w; c = y*a1B.w + ccB.w; h7 += e_b*c;
      eb += e_b;
    }
    float inv = (en > s) ? 1.0f/eb : 0.0f;
    float4 o0; o0.x=h0*inv; o0.y=h1*inv; o0.z=h2*inv; o0.w=h3*inv;
    float4 o1; o1.x=h4*inv; o1.y=h5*inv; o1.z=h6*inv; o1.w=h7*inv;
    *(float4*)(out_hent + (size_t)e*D + cb)     = o0;
    *(float4*)(out_hent + (size_t)e*D + cb + 4) = o1;
  }
}

// ------- K10: per-rel gather pass, packed pairs, x2 unrolled ----------------
__global__ __launch_bounds__(512) void k_rel(
    const int* __restrict__ roffs, const int* __restrict__ cntr,
    const u64* __restrict__ rpair,
    const u16* __restrict__ A, const u16* __restrict__ B,
    const float* __restrict__ R, const float* __restrict__ bprime,
    const float* __restrict__ a1c, const float* __restrict__ alpha,
    const float* __restrict__ beta, const float* __restrict__ rho,
    float* __restrict__ out_hrel){
  __shared__ float red[8][128];
  int t = threadIdx.x, lane = t & 63, w = t >> 6;
  int r = blockIdx.x;
  int cnt = cntr[r], base = roffs[r];
  float2 rr = *(const float2*)(R + (size_t)r*D + 2*lane);
  float bp0 = bprime[2*lane], bp1 = bprime[2*lane+1];
  float a1x = a1c[2*lane],     a1y = a1c[2*lane+1];
  float ccx = a1c[128+2*lane], ccy = a1c[128+2*lane+1];
  float kap = a1c[384];
  float rhor = rho[r];
  float sx = 0.f, sy = 0.f;
  for(int j=w; j<cnt; j+=16){
    {
      u64 pr = rpair[base+j];
      int t0 = (int)(pr & 0x3FFFF);
      int t1 = (int)((pr>>18) & 0x3FFFF);
      float s1 = alpha[t0] + beta[t1] + rhor + kap;
      float s2 = alpha[t1] + beta[t0] - rhor + kap;
      float e1 = expf(s1 >= 0.f ? -s1 : -0.01f*s1);
      float e2 = expf(s2 >= 0.f ? -s2 : -0.01f*s2);
      u32 ua0 = *(const u32*)(A + (size_t)t0*D + 2*lane);
      u32 ua1 = *(const u32*)(A + (size_t)t1*D + 2*lane);
      u32 ub0 = *(const u32*)(B + (size_t)t0*D + 2*lane);
      u32 ub1 = *(const u32*)(B + (size_t)t1*D + 2*lane);
      float y1x = bfl(ua0)+bfl(ub1)+rr.x+bp0;
      float y1y = bfh(ua0)+bfh(ub1)+rr.y+bp1;
      float y2x = bfl(ua1)+bfl(ub0)-rr.x+bp0;
      float y2y = bfh(ua1)+bfh(ub0)-rr.y+bp1;
      float c1x = y1x*a1x+ccx, c1y = y1y*a1y+ccy;
      float c2x = y2x*a1x+ccx, c2y = y2y*a1y+ccy;
      sx += e1*c1x - e2*c2x;
      sy += e1*c1y - e2*c2y;
    }
    int j2 = j + 8;
    if(j2 < cnt){
      u64 pr = rpair[base+j2];
      int t0 = (int)(pr & 0x3FFFF);
      int t1 = (int)((pr>>18) & 0x3FFFF);
      float s1 = alpha[t0] + beta[t1] + rhor + kap;
      float s2 = alpha[t1] + beta[t0] - rhor + kap;
      float e1 = expf(s1 >= 0.f ? -s1 : -0.01f*s1);
      float e2 = expf(s2 >= 0.f ? -s2 : -0.01f*s2);
      u32 ua0 = *(const u32*)(A + (size_t)t0*D + 2*lane);
      u32 ua1 = *(const u32*)(A + (size_t)t1*D + 2*lane);
      u32 ub0 = *(const u32*)(B + (size_t)t0*D + 2*lane);
      u32 ub1 = *(const u32*)(B + (size_t)t1*D + 2*lane);
      float y1x = bfl(ua0)+bfl(ub1)+rr.x+bp0;
      float y1y = bfh(ua0)+bfh(ub1)+rr.y+bp1;
      float y2x = bfl(ua1)+bfl(ub0)-rr.x+bp0;
      float y2y = bfh(ua1)+bfh(ub0)-rr.y+bp1;
      float c1x = y1x*a1x+ccx, c1y = y1y*a1y+ccy;
      float c2x = y2x*a1x+ccx, c2y = y2y*a1y+ccy;
      sx += e1*c1x - e2*c2x;
      sy += e1*c1y - e2*c2y;
    }
  }
  float2 p; p.x = sx; p.y = sy;
  *(float2*)&red[w][2*lane] = p;
  __syncthreads();
  if(t < 128){
    float s = 0.f;
    #pragma unroll
    for(int k=0;k<8;k++) s += red[k][t];
    float cf = cnt > 0 ? (float)cnt : 1.0f;
    out_hrel[(size_t)r*D + t] = s/cf;
  }
}

// ------- K12: RotatE score, 16-lane groups (4 triplets/wave) ----------------
__global__ __launch_bounds__(256) void k_score_bf(const u64* __restrict__ pair64,
    const u32* __restrict__ entbf, const float* __restrict__ cosr,
    const float* __restrict__ sinr, float* __restrict__ score){
  int t = threadIdx.x, lane = t & 63;
  int l16 = lane & 15, g = lane >> 4;
  int wid = blockIdx.x*4 + (t>>6), nw = gridDim.x*4;
  for(int i4 = wid*4; i4 < N_TRIP; i4 += nw*4){
    int i = i4 + g;
    u64 pr = pair64[i];
    int t0 = (int)(pr & 0x3FFFF);
    int t1 = (int)((pr>>18) & 0x3FFFF);
    int t2 = (int)(pr>>36);
    uint2 reh = *(const uint2*)(entbf + (size_t)t0*64 + l16*2);
    uint2 imh = *(const uint2*)(entbf + (size_t)t0*64 + 32 + l16*2);
    uint2 ret = *(const uint2*)(entbf + (size_t)t1*64 + l16*2);
    uint2 imt = *(const uint2*)(entbf + (size_t)t1*64 + 32 + l16*2);
    float4 cr = *(const float4*)(cosr + (size_t)t2*64 + l16*4);
    float4 sr = *(const float4*)(sinr + (size_t)t2*64 + l16*4);
    float rh[4] = {bfl(reh.x),bfh(reh.x),bfl(reh.y),bfh(reh.y)};
    float ih[4] = {bfl(imh.x),bfh(imh.x),bfl(imh.y),bfh(imh.y)};
    float rt[4] = {bfl(ret.x),bfh(ret.x),bfl(ret.y),bfh(ret.y)};
    float it[4] = {bfl(imt.x),bfh(imt.x),bfl(imt.y),bfh(imt.y)};
    float cc[4] = {cr.x,cr.y,cr.z,cr.w};
    float ss[4] = {sr.x,sr.y,sr.z,sr.w};
    float d = 0.f;
    #pragma unroll
    for(int k=0;k<4;k++){
      float res = cc[k]*rt[k] + ss[k]*it[k] - rh[k];
      float ims = cc[k]*it[k] - ss[k]*rt[k] - ih[k];
      d += sqrtf(res*res + ims*ims);
    }
    #pragma unroll
    for(int o=8;o>0;o>>=1) d += __shfl_xor(d,o,64);
    if(l16==0) score[i] = MARGINF - d;
  }
}

// fp32 fallback if workspace too small for entbf
__global__ __launch_bounds__(256) void k_score_fp(const u64* __restrict__ pair64,
    const float* __restrict__ ent, const float* __restrict__ cosr,
    const float* __restrict__ sinr, float* __restrict__ score){
  int t = threadIdx.x, lane = t & 63;
  int gw = blockIdx.x*4 + (t>>6), nw = gridDim.x*4;
  for(int i=gw; i<N_TRIP; i+=nw){
    u64 pr = pair64[i];
    int t0 = (int)(pr & 0x3FFFF);
    int t1 = (int)((pr>>18) & 0x3FFFF);
    int t2 = (int)(pr>>36);
    float re_h = ent[(size_t)t0*D + lane];
    float im_h = ent[(size_t)t0*D + 64 + lane];
    float re_t = ent[(size_t)t1*D + lane];
    float im_t = ent[(size_t)t1*D + 64 + lane];
    float cr = cosr[t2*64 + lane], sr = sinr[t2*64 + lane];
    float re_s = cr*re_t + sr*im_t - re_h;
    float im_s = cr*im_t - sr*re_t - im_h;
    float d = sqrtf(re_s*re_s + im_s*im_s);
    #pragma unroll
    for(int o=32;o>0;o>>=1) d += __shfl_xor(d,o,64);
    if(lane==0) score[i] = MARGINF - d;
  }
}

extern "C" void kernel_launch(void* const* d_in, const int* in_sizes, int n_in,
                              void* d_out, int out_size, void* d_ws, size_t ws_size,
                              hipStream_t stream){
  const int*   trip   = (const int*)  d_in[0];
  const float* ent    = (const float*)d_in[1];
  const float* rel    = (const float*)d_in[2];
  const float* W_a    = (const float*)d_in[3];
  const float* b_a    = (const float*)d_in[4];
  const float* W_a2   = (const float*)d_in[5];
  const float* b_a2   = (const float*)d_in[6];
  const float* gamma0 = (const float*)d_in[7];
  const float* beta0  = (const float*)d_in[8];
  const float* gamma1 = (const float*)d_in[9];
  const float* beta1  = (const float*)d_in[10];

  char* ws = (char*)d_ws;
  size_t off = 0;
  auto take = [&](size_t bytes)->void*{
    void* p = ws + off;
    off += (bytes + 255) & ~(size_t)255;
    return p;
  };
  // ---- zeroed scratch (contiguous from 0) ----
  int*   cnt0    = (int*)  take((size_t)N_ENT*4);
  int*   cnt1    = (int*)  take((size_t)N_ENT*4);
  int*   cntr    = (int*)  take((size_t)N_REL*4);
  float* stats   = (float*)take(640*4);
  size_t zero_bytes = off;
  // ---- fully-overwritten scratch (required) ----
  int*   offs      = (int*)  take((size_t)N_ENT*4);
  int*   cur       = (int*)  take((size_t)N_ENT*4);
  int*   bsum      = (int*)  take(512*4);
  int*   boffs     = (int*)  take(512*4);
  int*   roffs     = (int*)  take(512*4);
  int*   rcur      = (int*)  take(512*4);
  u32*   ebuf      = (u32*)  take((size_t)2*N_TRIP*4);
  u64*   pair64    = (u64*)  take((size_t)N_TRIP*8);
  u64*   rpair     = (u64*)  take((size_t)N_TRIP*8);
  float* scale_rel = (float*)take((size_t)N_REL*4);
  u16*   Wbf       = (u16*)  take(256*128*2);
  float* W2        = (float*)take(128*128*4);
  float* bprime    = (float*)take(128*4);
  float* a1c       = (float*)take(512*4);
  float* R         = (float*)take((size_t)N_REL*D*4);
  float* cosr      = (float*)take((size_t)N_REL*64*4);
  float* sinr      = (float*)take((size_t)N_REL*64*4);
  float* alpha     = (float*)take((size_t)N_ENT*4);
  float* betab     = (float*)take((size_t)N_ENT*4);
  float* rho       = (float*)take(512*4);
  float* pstat     = (float*)take((size_t)PREP_BLKS*512*4);
  float* pstat1    = (float*)take((size_t)BN1_BLKS*256*4);
  u16*   Abuf      = (u16*)  take((size_t)N_ENT*D*2);
  u16*   Bbuf      = (u16*)  take((size_t)N_ENT*D*2);
  u32*   entnbf    = (u32*)  take((size_t)N_ENT*64*4);
  // ---- optional: raw bf16 copy for k_score ----
  u32*   entbf     = (u32*)  take((size_t)N_ENT*64*4);
  bool use_bf = (off <= ws_size);
  (void)n_in; (void)in_sizes; (void)out_size;

  float* out_hent  = (float*)d_out;
  float* out_hrel  = out_hent + (size_t)N_ENT*D;
  float* out_score = out_hrel + (size_t)N_REL*D;

  hipMemsetAsync(d_ws, 0, zero_bytes, stream);

  const int SCAN_BLKS = (N_ENT + 1023)/1024;     // 196
  const int EDG_BLKS  = (N_TRIP + 2047)/2048;    // 98
  k_hist     <<<EDG_BLKS, 256, 0, stream>>>(trip, cnt0, cnt1, cntr);
  k_prep     <<<PREP_BLKS, 256, 0, stream>>>(ent, cnt0, cnt1, entnbf,
                                             use_bf ? entbf : (u32*)nullptr, pstat);
  k_redstats <<<64, 256, 0, stream>>>(pstat, stats);
  k_scan1    <<<SCAN_BLKS, 1024, 0, stream>>>(cnt0, cnt1, offs, bsum);
  k_scan2    <<<1, 512, 0, stream>>>(bsum, boffs, cntr, roffs, rcur, SCAN_BLKS);
  k_scan3    <<<SCAN_BLKS, 1024, 0, stream>>>(offs, boffs, cur);
  k_edges    <<<EDG_BLKS, 256, 0, stream>>>(trip, cur, rcur, ebuf, pair64, rpair);
  k_relstats <<<(N_REL+3)/4, 256, 0, stream>>>(rel, cntr, scale_rel, stats, cosr, sinr);
  k_bn0fin   <<<1, 384, 0, stream>>>(stats, W_a, b_a, gamma0, beta0, Wbf, W2, bprime);
  k_relproj  <<<N_REL, 128, 0, stream>>>(rel, scale_rel, W2, R);
  k_ab       <<<2048, 256, 0, stream>>>(entnbf, Wbf, Abuf, Bbuf);
  k_bn1stats <<<BN1_BLKS, 256, 0, stream>>>(pair64, Abuf, Bbuf, R, bprime, pstat1);
  k_bn1fin   <<<1, 128, 0, stream>>>(pstat1, gamma1, beta1, W_a2, b_a2, bprime, a1c);
  k_alphabeta<<<2048, 256, 0, stream>>>(Abuf, Bbuf, R, a1c, alpha, betab, rho);
  k_ent      <<<2048, 256, 0, stream>>>(offs, cur, ebuf, Abuf, Bbuf, R,
                                        bprime, a1c, alpha, betab, rho, out_hent);
  k_rel      <<<N_REL, 512, 0, stream>>>(roffs, cntr, rpair, Abuf, Bbuf, R,
                                         bprime, a1c, alpha, betab, rho, out_hrel);
  if(use_bf)
    k_score_bf<<<2048, 256, 0, stream>>>(pair64, entbf, cosr, sinr, out_score);
  else
    k_score_fp<<<2048, 256, 0, stream>>>(pair64, ent, cosr, sinr, out_score);
}